// Round 1
// baseline (2839.472 us; speedup 1.0000x reference)
//
#include <hip/hip_runtime.h>
#include <math.h>

typedef unsigned short u16;

// ---------- helpers ----------
__device__ __forceinline__ float bf2f(u16 u) {
  unsigned x = ((unsigned)u) << 16;
  return __uint_as_float(x);
}
__device__ __forceinline__ u16 f2bf(float f) {
  unsigned x = __float_as_uint(f);
  unsigned r = x + 0x7FFFu + ((x >> 16) & 1u);
  return (u16)(r >> 16);
}

// ---------- ws layout (bytes) ----------
static const size_t OFF_MINV   = 0;                       // 64*64 f32
static const size_t OFF_CM     = 16ull * 1024;            // 64*64 f32
static const size_t OFF_AU     = 32ull * 1024;            // 64 f32
static const size_t OFF_BUE    = 32ull * 1024 + 256;
static const size_t OFF_AP     = 32ull * 1024 + 512;
static const size_t OFF_APBE   = 32ull * 1024 + 768;      // unused shift
static const size_t OFF_AM     = 36ull * 1024;            // 256 f32
static const size_t OFF_BM     = 37ull * 1024;
static const size_t OFF_AF     = 38ull * 1024;
static const size_t OFF_BF     = 39ull * 1024;
static const size_t OFF_BS     = 40ull * 1024;            // scan block sums
static const size_t OFF_PART1  = 1ull  * 1024 * 1024;     // up to 1MB
static const size_t OFF_PART2  = 2ull  * 1024 * 1024;
static const size_t OFF_ROWPTR = 3ull  * 1024 * 1024;     // (N+1) int
static const size_t OFF_COUNT  = 3ull  * 1024 * 1024 + 512 * 1024;
static const size_t OFF_CURSOR = 4ull  * 1024 * 1024;
static const size_t OFF_LOGITS = 5ull  * 1024 * 1024;     // E f32
static const size_t OFF_SRCJ   = 18ull * 1024 * 1024;     // E int
static const size_t OFF_DSTI   = 31ull * 1024 * 1024;     // E int
static const size_t OFF_U      = 44ull * 1024 * 1024;     // N*64 f32 (also h after solve)
static const size_t OFF_P      = 70ull * 1024 * 1024;     // N*64 f32
static const size_t OFF_AGG    = 96ull * 1024 * 1024;     // N*64 f32
static const size_t OFF_H2     = 122ull * 1024 * 1024;    // N*256 bf16

// ---------- K0: C = c^T c, Minv = (I+C)^-1, CM = C @ Minv  (one block) ----------
__global__ __launch_bounds__(256) void k_prep(const float* __restrict__ c,
                                              float* __restrict__ minv_out,
                                              float* __restrict__ cm_out) {
  __shared__ float sm[12288];            // CC: [0,4096)  aug: [4096,12288)  cl: [8192,12288) (dies when aug built)
  float* CC  = sm;
  float* aug = sm + 4096;
  float* cl  = sm + 8192;
  int t = threadIdx.x;
  for (int idx = t; idx < 4096; idx += 256) cl[idx] = c[idx];
  __syncthreads();
  for (int idx = t; idx < 4096; idx += 256) {
    int a = idx >> 6, b = idx & 63;
    float s = 0.f;
    for (int k = 0; k < 64; ++k) s += cl[k * 64 + a] * cl[k * 64 + b];
    CC[idx] = s;
  }
  __syncthreads();
  for (int idx = t; idx < 8192; idx += 256) {
    int r = idx >> 7, cc = idx & 127;
    float v;
    if (cc < 64) v = CC[r * 64 + cc] + (r == cc ? 1.f : 0.f);
    else         v = ((cc - 64) == r) ? 1.f : 0.f;
    aug[idx] = v;
  }
  __syncthreads();
  for (int p = 0; p < 64; ++p) {
    float inv = 1.0f / aug[p * 128 + p];
    __syncthreads();
    for (int cc = t; cc < 128; cc += 256) aug[p * 128 + cc] *= inv;
    __syncthreads();
    int r  = t >> 2;
    int c0 = (t & 3) * 32;
    float f = aug[r * 128 + p];
    __syncthreads();
    if (r != p) {
      for (int cc = c0; cc < c0 + 32; ++cc) aug[r * 128 + cc] -= f * aug[p * 128 + cc];
    }
    __syncthreads();
  }
  for (int idx = t; idx < 4096; idx += 256) {
    int r = idx >> 6, cc = idx & 63;
    minv_out[idx] = aug[r * 128 + 64 + cc];
  }
  __syncthreads();
  for (int idx = t; idx < 4096; idx += 256) {
    int a = idx >> 6, b = idx & 63;
    float s = 0.f;
    for (int k = 0; k < 64; ++k) s += CC[a * 64 + k] * aug[k * 128 + 64 + b];
    cm_out[idx] = s;
  }
}

// ---------- skinny GEMM: A[N,256] @ W[256,64] -> out[N,64] ----------
// block: 16 rows/tile; thread (c16 = t&15 -> 4 cols, rg = t>>4 -> 1 row)
__global__ __launch_bounds__(256) void k_gemm_h(const float* __restrict__ A,
                                                const float* __restrict__ W,
                                                float* __restrict__ out, int ntiles) {
  __shared__ float aT[16 * 260];
  int t = threadIdx.x;
  int c16 = t & 15, rg = t >> 4;
  for (int tile = blockIdx.x; tile < ntiles; tile += gridDim.x) {
    int row0 = tile * 16;
    __syncthreads();
    const float4* Af = (const float4*)(A + (size_t)row0 * 256);
    for (int idx = t; idx < 1024; idx += 256) {
      int r = idx >> 6, k4 = idx & 63;
      ((float4*)(aT + r * 260))[k4] = Af[idx];
    }
    __syncthreads();
    float4 acc = make_float4(0.f, 0.f, 0.f, 0.f);
    const float* ar = aT + rg * 260;
#pragma unroll 4
    for (int k = 0; k < 256; ++k) {
      float4 w4 = *(const float4*)(W + k * 64 + c16 * 4);
      float a = ar[k];
      acc.x += a * w4.x; acc.y += a * w4.y; acc.z += a * w4.z; acc.w += a * w4.w;
    }
    ((float4*)out)[(size_t)(row0 + rg) * 16 + c16] = acc;
  }
}

// ---------- column stats (sum, sumsq) ----------
__global__ __launch_bounds__(256) void k_colstats64(const float* __restrict__ M,
                                                    float* __restrict__ p1, float* __restrict__ p2,
                                                    int nrows) {
  __shared__ float r1[256], r2[256];
  int col = threadIdx.x & 63, rg = threadIdx.x >> 6;
  float s1 = 0.f, s2 = 0.f;
  for (int row = blockIdx.x * 4 + rg; row < nrows; row += gridDim.x * 4) {
    float v = M[(size_t)row * 64 + col];
    s1 += v; s2 += v * v;
  }
  r1[rg * 64 + col] = s1; r2[rg * 64 + col] = s2;
  __syncthreads();
  if (rg == 0) {
    p1[blockIdx.x * 64 + col] = r1[col] + r1[64 + col] + r1[128 + col] + r1[192 + col];
    p2[blockIdx.x * 64 + col] = r2[col] + r2[64 + col] + r2[128 + col] + r2[192 + col];
  }
}

__global__ __launch_bounds__(256) void k_colstats256_f32(const float* __restrict__ M,
                                                         float* __restrict__ p1, float* __restrict__ p2,
                                                         int nrows) {
  int t = threadIdx.x;
  float s1 = 0.f, s2 = 0.f;
  for (int row = blockIdx.x; row < nrows; row += gridDim.x) {
    float v = M[(size_t)row * 256 + t];
    s1 += v; s2 += v * v;
  }
  p1[blockIdx.x * 256 + t] = s1;
  p2[blockIdx.x * 256 + t] = s2;
}

__global__ __launch_bounds__(256) void k_colstats256_bf16(const u16* __restrict__ M,
                                                          float* __restrict__ p1, float* __restrict__ p2,
                                                          int nrows) {
  int t = threadIdx.x;
  float s1 = 0.f, s2 = 0.f;
  for (int row = blockIdx.x; row < nrows; row += gridDim.x) {
    float v = bf2f(M[(size_t)row * 256 + t]);
    s1 += v; s2 += v * v;
  }
  p1[blockIdx.x * 256 + t] = s1;
  p2[blockIdx.x * 256 + t] = s2;
}

// ---------- reduce partials -> BN scale/shift ----------
__global__ __launch_bounds__(256) void k_reduce_fin(const float* __restrict__ part1,
                                                    const float* __restrict__ part2,
                                                    int nb, int C, float invN,
                                                    const float* __restrict__ gamma,
                                                    const float* __restrict__ beta,
                                                    float* __restrict__ a_out,
                                                    float* __restrict__ b_out) {
  int c = blockIdx.x;
  int t = threadIdx.x;
  float s1 = 0.f, s2 = 0.f;
  for (int b = t; b < nb; b += 256) {
    s1 += part1[(size_t)b * C + c];
    s2 += part2[(size_t)b * C + c];
  }
  for (int m = 32; m; m >>= 1) { s1 += __shfl_xor(s1, m); s2 += __shfl_xor(s2, m); }
  __shared__ float l1[4], l2[4];
  if ((t & 63) == 0) { l1[t >> 6] = s1; l2[t >> 6] = s2; }
  __syncthreads();
  if (t == 0) {
    s1 = l1[0] + l1[1] + l1[2] + l1[3];
    s2 = l2[0] + l2[1] + l2[2] + l2[3];
    float mu  = s1 * invN;
    float var = s2 * invN - mu * mu;
    float a = gamma[c] * rsqrtf(var + 1e-5f);
    a_out[c] = a;
    b_out[c] = beta[c] - mu * a;
  }
}

// ---------- CSR build ----------
__global__ void k_count(const int* __restrict__ ei, int E, int* __restrict__ cnt) {
  for (int e = blockIdx.x * blockDim.x + threadIdx.x; e < E; e += gridDim.x * blockDim.x)
    atomicAdd(&cnt[ei[e]], 1);
}

__global__ __launch_bounds__(256) void k_scanA(const int* __restrict__ cnt, int N,
                                               int* __restrict__ rowptr, int* __restrict__ bs) {
  __shared__ int s[256];
  int t = threadIdx.x, gi = blockIdx.x * 256 + t;
  int v = (gi < N) ? cnt[gi] : 0;
  s[t] = v;
  __syncthreads();
  for (int off = 1; off < 256; off <<= 1) {
    int add = (t >= off) ? s[t - off] : 0;
    __syncthreads();
    s[t] += add;
    __syncthreads();
  }
  if (gi < N) rowptr[gi + 1] = s[t];
  if (t == 255) bs[blockIdx.x] = s[255];
}

__global__ __launch_bounds__(512) void k_scanB(int* __restrict__ bs, int nb) {
  __shared__ int s[512];
  int t = threadIdx.x;
  s[t] = (t < nb) ? bs[t] : 0;
  __syncthreads();
  for (int off = 1; off < 512; off <<= 1) {
    int add = (t >= off) ? s[t - off] : 0;
    __syncthreads();
    s[t] += add;
    __syncthreads();
  }
  if (t < nb) bs[t] = s[t];
}

__global__ __launch_bounds__(256) void k_scanC(int N, int* __restrict__ rowptr, const int* __restrict__ bs) {
  int gi = blockIdx.x * 256 + threadIdx.x;
  if (gi == 0) rowptr[0] = 0;
  if (gi < N && blockIdx.x > 0) rowptr[gi + 1] += bs[blockIdx.x - 1];
}

__global__ void k_fill(const int* __restrict__ ei, const int* __restrict__ ej, int E,
                       const int* __restrict__ rowptr, int* __restrict__ cursor,
                       int* __restrict__ srcj, int* __restrict__ dsti) {
  for (int e = blockIdx.x * blockDim.x + threadIdx.x; e < E; e += gridDim.x * blockDim.x) {
    int i = ei[e], j = ej[e];
    int pos = atomicAdd(&cursor[i], 1);
    int slot = rowptr[i] + pos;
    srcj[slot] = j;
    dsti[slot] = i;
  }
}

// ---------- edge logits: -|| ap*(P[i]-P[j]) ||^2 (16 lanes per edge slot) ----------
__global__ __launch_bounds__(256) void k_logit(const float* __restrict__ P, const float* __restrict__ ap,
                                               const int* __restrict__ dsti, const int* __restrict__ srcj,
                                               int E, float* __restrict__ logitS) {
  int lane16 = threadIdx.x & 15;
  int gid = (blockIdx.x * 256 + threadIdx.x) >> 4;
  int ngroups = (gridDim.x * 256) >> 4;
  float4 a4 = ((const float4*)ap)[lane16];
  const float4* P4 = (const float4*)P;
  for (int slot = gid; slot < E; slot += ngroups) {
    int i = dsti[slot], j = srcj[slot];
    float4 u = P4[(size_t)i * 16 + lane16];
    float4 v = P4[(size_t)j * 16 + lane16];
    float dx = a4.x * (u.x - v.x), dy = a4.y * (u.y - v.y);
    float dz = a4.z * (u.z - v.z), dw = a4.w * (u.w - v.w);
    float acc = dx * dx + dy * dy + dz * dz + dw * dw;
    acc += __shfl_xor(acc, 1, 16);
    acc += __shfl_xor(acc, 2, 16);
    acc += __shfl_xor(acc, 4, 16);
    acc += __shfl_xor(acc, 8, 16);
    if (lane16 == 0) logitS[slot] = -acc;
  }
}

// ---------- per-node softmax + aggregation (one wave per node) ----------
__global__ __launch_bounds__(256) void k_node(const float* __restrict__ logitS, const int* __restrict__ srcj,
                                              const int* __restrict__ rowptr, const float* __restrict__ U,
                                              const float* __restrict__ au, const float* __restrict__ bue,
                                              int N, float* __restrict__ agg) {
  int lane = threadIdx.x & 63;
  int node = blockIdx.x * 4 + (threadIdx.x >> 6);
  if (node >= N) return;
  float aul = au[lane], buel = bue[lane];
  int b0 = rowptr[node], b1 = rowptr[node + 1];
  float acc = 0.f;
  if (b1 > b0) {
    float mx = -INFINITY;
    for (int s = b0 + lane; s < b1; s += 64) mx = fmaxf(mx, logitS[s]);
    for (int m = 32; m; m >>= 1) mx = fmaxf(mx, __shfl_xor(mx, m));
    float sm = 0.f;
    for (int s = b0 + lane; s < b1; s += 64) sm += __expf(logitS[s] - mx);
    for (int m = 32; m; m >>= 1) sm += __shfl_xor(sm, m);
    float inv = 1.0f / (sm + 1e-16f);
    for (int s = b0; s < b1; ++s) {
      float w = __expf(logitS[s] - mx) * inv;
      int j = srcj[s];
      float val = aul * U[(size_t)j * 64 + lane] + buel;
      acc += w * val;
    }
  }
  agg[(size_t)node * 64 + lane] = acc;
}

// ---------- h = (z + agg@C) @ Minv = z@Minv + agg@CM  (in-place into U) ----------
__global__ __launch_bounds__(256) void k_solve(float* __restrict__ U, const float* __restrict__ agg,
                                               const float* __restrict__ minv, const float* __restrict__ cmw,
                                               const float* __restrict__ au, const float* __restrict__ bue,
                                               int ntiles) {
  __shared__ float mS[4096];
  __shared__ float cS[4096];
  int t = threadIdx.x;
  int c16 = t & 15, rg = t >> 4;
  for (int idx = t; idx < 1024; idx += 256) {
    ((float4*)mS)[idx] = ((const float4*)minv)[idx];
    ((float4*)cS)[idx] = ((const float4*)cmw)[idx];
  }
  __syncthreads();
  for (int tile = blockIdx.x; tile < ntiles; tile += gridDim.x) {
    int row = tile * 16 + rg;
    const float* ur = U + (size_t)row * 64;
    const float* gr = agg + (size_t)row * 64;
    float4 acc = make_float4(0.f, 0.f, 0.f, 0.f);
#pragma unroll 4
    for (int k = 0; k < 64; ++k) {
      float z = au[k] * ur[k] + bue[k];
      float g = gr[k];
      float4 m4 = ((const float4*)mS)[k * 16 + c16];
      float4 c4 = ((const float4*)cS)[k * 16 + c16];
      acc.x += z * m4.x + g * c4.x;
      acc.y += z * m4.y + g * c4.y;
      acc.z += z * m4.z + g * c4.z;
      acc.w += z * m4.w + g * c4.w;
    }
    ((float4*)U)[(size_t)row * 16 + c16] = acc;
  }
}

// ---------- h[N,64] @ Wm[64,256] -> h2 bf16[N,256] ----------
__global__ __launch_bounds__(256) void k_gemm_m(const float* __restrict__ h, const float* __restrict__ Wm,
                                                u16* __restrict__ h2, int ntiles) {
  __shared__ float wS[64 * 256];
  int t = threadIdx.x;
  int c4 = t & 63, rg = t >> 6;
  for (int idx = t; idx < 4096; idx += 256) ((float4*)wS)[idx] = ((const float4*)Wm)[idx];
  __syncthreads();
  for (int tile = blockIdx.x; tile < ntiles; tile += gridDim.x) {
    int row0 = tile * 16 + rg * 4;
    float4 acc[4];
#pragma unroll
    for (int r = 0; r < 4; ++r) acc[r] = make_float4(0.f, 0.f, 0.f, 0.f);
    const float* h0 = h + (size_t)row0 * 64;
#pragma unroll 2
    for (int k = 0; k < 64; ++k) {
      float4 w4 = ((const float4*)wS)[k * 64 + c4];
#pragma unroll
      for (int r = 0; r < 4; ++r) {
        float hv = h0[r * 64 + k];
        acc[r].x += hv * w4.x; acc[r].y += hv * w4.y;
        acc[r].z += hv * w4.z; acc[r].w += hv * w4.w;
      }
    }
#pragma unroll
    for (int r = 0; r < 4; ++r) {
      ushort4 o = make_ushort4(f2bf(acc[r].x), f2bf(acc[r].y), f2bf(acc[r].z), f2bf(acc[r].w));
      ((ushort4*)h2)[(size_t)(row0 + r) * 64 + c4] = o;
    }
  }
}

// ---------- out_raw = [leaky(am*h2+bm), y] @ Wf[512,256] ----------
// tile: 20 rows; thread (c4 = t&63 -> 4 cols, rg = t>>6 -> 5 rows)
__global__ __launch_bounds__(256) void k_gemm_f(const u16* __restrict__ h2, const float* __restrict__ y,
                                                const float* __restrict__ Wf, const float* __restrict__ am,
                                                const float* __restrict__ bm, float* __restrict__ outraw,
                                                int ntiles) {
  __shared__ float aS[20 * 512];
  __shared__ float wS[2048];
  int t = threadIdx.x;
  int c4 = t & 63, rg = t >> 6;
  for (int tile = blockIdx.x; tile < ntiles; tile += gridDim.x) {
    int row0 = tile * 20;
    __syncthreads();
    for (int idx = t; idx < 5120; idx += 256) {
      int r = idx >> 8, k = idx & 255;
      float v = bf2f(h2[(size_t)(row0 + r) * 256 + k]);
      v = am[k] * v + bm[k];
      aS[r * 512 + k] = (v > 0.f) ? v : 0.01f * v;
    }
    for (int idx = t; idx < 5120; idx += 256) {
      int r = idx >> 8, k = idx & 255;
      aS[r * 512 + 256 + k] = y[(size_t)(row0 + r) * 256 + k];
    }
    __syncthreads();
    float4 acc[5];
#pragma unroll
    for (int r = 0; r < 5; ++r) acc[r] = make_float4(0.f, 0.f, 0.f, 0.f);
    for (int kt = 0; kt < 64; ++kt) {
      __syncthreads();
      for (int idx = t; idx < 2048; idx += 256) wS[idx] = Wf[kt * 2048 + idx];
      __syncthreads();
#pragma unroll
      for (int kk = 0; kk < 8; ++kk) {
        float4 w4 = ((const float4*)wS)[kk * 64 + c4];
        int k = kt * 8 + kk;
#pragma unroll
        for (int r = 0; r < 5; ++r) {
          float a = aS[(rg * 5 + r) * 512 + k];
          acc[r].x += a * w4.x; acc[r].y += a * w4.y;
          acc[r].z += a * w4.z; acc[r].w += a * w4.w;
        }
      }
    }
#pragma unroll
    for (int r = 0; r < 5; ++r)
      ((float4*)outraw)[(size_t)(row0 + rg * 5 + r) * 64 + c4] = acc[r];
  }
}

// ---------- final BN + leaky in place on d_out ----------
__global__ __launch_bounds__(256) void k_bnact(float* __restrict__ out, const float* __restrict__ af,
                                               const float* __restrict__ bf, int n4) {
  int i = blockIdx.x * 256 + threadIdx.x;
  int stride = gridDim.x * 256;
  float4* o4 = (float4*)out;
  const float4* a4p = (const float4*)af;
  const float4* b4p = (const float4*)bf;
  for (; i < n4; i += stride) {
    int c = i & 63;
    float4 a = a4p[c], b = b4p[c];
    float4 v = o4[i];
    v.x = a.x * v.x + b.x; v.x = (v.x > 0.f) ? v.x : 0.01f * v.x;
    v.y = a.y * v.y + b.y; v.y = (v.y > 0.f) ? v.y : 0.01f * v.y;
    v.z = a.z * v.z + b.z; v.z = (v.z > 0.f) ? v.z : 0.01f * v.z;
    v.w = a.w * v.w + b.w; v.w = (v.w > 0.f) ? v.w : 0.01f * v.w;
    o4[i] = v;
  }
}

extern "C" void kernel_launch(void* const* d_in, const int* in_sizes, int n_in,
                              void* d_out, int out_size, void* d_ws, size_t ws_size,
                              hipStream_t stream) {
  const float* x    = (const float*)d_in[0];
  const float* y    = (const float*)d_in[1];
  const int*   eidx = (const int*)d_in[3];
  const float* Wu   = (const float*)d_in[4];
  const float* gu   = (const float*)d_in[5];
  const float* bu   = (const float*)d_in[6];
  const float* Wp   = (const float*)d_in[7];
  const float* gp   = (const float*)d_in[8];
  const float* bp   = (const float*)d_in[9];
  const float* cIn  = (const float*)d_in[10];
  const float* Wm   = (const float*)d_in[11];
  const float* gm   = (const float*)d_in[12];
  const float* bm   = (const float*)d_in[13];
  const float* Wf   = (const float*)d_in[14];
  const float* gf   = (const float*)d_in[15];
  const float* bfv  = (const float*)d_in[16];

  const int N = in_sizes[0] / 256;
  const int E = in_sizes[3] / 2;
  const int* ei = eidx;
  const int* ej = eidx + E;

  char* ws = (char*)d_ws;
  float* MINV  = (float*)(ws + OFF_MINV);
  float* CMW   = (float*)(ws + OFF_CM);
  float* AU    = (float*)(ws + OFF_AU);
  float* BUE   = (float*)(ws + OFF_BUE);
  float* AP    = (float*)(ws + OFF_AP);
  float* APBE  = (float*)(ws + OFF_APBE);
  float* AM    = (float*)(ws + OFF_AM);
  float* BM    = (float*)(ws + OFF_BM);
  float* AF    = (float*)(ws + OFF_AF);
  float* BF    = (float*)(ws + OFF_BF);
  int*   BSC   = (int*)(ws + OFF_BS);
  float* PART1 = (float*)(ws + OFF_PART1);
  float* PART2 = (float*)(ws + OFF_PART2);
  int*   ROWPTR= (int*)(ws + OFF_ROWPTR);
  int*   COUNT = (int*)(ws + OFF_COUNT);
  int*   CURSOR= (int*)(ws + OFF_CURSOR);
  float* LOGITS= (float*)(ws + OFF_LOGITS);
  int*   SRCJ  = (int*)(ws + OFF_SRCJ);
  int*   DSTI  = (int*)(ws + OFF_DSTI);
  float* U     = (float*)(ws + OFF_U);
  float* P     = (float*)(ws + OFF_P);
  float* AGG   = (float*)(ws + OFF_AGG);
  u16*   H2    = (u16*)(ws + OFF_H2);

  const float invN = 1.0f / (float)N;
  const int ntiles16 = N / 16;   // 6250
  const int ntiles20 = N / 20;   // 5000
  const int nbScan   = (N + 255) / 256;

  hipMemsetAsync(COUNT, 0, (size_t)N * 4, stream);
  hipMemsetAsync(CURSOR, 0, (size_t)N * 4, stream);

  k_prep<<<1, 256, 0, stream>>>(cIn, MINV, CMW);

  // unary / pairwise embeddings + BN params
  k_gemm_h<<<1024, 256, 0, stream>>>(x, Wu, U, ntiles16);
  k_colstats64<<<1024, 256, 0, stream>>>(U, PART1, PART2, N);
  k_reduce_fin<<<64, 256, 0, stream>>>(PART1, PART2, 1024, 64, invN, gu, bu, AU, BUE);

  k_gemm_h<<<1024, 256, 0, stream>>>(y, Wp, P, ntiles16);
  k_colstats64<<<1024, 256, 0, stream>>>(P, PART1, PART2, N);
  k_reduce_fin<<<64, 256, 0, stream>>>(PART1, PART2, 1024, 64, invN, gp, bp, AP, APBE);

  // CSR build (group edges by destination i)
  k_count<<<2048, 256, 0, stream>>>(ei, E, COUNT);
  k_scanA<<<nbScan, 256, 0, stream>>>(COUNT, N, ROWPTR, BSC);
  k_scanB<<<1, 512, 0, stream>>>(BSC, nbScan);
  k_scanC<<<nbScan, 256, 0, stream>>>(N, ROWPTR, BSC);
  k_fill<<<2048, 256, 0, stream>>>(ei, ej, E, ROWPTR, CURSOR, SRCJ, DSTI);

  // edge logits, per-node softmax + aggregation
  k_logit<<<4096, 256, 0, stream>>>(P, AP, DSTI, SRCJ, E, LOGITS);
  k_node<<<(N + 3) / 4, 256, 0, stream>>>(LOGITS, SRCJ, ROWPTR, U, AU, BUE, N, AGG);

  // CRF linear solve (in place into U)
  k_solve<<<2048, 256, 0, stream>>>(U, AGG, MINV, CMW, AU, BUE, ntiles16);

  // h @ Wm -> h2 (bf16) + BN params
  k_gemm_m<<<1024, 256, 0, stream>>>(U, Wm, H2, ntiles16);
  k_colstats256_bf16<<<1024, 256, 0, stream>>>(H2, PART1, PART2, N);
  k_reduce_fin<<<256, 256, 0, stream>>>(PART1, PART2, 1024, 256, invN, gm, bm, AM, BM);

  // cat([leaky(bn(h2)), y]) @ Wf -> raw into d_out, then BN + leaky in place
  k_gemm_f<<<1024, 256, 0, stream>>>(H2, y, Wf, AM, BM, (float*)d_out, ntiles20);
  k_colstats256_f32<<<1024, 256, 0, stream>>>((float*)d_out, PART1, PART2, N);
  k_reduce_fin<<<256, 256, 0, stream>>>(PART1, PART2, 1024, 256, invN, gf, bfv, AF, BF);
  k_bnact<<<2048, 256, 0, stream>>>((float*)d_out, AF, BF, N * 64);
}

// Round 2
// 1494.344 us; speedup vs baseline: 1.9001x; 1.9001x over previous
//
#include <hip/hip_runtime.h>
#include <math.h>

typedef unsigned short u16;
typedef short s16x8 __attribute__((ext_vector_type(8)));
typedef unsigned short u16x8 __attribute__((ext_vector_type(8)));
typedef float f32x4 __attribute__((ext_vector_type(4)));

// ---------- helpers ----------
__device__ __forceinline__ float bf2f(u16 u) {
  unsigned x = ((unsigned)u) << 16;
  return __uint_as_float(x);
}
__device__ __forceinline__ u16 f2bf(float f) {
  unsigned x = __float_as_uint(f);
  unsigned r = x + 0x7FFFu + ((x >> 16) & 1u);
  return (u16)(r >> 16);
}

// ---------- ws layout (bytes) ----------
static const size_t OFF_MINV   = 0;                       // 64*64 f32
static const size_t OFF_CM     = 16ull * 1024;            // 64*64 f32
static const size_t OFF_AU     = 32ull * 1024;            // 64 f32
static const size_t OFF_BUE    = 32ull * 1024 + 256;
static const size_t OFF_AP     = 32ull * 1024 + 512;
static const size_t OFF_APBE   = 32ull * 1024 + 768;
static const size_t OFF_AM     = 36ull * 1024;            // 256 f32
static const size_t OFF_BM     = 37ull * 1024;
static const size_t OFF_AF     = 38ull * 1024;
static const size_t OFF_BF     = 39ull * 1024;
static const size_t OFF_BS     = 40ull * 1024;            // scan block sums (~1.6KB)
static const size_t OFF_WUT    = 64ull * 1024;            // 64*256 bf16 = 32KB
static const size_t OFF_WMT    = 128ull * 1024;           // 256*64 bf16 = 32KB
static const size_t OFF_WFT    = 192ull * 1024;           // 256*512 bf16 = 256KB
static const size_t OFF_PART1  = 1ull  * 1024 * 1024;
static const size_t OFF_PART2  = 2ull  * 1024 * 1024;
static const size_t OFF_ROWPTR = 3ull  * 1024 * 1024;     // (N+1) int
static const size_t OFF_COUNT  = 3ull  * 1024 * 1024 + 512 * 1024;
static const size_t OFF_CURSOR = 4ull  * 1024 * 1024;
static const size_t OFF_LOGITS = 5ull  * 1024 * 1024;     // E f32 (dead after k_node; reused as UB bf16 N*64)
static const size_t OFF_SRCJ   = 18ull * 1024 * 1024;     // E int
static const size_t OFF_DSTI   = 31ull * 1024 * 1024;     // E int
static const size_t OFF_U      = 44ull * 1024 * 1024;     // N*64 f32 (raw xu)
static const size_t OFF_P      = 70ull * 1024 * 1024;     // N*64 f32
static const size_t OFF_AGG    = 96ull * 1024 * 1024;     // N*64 f32
static const size_t OFF_H2     = 122ull * 1024 * 1024;    // N*256 bf16 (early: reused as XB bf16 N*256)

// ---------- K0: C = c^T c, Minv = (I+C)^-1, CM = C @ Minv  (one block) ----------
__global__ __launch_bounds__(256) void k_prep(const float* __restrict__ c,
                                              float* __restrict__ minv_out,
                                              float* __restrict__ cm_out) {
  __shared__ float sm[12288];
  float* CC  = sm;
  float* aug = sm + 4096;
  float* cl  = sm + 8192;
  int t = threadIdx.x;
  for (int idx = t; idx < 4096; idx += 256) cl[idx] = c[idx];
  __syncthreads();
  for (int idx = t; idx < 4096; idx += 256) {
    int a = idx >> 6, b = idx & 63;
    float s = 0.f;
    for (int k = 0; k < 64; ++k) s += cl[k * 64 + a] * cl[k * 64 + b];
    CC[idx] = s;
  }
  __syncthreads();
  for (int idx = t; idx < 8192; idx += 256) {
    int r = idx >> 7, cc = idx & 127;
    float v;
    if (cc < 64) v = CC[r * 64 + cc] + (r == cc ? 1.f : 0.f);
    else         v = ((cc - 64) == r) ? 1.f : 0.f;
    aug[idx] = v;
  }
  __syncthreads();
  for (int p = 0; p < 64; ++p) {
    float inv = 1.0f / aug[p * 128 + p];
    __syncthreads();
    for (int cc = t; cc < 128; cc += 256) aug[p * 128 + cc] *= inv;
    __syncthreads();
    int r  = t >> 2;
    int c0 = (t & 3) * 32;
    float f = aug[r * 128 + p];
    __syncthreads();
    if (r != p) {
      for (int cc = c0; cc < c0 + 32; ++cc) aug[r * 128 + cc] -= f * aug[p * 128 + cc];
    }
    __syncthreads();
  }
  for (int idx = t; idx < 4096; idx += 256) {
    int r = idx >> 6, cc = idx & 63;
    minv_out[idx] = aug[r * 128 + 64 + cc];
  }
  __syncthreads();
  for (int idx = t; idx < 4096; idx += 256) {
    int a = idx >> 6, b = idx & 63;
    float s = 0.f;
    for (int k = 0; k < 64; ++k) s += CC[a * 64 + k] * aug[k * 128 + 64 + b];
    cm_out[idx] = s;
  }
}

// ---------- transpose + convert weights: in f32 [Kd][Nc] -> out bf16 [Nc][Kd] ----------
__global__ __launch_bounds__(256) void k_tcvt(const float* __restrict__ in, u16* __restrict__ outb,
                                              int Kd, int Nc) {
  int i = blockIdx.x * 256 + threadIdx.x;
  if (i < Kd * Nc) {
    int k = i / Nc, n = i - k * Nc;
    outb[(size_t)n * Kd + k] = f2bf(in[i]);
  }
}

// ---------- f32 -> bf16, 8 elems/thread ----------
__global__ __launch_bounds__(256) void k_f2b8(const float* __restrict__ in, u16* __restrict__ outb, int n8) {
  for (int i = blockIdx.x * 256 + threadIdx.x; i < n8; i += gridDim.x * 256) {
    float4 a = ((const float4*)in)[i * 2];
    float4 b = ((const float4*)in)[i * 2 + 1];
    u16x8 o;
    o[0] = f2bf(a.x); o[1] = f2bf(a.y); o[2] = f2bf(a.z); o[3] = f2bf(a.w);
    o[4] = f2bf(b.x); o[5] = f2bf(b.y); o[6] = f2bf(b.z); o[7] = f2bf(b.w);
    ((u16x8*)outb)[i] = o;
  }
}

// ---------- MFMA GEMM: C[M,Ncols] = A[M,K] @ Bt[Ncols,K]^T (bf16 in, f32 acc) ----------
// BM=128, BK=64, 4 waves (2x2), wave tile 64 x BN/2.
// AMODE 0: A from Abf [M][ldA] bf16.
// AMODE 1: A fused: k<256 -> leaky(am*h2+bm) from h2 bf16 [M][256]; k>=256 -> y f32 [M][256].
// OBF 0: C f32; OBF 1: C bf16.
template<int BN, int AMODE, int OBF>
__global__ __launch_bounds__(256) void k_mfma(const u16* __restrict__ Abf, int ldA, int K, int M,
                                              const u16* __restrict__ h2, const float* __restrict__ yy,
                                              const float* __restrict__ am, const float* __restrict__ bm,
                                              const u16* __restrict__ Bt,
                                              float* __restrict__ Cf, u16* __restrict__ Cb, int ldC) {
  constexpr int WN  = BN / 2;
  constexpr int FN  = WN / 16;
  constexpr int NPB = BN / 32;            // B staging passes (BN*8 chunk-slots / 256 threads)
  __shared__ u16 lds[2][(128 + BN) * 64];

  int t = threadIdx.x;
  int wid = t >> 6, lane = t & 63;
  int wr = wid >> 1, wc = wid & 1;
  int lr = lane & 15, lk = lane >> 4;
  int m0 = blockIdx.x * 128;
  int n0 = blockIdx.y * BN;
  int nK = K >> 6;

  int sidx = t;                           // staging: r = idx>>3 (row), c8 = idx&7 (16B chunk)
  u16x8 ra[4];
  u16x8 rb[NPB];

  f32x4 acc[4][FN];
#pragma unroll
  for (int m = 0; m < 4; ++m)
#pragma unroll
    for (int n = 0; n < FN; ++n) acc[m][n] = (f32x4){0.f, 0.f, 0.f, 0.f};

  // ---- staging loads (global -> regs) ----
  auto loadTile = [&](int kk) {
    int kk0 = kk * 64;
#pragma unroll
    for (int p = 0; p < 4; ++p) {
      int idx = p * 256 + sidx;
      int r = idx >> 3, c8 = idx & 7;
      int row = m0 + r; if (row >= M) row = M - 1;
      int k = kk0 + c8 * 8;
      if constexpr (AMODE == 0) {
        ra[p] = *(const u16x8*)(Abf + (size_t)row * ldA + k);
      } else {
        if (kk0 < 256) {
          u16x8 h8 = *(const u16x8*)(h2 + (size_t)row * 256 + k);
          float av[8], bv[8];
          *(float4*)(av)     = *(const float4*)(am + k);
          *(float4*)(av + 4) = *(const float4*)(am + k + 4);
          *(float4*)(bv)     = *(const float4*)(bm + k);
          *(float4*)(bv + 4) = *(const float4*)(bm + k + 4);
          u16x8 o;
#pragma unroll
          for (int j = 0; j < 8; ++j) {
            float v = bf2f((u16)h8[j]) * av[j] + bv[j];
            v = v > 0.f ? v : 0.01f * v;
            o[j] = f2bf(v);
          }
          ra[p] = o;
        } else {
          float yv[8];
          *(float4*)(yv)     = *(const float4*)(yy + (size_t)row * 256 + (k - 256));
          *(float4*)(yv + 4) = *(const float4*)(yy + (size_t)row * 256 + (k - 256) + 4);
          u16x8 o;
#pragma unroll
          for (int j = 0; j < 8; ++j) o[j] = f2bf(yv[j]);
          ra[p] = o;
        }
      }
    }
#pragma unroll
    for (int p = 0; p < NPB; ++p) {
      int idx = p * 256 + sidx;
      int r = idx >> 3, c8 = idx & 7;
      rb[p] = *(const u16x8*)(Bt + (size_t)(n0 + r) * K + kk0 + c8 * 8);
    }
  };

  // ---- regs -> LDS (XOR-swizzled: byte ^= (row&7)<<4 within 128B rows) ----
  auto dswrite = [&](int b) {
    char* As  = (char*)&lds[b][0];
    char* Bsc = As + 128 * 64 * 2;
#pragma unroll
    for (int p = 0; p < 4; ++p) {
      int idx = p * 256 + sidx;
      int r = idx >> 3, c8 = idx & 7;
      *(u16x8*)(As + r * 128 + ((c8 * 16) ^ ((r & 7) << 4))) = ra[p];
    }
#pragma unroll
    for (int p = 0; p < NPB; ++p) {
      int idx = p * 256 + sidx;
      int r = idx >> 3, c8 = idx & 7;
      *(u16x8*)(Bsc + r * 128 + ((c8 * 16) ^ ((r & 7) << 4))) = rb[p];
    }
  };

  auto compute = [&](int b) {
    const char* As  = (const char*)&lds[b][0];
    const char* Bsc = As + 128 * 64 * 2;
#pragma unroll
    for (int ks = 0; ks < 2; ++ks) {
      int kb = ks * 64 + lk * 16;
      s16x8 af[4], bfr[FN];
#pragma unroll
      for (int m = 0; m < 4; ++m) {
        int row = wr * 64 + m * 16 + lr;
        af[m] = *(const s16x8*)(As + row * 128 + (kb ^ ((row & 7) << 4)));
      }
#pragma unroll
      for (int n = 0; n < FN; ++n) {
        int row = wc * WN + n * 16 + lr;
        bfr[n] = *(const s16x8*)(Bsc + row * 128 + (kb ^ ((row & 7) << 4)));
      }
#pragma unroll
      for (int m = 0; m < 4; ++m)
#pragma unroll
        for (int n = 0; n < FN; ++n)
          acc[m][n] = __builtin_amdgcn_mfma_f32_16x16x32_bf16(af[m], bfr[n], acc[m][n], 0, 0, 0);
    }
  };

  // ---- pipelined K loop ----
  loadTile(0);
  dswrite(0);
  __syncthreads();
  for (int kk = 0; kk < nK; ++kk) {
    int b = kk & 1;
    if (kk + 1 < nK) loadTile(kk + 1);   // issue next-tile loads before compute (latency hides)
    compute(b);
    if (kk + 1 < nK) { dswrite(b ^ 1); __syncthreads(); }
  }

  // ---- C write: row=(lane>>4)*4+q, col=lane&15 per 16x16 fragment ----
#pragma unroll
  for (int m = 0; m < 4; ++m) {
#pragma unroll
    for (int n = 0; n < FN; ++n) {
      int col = n0 + wc * WN + n * 16 + lr;
#pragma unroll
      for (int q = 0; q < 4; ++q) {
        int row = m0 + wr * 64 + m * 16 + lk * 4 + q;
        if (row < M) {
          if constexpr (OBF) Cb[(size_t)row * ldC + col] = f2bf(acc[m][n][q]);
          else               Cf[(size_t)row * ldC + col] = acc[m][n][q];
        }
      }
    }
  }
}

// ---------- skinny f32 GEMM (kept for su path, accuracy-critical) ----------
__global__ __launch_bounds__(256) void k_gemm_h(const float* __restrict__ A,
                                                const float* __restrict__ W,
                                                float* __restrict__ out, int ntiles) {
  __shared__ float aT[16 * 260];
  int t = threadIdx.x;
  int c16 = t & 15, rg = t >> 4;
  for (int tile = blockIdx.x; tile < ntiles; tile += gridDim.x) {
    int row0 = tile * 16;
    __syncthreads();
    const float4* Af = (const float4*)(A + (size_t)row0 * 256);
    for (int idx = t; idx < 1024; idx += 256) {
      int r = idx >> 6, k4 = idx & 63;
      ((float4*)(aT + r * 260))[k4] = Af[idx];
    }
    __syncthreads();
    float4 acc = make_float4(0.f, 0.f, 0.f, 0.f);
    const float* ar = aT + rg * 260;
#pragma unroll 4
    for (int k = 0; k < 256; ++k) {
      float4 w4 = *(const float4*)(W + k * 64 + c16 * 4);
      float a = ar[k];
      acc.x += a * w4.x; acc.y += a * w4.y; acc.z += a * w4.z; acc.w += a * w4.w;
    }
    ((float4*)out)[(size_t)(row0 + rg) * 16 + c16] = acc;
  }
}

// ---------- column stats ----------
__global__ __launch_bounds__(256) void k_colstats64(const float* __restrict__ M,
                                                    float* __restrict__ p1, float* __restrict__ p2,
                                                    int nrows) {
  __shared__ float r1[256], r2[256];
  int col = threadIdx.x & 63, rg = threadIdx.x >> 6;
  float s1 = 0.f, s2 = 0.f;
  for (int row = blockIdx.x * 4 + rg; row < nrows; row += gridDim.x * 4) {
    float v = M[(size_t)row * 64 + col];
    s1 += v; s2 += v * v;
  }
  r1[rg * 64 + col] = s1; r2[rg * 64 + col] = s2;
  __syncthreads();
  if (rg == 0) {
    p1[blockIdx.x * 64 + col] = r1[col] + r1[64 + col] + r1[128 + col] + r1[192 + col];
    p2[blockIdx.x * 64 + col] = r2[col] + r2[64 + col] + r2[128 + col] + r2[192 + col];
  }
}

__global__ __launch_bounds__(256) void k_colstats256_f32(const float* __restrict__ M,
                                                         float* __restrict__ p1, float* __restrict__ p2,
                                                         int nrows) {
  int t = threadIdx.x;
  float s1 = 0.f, s2 = 0.f;
  for (int row = blockIdx.x; row < nrows; row += gridDim.x) {
    float v = M[(size_t)row * 256 + t];
    s1 += v; s2 += v * v;
  }
  p1[blockIdx.x * 256 + t] = s1;
  p2[blockIdx.x * 256 + t] = s2;
}

__global__ __launch_bounds__(256) void k_colstats256_bf16(const u16* __restrict__ M,
                                                          float* __restrict__ p1, float* __restrict__ p2,
                                                          int nrows) {
  int t = threadIdx.x;
  float s1 = 0.f, s2 = 0.f;
  for (int row = blockIdx.x; row < nrows; row += gridDim.x) {
    float v = bf2f(M[(size_t)row * 256 + t]);
    s1 += v; s2 += v * v;
  }
  p1[blockIdx.x * 256 + t] = s1;
  p2[blockIdx.x * 256 + t] = s2;
}

// ---------- reduce partials -> BN scale/shift ----------
__global__ __launch_bounds__(256) void k_reduce_fin(const float* __restrict__ part1,
                                                    const float* __restrict__ part2,
                                                    int nb, int C, float invN,
                                                    const float* __restrict__ gamma,
                                                    const float* __restrict__ beta,
                                                    float* __restrict__ a_out,
                                                    float* __restrict__ b_out) {
  int c = blockIdx.x;
  int t = threadIdx.x;
  float s1 = 0.f, s2 = 0.f;
  for (int b = t; b < nb; b += 256) {
    s1 += part1[(size_t)b * C + c];
    s2 += part2[(size_t)b * C + c];
  }
  for (int m = 32; m; m >>= 1) { s1 += __shfl_xor(s1, m); s2 += __shfl_xor(s2, m); }
  __shared__ float l1[4], l2[4];
  if ((t & 63) == 0) { l1[t >> 6] = s1; l2[t >> 6] = s2; }
  __syncthreads();
  if (t == 0) {
    s1 = l1[0] + l1[1] + l1[2] + l1[3];
    s2 = l2[0] + l2[1] + l2[2] + l2[3];
    float mu  = s1 * invN;
    float var = s2 * invN - mu * mu;
    float a = gamma[c] * rsqrtf(var + 1e-5f);
    a_out[c] = a;
    b_out[c] = beta[c] - mu * a;
  }
}

// ---------- CSR build ----------
__global__ void k_count(const int* __restrict__ ei, int E, int* __restrict__ cnt) {
  for (int e = blockIdx.x * blockDim.x + threadIdx.x; e < E; e += gridDim.x * blockDim.x)
    atomicAdd(&cnt[ei[e]], 1);
}

__global__ __launch_bounds__(256) void k_scanA(const int* __restrict__ cnt, int N,
                                               int* __restrict__ rowptr, int* __restrict__ bs) {
  __shared__ int s[256];
  int t = threadIdx.x, gi = blockIdx.x * 256 + t;
  int v = (gi < N) ? cnt[gi] : 0;
  s[t] = v;
  __syncthreads();
  for (int off = 1; off < 256; off <<= 1) {
    int add = (t >= off) ? s[t - off] : 0;
    __syncthreads();
    s[t] += add;
    __syncthreads();
  }
  if (gi < N) rowptr[gi + 1] = s[t];
  if (t == 255) bs[blockIdx.x] = s[255];
}

__global__ __launch_bounds__(512) void k_scanB(int* __restrict__ bs, int nb) {
  __shared__ int s[512];
  int t = threadIdx.x;
  s[t] = (t < nb) ? bs[t] : 0;
  __syncthreads();
  for (int off = 1; off < 512; off <<= 1) {
    int add = (t >= off) ? s[t - off] : 0;
    __syncthreads();
    s[t] += add;
    __syncthreads();
  }
  if (t < nb) bs[t] = s[t];
}

__global__ __launch_bounds__(256) void k_scanC(int N, int* __restrict__ rowptr, const int* __restrict__ bs) {
  int gi = blockIdx.x * 256 + threadIdx.x;
  if (gi == 0) rowptr[0] = 0;
  if (gi < N && blockIdx.x > 0) rowptr[gi + 1] += bs[blockIdx.x - 1];
}

__global__ void k_fill(const int* __restrict__ ei, const int* __restrict__ ej, int E,
                       const int* __restrict__ rowptr, int* __restrict__ cursor,
                       int* __restrict__ srcj, int* __restrict__ dsti) {
  for (int e = blockIdx.x * blockDim.x + threadIdx.x; e < E; e += gridDim.x * blockDim.x) {
    int i = ei[e], j = ej[e];
    int pos = atomicAdd(&cursor[i], 1);
    int slot = rowptr[i] + pos;
    srcj[slot] = j;
    dsti[slot] = i;
  }
}

// ---------- edge logits ----------
__global__ __launch_bounds__(256) void k_logit(const float* __restrict__ P, const float* __restrict__ ap,
                                               const int* __restrict__ dsti, const int* __restrict__ srcj,
                                               int E, float* __restrict__ logitS) {
  int lane16 = threadIdx.x & 15;
  int gid = (blockIdx.x * 256 + threadIdx.x) >> 4;
  int ngroups = (gridDim.x * 256) >> 4;
  float4 a4 = ((const float4*)ap)[lane16];
  const float4* P4 = (const float4*)P;
  for (int slot = gid; slot < E; slot += ngroups) {
    int i = dsti[slot], j = srcj[slot];
    float4 u = P4[(size_t)i * 16 + lane16];
    float4 v = P4[(size_t)j * 16 + lane16];
    float dx = a4.x * (u.x - v.x), dy = a4.y * (u.y - v.y);
    float dz = a4.z * (u.z - v.z), dw = a4.w * (u.w - v.w);
    float acc = dx * dx + dy * dy + dz * dz + dw * dw;
    acc += __shfl_xor(acc, 1, 16);
    acc += __shfl_xor(acc, 2, 16);
    acc += __shfl_xor(acc, 4, 16);
    acc += __shfl_xor(acc, 8, 16);
    if (lane16 == 0) logitS[slot] = -acc;
  }
}

// ---------- per-node softmax + aggregation ----------
__global__ __launch_bounds__(256) void k_node(const float* __restrict__ logitS, const int* __restrict__ srcj,
                                              const int* __restrict__ rowptr, const float* __restrict__ U,
                                              const float* __restrict__ au, const float* __restrict__ bue,
                                              int N, float* __restrict__ agg) {
  int lane = threadIdx.x & 63;
  int node = blockIdx.x * 4 + (threadIdx.x >> 6);
  if (node >= N) return;
  float aul = au[lane], buel = bue[lane];
  int b0 = rowptr[node], b1 = rowptr[node + 1];
  float acc = 0.f;
  if (b1 > b0) {
    float mx = -INFINITY;
    for (int s = b0 + lane; s < b1; s += 64) mx = fmaxf(mx, logitS[s]);
    for (int m = 32; m; m >>= 1) mx = fmaxf(mx, __shfl_xor(mx, m));
    float sm = 0.f;
    for (int s = b0 + lane; s < b1; s += 64) sm += __expf(logitS[s] - mx);
    for (int m = 32; m; m >>= 1) sm += __shfl_xor(sm, m);
    float inv = 1.0f / (sm + 1e-16f);
    for (int s = b0; s < b1; ++s) {
      float w = __expf(logitS[s] - mx) * inv;
      int j = srcj[s];
      float val = aul * U[(size_t)j * 64 + lane] + buel;
      acc += w * val;
    }
  }
  agg[(size_t)node * 64 + lane] = acc;
}

// ---------- h = (z + agg@C) @ Minv, output bf16 ----------
__global__ __launch_bounds__(256) void k_solve(const float* __restrict__ U, const float* __restrict__ agg,
                                               const float* __restrict__ minv, const float* __restrict__ cmw,
                                               const float* __restrict__ au, const float* __restrict__ bue,
                                               u16* __restrict__ UB, int ntiles) {
  __shared__ float mS[4096];
  __shared__ float cS[4096];
  int t = threadIdx.x;
  int c16 = t & 15, rg = t >> 4;
  for (int idx = t; idx < 1024; idx += 256) {
    ((float4*)mS)[idx] = ((const float4*)minv)[idx];
    ((float4*)cS)[idx] = ((const float4*)cmw)[idx];
  }
  __syncthreads();
  for (int tile = blockIdx.x; tile < ntiles; tile += gridDim.x) {
    int row = tile * 16 + rg;
    const float* ur = U + (size_t)row * 64;
    const float* gr = agg + (size_t)row * 64;
    float4 acc = make_float4(0.f, 0.f, 0.f, 0.f);
#pragma unroll 4
    for (int k = 0; k < 64; ++k) {
      float z = au[k] * ur[k] + bue[k];
      float g = gr[k];
      float4 m4 = ((const float4*)mS)[k * 16 + c16];
      float4 c4 = ((const float4*)cS)[k * 16 + c16];
      acc.x += z * m4.x + g * c4.x;
      acc.y += z * m4.y + g * c4.y;
      acc.z += z * m4.z + g * c4.z;
      acc.w += z * m4.w + g * c4.w;
    }
    ((ushort4*)UB)[(size_t)row * 16 + c16] =
        make_ushort4(f2bf(acc.x), f2bf(acc.y), f2bf(acc.z), f2bf(acc.w));
  }
}

// ---------- final BN + leaky in place ----------
__global__ __launch_bounds__(256) void k_bnact(float* __restrict__ out, const float* __restrict__ af,
                                               const float* __restrict__ bf, int n4) {
  int i = blockIdx.x * 256 + threadIdx.x;
  int stride = gridDim.x * 256;
  float4* o4 = (float4*)out;
  const float4* a4p = (const float4*)af;
  const float4* b4p = (const float4*)bf;
  for (; i < n4; i += stride) {
    int c = i & 63;
    float4 a = a4p[c], b = b4p[c];
    float4 v = o4[i];
    v.x = a.x * v.x + b.x; v.x = (v.x > 0.f) ? v.x : 0.01f * v.x;
    v.y = a.y * v.y + b.y; v.y = (v.y > 0.f) ? v.y : 0.01f * v.y;
    v.z = a.z * v.z + b.z; v.z = (v.z > 0.f) ? v.z : 0.01f * v.z;
    v.w = a.w * v.w + b.w; v.w = (v.w > 0.f) ? v.w : 0.01f * v.w;
    o4[i] = v;
  }
}

extern "C" void kernel_launch(void* const* d_in, const int* in_sizes, int n_in,
                              void* d_out, int out_size, void* d_ws, size_t ws_size,
                              hipStream_t stream) {
  const float* x    = (const float*)d_in[0];
  const float* y    = (const float*)d_in[1];
  const int*   eidx = (const int*)d_in[3];
  const float* Wu   = (const float*)d_in[4];
  const float* gu   = (const float*)d_in[5];
  const float* bu   = (const float*)d_in[6];
  const float* Wp   = (const float*)d_in[7];
  const float* gp   = (const float*)d_in[8];
  const float* bp   = (const float*)d_in[9];
  const float* cIn  = (const float*)d_in[10];
  const float* Wm   = (const float*)d_in[11];
  const float* gm   = (const float*)d_in[12];
  const float* bm   = (const float*)d_in[13];
  const float* Wf   = (const float*)d_in[14];
  const float* gf   = (const float*)d_in[15];
  const float* bfv  = (const float*)d_in[16];

  const int N = in_sizes[0] / 256;
  const int E = in_sizes[3] / 2;
  const int* ei = eidx;
  const int* ej = eidx + E;

  char* ws = (char*)d_ws;
  float* MINV  = (float*)(ws + OFF_MINV);
  float* CMW   = (float*)(ws + OFF_CM);
  float* AU    = (float*)(ws + OFF_AU);
  float* BUE   = (float*)(ws + OFF_BUE);
  float* AP    = (float*)(ws + OFF_AP);
  float* APBE  = (float*)(ws + OFF_APBE);
  float* AM    = (float*)(ws + OFF_AM);
  float* BM    = (float*)(ws + OFF_BM);
  float* AF    = (float*)(ws + OFF_AF);
  float* BF    = (float*)(ws + OFF_BF);
  int*   BSC   = (int*)(ws + OFF_BS);
  u16*   WUT   = (u16*)(ws + OFF_WUT);
  u16*   WMT   = (u16*)(ws + OFF_WMT);
  u16*   WFT   = (u16*)(ws + OFF_WFT);
  float* PART1 = (float*)(ws + OFF_PART1);
  float* PART2 = (float*)(ws + OFF_PART2);
  int*   ROWPTR= (int*)(ws + OFF_ROWPTR);
  int*   COUNT = (int*)(ws + OFF_COUNT);
  int*   CURSOR= (int*)(ws + OFF_CURSOR);
  float* LOGITS= (float*)(ws + OFF_LOGITS);
  u16*   UB    = (u16*)(ws + OFF_LOGITS);     // reuses LOGITS region (dead after k_node)
  int*   SRCJ  = (int*)(ws + OFF_SRCJ);
  int*   DSTI  = (int*)(ws + OFF_DSTI);
  float* U     = (float*)(ws + OFF_U);
  float* P     = (float*)(ws + OFF_P);
  float* AGG   = (float*)(ws + OFF_AGG);
  u16*   XB    = (u16*)(ws + OFF_H2);         // early use of H2 region
  u16*   H2    = (u16*)(ws + OFF_H2);

  const float invN = 1.0f / (float)N;
  const int ntiles16 = N / 16;
  const int nbScan   = (N + 255) / 256;
  const int mtiles   = (N + 127) / 128;       // 782

  hipMemsetAsync(COUNT, 0, (size_t)N * 4, stream);
  hipMemsetAsync(CURSOR, 0, (size_t)N * 4, stream);

  k_prep<<<1, 256, 0, stream>>>(cIn, MINV, CMW);
  k_tcvt<<<64,  256, 0, stream>>>(Wu, WUT, 256, 64);
  k_tcvt<<<64,  256, 0, stream>>>(Wm, WMT, 64, 256);
  k_tcvt<<<512, 256, 0, stream>>>(Wf, WFT, 512, 256);

  // unary embedding: x -> bf16 -> MFMA GEMM -> U (raw xu, f32), then BN params
  k_f2b8<<<2048, 256, 0, stream>>>(x, XB, N * 256 / 8);
  k_mfma<64, 0, 0><<<dim3(mtiles, 1), 256, 0, stream>>>(
      XB, 256, 256, N, nullptr, nullptr, nullptr, nullptr, WUT, U, nullptr, 64);
  k_colstats64<<<1024, 256, 0, stream>>>(U, PART1, PART2, N);
  k_reduce_fin<<<64, 256, 0, stream>>>(PART1, PART2, 1024, 64, invN, gu, bu, AU, BUE);

  // pairwise embedding stays f32 (feeds distance logits)
  k_gemm_h<<<1024, 256, 0, stream>>>(y, Wp, P, ntiles16);
  k_colstats64<<<1024, 256, 0, stream>>>(P, PART1, PART2, N);
  k_reduce_fin<<<64, 256, 0, stream>>>(PART1, PART2, 1024, 64, invN, gp, bp, AP, APBE);

  // CSR build
  k_count<<<2048, 256, 0, stream>>>(ei, E, COUNT);
  k_scanA<<<nbScan, 256, 0, stream>>>(COUNT, N, ROWPTR, BSC);
  k_scanB<<<1, 512, 0, stream>>>(BSC, nbScan);
  k_scanC<<<nbScan, 256, 0, stream>>>(N, ROWPTR, BSC);
  k_fill<<<2048, 256, 0, stream>>>(ei, ej, E, ROWPTR, CURSOR, SRCJ, DSTI);

  // edge softmax + aggregation
  k_logit<<<4096, 256, 0, stream>>>(P, AP, DSTI, SRCJ, E, LOGITS);
  k_node<<<(N + 3) / 4, 256, 0, stream>>>(LOGITS, SRCJ, ROWPTR, U, AU, BUE, N, AGG);

  // CRF solve -> h (bf16)   [UB overwrites LOGITS region: logits are dead here]
  k_solve<<<2048, 256, 0, stream>>>(U, AGG, MINV, CMW, AU, BUE, UB, ntiles16);

  // h @ Wm -> h2 bf16 (MFMA), then BN params
  k_mfma<128, 0, 1><<<dim3(mtiles, 2), 256, 0, stream>>>(
      UB, 64, 64, N, nullptr, nullptr, nullptr, nullptr, WMT, nullptr, H2, 256);
  k_colstats256_bf16<<<1024, 256, 0, stream>>>(H2, PART1, PART2, N);
  k_reduce_fin<<<256, 256, 0, stream>>>(PART1, PART2, 1024, 256, invN, gm, bm, AM, BM);

  // [leaky(bn(h2)), y] @ Wf -> raw out (MFMA, fused A build), then BN + leaky
  k_mfma<128, 1, 0><<<dim3(mtiles, 2), 256, 0, stream>>>(
      nullptr, 0, 512, N, H2, y, AM, BM, WFT, (float*)d_out, nullptr, 256);
  k_colstats256_f32<<<1024, 256, 0, stream>>>((float*)d_out, PART1, PART2, N);
  k_reduce_fin<<<256, 256, 0, stream>>>(PART1, PART2, 1024, 256, invN, gf, bfv, AF, BF);
  k_bnact<<<2048, 256, 0, stream>>>((float*)d_out, AF, BF, N * 64);
}

// Round 3
// 1124.461 us; speedup vs baseline: 2.5252x; 1.3289x over previous
//
#include <hip/hip_runtime.h>
#include <hip/hip_fp16.h>
#include <math.h>

typedef unsigned short u16;
typedef short s16x8 __attribute__((ext_vector_type(8)));
typedef unsigned short u16x8 __attribute__((ext_vector_type(8)));
typedef float f32x4 __attribute__((ext_vector_type(4)));

// ---------- helpers ----------
__device__ __forceinline__ float bf2f(u16 u) {
  unsigned x = ((unsigned)u) << 16;
  return __uint_as_float(x);
}
__device__ __forceinline__ u16 f2bf(float f) {
  unsigned x = __float_as_uint(f);
  unsigned r = x + 0x7FFFu + ((x >> 16) & 1u);
  return (u16)(r >> 16);
}

// ---------- ws layout (bytes) ----------
static const size_t OFF_MINV   = 0;                       // 64*64 f32
static const size_t OFF_CM     = 16ull * 1024;            // 64*64 f32
static const size_t OFF_AU     = 32ull * 1024;            // 64 f32
static const size_t OFF_BUE    = 32ull * 1024 + 256;
static const size_t OFF_AP     = 32ull * 1024 + 512;
static const size_t OFF_APBE   = 32ull * 1024 + 768;
static const size_t OFF_AM     = 36ull * 1024;            // 256 f32
static const size_t OFF_BM     = 37ull * 1024;
static const size_t OFF_AF     = 38ull * 1024;
static const size_t OFF_BF     = 39ull * 1024;
static const size_t OFF_BS     = 40ull * 1024;            // scan block sums
static const size_t OFF_WUT    = 64ull * 1024;            // 64*256 bf16
static const size_t OFF_WMT    = 128ull * 1024;           // 256*64 bf16
static const size_t OFF_WFT    = 192ull * 1024;           // 256*512 bf16 (ends 448KB)
static const size_t OFF_WPH    = 512ull * 1024;           // 64*256 bf16 hi
static const size_t OFF_WPL    = 576ull * 1024;           // 64*256 bf16 lo
static const size_t OFF_PART1  = 1ull  * 1024 * 1024;
static const size_t OFF_PART2  = 2ull  * 1024 * 1024;
static const size_t OFF_ROWPTR = 3ull  * 1024 * 1024;     // (N+1) int
static const size_t OFF_COUNT  = 3ull  * 1024 * 1024 + 512 * 1024;
static const size_t OFF_CURSOR = 4ull  * 1024 * 1024;
static const size_t OFF_LOGITS = 5ull  * 1024 * 1024;     // E f32; dead after k_node -> HB bf16 N*64
static const size_t OFF_SRCJ   = 18ull * 1024 * 1024;     // E int
static const size_t OFF_DSTI   = 31ull * 1024 * 1024;     // E int
static const size_t OFF_U      = 44ull * 1024 * 1024;     // UBRAW bf16 N*64 (12.8MB)
static const size_t OFF_UN     = 57ull * 1024 * 1024;     // UN bf16 N*64 (12.8MB)
static const size_t OFF_P      = 70ull * 1024 * 1024;     // P f32 N*64 (25.6MB)
static const size_t OFF_AGG    = 96ull * 1024 * 1024;     // PS f16 N*64 early (dead after k_logit), then AGG f32 N*64
static const size_t OFF_H2     = 122ull * 1024 * 1024;    // H2 bf16 N*256

// ---------- K0: C = c^T c, Minv = (I+C)^-1, CM = C @ Minv ----------
__global__ __launch_bounds__(256) void k_prep(const float* __restrict__ c,
                                              float* __restrict__ minv_out,
                                              float* __restrict__ cm_out) {
  __shared__ float sm[12288];
  float* CC  = sm;
  float* aug = sm + 4096;
  float* cl  = sm + 8192;
  int t = threadIdx.x;
  for (int idx = t; idx < 4096; idx += 256) cl[idx] = c[idx];
  __syncthreads();
  for (int idx = t; idx < 4096; idx += 256) {
    int a = idx >> 6, b = idx & 63;
    float s = 0.f;
    for (int k = 0; k < 64; ++k) s += cl[k * 64 + a] * cl[k * 64 + b];
    CC[idx] = s;
  }
  __syncthreads();
  for (int idx = t; idx < 8192; idx += 256) {
    int r = idx >> 7, cc = idx & 127;
    float v;
    if (cc < 64) v = CC[r * 64 + cc] + (r == cc ? 1.f : 0.f);
    else         v = ((cc - 64) == r) ? 1.f : 0.f;
    aug[idx] = v;
  }
  __syncthreads();
  for (int p = 0; p < 64; ++p) {
    float inv = 1.0f / aug[p * 128 + p];
    __syncthreads();
    for (int cc = t; cc < 128; cc += 256) aug[p * 128 + cc] *= inv;
    __syncthreads();
    int r  = t >> 2;
    int c0 = (t & 3) * 32;
    float f = aug[r * 128 + p];
    __syncthreads();
    if (r != p) {
      for (int cc = c0; cc < c0 + 32; ++cc) aug[r * 128 + cc] -= f * aug[p * 128 + cc];
    }
    __syncthreads();
  }
  for (int idx = t; idx < 4096; idx += 256) {
    int r = idx >> 6, cc = idx & 63;
    minv_out[idx] = aug[r * 128 + 64 + cc];
  }
  __syncthreads();
  for (int idx = t; idx < 4096; idx += 256) {
    int a = idx >> 6, b = idx & 63;
    float s = 0.f;
    for (int k = 0; k < 64; ++k) s += CC[a * 64 + k] * aug[k * 128 + 64 + b];
    cm_out[idx] = s;
  }
}

// ---------- transpose + convert weights: f32 [Kd][Nc] -> bf16 [Nc][Kd] ----------
__global__ __launch_bounds__(256) void k_tcvt(const float* __restrict__ in, u16* __restrict__ outb,
                                              int Kd, int Nc) {
  int i = blockIdx.x * 256 + threadIdx.x;
  if (i < Kd * Nc) {
    int k = i / Nc, n = i - k * Nc;
    outb[(size_t)n * Kd + k] = f2bf(in[i]);
  }
}

// ---------- transpose + hi/lo split: Wp f32 [256][64] -> WPH/WPL bf16 [64][256] ----------
__global__ __launch_bounds__(256) void k_tcvt_split(const float* __restrict__ in,
                                                    u16* __restrict__ outh, u16* __restrict__ outl) {
  int i = blockIdx.x * 256 + threadIdx.x;
  if (i < 256 * 64) {
    int k = i >> 6, n = i & 63;
    float v = in[i];
    u16 h = f2bf(v);
    float lo = v - bf2f(h);
    outh[(size_t)n * 256 + k] = h;
    outl[(size_t)n * 256 + k] = f2bf(lo);
  }
}

// ---------- MFMA GEMM: C[M,*] = A[M,K] @ Bt[*,K]^T ----------
// AMODE 0: A bf16 [M][ldA]. AMODE 1: fused [leaky(am*h2+bm) | y] (K=512).
// AMODE 2: A f32 [M][ldA], converted in staging. OBF: 0 f32 out, 1 bf16 out.
template<int BN, int AMODE, int OBF>
__global__ __launch_bounds__(256) void k_mfma(const u16* __restrict__ Abf, const float* __restrict__ Af32,
                                              int ldA, int K, int M,
                                              const u16* __restrict__ h2, const float* __restrict__ yy,
                                              const float* __restrict__ am, const float* __restrict__ bm,
                                              const u16* __restrict__ Bt,
                                              float* __restrict__ Cf, u16* __restrict__ Cb, int ldC) {
  constexpr int WN  = BN / 2;
  constexpr int FN  = WN / 16;
  constexpr int NPB = BN / 32;
  __shared__ u16 lds[2][(128 + BN) * 64];

  int t = threadIdx.x;
  int wid = t >> 6, lane = t & 63;
  int wr = wid >> 1, wc = wid & 1;
  int lr = lane & 15, lk = lane >> 4;
  int m0 = blockIdx.x * 128;
  int n0 = blockIdx.y * BN;
  int nK = K >> 6;

  int sidx = t;
  u16x8 ra[4];
  u16x8 rb[NPB];

  f32x4 acc[4][FN];
#pragma unroll
  for (int m = 0; m < 4; ++m)
#pragma unroll
    for (int n = 0; n < FN; ++n) acc[m][n] = (f32x4){0.f, 0.f, 0.f, 0.f};

  auto loadTile = [&](int kk) {
    int kk0 = kk * 64;
#pragma unroll
    for (int p = 0; p < 4; ++p) {
      int idx = p * 256 + sidx;
      int r = idx >> 3, c8 = idx & 7;
      int row = m0 + r; if (row >= M) row = M - 1;
      int k = kk0 + c8 * 8;
      if constexpr (AMODE == 0) {
        ra[p] = *(const u16x8*)(Abf + (size_t)row * ldA + k);
      } else if constexpr (AMODE == 2) {
        const float* src = Af32 + (size_t)row * ldA + k;
        float4 a = *(const float4*)src;
        float4 b = *(const float4*)(src + 4);
        u16x8 o;
        o[0] = f2bf(a.x); o[1] = f2bf(a.y); o[2] = f2bf(a.z); o[3] = f2bf(a.w);
        o[4] = f2bf(b.x); o[5] = f2bf(b.y); o[6] = f2bf(b.z); o[7] = f2bf(b.w);
        ra[p] = o;
      } else {
        if (kk0 < 256) {
          u16x8 h8 = *(const u16x8*)(h2 + (size_t)row * 256 + k);
          float av[8], bv[8];
          *(float4*)(av)     = *(const float4*)(am + k);
          *(float4*)(av + 4) = *(const float4*)(am + k + 4);
          *(float4*)(bv)     = *(const float4*)(bm + k);
          *(float4*)(bv + 4) = *(const float4*)(bm + k + 4);
          u16x8 o;
#pragma unroll
          for (int j = 0; j < 8; ++j) {
            float v = bf2f((u16)h8[j]) * av[j] + bv[j];
            v = v > 0.f ? v : 0.01f * v;
            o[j] = f2bf(v);
          }
          ra[p] = o;
        } else {
          float yv[8];
          *(float4*)(yv)     = *(const float4*)(yy + (size_t)row * 256 + (k - 256));
          *(float4*)(yv + 4) = *(const float4*)(yy + (size_t)row * 256 + (k - 256) + 4);
          u16x8 o;
#pragma unroll
          for (int j = 0; j < 8; ++j) o[j] = f2bf(yv[j]);
          ra[p] = o;
        }
      }
    }
#pragma unroll
    for (int p = 0; p < NPB; ++p) {
      int idx = p * 256 + sidx;
      int r = idx >> 3, c8 = idx & 7;
      rb[p] = *(const u16x8*)(Bt + (size_t)(n0 + r) * K + kk0 + c8 * 8);
    }
  };

  auto dswrite = [&](int b) {
    char* As  = (char*)&lds[b][0];
    char* Bsc = As + 128 * 64 * 2;
#pragma unroll
    for (int p = 0; p < 4; ++p) {
      int idx = p * 256 + sidx;
      int r = idx >> 3, c8 = idx & 7;
      *(u16x8*)(As + r * 128 + ((c8 * 16) ^ ((r & 7) << 4))) = ra[p];
    }
#pragma unroll
    for (int p = 0; p < NPB; ++p) {
      int idx = p * 256 + sidx;
      int r = idx >> 3, c8 = idx & 7;
      *(u16x8*)(Bsc + r * 128 + ((c8 * 16) ^ ((r & 7) << 4))) = rb[p];
    }
  };

  auto compute = [&](int b) {
    const char* As  = (const char*)&lds[b][0];
    const char* Bsc = As + 128 * 64 * 2;
#pragma unroll
    for (int ks = 0; ks < 2; ++ks) {
      int kb = ks * 64 + lk * 16;
      s16x8 af[4], bfr[FN];
#pragma unroll
      for (int m = 0; m < 4; ++m) {
        int row = wr * 64 + m * 16 + lr;
        af[m] = *(const s16x8*)(As + row * 128 + (kb ^ ((row & 7) << 4)));
      }
#pragma unroll
      for (int n = 0; n < FN; ++n) {
        int row = wc * WN + n * 16 + lr;
        bfr[n] = *(const s16x8*)(Bsc + row * 128 + (kb ^ ((row & 7) << 4)));
      }
#pragma unroll
      for (int m = 0; m < 4; ++m)
#pragma unroll
        for (int n = 0; n < FN; ++n)
          acc[m][n] = __builtin_amdgcn_mfma_f32_16x16x32_bf16(af[m], bfr[n], acc[m][n], 0, 0, 0);
    }
  };

  loadTile(0);
  dswrite(0);
  __syncthreads();
  for (int kk = 0; kk < nK; ++kk) {
    int b = kk & 1;
    if (kk + 1 < nK) loadTile(kk + 1);
    compute(b);
    if (kk + 1 < nK) { dswrite(b ^ 1); __syncthreads(); }
  }

#pragma unroll
  for (int m = 0; m < 4; ++m) {
#pragma unroll
    for (int n = 0; n < FN; ++n) {
      int col = n0 + wc * WN + n * 16 + lr;
#pragma unroll
      for (int q = 0; q < 4; ++q) {
        int row = m0 + wr * 64 + m * 16 + lk * 4 + q;
        if (row < M) {
          if constexpr (OBF) Cb[(size_t)row * ldC + col] = f2bf(acc[m][n][q]);
          else               Cf[(size_t)row * ldC + col] = acc[m][n][q];
        }
      }
    }
  }
}

// ---------- split-bf16 MFMA (f32 accuracy): P[M,64] = y[M,256] @ Wp ----------
// A split hi/lo on the fly; B pre-split (WPH/WPL). acc = Ah*Bh + Ah*Bl + Al*Bh.
__global__ __launch_bounds__(256) void k_mfma_split(const float* __restrict__ Af, int K, int M,
                                                    const u16* __restrict__ Bh, const u16* __restrict__ Bl,
                                                    float* __restrict__ Cf) {
  __shared__ u16 sAh[128 * 64], sAl[128 * 64], sBh[64 * 64], sBl[64 * 64];  // 48KB
  int t = threadIdx.x;
  int wid = t >> 6, lane = t & 63;
  int wr = wid >> 1, wc = wid & 1;
  int lr = lane & 15, lk = lane >> 4;
  int m0 = blockIdx.x * 128;
  int nK = K >> 6;

  u16x8 rah[4], ral[4], rbh[2], rbl[2];
  f32x4 acc[4][2];
#pragma unroll
  for (int m = 0; m < 4; ++m)
#pragma unroll
    for (int n = 0; n < 2; ++n) acc[m][n] = (f32x4){0.f, 0.f, 0.f, 0.f};

  auto loadTile = [&](int kk) {
    int kk0 = kk * 64;
#pragma unroll
    for (int p = 0; p < 4; ++p) {
      int idx = p * 256 + t;
      int r = idx >> 3, c8 = idx & 7;
      int row = m0 + r; if (row >= M) row = M - 1;
      const float* src = Af + (size_t)row * K + kk0 + c8 * 8;
      float4 a = *(const float4*)src;
      float4 b = *(const float4*)(src + 4);
      float v[8];
      *(float4*)(v) = a; *(float4*)(v + 4) = b;
      u16x8 oh, ol;
#pragma unroll
      for (int j = 0; j < 8; ++j) {
        u16 h = f2bf(v[j]);
        oh[j] = h;
        ol[j] = f2bf(v[j] - bf2f(h));
      }
      rah[p] = oh; ral[p] = ol;
    }
#pragma unroll
    for (int p = 0; p < 2; ++p) {
      int idx = p * 256 + t;
      int r = idx >> 3, c8 = idx & 7;
      rbh[p] = *(const u16x8*)(Bh + (size_t)r * K + kk0 + c8 * 8);
      rbl[p] = *(const u16x8*)(Bl + (size_t)r * K + kk0 + c8 * 8);
    }
  };

  auto dswrite = [&]() {
    char* Ah = (char*)sAh; char* Al = (char*)sAl;
    char* Bhc = (char*)sBh; char* Blc = (char*)sBl;
#pragma unroll
    for (int p = 0; p < 4; ++p) {
      int idx = p * 256 + t;
      int r = idx >> 3, c8 = idx & 7;
      int off = r * 128 + ((c8 * 16) ^ ((r & 7) << 4));
      *(u16x8*)(Ah + off) = rah[p];
      *(u16x8*)(Al + off) = ral[p];
    }
#pragma unroll
    for (int p = 0; p < 2; ++p) {
      int idx = p * 256 + t;
      int r = idx >> 3, c8 = idx & 7;
      int off = r * 128 + ((c8 * 16) ^ ((r & 7) << 4));
      *(u16x8*)(Bhc + off) = rbh[p];
      *(u16x8*)(Blc + off) = rbl[p];
    }
  };

  auto compute = [&]() {
    const char* Ah = (const char*)sAh; const char* Al = (const char*)sAl;
    const char* Bhc = (const char*)sBh; const char* Blc = (const char*)sBl;
#pragma unroll
    for (int ks = 0; ks < 2; ++ks) {
      int kb = ks * 64 + lk * 16;
      s16x8 fah[4], fal[4], fbh[2], fbl[2];
#pragma unroll
      for (int m = 0; m < 4; ++m) {
        int row = wr * 64 + m * 16 + lr;
        int off = row * 128 + (kb ^ ((row & 7) << 4));
        fah[m] = *(const s16x8*)(Ah + off);
        fal[m] = *(const s16x8*)(Al + off);
      }
#pragma unroll
      for (int n = 0; n < 2; ++n) {
        int row = wc * 32 + n * 16 + lr;
        int off = row * 128 + (kb ^ ((row & 7) << 4));
        fbh[n] = *(const s16x8*)(Bhc + off);
        fbl[n] = *(const s16x8*)(Blc + off);
      }
#pragma unroll
      for (int m = 0; m < 4; ++m)
#pragma unroll
        for (int n = 0; n < 2; ++n) {
          acc[m][n] = __builtin_amdgcn_mfma_f32_16x16x32_bf16(fah[m], fbh[n], acc[m][n], 0, 0, 0);
          acc[m][n] = __builtin_amdgcn_mfma_f32_16x16x32_bf16(fah[m], fbl[n], acc[m][n], 0, 0, 0);
          acc[m][n] = __builtin_amdgcn_mfma_f32_16x16x32_bf16(fal[m], fbh[n], acc[m][n], 0, 0, 0);
        }
    }
  };

  loadTile(0);
  for (int kk = 0; kk < nK; ++kk) {
    __syncthreads();
    dswrite();
    __syncthreads();
    if (kk + 1 < nK) loadTile(kk + 1);
    compute();
  }

#pragma unroll
  for (int m = 0; m < 4; ++m) {
#pragma unroll
    for (int n = 0; n < 2; ++n) {
      int col = wc * 32 + n * 16 + lr;
#pragma unroll
      for (int q = 0; q < 4; ++q) {
        int row = m0 + wr * 64 + m * 16 + lk * 4 + q;
        if (row < M) Cf[(size_t)row * 64 + col] = acc[m][n][q];
      }
    }
  }
}

// ---------- column stats ----------
__global__ __launch_bounds__(256) void k_colstats64(const float* __restrict__ M,
                                                    float* __restrict__ p1, float* __restrict__ p2,
                                                    int nrows) {
  __shared__ float r1[256], r2[256];
  int col = threadIdx.x & 63, rg = threadIdx.x >> 6;
  float s1 = 0.f, s2 = 0.f;
  for (int row = blockIdx.x * 4 + rg; row < nrows; row += gridDim.x * 4) {
    float v = M[(size_t)row * 64 + col];
    s1 += v; s2 += v * v;
  }
  r1[rg * 64 + col] = s1; r2[rg * 64 + col] = s2;
  __syncthreads();
  if (rg == 0) {
    p1[blockIdx.x * 64 + col] = r1[col] + r1[64 + col] + r1[128 + col] + r1[192 + col];
    p2[blockIdx.x * 64 + col] = r2[col] + r2[64 + col] + r2[128 + col] + r2[192 + col];
  }
}

__global__ __launch_bounds__(256) void k_colstats64_bf16(const u16* __restrict__ M,
                                                         float* __restrict__ p1, float* __restrict__ p2,
                                                         int nrows) {
  __shared__ float r1[256], r2[256];
  int col = threadIdx.x & 63, rg = threadIdx.x >> 6;
  float s1 = 0.f, s2 = 0.f;
  for (int row = blockIdx.x * 4 + rg; row < nrows; row += gridDim.x * 4) {
    float v = bf2f(M[(size_t)row * 64 + col]);
    s1 += v; s2 += v * v;
  }
  r1[rg * 64 + col] = s1; r2[rg * 64 + col] = s2;
  __syncthreads();
  if (rg == 0) {
    p1[blockIdx.x * 64 + col] = r1[col] + r1[64 + col] + r1[128 + col] + r1[192 + col];
    p2[blockIdx.x * 64 + col] = r2[col] + r2[64 + col] + r2[128 + col] + r2[192 + col];
  }
}

__global__ __launch_bounds__(256) void k_colstats256_f32(const float* __restrict__ M,
                                                         float* __restrict__ p1, float* __restrict__ p2,
                                                         int nrows) {
  int t = threadIdx.x;
  float s1 = 0.f, s2 = 0.f;
  for (int row = blockIdx.x; row < nrows; row += gridDim.x) {
    float v = M[(size_t)row * 256 + t];
    s1 += v; s2 += v * v;
  }
  p1[blockIdx.x * 256 + t] = s1;
  p2[blockIdx.x * 256 + t] = s2;
}

__global__ __launch_bounds__(256) void k_colstats256_bf16(const u16* __restrict__ M,
                                                          float* __restrict__ p1, float* __restrict__ p2,
                                                          int nrows) {
  int t = threadIdx.x;
  float s1 = 0.f, s2 = 0.f;
  for (int row = blockIdx.x; row < nrows; row += gridDim.x) {
    float v = bf2f(M[(size_t)row * 256 + t]);
    s1 += v; s2 += v * v;
  }
  p1[blockIdx.x * 256 + t] = s1;
  p2[blockIdx.x * 256 + t] = s2;
}

// ---------- reduce partials -> BN scale/shift ----------
__global__ __launch_bounds__(256) void k_reduce_fin(const float* __restrict__ part1,
                                                    const float* __restrict__ part2,
                                                    int nb, int C, float invN,
                                                    const float* __restrict__ gamma,
                                                    const float* __restrict__ beta,
                                                    float* __restrict__ a_out,
                                                    float* __restrict__ b_out) {
  int c = blockIdx.x;
  int t = threadIdx.x;
  float s1 = 0.f, s2 = 0.f;
  for (int b = t; b < nb; b += 256) {
    s1 += part1[(size_t)b * C + c];
    s2 += part2[(size_t)b * C + c];
  }
  for (int m = 32; m; m >>= 1) { s1 += __shfl_xor(s1, m); s2 += __shfl_xor(s2, m); }
  __shared__ float l1[4], l2[4];
  if ((t & 63) == 0) { l1[t >> 6] = s1; l2[t >> 6] = s2; }
  __syncthreads();
  if (t == 0) {
    s1 = l1[0] + l1[1] + l1[2] + l1[3];
    s2 = l2[0] + l2[1] + l2[2] + l2[3];
    float mu  = s1 * invN;
    float var = s2 * invN - mu * mu;
    float a = gamma[c] * rsqrtf(var + 1e-5f);
    a_out[c] = a;
    b_out[c] = beta[c] - mu * a;
  }
}

// ---------- UN = bf16(au*xu + bue) ----------
__global__ __launch_bounds__(256) void k_scaleUN(const u16* __restrict__ ub, const float* __restrict__ au,
                                                 const float* __restrict__ bue, u16* __restrict__ un, int n8) {
  for (int i = blockIdx.x * 256 + threadIdx.x; i < n8; i += gridDim.x * 256) {
    int c0 = (i & 7) * 8;
    float4 a0 = *(const float4*)(au + c0), a1 = *(const float4*)(au + c0 + 4);
    float4 b0 = *(const float4*)(bue + c0), b1 = *(const float4*)(bue + c0 + 4);
    float av[8], bv[8];
    *(float4*)(av) = a0; *(float4*)(av + 4) = a1;
    *(float4*)(bv) = b0; *(float4*)(bv + 4) = b1;
    u16x8 in = ((const u16x8*)ub)[i];
    u16x8 o;
#pragma unroll
    for (int j = 0; j < 8; ++j) o[j] = f2bf(bf2f((u16)in[j]) * av[j] + bv[j]);
    ((u16x8*)un)[i] = o;
  }
}

// ---------- PS = f16(ap * su) ----------
__global__ __launch_bounds__(256) void k_scaleP(const float* __restrict__ P, const float* __restrict__ ap,
                                                __half* __restrict__ PS, int n8) {
  for (int i = blockIdx.x * 256 + threadIdx.x; i < n8; i += gridDim.x * 256) {
    int c0 = (i & 7) * 8;
    float4 s0 = *(const float4*)(ap + c0), s1 = *(const float4*)(ap + c0 + 4);
    float4 a = ((const float4*)P)[i * 2];
    float4 b = ((const float4*)P)[i * 2 + 1];
    __half2 o0 = __floats2half2_rn(a.x * s0.x, a.y * s0.y);
    __half2 o1 = __floats2half2_rn(a.z * s0.z, a.w * s0.w);
    __half2 o2 = __floats2half2_rn(b.x * s1.x, b.y * s1.y);
    __half2 o3 = __floats2half2_rn(b.z * s1.z, b.w * s1.w);
    uint4 out;
    out.x = *(unsigned*)&o0; out.y = *(unsigned*)&o1;
    out.z = *(unsigned*)&o2; out.w = *(unsigned*)&o3;
    ((uint4*)PS)[i] = out;
  }
}

// ---------- CSR build ----------
__global__ void k_count(const int* __restrict__ ei, int E, int* __restrict__ cnt) {
  for (int e = blockIdx.x * blockDim.x + threadIdx.x; e < E; e += gridDim.x * blockDim.x)
    atomicAdd(&cnt[ei[e]], 1);
}

__global__ __launch_bounds__(256) void k_scanA(const int* __restrict__ cnt, int N,
                                               int* __restrict__ rowptr, int* __restrict__ bs) {
  __shared__ int s[256];
  int t = threadIdx.x, gi = blockIdx.x * 256 + t;
  int v = (gi < N) ? cnt[gi] : 0;
  s[t] = v;
  __syncthreads();
  for (int off = 1; off < 256; off <<= 1) {
    int add = (t >= off) ? s[t - off] : 0;
    __syncthreads();
    s[t] += add;
    __syncthreads();
  }
  if (gi < N) rowptr[gi + 1] = s[t];
  if (t == 255) bs[blockIdx.x] = s[255];
}

__global__ __launch_bounds__(512) void k_scanB(int* __restrict__ bs, int nb) {
  __shared__ int s[512];
  int t = threadIdx.x;
  s[t] = (t < nb) ? bs[t] : 0;
  __syncthreads();
  for (int off = 1; off < 512; off <<= 1) {
    int add = (t >= off) ? s[t - off] : 0;
    __syncthreads();
    s[t] += add;
    __syncthreads();
  }
  if (t < nb) bs[t] = s[t];
}

__global__ __launch_bounds__(256) void k_scanC(int N, int* __restrict__ rowptr, const int* __restrict__ bs) {
  int gi = blockIdx.x * 256 + threadIdx.x;
  if (gi == 0) rowptr[0] = 0;
  if (gi < N && blockIdx.x > 0) rowptr[gi + 1] += bs[blockIdx.x - 1];
}

__global__ void k_fill(const int* __restrict__ ei, const int* __restrict__ ej, int E,
                       const int* __restrict__ rowptr, int* __restrict__ cursor,
                       int* __restrict__ srcj, int* __restrict__ dsti) {
  for (int e = blockIdx.x * blockDim.x + threadIdx.x; e < E; e += gridDim.x * blockDim.x) {
    int i = ei[e], j = ej[e];
    int pos = atomicAdd(&cursor[i], 1);
    int slot = rowptr[i] + pos;
    srcj[slot] = j;
    dsti[slot] = i;
  }
}

// ---------- edge logits from f16 scaled table: -||PS_i - PS_j||^2 ----------
__global__ __launch_bounds__(256) void k_logit(const __half* __restrict__ PS,
                                               const int* __restrict__ dsti, const int* __restrict__ srcj,
                                               int E, float* __restrict__ logitS) {
  int lane16 = threadIdx.x & 15;
  int gid = (blockIdx.x * 256 + threadIdx.x) >> 4;
  int ngroups = (gridDim.x * 256) >> 4;
  const uint2* P2 = (const uint2*)PS;   // 4 halves per uint2; 16 uint2 per row
  for (int slot = gid; slot < E; slot += ngroups) {
    int i = dsti[slot], j = srcj[slot];
    uint2 uu = P2[(size_t)i * 16 + lane16];
    uint2 vv = P2[(size_t)j * 16 + lane16];
    float2 u0 = __half22float2(*(const __half2*)&uu.x);
    float2 u1 = __half22float2(*(const __half2*)&uu.y);
    float2 v0 = __half22float2(*(const __half2*)&vv.x);
    float2 v1 = __half22float2(*(const __half2*)&vv.y);
    float d0 = u0.x - v0.x, d1 = u0.y - v0.y, d2 = u1.x - v1.x, d3 = u1.y - v1.y;
    float acc = d0 * d0 + d1 * d1 + d2 * d2 + d3 * d3;
    acc += __shfl_xor(acc, 1, 16);
    acc += __shfl_xor(acc, 2, 16);
    acc += __shfl_xor(acc, 4, 16);
    acc += __shfl_xor(acc, 8, 16);
    if (lane16 == 0) logitS[slot] = -acc;
  }
}

// ---------- per-node softmax + aggregation (register-cached edges, 4x ILP) ----------
__global__ __launch_bounds__(256) void k_node(const float* __restrict__ logitS, const int* __restrict__ srcj,
                                              const int* __restrict__ rowptr, const u16* __restrict__ UN,
                                              int N, float* __restrict__ agg) {
  int lane = threadIdx.x & 63;
  int node = blockIdx.x * 4 + (threadIdx.x >> 6);
  if (node >= N) return;
  int b0 = rowptr[node], b1 = rowptr[node + 1];
  int deg = b1 - b0;
  float acc = 0.f;
  if (deg > 0) {
    int cnt = deg < 64 ? deg : 64;
    float lg = (lane < cnt) ? logitS[b0 + lane] : -INFINITY;
    int jj   = (lane < cnt) ? srcj[b0 + lane] : 0;
    float mx = lg;
    for (int s = b0 + 64 + lane; s < b1; s += 64) mx = fmaxf(mx, logitS[s]);
    for (int m = 32; m; m >>= 1) mx = fmaxf(mx, __shfl_xor(mx, m));
    float ex = (lane < cnt) ? __expf(lg - mx) : 0.f;
    float sm = ex;
    for (int s = b0 + 64 + lane; s < b1; s += 64) sm += __expf(logitS[s] - mx);
    for (int m = 32; m; m >>= 1) sm += __shfl_xor(sm, m);
    float inv = 1.0f / (sm + 1e-16f);
    float w = ex * inv;
    int ss = 0;
    for (; ss + 4 <= cnt; ss += 4) {
      int   j0 = __shfl(jj, ss),     j1 = __shfl(jj, ss + 1);
      int   j2 = __shfl(jj, ss + 2), j3 = __shfl(jj, ss + 3);
      float w0 = __shfl(w, ss),      w1 = __shfl(w, ss + 1);
      float w2 = __shfl(w, ss + 2),  w3 = __shfl(w, ss + 3);
      float v0 = bf2f(UN[(size_t)j0 * 64 + lane]);
      float v1 = bf2f(UN[(size_t)j1 * 64 + lane]);
      float v2 = bf2f(UN[(size_t)j2 * 64 + lane]);
      float v3 = bf2f(UN[(size_t)j3 * 64 + lane]);
      acc += w0 * v0 + w1 * v1 + w2 * v2 + w3 * v3;
    }
    for (; ss < cnt; ++ss) {
      int j0 = __shfl(jj, ss);
      float w0 = __shfl(w, ss);
      acc += w0 * bf2f(UN[(size_t)j0 * 64 + lane]);
    }
    for (int s = b0 + 64; s < b1; ++s) {   // rare deg>64 tail
      float w0 = __expf(logitS[s] - mx) * inv;
      acc += w0 * bf2f(UN[(size_t)srcj[s] * 64 + lane]);
    }
  }
  agg[(size_t)node * 64 + lane] = acc;
}

// ---------- h = (z + agg@C) @ Minv, z = UN (bf16), out bf16 ----------
__global__ __launch_bounds__(256) void k_solve(const u16* __restrict__ UN, const float* __restrict__ agg,
                                               const float* __restrict__ minv, const float* __restrict__ cmw,
                                               u16* __restrict__ HB, int ntiles) {
  __shared__ float mS[4096];
  __shared__ float cS[4096];
  int t = threadIdx.x;
  int c16 = t & 15, rg = t >> 4;
  for (int idx = t; idx < 1024; idx += 256) {
    ((float4*)mS)[idx] = ((const float4*)minv)[idx];
    ((float4*)cS)[idx] = ((const float4*)cmw)[idx];
  }
  __syncthreads();
  for (int tile = blockIdx.x; tile < ntiles; tile += gridDim.x) {
    int row = tile * 16 + rg;
    const u16*  ur = UN + (size_t)row * 64;
    const float* gr = agg + (size_t)row * 64;
    float4 acc = make_float4(0.f, 0.f, 0.f, 0.f);
#pragma unroll 4
    for (int k = 0; k < 64; ++k) {
      float z = bf2f(ur[k]);
      float g = gr[k];
      float4 m4 = ((const float4*)mS)[k * 16 + c16];
      float4 c4 = ((const float4*)cS)[k * 16 + c16];
      acc.x += z * m4.x + g * c4.x;
      acc.y += z * m4.y + g * c4.y;
      acc.z += z * m4.z + g * c4.z;
      acc.w += z * m4.w + g * c4.w;
    }
    ((ushort4*)HB)[(size_t)row * 16 + c16] =
        make_ushort4(f2bf(acc.x), f2bf(acc.y), f2bf(acc.z), f2bf(acc.w));
  }
}

// ---------- final BN + leaky in place ----------
__global__ __launch_bounds__(256) void k_bnact(float* __restrict__ out, const float* __restrict__ af,
                                               const float* __restrict__ bf, int n4) {
  int i = blockIdx.x * 256 + threadIdx.x;
  int stride = gridDim.x * 256;
  float4* o4 = (float4*)out;
  const float4* a4p = (const float4*)af;
  const float4* b4p = (const float4*)bf;
  for (; i < n4; i += stride) {
    int c = i & 63;
    float4 a = a4p[c], b = b4p[c];
    float4 v = o4[i];
    v.x = a.x * v.x + b.x; v.x = (v.x > 0.f) ? v.x : 0.01f * v.x;
    v.y = a.y * v.y + b.y; v.y = (v.y > 0.f) ? v.y : 0.01f * v.y;
    v.z = a.z * v.z + b.z; v.z = (v.z > 0.f) ? v.z : 0.01f * v.z;
    v.w = a.w * v.w + b.w; v.w = (v.w > 0.f) ? v.w : 0.01f * v.w;
    o4[i] = v;
  }
}

extern "C" void kernel_launch(void* const* d_in, const int* in_sizes, int n_in,
                              void* d_out, int out_size, void* d_ws, size_t ws_size,
                              hipStream_t stream) {
  const float* x    = (const float*)d_in[0];
  const float* y    = (const float*)d_in[1];
  const int*   eidx = (const int*)d_in[3];
  const float* Wu   = (const float*)d_in[4];
  const float* gu   = (const float*)d_in[5];
  const float* bu   = (const float*)d_in[6];
  const float* Wp   = (const float*)d_in[7];
  const float* gp   = (const float*)d_in[8];
  const float* bp   = (const float*)d_in[9];
  const float* cIn  = (const float*)d_in[10];
  const float* Wm   = (const float*)d_in[11];
  const float* gm   = (const float*)d_in[12];
  const float* bm   = (const float*)d_in[13];
  const float* Wf   = (const float*)d_in[14];
  const float* gf   = (const float*)d_in[15];
  const float* bfv  = (const float*)d_in[16];

  const int N = in_sizes[0] / 256;
  const int E = in_sizes[3] / 2;
  const int* ei = eidx;
  const int* ej = eidx + E;

  char* ws = (char*)d_ws;
  float* MINV  = (float*)(ws + OFF_MINV);
  float* CMW   = (float*)(ws + OFF_CM);
  float* AU    = (float*)(ws + OFF_AU);
  float* BUE   = (float*)(ws + OFF_BUE);
  float* AP    = (float*)(ws + OFF_AP);
  float* APBE  = (float*)(ws + OFF_APBE);
  float* AM    = (float*)(ws + OFF_AM);
  float* BM    = (float*)(ws + OFF_BM);
  float* AF    = (float*)(ws + OFF_AF);
  float* BF    = (float*)(ws + OFF_BF);
  int*   BSC   = (int*)(ws + OFF_BS);
  u16*   WUT   = (u16*)(ws + OFF_WUT);
  u16*   WMT   = (u16*)(ws + OFF_WMT);
  u16*   WFT   = (u16*)(ws + OFF_WFT);
  u16*   WPH   = (u16*)(ws + OFF_WPH);
  u16*   WPL   = (u16*)(ws + OFF_WPL);
  float* PART1 = (float*)(ws + OFF_PART1);
  float* PART2 = (float*)(ws + OFF_PART2);
  int*   ROWPTR= (int*)(ws + OFF_ROWPTR);
  int*   COUNT = (int*)(ws + OFF_COUNT);
  int*   CURSOR= (int*)(ws + OFF_CURSOR);
  float* LOGITS= (float*)(ws + OFF_LOGITS);
  u16*   HB    = (u16*)(ws + OFF_LOGITS);    // reuses LOGITS region (dead after k_node)
  int*   SRCJ  = (int*)(ws + OFF_SRCJ);
  int*   DSTI  = (int*)(ws + OFF_DSTI);
  u16*   UBRAW = (u16*)(ws + OFF_U);
  u16*   UN    = (u16*)(ws + OFF_UN);
  float* P     = (float*)(ws + OFF_P);
  __half* PS   = (__half*)(ws + OFF_AGG);    // PS dead after k_logit; AGG overwrites
  float* AGG   = (float*)(ws + OFF_AGG);
  u16*   H2    = (u16*)(ws + OFF_H2);

  const float invN = 1.0f / (float)N;
  const int ntiles16 = N / 16;
  const int nbScan   = (N + 255) / 256;
  const int mtiles   = (N + 127) / 128;
  const int n8       = N * 64 / 8;

  hipMemsetAsync(COUNT, 0, (size_t)N * 4, stream);
  hipMemsetAsync(CURSOR, 0, (size_t)N * 4, stream);

  k_prep<<<1, 256, 0, stream>>>(cIn, MINV, CMW);
  k_tcvt<<<64,  256, 0, stream>>>(Wu, WUT, 256, 64);
  k_tcvt<<<64,  256, 0, stream>>>(Wm, WMT, 64, 256);
  k_tcvt<<<512, 256, 0, stream>>>(Wf, WFT, 512, 256);
  k_tcvt_split<<<64, 256, 0, stream>>>(Wp, WPH, WPL);

  // unary embedding: x (f32, converted in staging) @ Wu -> UBRAW bf16; BN params; UN table
  k_mfma<64, 2, 1><<<dim3(mtiles, 1), 256, 0, stream>>>(
      nullptr, x, 256, 256, N, nullptr, nullptr, nullptr, nullptr, WUT, nullptr, UBRAW, 64);
  k_colstats64_bf16<<<1024, 256, 0, stream>>>(UBRAW, PART1, PART2, N);
  k_reduce_fin<<<64, 256, 0, stream>>>(PART1, PART2, 1024, 64, invN, gu, bu, AU, BUE);
  k_scaleUN<<<1024, 256, 0, stream>>>(UBRAW, AU, BUE, UN, n8);

  // pairwise embedding: split-bf16 MFMA (f32 accuracy) -> P f32; BN scale; PS f16 table
  k_mfma_split<<<mtiles, 256, 0, stream>>>(y, 256, N, WPH, WPL, P);
  k_colstats64<<<1024, 256, 0, stream>>>(P, PART1, PART2, N);
  k_reduce_fin<<<64, 256, 0, stream>>>(PART1, PART2, 1024, 64, invN, gp, bp, AP, APBE);
  k_scaleP<<<1024, 256, 0, stream>>>(P, AP, PS, n8);

  // CSR build
  k_count<<<2048, 256, 0, stream>>>(ei, E, COUNT);
  k_scanA<<<nbScan, 256, 0, stream>>>(COUNT, N, ROWPTR, BSC);
  k_scanB<<<1, 512, 0, stream>>>(BSC, nbScan);
  k_scanC<<<nbScan, 256, 0, stream>>>(N, ROWPTR, BSC);
  k_fill<<<2048, 256, 0, stream>>>(ei, ej, E, ROWPTR, CURSOR, SRCJ, DSTI);

  // edge softmax + aggregation (AGG overwrites PS region after k_logit is done)
  k_logit<<<4096, 256, 0, stream>>>(PS, DSTI, SRCJ, E, LOGITS);
  k_node<<<(N + 3) / 4, 256, 0, stream>>>(LOGITS, SRCJ, ROWPTR, UN, N, AGG);

  // CRF solve -> h bf16 (HB overwrites LOGITS region)
  k_solve<<<2048, 256, 0, stream>>>(UN, AGG, MINV, CMW, HB, ntiles16);

  // h @ Wm -> h2 bf16; BN params
  k_mfma<128, 0, 1><<<dim3(mtiles, 2), 256, 0, stream>>>(
      HB, nullptr, 64, 64, N, nullptr, nullptr, nullptr, nullptr, WMT, nullptr, H2, 256);
  k_colstats256_bf16<<<1024, 256, 0, stream>>>(H2, PART1, PART2, N);
  k_reduce_fin<<<256, 256, 0, stream>>>(PART1, PART2, 1024, 256, invN, gm, bm, AM, BM);

  // [leaky(bn(h2)), y] @ Wf -> raw out; BN + leaky
  k_mfma<128, 1, 0><<<dim3(mtiles, 2), 256, 0, stream>>>(
      nullptr, nullptr, 0, 512, N, H2, y, AM, BM, WFT, (float*)d_out, nullptr, 256);
  k_colstats256_f32<<<1024, 256, 0, stream>>>((float*)d_out, PART1, PART2, N);
  k_reduce_fin<<<256, 256, 0, stream>>>(PART1, PART2, 1024, 256, invN, gf, bfv, AF, BF);
  k_bnact<<<2048, 256, 0, stream>>>((float*)d_out, AF, BF, N * 64);
}

// Round 4
// 930.914 us; speedup vs baseline: 3.0502x; 1.2079x over previous
//
#include <hip/hip_runtime.h>
#include <hip/hip_fp16.h>
#include <math.h>

typedef unsigned short u16;
typedef short s16x8 __attribute__((ext_vector_type(8)));
typedef unsigned short u16x8 __attribute__((ext_vector_type(8)));
typedef float f32x4 __attribute__((ext_vector_type(4)));

// ---------- helpers ----------
__device__ __forceinline__ float bf2f(u16 u) {
  unsigned x = ((unsigned)u) << 16;
  return __uint_as_float(x);
}
__device__ __forceinline__ u16 f2bf(float f) {
  unsigned x = __float_as_uint(f);
  unsigned r = x + 0x7FFFu + ((x >> 16) & 1u);
  return (u16)(r >> 16);
}

// ---------- ws layout (bytes) ----------
static const size_t OFF_MINV   = 0;                       // 64*64 f32
static const size_t OFF_CM     = 16ull * 1024;
static const size_t OFF_AU     = 32ull * 1024;
static const size_t OFF_BUE    = 32ull * 1024 + 256;
static const size_t OFF_AP     = 32ull * 1024 + 512;
static const size_t OFF_APBE   = 32ull * 1024 + 768;
static const size_t OFF_AM     = 36ull * 1024;
static const size_t OFF_BM     = 37ull * 1024;
static const size_t OFF_AF     = 38ull * 1024;
static const size_t OFF_BF     = 39ull * 1024;
static const size_t OFF_BS     = 40ull * 1024;
static const size_t OFF_WUT    = 64ull * 1024;            // 64*256 bf16
static const size_t OFF_WMT    = 128ull * 1024;           // 256*64 bf16
static const size_t OFF_WFT    = 192ull * 1024;           // 256*512 bf16
static const size_t OFF_WPH    = 512ull * 1024;
static const size_t OFF_WPL    = 576ull * 1024;
static const size_t OFF_PART1  = 1ull  * 1024 * 1024;     // [mtiles][256] f32 (800KB max)
static const size_t OFF_PART2  = 2ull  * 1024 * 1024;
static const size_t OFF_ROWPTR = 3ull  * 1024 * 1024;     // (N+1) int
static const size_t OFF_COUNT  = 3ull  * 1024 * 1024 + 512 * 1024;
static const size_t OFF_CURSOR = 4ull  * 1024 * 1024;
static const size_t OFF_LOGITS = 5ull  * 1024 * 1024;     // E f32 edge-order; later HB bf16 N*64
static const size_t OFF_JL     = 18ull * 1024 * 1024;     // E uint2 (25.6MB); later RAWO bf16 N*256 (18..69.2MB)
static const size_t OFF_U      = 44ull * 1024 * 1024;     // UBRAW bf16 N*64
static const size_t OFF_UN     = 57ull * 1024 * 1024;     // UN bf16 N*64
static const size_t OFF_P      = 70ull * 1024 * 1024;     // P f32 N*64
static const size_t OFF_AGG    = 96ull * 1024 * 1024;     // PS f16 early, then AGG f32
static const size_t OFF_H2     = 122ull * 1024 * 1024;    // H2 bf16 N*256

// ---------- K0: C = c^T c, Minv = (I+C)^-1, CM = C @ Minv ----------
__global__ __launch_bounds__(256) void k_prep(const float* __restrict__ c,
                                              float* __restrict__ minv_out,
                                              float* __restrict__ cm_out) {
  __shared__ float sm[12288];
  float* CC  = sm;
  float* aug = sm + 4096;
  float* cl  = sm + 8192;
  int t = threadIdx.x;
  for (int idx = t; idx < 4096; idx += 256) cl[idx] = c[idx];
  __syncthreads();
  for (int idx = t; idx < 4096; idx += 256) {
    int a = idx >> 6, b = idx & 63;
    float s = 0.f;
    for (int k = 0; k < 64; ++k) s += cl[k * 64 + a] * cl[k * 64 + b];
    CC[idx] = s;
  }
  __syncthreads();
  for (int idx = t; idx < 8192; idx += 256) {
    int r = idx >> 7, cc = idx & 127;
    float v;
    if (cc < 64) v = CC[r * 64 + cc] + (r == cc ? 1.f : 0.f);
    else         v = ((cc - 64) == r) ? 1.f : 0.f;
    aug[idx] = v;
  }
  __syncthreads();
  for (int p = 0; p < 64; ++p) {
    float inv = 1.0f / aug[p * 128 + p];
    __syncthreads();
    for (int cc = t; cc < 128; cc += 256) aug[p * 128 + cc] *= inv;
    __syncthreads();
    int r  = t >> 2;
    int c0 = (t & 3) * 32;
    float f = aug[r * 128 + p];
    __syncthreads();
    if (r != p) {
      for (int cc = c0; cc < c0 + 32; ++cc) aug[r * 128 + cc] -= f * aug[p * 128 + cc];
    }
    __syncthreads();
  }
  for (int idx = t; idx < 4096; idx += 256) {
    int r = idx >> 6, cc = idx & 63;
    minv_out[idx] = aug[r * 128 + 64 + cc];
  }
  __syncthreads();
  for (int idx = t; idx < 4096; idx += 256) {
    int a = idx >> 6, b = idx & 63;
    float s = 0.f;
    for (int k = 0; k < 64; ++k) s += CC[a * 64 + k] * aug[k * 128 + 64 + b];
    cm_out[idx] = s;
  }
}

// ---------- transpose + convert weights: f32 [Kd][Nc] -> bf16 [Nc][Kd] ----------
__global__ __launch_bounds__(256) void k_tcvt(const float* __restrict__ in, u16* __restrict__ outb,
                                              int Kd, int Nc) {
  int i = blockIdx.x * 256 + threadIdx.x;
  if (i < Kd * Nc) {
    int k = i / Nc, n = i - k * Nc;
    outb[(size_t)n * Kd + k] = f2bf(in[i]);
  }
}

// ---------- transpose + hi/lo split ----------
__global__ __launch_bounds__(256) void k_tcvt_split(const float* __restrict__ in,
                                                    u16* __restrict__ outh, u16* __restrict__ outl) {
  int i = blockIdx.x * 256 + threadIdx.x;
  if (i < 256 * 64) {
    int k = i >> 6, n = i & 63;
    float v = in[i];
    u16 h = f2bf(v);
    float lo = v - bf2f(h);
    outh[(size_t)n * 256 + k] = h;
    outl[(size_t)n * 256 + k] = f2bf(lo);
  }
}

// ---------- MFMA GEMM with optional fused column-stats ----------
// AMODE 0: A bf16. AMODE 1: fused [leaky(am*h2+bm)|y]. AMODE 2: A f32 cvt in staging.
// OBF: 0 f32 out, 1 bf16 out. STATS: per-block col partial sums -> p1/p2[bx*ncTot + n0 + c].
template<int BN, int AMODE, int OBF, int STATS>
__global__ __launch_bounds__(256) void k_mfma(const u16* __restrict__ Abf, const float* __restrict__ Af32,
                                              int ldA, int K, int M,
                                              const u16* __restrict__ h2, const float* __restrict__ yy,
                                              const float* __restrict__ am, const float* __restrict__ bm,
                                              const u16* __restrict__ Bt,
                                              float* __restrict__ Cf, u16* __restrict__ Cb, int ldC,
                                              int ncTot, float* __restrict__ p1, float* __restrict__ p2) {
  constexpr int WN  = BN / 2;
  constexpr int FN  = WN / 16;
  constexpr int NPB = BN / 32;
  __shared__ u16 lds[2][(128 + BN) * 64];

  int t = threadIdx.x;
  int wid = t >> 6, lane = t & 63;
  int wr = wid >> 1, wc = wid & 1;
  int lr = lane & 15, lk = lane >> 4;
  int m0 = blockIdx.x * 128;
  int n0 = blockIdx.y * BN;
  int nK = K >> 6;

  int sidx = t;
  u16x8 ra[4];
  u16x8 rb[NPB];

  f32x4 acc[4][FN];
#pragma unroll
  for (int m = 0; m < 4; ++m)
#pragma unroll
    for (int n = 0; n < FN; ++n) acc[m][n] = (f32x4){0.f, 0.f, 0.f, 0.f};

  auto loadTile = [&](int kk) {
    int kk0 = kk * 64;
#pragma unroll
    for (int p = 0; p < 4; ++p) {
      int idx = p * 256 + sidx;
      int r = idx >> 3, c8 = idx & 7;
      int row = m0 + r; if (row >= M) row = M - 1;
      int k = kk0 + c8 * 8;
      if constexpr (AMODE == 0) {
        ra[p] = *(const u16x8*)(Abf + (size_t)row * ldA + k);
      } else if constexpr (AMODE == 2) {
        const float* src = Af32 + (size_t)row * ldA + k;
        float4 a = *(const float4*)src;
        float4 b = *(const float4*)(src + 4);
        u16x8 o;
        o[0] = f2bf(a.x); o[1] = f2bf(a.y); o[2] = f2bf(a.z); o[3] = f2bf(a.w);
        o[4] = f2bf(b.x); o[5] = f2bf(b.y); o[6] = f2bf(b.z); o[7] = f2bf(b.w);
        ra[p] = o;
      } else {
        if (kk0 < 256) {
          u16x8 h8 = *(const u16x8*)(h2 + (size_t)row * 256 + k);
          float av[8], bv[8];
          *(float4*)(av)     = *(const float4*)(am + k);
          *(float4*)(av + 4) = *(const float4*)(am + k + 4);
          *(float4*)(bv)     = *(const float4*)(bm + k);
          *(float4*)(bv + 4) = *(const float4*)(bm + k + 4);
          u16x8 o;
#pragma unroll
          for (int j = 0; j < 8; ++j) {
            float v = bf2f((u16)h8[j]) * av[j] + bv[j];
            v = v > 0.f ? v : 0.01f * v;
            o[j] = f2bf(v);
          }
          ra[p] = o;
        } else {
          float yv[8];
          *(float4*)(yv)     = *(const float4*)(yy + (size_t)row * 256 + (k - 256));
          *(float4*)(yv + 4) = *(const float4*)(yy + (size_t)row * 256 + (k - 256) + 4);
          u16x8 o;
#pragma unroll
          for (int j = 0; j < 8; ++j) o[j] = f2bf(yv[j]);
          ra[p] = o;
        }
      }
    }
#pragma unroll
    for (int p = 0; p < NPB; ++p) {
      int idx = p * 256 + sidx;
      int r = idx >> 3, c8 = idx & 7;
      rb[p] = *(const u16x8*)(Bt + (size_t)(n0 + r) * K + kk0 + c8 * 8);
    }
  };

  auto dswrite = [&](int b) {
    char* As  = (char*)&lds[b][0];
    char* Bsc = As + 128 * 64 * 2;
#pragma unroll
    for (int p = 0; p < 4; ++p) {
      int idx = p * 256 + sidx;
      int r = idx >> 3, c8 = idx & 7;
      *(u16x8*)(As + r * 128 + ((c8 * 16) ^ ((r & 7) << 4))) = ra[p];
    }
#pragma unroll
    for (int p = 0; p < NPB; ++p) {
      int idx = p * 256 + sidx;
      int r = idx >> 3, c8 = idx & 7;
      *(u16x8*)(Bsc + r * 128 + ((c8 * 16) ^ ((r & 7) << 4))) = rb[p];
    }
  };

  auto compute = [&](int b) {
    const char* As  = (const char*)&lds[b][0];
    const char* Bsc = As + 128 * 64 * 2;
#pragma unroll
    for (int ks = 0; ks < 2; ++ks) {
      int kb = ks * 64 + lk * 16;
      s16x8 af[4], bfr[FN];
#pragma unroll
      for (int m = 0; m < 4; ++m) {
        int row = wr * 64 + m * 16 + lr;
        af[m] = *(const s16x8*)(As + row * 128 + (kb ^ ((row & 7) << 4)));
      }
#pragma unroll
      for (int n = 0; n < FN; ++n) {
        int row = wc * WN + n * 16 + lr;
        bfr[n] = *(const s16x8*)(Bsc + row * 128 + (kb ^ ((row & 7) << 4)));
      }
#pragma unroll
      for (int m = 0; m < 4; ++m)
#pragma unroll
        for (int n = 0; n < FN; ++n)
          acc[m][n] = __builtin_amdgcn_mfma_f32_16x16x32_bf16(af[m], bfr[n], acc[m][n], 0, 0, 0);
    }
  };

  loadTile(0);
  dswrite(0);
  __syncthreads();
  for (int kk = 0; kk < nK; ++kk) {
    int b = kk & 1;
    if (kk + 1 < nK) loadTile(kk + 1);
    compute(b);
    if (kk + 1 < nK) { dswrite(b ^ 1); __syncthreads(); }
  }

#pragma unroll
  for (int m = 0; m < 4; ++m) {
#pragma unroll
    for (int n = 0; n < FN; ++n) {
      int col = n0 + wc * WN + n * 16 + lr;
#pragma unroll
      for (int q = 0; q < 4; ++q) {
        int row = m0 + wr * 64 + m * 16 + lk * 4 + q;
        if (row < M) {
          if constexpr (OBF) Cb[(size_t)row * ldC + col] = f2bf(acc[m][n][q]);
          else               Cf[(size_t)row * ldC + col] = acc[m][n][q];
        }
      }
    }
  }

  if constexpr (STATS) {
    __syncthreads();                 // all LDS reads done; reuse as stats buffer
    float* sb = (float*)&lds[0][0];  // [2][BN][2]
#pragma unroll
    for (int n = 0; n < FN; ++n) {
      float s1 = 0.f, s2 = 0.f;
#pragma unroll
      for (int m = 0; m < 4; ++m)
#pragma unroll
        for (int q = 0; q < 4; ++q) {
          int row = m0 + wr * 64 + m * 16 + lk * 4 + q;
          float v = (row < M) ? acc[m][n][q] : 0.f;
          s1 += v; s2 += v * v;
        }
      s1 += __shfl_xor(s1, 16); s2 += __shfl_xor(s2, 16);
      s1 += __shfl_xor(s1, 32); s2 += __shfl_xor(s2, 32);
      if (lk == 0) {
        int c = wc * WN + n * 16 + lr;
        sb[(wr * BN + c) * 2 + 0] = s1;
        sb[(wr * BN + c) * 2 + 1] = s2;
      }
    }
    __syncthreads();
    if (t < BN) {
      float s1 = sb[t * 2]     + sb[(BN + t) * 2];
      float s2 = sb[t * 2 + 1] + sb[(BN + t) * 2 + 1];
      p1[(size_t)blockIdx.x * ncTot + n0 + t] = s1;
      p2[(size_t)blockIdx.x * ncTot + n0 + t] = s2;
    }
  }
}

// ---------- split-bf16 MFMA (f32 accuracy) with fused stats ----------
__global__ __launch_bounds__(256) void k_mfma_split(const float* __restrict__ Af, int K, int M,
                                                    const u16* __restrict__ Bh, const u16* __restrict__ Bl,
                                                    float* __restrict__ Cf,
                                                    float* __restrict__ p1, float* __restrict__ p2) {
  __shared__ u16 sAh[128 * 64], sAl[128 * 64], sBh[64 * 64], sBl[64 * 64];
  int t = threadIdx.x;
  int wid = t >> 6, lane = t & 63;
  int wr = wid >> 1, wc = wid & 1;
  int lr = lane & 15, lk = lane >> 4;
  int m0 = blockIdx.x * 128;
  int nK = K >> 6;

  u16x8 rah[4], ral[4], rbh[2], rbl[2];
  f32x4 acc[4][2];
#pragma unroll
  for (int m = 0; m < 4; ++m)
#pragma unroll
    for (int n = 0; n < 2; ++n) acc[m][n] = (f32x4){0.f, 0.f, 0.f, 0.f};

  auto loadTile = [&](int kk) {
    int kk0 = kk * 64;
#pragma unroll
    for (int p = 0; p < 4; ++p) {
      int idx = p * 256 + t;
      int r = idx >> 3, c8 = idx & 7;
      int row = m0 + r; if (row >= M) row = M - 1;
      const float* src = Af + (size_t)row * K + kk0 + c8 * 8;
      float4 a = *(const float4*)src;
      float4 b = *(const float4*)(src + 4);
      float v[8];
      *(float4*)(v) = a; *(float4*)(v + 4) = b;
      u16x8 oh, ol;
#pragma unroll
      for (int j = 0; j < 8; ++j) {
        u16 h = f2bf(v[j]);
        oh[j] = h;
        ol[j] = f2bf(v[j] - bf2f(h));
      }
      rah[p] = oh; ral[p] = ol;
    }
#pragma unroll
    for (int p = 0; p < 2; ++p) {
      int idx = p * 256 + t;
      int r = idx >> 3, c8 = idx & 7;
      rbh[p] = *(const u16x8*)(Bh + (size_t)r * K + kk0 + c8 * 8);
      rbl[p] = *(const u16x8*)(Bl + (size_t)r * K + kk0 + c8 * 8);
    }
  };

  auto dswrite = [&]() {
    char* Ah = (char*)sAh; char* Al = (char*)sAl;
    char* Bhc = (char*)sBh; char* Blc = (char*)sBl;
#pragma unroll
    for (int p = 0; p < 4; ++p) {
      int idx = p * 256 + t;
      int r = idx >> 3, c8 = idx & 7;
      int off = r * 128 + ((c8 * 16) ^ ((r & 7) << 4));
      *(u16x8*)(Ah + off) = rah[p];
      *(u16x8*)(Al + off) = ral[p];
    }
#pragma unroll
    for (int p = 0; p < 2; ++p) {
      int idx = p * 256 + t;
      int r = idx >> 3, c8 = idx & 7;
      int off = r * 128 + ((c8 * 16) ^ ((r & 7) << 4));
      *(u16x8*)(Bhc + off) = rbh[p];
      *(u16x8*)(Blc + off) = rbl[p];
    }
  };

  auto compute = [&]() {
    const char* Ah = (const char*)sAh; const char* Al = (const char*)sAl;
    const char* Bhc = (const char*)sBh; const char* Blc = (const char*)sBl;
#pragma unroll
    for (int ks = 0; ks < 2; ++ks) {
      int kb = ks * 64 + lk * 16;
      s16x8 fah[4], fal[4], fbh[2], fbl[2];
#pragma unroll
      for (int m = 0; m < 4; ++m) {
        int row = wr * 64 + m * 16 + lr;
        int off = row * 128 + (kb ^ ((row & 7) << 4));
        fah[m] = *(const s16x8*)(Ah + off);
        fal[m] = *(const s16x8*)(Al + off);
      }
#pragma unroll
      for (int n = 0; n < 2; ++n) {
        int row = wc * 32 + n * 16 + lr;
        int off = row * 128 + (kb ^ ((row & 7) << 4));
        fbh[n] = *(const s16x8*)(Bhc + off);
        fbl[n] = *(const s16x8*)(Blc + off);
      }
#pragma unroll
      for (int m = 0; m < 4; ++m)
#pragma unroll
        for (int n = 0; n < 2; ++n) {
          acc[m][n] = __builtin_amdgcn_mfma_f32_16x16x32_bf16(fah[m], fbh[n], acc[m][n], 0, 0, 0);
          acc[m][n] = __builtin_amdgcn_mfma_f32_16x16x32_bf16(fah[m], fbl[n], acc[m][n], 0, 0, 0);
          acc[m][n] = __builtin_amdgcn_mfma_f32_16x16x32_bf16(fal[m], fbh[n], acc[m][n], 0, 0, 0);
        }
    }
  };

  loadTile(0);
  for (int kk = 0; kk < nK; ++kk) {
    __syncthreads();
    dswrite();
    __syncthreads();
    if (kk + 1 < nK) loadTile(kk + 1);
    compute();
  }

#pragma unroll
  for (int m = 0; m < 4; ++m) {
#pragma unroll
    for (int n = 0; n < 2; ++n) {
      int col = wc * 32 + n * 16 + lr;
#pragma unroll
      for (int q = 0; q < 4; ++q) {
        int row = m0 + wr * 64 + m * 16 + lk * 4 + q;
        if (row < M) Cf[(size_t)row * 64 + col] = acc[m][n][q];
      }
    }
  }

  __syncthreads();
  float* sb = (float*)sAh;   // [2][64][2]
#pragma unroll
  for (int n = 0; n < 2; ++n) {
    float s1 = 0.f, s2 = 0.f;
#pragma unroll
    for (int m = 0; m < 4; ++m)
#pragma unroll
      for (int q = 0; q < 4; ++q) {
        int row = m0 + wr * 64 + m * 16 + lk * 4 + q;
        float v = (row < M) ? acc[m][n][q] : 0.f;
        s1 += v; s2 += v * v;
      }
    s1 += __shfl_xor(s1, 16); s2 += __shfl_xor(s2, 16);
    s1 += __shfl_xor(s1, 32); s2 += __shfl_xor(s2, 32);
    if (lk == 0) {
      int c = wc * 32 + n * 16 + lr;
      sb[(wr * 64 + c) * 2 + 0] = s1;
      sb[(wr * 64 + c) * 2 + 1] = s2;
    }
  }
  __syncthreads();
  if (t < 64) {
    float s1 = sb[t * 2]     + sb[(64 + t) * 2];
    float s2 = sb[t * 2 + 1] + sb[(64 + t) * 2 + 1];
    p1[(size_t)blockIdx.x * 64 + t] = s1;
    p2[(size_t)blockIdx.x * 64 + t] = s2;
  }
}

// ---------- reduce partials -> BN scale/shift ----------
__global__ __launch_bounds__(256) void k_reduce_fin(const float* __restrict__ part1,
                                                    const float* __restrict__ part2,
                                                    int nb, int C, float invN,
                                                    const float* __restrict__ gamma,
                                                    const float* __restrict__ beta,
                                                    float* __restrict__ a_out,
                                                    float* __restrict__ b_out) {
  int c = blockIdx.x;
  int t = threadIdx.x;
  float s1 = 0.f, s2 = 0.f;
  for (int b = t; b < nb; b += 256) {
    s1 += part1[(size_t)b * C + c];
    s2 += part2[(size_t)b * C + c];
  }
  for (int m = 32; m; m >>= 1) { s1 += __shfl_xor(s1, m); s2 += __shfl_xor(s2, m); }
  __shared__ float l1[4], l2[4];
  if ((t & 63) == 0) { l1[t >> 6] = s1; l2[t >> 6] = s2; }
  __syncthreads();
  if (t == 0) {
    s1 = l1[0] + l1[1] + l1[2] + l1[3];
    s2 = l2[0] + l2[1] + l2[2] + l2[3];
    float mu  = s1 * invN;
    float var = s2 * invN - mu * mu;
    float a = gamma[c] * rsqrtf(var + 1e-5f);
    a_out[c] = a;
    b_out[c] = beta[c] - mu * a;
  }
}

// ---------- UN = bf16(au*xu + bue) ----------
__global__ __launch_bounds__(256) void k_scaleUN(const u16* __restrict__ ub, const float* __restrict__ au,
                                                 const float* __restrict__ bue, u16* __restrict__ un, int n8) {
  for (int i = blockIdx.x * 256 + threadIdx.x; i < n8; i += gridDim.x * 256) {
    int c0 = (i & 7) * 8;
    float av[8], bv[8];
    *(float4*)(av) = *(const float4*)(au + c0);  *(float4*)(av + 4) = *(const float4*)(au + c0 + 4);
    *(float4*)(bv) = *(const float4*)(bue + c0); *(float4*)(bv + 4) = *(const float4*)(bue + c0 + 4);
    u16x8 in = ((const u16x8*)ub)[i];
    u16x8 o;
#pragma unroll
    for (int j = 0; j < 8; ++j) o[j] = f2bf(bf2f((u16)in[j]) * av[j] + bv[j]);
    ((u16x8*)un)[i] = o;
  }
}

// ---------- PS = f16(ap * su) ----------
__global__ __launch_bounds__(256) void k_scaleP(const float* __restrict__ P, const float* __restrict__ ap,
                                                __half* __restrict__ PS, int n8) {
  for (int i = blockIdx.x * 256 + threadIdx.x; i < n8; i += gridDim.x * 256) {
    int c0 = (i & 7) * 8;
    float4 s0 = *(const float4*)(ap + c0), s1 = *(const float4*)(ap + c0 + 4);
    float4 a = ((const float4*)P)[i * 2];
    float4 b = ((const float4*)P)[i * 2 + 1];
    __half2 o0 = __floats2half2_rn(a.x * s0.x, a.y * s0.y);
    __half2 o1 = __floats2half2_rn(a.z * s0.z, a.w * s0.w);
    __half2 o2 = __floats2half2_rn(b.x * s1.x, b.y * s1.y);
    __half2 o3 = __floats2half2_rn(b.z * s1.z, b.w * s1.w);
    uint4 out;
    out.x = *(unsigned*)&o0; out.y = *(unsigned*)&o1;
    out.z = *(unsigned*)&o2; out.w = *(unsigned*)&o3;
    ((uint4*)PS)[i] = out;
  }
}

// ---------- CSR scans ----------
__global__ __launch_bounds__(256) void k_scanA(const int* __restrict__ cnt, int N,
                                               int* __restrict__ rowptr, int* __restrict__ bs) {
  __shared__ int s[256];
  int t = threadIdx.x, gi = blockIdx.x * 256 + t;
  int v = (gi < N) ? cnt[gi] : 0;
  s[t] = v;
  __syncthreads();
  for (int off = 1; off < 256; off <<= 1) {
    int add = (t >= off) ? s[t - off] : 0;
    __syncthreads();
    s[t] += add;
    __syncthreads();
  }
  if (gi < N) rowptr[gi + 1] = s[t];
  if (t == 255) bs[blockIdx.x] = s[255];
}

__global__ __launch_bounds__(512) void k_scanB(int* __restrict__ bs, int nb) {
  __shared__ int s[512];
  int t = threadIdx.x;
  s[t] = (t < nb) ? bs[t] : 0;
  __syncthreads();
  for (int off = 1; off < 512; off <<= 1) {
    int add = (t >= off) ? s[t - off] : 0;
    __syncthreads();
    s[t] += add;
    __syncthreads();
  }
  if (t < nb) bs[t] = s[t];
}

__global__ __launch_bounds__(256) void k_scanC(int N, int* __restrict__ rowptr, const int* __restrict__ bs) {
  int gi = blockIdx.x * 256 + threadIdx.x;
  if (gi == 0) rowptr[0] = 0;
  if (gi < N && blockIdx.x > 0) rowptr[gi + 1] += bs[blockIdx.x - 1];
}

// ---------- edge-order logits + degree count (fused) ----------
__global__ __launch_bounds__(256) void k_logit(const __half* __restrict__ PS,
                                               const int* __restrict__ ei, const int* __restrict__ ej,
                                               int E, float* __restrict__ logitE, int* __restrict__ cnt) {
  int lane16 = threadIdx.x & 15;
  int gid = (blockIdx.x * 256 + threadIdx.x) >> 4;
  int ngroups = (gridDim.x * 256) >> 4;
  const uint2* P2 = (const uint2*)PS;
  for (int e = gid; e < E; e += ngroups) {
    int i = ei[e], j = ej[e];
    uint2 uu = P2[(size_t)i * 16 + lane16];
    uint2 vv = P2[(size_t)j * 16 + lane16];
    float2 u0 = __half22float2(*(const __half2*)&uu.x);
    float2 u1 = __half22float2(*(const __half2*)&uu.y);
    float2 v0 = __half22float2(*(const __half2*)&vv.x);
    float2 v1 = __half22float2(*(const __half2*)&vv.y);
    float d0 = u0.x - v0.x, d1 = u0.y - v0.y, d2 = u1.x - v1.x, d3 = u1.y - v1.y;
    float acc = d0 * d0 + d1 * d1 + d2 * d2 + d3 * d3;
    acc += __shfl_xor(acc, 1, 16);
    acc += __shfl_xor(acc, 2, 16);
    acc += __shfl_xor(acc, 4, 16);
    acc += __shfl_xor(acc, 8, 16);
    if (lane16 == 0) {
      logitE[e] = -acc;
      atomicAdd(&cnt[i], 1);
    }
  }
}

// ---------- bucket fill: packed {j, logit} 8B scatter ----------
__global__ void k_fill(const int* __restrict__ ei, const int* __restrict__ ej,
                       const float* __restrict__ lg, int E,
                       const int* __restrict__ rowptr, int* __restrict__ cursor,
                       uint2* __restrict__ JL) {
  for (int e = blockIdx.x * blockDim.x + threadIdx.x; e < E; e += gridDim.x * blockDim.x) {
    int i = ei[e];
    int pos = atomicAdd(&cursor[i], 1);
    uint2 v;
    v.x = (unsigned)ej[e];
    v.y = __float_as_uint(lg[e]);
    JL[rowptr[i] + pos] = v;
  }
}

// ---------- per-node softmax + aggregation ----------
__global__ __launch_bounds__(256) void k_node(const uint2* __restrict__ JL,
                                              const int* __restrict__ rowptr, const u16* __restrict__ UN,
                                              int N, float* __restrict__ agg) {
  int lane = threadIdx.x & 63;
  int node = blockIdx.x * 4 + (threadIdx.x >> 6);
  if (node >= N) return;
  int b0 = rowptr[node], b1 = rowptr[node + 1];
  int deg = b1 - b0;
  float acc = 0.f;
  if (deg > 0) {
    int cnt = deg < 64 ? deg : 64;
    int jj = 0; float lg = -INFINITY;
    if (lane < cnt) {
      uint2 v = JL[b0 + lane];
      jj = (int)v.x;
      lg = __uint_as_float(v.y);
    }
    float mx = lg;
    for (int s = b0 + 64 + lane; s < b1; s += 64) mx = fmaxf(mx, __uint_as_float(JL[s].y));
    for (int m = 32; m; m >>= 1) mx = fmaxf(mx, __shfl_xor(mx, m));
    float ex = (lane < cnt) ? __expf(lg - mx) : 0.f;
    float sm = ex;
    for (int s = b0 + 64 + lane; s < b1; s += 64) sm += __expf(__uint_as_float(JL[s].y) - mx);
    for (int m = 32; m; m >>= 1) sm += __shfl_xor(sm, m);
    float inv = 1.0f / (sm + 1e-16f);
    float w = ex * inv;
    int ss = 0;
    for (; ss + 4 <= cnt; ss += 4) {
      int   j0 = __shfl(jj, ss),     j1 = __shfl(jj, ss + 1);
      int   j2 = __shfl(jj, ss + 2), j3 = __shfl(jj, ss + 3);
      float w0 = __shfl(w, ss),      w1 = __shfl(w, ss + 1);
      float w2 = __shfl(w, ss + 2),  w3 = __shfl(w, ss + 3);
      float v0 = bf2f(UN[(size_t)j0 * 64 + lane]);
      float v1 = bf2f(UN[(size_t)j1 * 64 + lane]);
      float v2 = bf2f(UN[(size_t)j2 * 64 + lane]);
      float v3 = bf2f(UN[(size_t)j3 * 64 + lane]);
      acc += w0 * v0 + w1 * v1 + w2 * v2 + w3 * v3;
    }
    for (; ss < cnt; ++ss) {
      int j0 = __shfl(jj, ss);
      float w0 = __shfl(w, ss);
      acc += w0 * bf2f(UN[(size_t)j0 * 64 + lane]);
    }
    for (int s = b0 + 64; s < b1; ++s) {   // rare deg>64 tail
      uint2 v = JL[s];
      acc += __expf(__uint_as_float(v.y) - mx) * inv * bf2f(UN[(size_t)(int)v.x * 64 + lane]);
    }
  }
  agg[(size_t)node * 64 + lane] = acc;
}

// ---------- h = (z + agg@C) @ Minv, z = UN (bf16), out bf16 ----------
__global__ __launch_bounds__(256) void k_solve(const u16* __restrict__ UN, const float* __restrict__ agg,
                                               const float* __restrict__ minv, const float* __restrict__ cmw,
                                               u16* __restrict__ HB, int ntiles) {
  __shared__ float mS[4096];
  __shared__ float cS[4096];
  int t = threadIdx.x;
  int c16 = t & 15, rg = t >> 4;
  for (int idx = t; idx < 1024; idx += 256) {
    ((float4*)mS)[idx] = ((const float4*)minv)[idx];
    ((float4*)cS)[idx] = ((const float4*)cmw)[idx];
  }
  __syncthreads();
  for (int tile = blockIdx.x; tile < ntiles; tile += gridDim.x) {
    int row = tile * 16 + rg;
    const u16*  ur = UN + (size_t)row * 64;
    const float* gr = agg + (size_t)row * 64;
    float4 acc = make_float4(0.f, 0.f, 0.f, 0.f);
#pragma unroll 4
    for (int k = 0; k < 64; ++k) {
      float z = bf2f(ur[k]);
      float g = gr[k];
      float4 m4 = ((const float4*)mS)[k * 16 + c16];
      float4 c4 = ((const float4*)cS)[k * 16 + c16];
      acc.x += z * m4.x + g * c4.x;
      acc.y += z * m4.y + g * c4.y;
      acc.z += z * m4.z + g * c4.z;
      acc.w += z * m4.w + g * c4.w;
    }
    ((ushort4*)HB)[(size_t)row * 16 + c16] =
        make_ushort4(f2bf(acc.x), f2bf(acc.y), f2bf(acc.z), f2bf(acc.w));
  }
}

// ---------- final BN + leaky: bf16 raw -> f32 out ----------
__global__ __launch_bounds__(256) void k_bnact16(const u16* __restrict__ raw, const float* __restrict__ af,
                                                 const float* __restrict__ bfp, float* __restrict__ out, int n8) {
  int i = blockIdx.x * 256 + threadIdx.x;
  int stride = gridDim.x * 256;
  for (; i < n8; i += stride) {
    int c0 = (i & 31) * 8;
    float av[8], bv[8];
    *(float4*)(av) = *(const float4*)(af + c0);  *(float4*)(av + 4) = *(const float4*)(af + c0 + 4);
    *(float4*)(bv) = *(const float4*)(bfp + c0); *(float4*)(bv + 4) = *(const float4*)(bfp + c0 + 4);
    u16x8 r = ((const u16x8*)raw)[i];
    float o[8];
#pragma unroll
    for (int j = 0; j < 8; ++j) {
      float v = bf2f((u16)r[j]) * av[j] + bv[j];
      o[j] = (v > 0.f) ? v : 0.01f * v;
    }
    ((float4*)out)[i * 2]     = *(float4*)(o);
    ((float4*)out)[i * 2 + 1] = *(float4*)(o + 4);
  }
}

extern "C" void kernel_launch(void* const* d_in, const int* in_sizes, int n_in,
                              void* d_out, int out_size, void* d_ws, size_t ws_size,
                              hipStream_t stream) {
  const float* x    = (const float*)d_in[0];
  const float* y    = (const float*)d_in[1];
  const int*   eidx = (const int*)d_in[3];
  const float* Wu   = (const float*)d_in[4];
  const float* gu   = (const float*)d_in[5];
  const float* bu   = (const float*)d_in[6];
  const float* Wp   = (const float*)d_in[7];
  const float* gp   = (const float*)d_in[8];
  const float* bp   = (const float*)d_in[9];
  const float* cIn  = (const float*)d_in[10];
  const float* Wm   = (const float*)d_in[11];
  const float* gm   = (const float*)d_in[12];
  const float* bm   = (const float*)d_in[13];
  const float* Wf   = (const float*)d_in[14];
  const float* gf   = (const float*)d_in[15];
  const float* bfv  = (const float*)d_in[16];

  const int N = in_sizes[0] / 256;
  const int E = in_sizes[3] / 2;
  const int* ei = eidx;
  const int* ej = eidx + E;

  char* ws = (char*)d_ws;
  float* MINV  = (float*)(ws + OFF_MINV);
  float* CMW   = (float*)(ws + OFF_CM);
  float* AU    = (float*)(ws + OFF_AU);
  float* BUE   = (float*)(ws + OFF_BUE);
  float* AP    = (float*)(ws + OFF_AP);
  float* APBE  = (float*)(ws + OFF_APBE);
  float* AM    = (float*)(ws + OFF_AM);
  float* BM    = (float*)(ws + OFF_BM);
  float* AF    = (float*)(ws + OFF_AF);
  float* BF    = (float*)(ws + OFF_BF);
  int*   BSC   = (int*)(ws + OFF_BS);
  u16*   WUT   = (u16*)(ws + OFF_WUT);
  u16*   WMT   = (u16*)(ws + OFF_WMT);
  u16*   WFT   = (u16*)(ws + OFF_WFT);
  u16*   WPH   = (u16*)(ws + OFF_WPH);
  u16*   WPL   = (u16*)(ws + OFF_WPL);
  float* PART1 = (float*)(ws + OFF_PART1);
  float* PART2 = (float*)(ws + OFF_PART2);
  int*   ROWPTR= (int*)(ws + OFF_ROWPTR);
  int*   COUNT = (int*)(ws + OFF_COUNT);
  int*   CURSOR= (int*)(ws + OFF_CURSOR);
  float* LOGITE= (float*)(ws + OFF_LOGITS);
  u16*   HB    = (u16*)(ws + OFF_LOGITS);    // reuse (logits dead after k_fill)
  uint2* JL    = (uint2*)(ws + OFF_JL);
  u16*   RAWO  = (u16*)(ws + OFF_JL);        // reuse JL+U+UN span (dead after k_solve)
  u16*   UBRAW = (u16*)(ws + OFF_U);
  u16*   UN    = (u16*)(ws + OFF_UN);
  float* P     = (float*)(ws + OFF_P);
  __half* PS   = (__half*)(ws + OFF_AGG);    // PS dead after k_logit; AGG overwrites
  float* AGG   = (float*)(ws + OFF_AGG);
  u16*   H2    = (u16*)(ws + OFF_H2);

  const float invN = 1.0f / (float)N;
  const int ntiles16 = N / 16;
  const int nbScan   = (N + 255) / 256;
  const int mtiles   = (N + 127) / 128;
  const int n8_64    = N * 64 / 8;
  const int n8_256   = N * 256 / 8;

  hipMemsetAsync(COUNT, 0, (size_t)N * 4, stream);
  hipMemsetAsync(CURSOR, 0, (size_t)N * 4, stream);

  k_prep<<<1, 256, 0, stream>>>(cIn, MINV, CMW);
  k_tcvt<<<64,  256, 0, stream>>>(Wu, WUT, 256, 64);
  k_tcvt<<<64,  256, 0, stream>>>(Wm, WMT, 64, 256);
  k_tcvt<<<512, 256, 0, stream>>>(Wf, WFT, 512, 256);
  k_tcvt_split<<<64, 256, 0, stream>>>(Wp, WPH, WPL);

  // unary embedding (stats fused) -> UBRAW bf16; BN params; UN table
  k_mfma<64, 2, 1, 1><<<dim3(mtiles, 1), 256, 0, stream>>>(
      nullptr, x, 256, 256, N, nullptr, nullptr, nullptr, nullptr, WUT,
      nullptr, UBRAW, 64, 64, PART1, PART2);
  k_reduce_fin<<<64, 256, 0, stream>>>(PART1, PART2, mtiles, 64, invN, gu, bu, AU, BUE);
  k_scaleUN<<<1024, 256, 0, stream>>>(UBRAW, AU, BUE, UN, n8_64);

  // pairwise embedding: split-bf16 MFMA (stats fused) -> P f32; PS f16 table
  k_mfma_split<<<mtiles, 256, 0, stream>>>(y, 256, N, WPH, WPL, P, PART1, PART2);
  k_reduce_fin<<<64, 256, 0, stream>>>(PART1, PART2, mtiles, 64, invN, gp, bp, AP, APBE);
  k_scaleP<<<1024, 256, 0, stream>>>(P, AP, PS, n8_64);

  // edge-order logits + degree counts (fused), then CSR scans + packed fill
  k_logit<<<4096, 256, 0, stream>>>(PS, ei, ej, E, LOGITE, COUNT);
  k_scanA<<<nbScan, 256, 0, stream>>>(COUNT, N, ROWPTR, BSC);
  k_scanB<<<1, 512, 0, stream>>>(BSC, nbScan);
  k_scanC<<<nbScan, 256, 0, stream>>>(N, ROWPTR, BSC);
  k_fill<<<2048, 256, 0, stream>>>(ei, ej, LOGITE, E, ROWPTR, CURSOR, JL);

  // per-node softmax + aggregation
  k_node<<<(N + 3) / 4, 256, 0, stream>>>(JL, ROWPTR, UN, N, AGG);

  // CRF solve -> h bf16 (HB overwrites logit region)
  k_solve<<<2048, 256, 0, stream>>>(UN, AGG, MINV, CMW, HB, ntiles16);

  // h @ Wm -> h2 bf16 (stats fused)
  k_mfma<128, 0, 1, 1><<<dim3(mtiles, 2), 256, 0, stream>>>(
      HB, nullptr, 64, 64, N, nullptr, nullptr, nullptr, nullptr, WMT,
      nullptr, H2, 256, 256, PART1, PART2);
  k_reduce_fin<<<256, 256, 0, stream>>>(PART1, PART2, mtiles, 256, invN, gm, bm, AM, BM);

  // [leaky(bn(h2)), y] @ Wf -> raw bf16 (stats fused), then BN + leaky -> d_out f32
  k_mfma<128, 1, 1, 1><<<dim3(mtiles, 2), 256, 0, stream>>>(
      nullptr, nullptr, 0, 512, N, H2, y, AM, BM, WFT,
      nullptr, RAWO, 256, 256, PART1, PART2);
  k_reduce_fin<<<256, 256, 0, stream>>>(PART1, PART2, mtiles, 256, invN, gf, bfv, AF, BF);
  k_bnact16<<<2048, 256, 0, stream>>>(RAWO, AF, BF, (float*)d_out, n8_256);
}

// Round 6
// 881.910 us; speedup vs baseline: 3.2197x; 1.0556x over previous
//
#include <hip/hip_runtime.h>
#include <hip/hip_fp16.h>
#include <math.h>

typedef unsigned short u16;
typedef short s16x8 __attribute__((ext_vector_type(8)));
typedef unsigned short u16x8 __attribute__((ext_vector_type(8)));
typedef float f32x4 __attribute__((ext_vector_type(4)));

// ---------- helpers ----------
__device__ __forceinline__ float bf2f(u16 u) {
  unsigned x = ((unsigned)u) << 16;
  return __uint_as_float(x);
}
__device__ __forceinline__ u16 f2bf(float f) {
  unsigned x = __float_as_uint(f);
  unsigned r = x + 0x7FFFu + ((x >> 16) & 1u);
  return (u16)(r >> 16);
}

// ---------- ws layout (bytes) ----------
// 0..0.5MB   : small params (MINV/CM/BN vectors/scan sums)
// 0.5..1MB   : WPH/WPL
// 1..3MB     : PART1/PART2
// 3..5MB     : ROWPTR, COUNT
// 5..17.8MB  : RANK (E int)          -> after k_fill dead -> HB bf16 N*64
// 18..30.8MB : SRCJ (E int)          -> after k_nodeall dead -> RAWO bf16 N*256 (18..69.2MB)
// 44..56.8MB : UBRAW bf16 N*64
// 57..69.8MB : UN bf16 N*64          (dead after k_solve; RAWO overlap OK)
// 70..95.6MB : P f32 N*64            -> after k_scaleP dead -> AGG f32 N*64
// 109..121.8 : PS f16 N*64           (dead after k_nodeall)
// 122..173.2 : H2 bf16 N*256
static const size_t OFF_MINV   = 0;
static const size_t OFF_CM     = 16ull * 1024;
static const size_t OFF_AU     = 32ull * 1024;
static const size_t OFF_BUE    = 32ull * 1024 + 256;
static const size_t OFF_AP     = 32ull * 1024 + 512;
static const size_t OFF_APBE   = 32ull * 1024 + 768;
static const size_t OFF_AM     = 36ull * 1024;
static const size_t OFF_BM     = 37ull * 1024;
static const size_t OFF_AF     = 38ull * 1024;
static const size_t OFF_BF     = 39ull * 1024;
static const size_t OFF_BS     = 40ull * 1024;
static const size_t OFF_WUT    = 64ull * 1024;
static const size_t OFF_WMT    = 128ull * 1024;
static const size_t OFF_WFT    = 192ull * 1024;
static const size_t OFF_WPH    = 512ull * 1024;
static const size_t OFF_WPL    = 576ull * 1024;
static const size_t OFF_PART1  = 1ull  * 1024 * 1024;
static const size_t OFF_PART2  = 2ull  * 1024 * 1024;
static const size_t OFF_ROWPTR = 3ull  * 1024 * 1024;
static const size_t OFF_COUNT  = 3ull  * 1024 * 1024 + 512 * 1024;
static const size_t OFF_RANK   = 5ull  * 1024 * 1024;
static const size_t OFF_SRCJ   = 18ull * 1024 * 1024;
static const size_t OFF_U      = 44ull * 1024 * 1024;
static const size_t OFF_UN     = 57ull * 1024 * 1024;
static const size_t OFF_P      = 70ull * 1024 * 1024;     // P f32 early; AGG f32 after k_scaleP
static const size_t OFF_PS     = 109ull * 1024 * 1024;
static const size_t OFF_H2     = 122ull * 1024 * 1024;

// ---------- K0: C = c^T c, Minv = (I+C)^-1, CM = C @ Minv ----------
__global__ __launch_bounds__(256) void k_prep(const float* __restrict__ c,
                                              float* __restrict__ minv_out,
                                              float* __restrict__ cm_out) {
  __shared__ float sm[12288];
  float* CC  = sm;
  float* aug = sm + 4096;
  float* cl  = sm + 8192;
  int t = threadIdx.x;
  for (int idx = t; idx < 4096; idx += 256) cl[idx] = c[idx];
  __syncthreads();
  for (int idx = t; idx < 4096; idx += 256) {
    int a = idx >> 6, b = idx & 63;
    float s = 0.f;
    for (int k = 0; k < 64; ++k) s += cl[k * 64 + a] * cl[k * 64 + b];
    CC[idx] = s;
  }
  __syncthreads();
  for (int idx = t; idx < 8192; idx += 256) {
    int r = idx >> 7, cc = idx & 127;
    float v;
    if (cc < 64) v = CC[r * 64 + cc] + (r == cc ? 1.f : 0.f);
    else         v = ((cc - 64) == r) ? 1.f : 0.f;
    aug[idx] = v;
  }
  __syncthreads();
  for (int p = 0; p < 64; ++p) {
    float inv = 1.0f / aug[p * 128 + p];
    __syncthreads();
    for (int cc = t; cc < 128; cc += 256) aug[p * 128 + cc] *= inv;
    __syncthreads();
    int r  = t >> 2;
    int c0 = (t & 3) * 32;
    float f = aug[r * 128 + p];
    __syncthreads();
    if (r != p) {
      for (int cc = c0; cc < c0 + 32; ++cc) aug[r * 128 + cc] -= f * aug[p * 128 + cc];
    }
    __syncthreads();
  }
  for (int idx = t; idx < 4096; idx += 256) {
    int r = idx >> 6, cc = idx & 63;
    minv_out[idx] = aug[r * 128 + 64 + cc];
  }
  __syncthreads();
  for (int idx = t; idx < 4096; idx += 256) {
    int a = idx >> 6, b = idx & 63;
    float s = 0.f;
    for (int k = 0; k < 64; ++k) s += CC[a * 64 + k] * aug[k * 128 + 64 + b];
    cm_out[idx] = s;
  }
}

// ---------- transpose + convert weights ----------
__global__ __launch_bounds__(256) void k_tcvt(const float* __restrict__ in, u16* __restrict__ outb,
                                              int Kd, int Nc) {
  int i = blockIdx.x * 256 + threadIdx.x;
  if (i < Kd * Nc) {
    int k = i / Nc, n = i - k * Nc;
    outb[(size_t)n * Kd + k] = f2bf(in[i]);
  }
}

__global__ __launch_bounds__(256) void k_tcvt_split(const float* __restrict__ in,
                                                    u16* __restrict__ outh, u16* __restrict__ outl) {
  int i = blockIdx.x * 256 + threadIdx.x;
  if (i < 256 * 64) {
    int k = i >> 6, n = i & 63;
    float v = in[i];
    u16 h = f2bf(v);
    float lo = v - bf2f(h);
    outh[(size_t)n * 256 + k] = h;
    outl[(size_t)n * 256 + k] = f2bf(lo);
  }
}

// ---------- MFMA GEMM with optional fused column-stats ----------
template<int BN, int AMODE, int OBF, int STATS>
__global__ __launch_bounds__(256) void k_mfma(const u16* __restrict__ Abf, const float* __restrict__ Af32,
                                              int ldA, int K, int M,
                                              const u16* __restrict__ h2, const float* __restrict__ yy,
                                              const float* __restrict__ am, const float* __restrict__ bm,
                                              const u16* __restrict__ Bt,
                                              float* __restrict__ Cf, u16* __restrict__ Cb, int ldC,
                                              int ncTot, float* __restrict__ p1, float* __restrict__ p2) {
  constexpr int WN  = BN / 2;
  constexpr int FN  = WN / 16;
  constexpr int NPB = BN / 32;
  __shared__ u16 lds[2][(128 + BN) * 64];

  int t = threadIdx.x;
  int wid = t >> 6, lane = t & 63;
  int wr = wid >> 1, wc = wid & 1;
  int lr = lane & 15, lk = lane >> 4;
  int m0 = blockIdx.x * 128;
  int n0 = blockIdx.y * BN;
  int nK = K >> 6;

  int sidx = t;
  u16x8 ra[4];
  u16x8 rb[NPB];

  f32x4 acc[4][FN];
#pragma unroll
  for (int m = 0; m < 4; ++m)
#pragma unroll
    for (int n = 0; n < FN; ++n) acc[m][n] = (f32x4){0.f, 0.f, 0.f, 0.f};

  auto loadTile = [&](int kk) {
    int kk0 = kk * 64;
#pragma unroll
    for (int p = 0; p < 4; ++p) {
      int idx = p * 256 + sidx;
      int r = idx >> 3, c8 = idx & 7;
      int row = m0 + r; if (row >= M) row = M - 1;
      int k = kk0 + c8 * 8;
      if constexpr (AMODE == 0) {
        ra[p] = *(const u16x8*)(Abf + (size_t)row * ldA + k);
      } else if constexpr (AMODE == 2) {
        const float* src = Af32 + (size_t)row * ldA + k;
        float4 a = *(const float4*)src;
        float4 b = *(const float4*)(src + 4);
        u16x8 o;
        o[0] = f2bf(a.x); o[1] = f2bf(a.y); o[2] = f2bf(a.z); o[3] = f2bf(a.w);
        o[4] = f2bf(b.x); o[5] = f2bf(b.y); o[6] = f2bf(b.z); o[7] = f2bf(b.w);
        ra[p] = o;
      } else {
        if (kk0 < 256) {
          u16x8 h8 = *(const u16x8*)(h2 + (size_t)row * 256 + k);
          float av[8], bv[8];
          *(float4*)(av)     = *(const float4*)(am + k);
          *(float4*)(av + 4) = *(const float4*)(am + k + 4);
          *(float4*)(bv)     = *(const float4*)(bm + k);
          *(float4*)(bv + 4) = *(const float4*)(bm + k + 4);
          u16x8 o;
#pragma unroll
          for (int j = 0; j < 8; ++j) {
            float v = bf2f((u16)h8[j]) * av[j] + bv[j];
            v = v > 0.f ? v : 0.01f * v;
            o[j] = f2bf(v);
          }
          ra[p] = o;
        } else {
          float yv[8];
          *(float4*)(yv)     = *(const float4*)(yy + (size_t)row * 256 + (k - 256));
          *(float4*)(yv + 4) = *(const float4*)(yy + (size_t)row * 256 + (k - 256) + 4);
          u16x8 o;
#pragma unroll
          for (int j = 0; j < 8; ++j) o[j] = f2bf(yv[j]);
          ra[p] = o;
        }
      }
    }
#pragma unroll
    for (int p = 0; p < NPB; ++p) {
      int idx = p * 256 + sidx;
      int r = idx >> 3, c8 = idx & 7;
      rb[p] = *(const u16x8*)(Bt + (size_t)(n0 + r) * K + kk0 + c8 * 8);
    }
  };

  auto dswrite = [&](int b) {
    char* As  = (char*)&lds[b][0];
    char* Bsc = As + 128 * 64 * 2;
#pragma unroll
    for (int p = 0; p < 4; ++p) {
      int idx = p * 256 + sidx;
      int r = idx >> 3, c8 = idx & 7;
      *(u16x8*)(As + r * 128 + ((c8 * 16) ^ ((r & 7) << 4))) = ra[p];
    }
#pragma unroll
    for (int p = 0; p < NPB; ++p) {
      int idx = p * 256 + sidx;
      int r = idx >> 3, c8 = idx & 7;
      *(u16x8*)(Bsc + r * 128 + ((c8 * 16) ^ ((r & 7) << 4))) = rb[p];
    }
  };

  auto compute = [&](int b) {
    const char* As  = (const char*)&lds[b][0];
    const char* Bsc = As + 128 * 64 * 2;
#pragma unroll
    for (int ks = 0; ks < 2; ++ks) {
      int kb = ks * 64 + lk * 16;
      s16x8 af[4], bfr[FN];
#pragma unroll
      for (int m = 0; m < 4; ++m) {
        int row = wr * 64 + m * 16 + lr;
        af[m] = *(const s16x8*)(As + row * 128 + (kb ^ ((row & 7) << 4)));
      }
#pragma unroll
      for (int n = 0; n < FN; ++n) {
        int row = wc * WN + n * 16 + lr;
        bfr[n] = *(const s16x8*)(Bsc + row * 128 + (kb ^ ((row & 7) << 4)));
      }
#pragma unroll
      for (int m = 0; m < 4; ++m)
#pragma unroll
        for (int n = 0; n < FN; ++n)
          acc[m][n] = __builtin_amdgcn_mfma_f32_16x16x32_bf16(af[m], bfr[n], acc[m][n], 0, 0, 0);
    }
  };

  loadTile(0);
  dswrite(0);
  __syncthreads();
  for (int kk = 0; kk < nK; ++kk) {
    int b = kk & 1;
    if (kk + 1 < nK) loadTile(kk + 1);
    compute(b);
    if (kk + 1 < nK) { dswrite(b ^ 1); __syncthreads(); }
  }

#pragma unroll
  for (int m = 0; m < 4; ++m) {
#pragma unroll
    for (int n = 0; n < FN; ++n) {
      int col = n0 + wc * WN + n * 16 + lr;
#pragma unroll
      for (int q = 0; q < 4; ++q) {
        int row = m0 + wr * 64 + m * 16 + lk * 4 + q;
        if (row < M) {
          if constexpr (OBF) Cb[(size_t)row * ldC + col] = f2bf(acc[m][n][q]);
          else               Cf[(size_t)row * ldC + col] = acc[m][n][q];
        }
      }
    }
  }

  if constexpr (STATS) {
    __syncthreads();
    float* sb = (float*)&lds[0][0];
#pragma unroll
    for (int n = 0; n < FN; ++n) {
      float s1 = 0.f, s2 = 0.f;
#pragma unroll
      for (int m = 0; m < 4; ++m)
#pragma unroll
        for (int q = 0; q < 4; ++q) {
          int row = m0 + wr * 64 + m * 16 + lk * 4 + q;
          float v = (row < M) ? acc[m][n][q] : 0.f;
          s1 += v; s2 += v * v;
        }
      s1 += __shfl_xor(s1, 16); s2 += __shfl_xor(s2, 16);
      s1 += __shfl_xor(s1, 32); s2 += __shfl_xor(s2, 32);
      if (lk == 0) {
        int c = wc * WN + n * 16 + lr;
        sb[(wr * BN + c) * 2 + 0] = s1;
        sb[(wr * BN + c) * 2 + 1] = s2;
      }
    }
    __syncthreads();
    if (t < BN) {
      float s1 = sb[t * 2]     + sb[(BN + t) * 2];
      float s2 = sb[t * 2 + 1] + sb[(BN + t) * 2 + 1];
      p1[(size_t)blockIdx.x * ncTot + n0 + t] = s1;
      p2[(size_t)blockIdx.x * ncTot + n0 + t] = s2;
    }
  }
}

// ---------- split-bf16 MFMA (f32 accuracy) with fused stats ----------
__global__ __launch_bounds__(256) void k_mfma_split(const float* __restrict__ Af, int K, int M,
                                                    const u16* __restrict__ Bh, const u16* __restrict__ Bl,
                                                    float* __restrict__ Cf,
                                                    float* __restrict__ p1, float* __restrict__ p2) {
  __shared__ u16 sAh[128 * 64], sAl[128 * 64], sBh[64 * 64], sBl[64 * 64];
  int t = threadIdx.x;
  int wid = t >> 6, lane = t & 63;
  int wr = wid >> 1, wc = wid & 1;
  int lr = lane & 15, lk = lane >> 4;
  int m0 = blockIdx.x * 128;
  int nK = K >> 6;

  u16x8 rah[4], ral[4], rbh[2], rbl[2];
  f32x4 acc[4][2];
#pragma unroll
  for (int m = 0; m < 4; ++m)
#pragma unroll
    for (int n = 0; n < 2; ++n) acc[m][n] = (f32x4){0.f, 0.f, 0.f, 0.f};

  auto loadTile = [&](int kk) {
    int kk0 = kk * 64;
#pragma unroll
    for (int p = 0; p < 4; ++p) {
      int idx = p * 256 + t;
      int r = idx >> 3, c8 = idx & 7;
      int row = m0 + r; if (row >= M) row = M - 1;
      const float* src = Af + (size_t)row * K + kk0 + c8 * 8;
      float4 a = *(const float4*)src;
      float4 b = *(const float4*)(src + 4);
      float v[8];
      *(float4*)(v) = a; *(float4*)(v + 4) = b;
      u16x8 oh, ol;
#pragma unroll
      for (int j = 0; j < 8; ++j) {
        u16 h = f2bf(v[j]);
        oh[j] = h;
        ol[j] = f2bf(v[j] - bf2f(h));
      }
      rah[p] = oh; ral[p] = ol;
    }
#pragma unroll
    for (int p = 0; p < 2; ++p) {
      int idx = p * 256 + t;
      int r = idx >> 3, c8 = idx & 7;
      rbh[p] = *(const u16x8*)(Bh + (size_t)r * K + kk0 + c8 * 8);
      rbl[p] = *(const u16x8*)(Bl + (size_t)r * K + kk0 + c8 * 8);
    }
  };

  auto dswrite = [&]() {
    char* Ah = (char*)sAh; char* Al = (char*)sAl;
    char* Bhc = (char*)sBh; char* Blc = (char*)sBl;
#pragma unroll
    for (int p = 0; p < 4; ++p) {
      int idx = p * 256 + t;
      int r = idx >> 3, c8 = idx & 7;
      int off = r * 128 + ((c8 * 16) ^ ((r & 7) << 4));
      *(u16x8*)(Ah + off) = rah[p];
      *(u16x8*)(Al + off) = ral[p];
    }
#pragma unroll
    for (int p = 0; p < 2; ++p) {
      int idx = p * 256 + t;
      int r = idx >> 3, c8 = idx & 7;
      int off = r * 128 + ((c8 * 16) ^ ((r & 7) << 4));
      *(u16x8*)(Bhc + off) = rbh[p];
      *(u16x8*)(Blc + off) = rbl[p];
    }
  };

  auto compute = [&]() {
    const char* Ah = (const char*)sAh; const char* Al = (const char*)sAl;
    const char* Bhc = (const char*)sBh; const char* Blc = (const char*)sBl;
#pragma unroll
    for (int ks = 0; ks < 2; ++ks) {
      int kb = ks * 64 + lk * 16;
      s16x8 fah[4], fal[4], fbh[2], fbl[2];
#pragma unroll
      for (int m = 0; m < 4; ++m) {
        int row = wr * 64 + m * 16 + lr;
        int off = row * 128 + (kb ^ ((row & 7) << 4));
        fah[m] = *(const s16x8*)(Ah + off);
        fal[m] = *(const s16x8*)(Al + off);
      }
#pragma unroll
      for (int n = 0; n < 2; ++n) {
        int row = wc * 32 + n * 16 + lr;
        int off = row * 128 + (kb ^ ((row & 7) << 4));
        fbh[n] = *(const s16x8*)(Bhc + off);
        fbl[n] = *(const s16x8*)(Blc + off);
      }
#pragma unroll
      for (int m = 0; m < 4; ++m)
#pragma unroll
        for (int n = 0; n < 2; ++n) {
          acc[m][n] = __builtin_amdgcn_mfma_f32_16x16x32_bf16(fah[m], fbh[n], acc[m][n], 0, 0, 0);
          acc[m][n] = __builtin_amdgcn_mfma_f32_16x16x32_bf16(fah[m], fbl[n], acc[m][n], 0, 0, 0);
          acc[m][n] = __builtin_amdgcn_mfma_f32_16x16x32_bf16(fal[m], fbh[n], acc[m][n], 0, 0, 0);
        }
    }
  };

  loadTile(0);
  for (int kk = 0; kk < nK; ++kk) {
    __syncthreads();
    dswrite();
    __syncthreads();
    if (kk + 1 < nK) loadTile(kk + 1);
    compute();
  }

#pragma unroll
  for (int m = 0; m < 4; ++m) {
#pragma unroll
    for (int n = 0; n < 2; ++n) {
      int col = wc * 32 + n * 16 + lr;
#pragma unroll
      for (int q = 0; q < 4; ++q) {
        int row = m0 + wr * 64 + m * 16 + lk * 4 + q;
        if (row < M) Cf[(size_t)row * 64 + col] = acc[m][n][q];
      }
    }
  }

  __syncthreads();
  float* sb = (float*)sAh;
#pragma unroll
  for (int n = 0; n < 2; ++n) {
    float s1 = 0.f, s2 = 0.f;
#pragma unroll
    for (int m = 0; m < 4; ++m)
#pragma unroll
      for (int q = 0; q < 4; ++q) {
        int row = m0 + wr * 64 + m * 16 + lk * 4 + q;
        float v = (row < M) ? acc[m][n][q] : 0.f;
        s1 += v; s2 += v * v;
      }
    s1 += __shfl_xor(s1, 16); s2 += __shfl_xor(s2, 16);
    s1 += __shfl_xor(s1, 32); s2 += __shfl_xor(s2, 32);
    if (lk == 0) {
      int c = wc * 32 + n * 16 + lr;
      sb[(wr * 64 + c) * 2 + 0] = s1;
      sb[(wr * 64 + c) * 2 + 1] = s2;
    }
  }
  __syncthreads();
  if (t < 64) {
    float s1 = sb[t * 2]     + sb[(64 + t) * 2];
    float s2 = sb[t * 2 + 1] + sb[(64 + t) * 2 + 1];
    p1[(size_t)blockIdx.x * 64 + t] = s1;
    p2[(size_t)blockIdx.x * 64 + t] = s2;
  }
}

// ---------- reduce partials -> BN scale/shift ----------
__global__ __launch_bounds__(256) void k_reduce_fin(const float* __restrict__ part1,
                                                    const float* __restrict__ part2,
                                                    int nb, int C, float invN,
                                                    const float* __restrict__ gamma,
                                                    const float* __restrict__ beta,
                                                    float* __restrict__ a_out,
                                                    float* __restrict__ b_out) {
  int c = blockIdx.x;
  int t = threadIdx.x;
  float s1 = 0.f, s2 = 0.f;
  for (int b = t; b < nb; b += 256) {
    s1 += part1[(size_t)b * C + c];
    s2 += part2[(size_t)b * C + c];
  }
  for (int m = 32; m; m >>= 1) { s1 += __shfl_xor(s1, m); s2 += __shfl_xor(s2, m); }
  __shared__ float l1[4], l2[4];
  if ((t & 63) == 0) { l1[t >> 6] = s1; l2[t >> 6] = s2; }
  __syncthreads();
  if (t == 0) {
    s1 = l1[0] + l1[1] + l1[2] + l1[3];
    s2 = l2[0] + l2[1] + l2[2] + l2[3];
    float mu  = s1 * invN;
    float var = s2 * invN - mu * mu;
    float a = gamma[c] * rsqrtf(var + 1e-5f);
    a_out[c] = a;
    b_out[c] = beta[c] - mu * a;
  }
}

// ---------- UN = bf16(au*xu + bue) ----------
__global__ __launch_bounds__(256) void k_scaleUN(const u16* __restrict__ ub, const float* __restrict__ au,
                                                 const float* __restrict__ bue, u16* __restrict__ un, int n8) {
  for (int i = blockIdx.x * 256 + threadIdx.x; i < n8; i += gridDim.x * 256) {
    int c0 = (i & 7) * 8;
    float av[8], bv[8];
    *(float4*)(av) = *(const float4*)(au + c0);  *(float4*)(av + 4) = *(const float4*)(au + c0 + 4);
    *(float4*)(bv) = *(const float4*)(bue + c0); *(float4*)(bv + 4) = *(const float4*)(bue + c0 + 4);
    u16x8 in = ((const u16x8*)ub)[i];
    u16x8 o;
#pragma unroll
    for (int j = 0; j < 8; ++j) o[j] = f2bf(bf2f((u16)in[j]) * av[j] + bv[j]);
    ((u16x8*)un)[i] = o;
  }
}

// ---------- PS = f16(ap * su) ----------
__global__ __launch_bounds__(256) void k_scaleP(const float* __restrict__ P, const float* __restrict__ ap,
                                                __half* __restrict__ PS, int n8) {
  for (int i = blockIdx.x * 256 + threadIdx.x; i < n8; i += gridDim.x * 256) {
    int c0 = (i & 7) * 8;
    float4 s0 = *(const float4*)(ap + c0), s1 = *(const float4*)(ap + c0 + 4);
    float4 a = ((const float4*)P)[i * 2];
    float4 b = ((const float4*)P)[i * 2 + 1];
    __half2 o0 = __floats2half2_rn(a.x * s0.x, a.y * s0.y);
    __half2 o1 = __floats2half2_rn(a.z * s0.z, a.w * s0.w);
    __half2 o2 = __floats2half2_rn(b.x * s1.x, b.y * s1.y);
    __half2 o3 = __floats2half2_rn(b.z * s1.z, b.w * s1.w);
    uint4 out;
    out.x = *(unsigned*)&o0; out.y = *(unsigned*)&o1;
    out.z = *(unsigned*)&o2; out.w = *(unsigned*)&o3;
    ((uint4*)PS)[i] = out;
  }
}

// ---------- degree count + per-edge rank (one atomic pass) ----------
__global__ void k_count(const int* __restrict__ ei, int E, int* __restrict__ cnt,
                        int* __restrict__ rank) {
  for (int e = blockIdx.x * blockDim.x + threadIdx.x; e < E; e += gridDim.x * blockDim.x)
    rank[e] = atomicAdd(&cnt[ei[e]], 1);
}

// ---------- CSR scans ----------
__global__ __launch_bounds__(256) void k_scanA(const int* __restrict__ cnt, int N,
                                               int* __restrict__ rowptr, int* __restrict__ bs) {
  __shared__ int s[256];
  int t = threadIdx.x, gi = blockIdx.x * 256 + t;
  int v = (gi < N) ? cnt[gi] : 0;
  s[t] = v;
  __syncthreads();
  for (int off = 1; off < 256; off <<= 1) {
    int add = (t >= off) ? s[t - off] : 0;
    __syncthreads();
    s[t] += add;
    __syncthreads();
  }
  if (gi < N) rowptr[gi + 1] = s[t];
  if (t == 255) bs[blockIdx.x] = s[255];
}

__global__ __launch_bounds__(512) void k_scanB(int* __restrict__ bs, int nb) {
  __shared__ int s[512];
  int t = threadIdx.x;
  s[t] = (t < nb) ? bs[t] : 0;
  __syncthreads();
  for (int off = 1; off < 512; off <<= 1) {
    int add = (t >= off) ? s[t - off] : 0;
    __syncthreads();
    s[t] += add;
    __syncthreads();
  }
  if (t < nb) bs[t] = s[t];
}

__global__ __launch_bounds__(256) void k_scanC(int N, int* __restrict__ rowptr, const int* __restrict__ bs) {
  int gi = blockIdx.x * 256 + threadIdx.x;
  if (gi == 0) rowptr[0] = 0;
  if (gi < N && blockIdx.x > 0) rowptr[gi + 1] += bs[blockIdx.x - 1];
}

// ---------- bucket fill: atomic-free 4B scatter ----------
__global__ void k_fill(const int* __restrict__ ei, const int* __restrict__ ej,
                       const int* __restrict__ rank, int E,
                       const int* __restrict__ rowptr, int* __restrict__ srcj) {
  for (int e = blockIdx.x * blockDim.x + threadIdx.x; e < E; e += gridDim.x * blockDim.x)
    srcj[rowptr[ei[e]] + rank[e]] = ej[e];
}

// ---------- fused per-node: logits from PS (i-row amortized) + softmax + UN aggregation ----------
__global__ __launch_bounds__(256) void k_nodeall(const __half* __restrict__ PS,
                                                 const int* __restrict__ srcj,
                                                 const int* __restrict__ rowptr,
                                                 const u16* __restrict__ UN,
                                                 int N, float* __restrict__ agg) {
  int lane = threadIdx.x & 63;
  int node = blockIdx.x * 4 + (threadIdx.x >> 6);
  if (node >= N) return;
  int lane16 = lane & 15;
  int g4 = lane >> 4;
  const uint2* P2 = (const uint2*)PS;
  uint2 uu = P2[(size_t)node * 16 + lane16];
  float2 ua = __half22float2(*(const __half2*)&uu.x);
  float2 ub = __half22float2(*(const __half2*)&uu.y);
  float psl = __half2float(PS[(size_t)node * 64 + lane]);   // per-lane channel (rare tails)
  int b0 = rowptr[node], b1 = rowptr[node + 1];
  int deg = b1 - b0;
  float acc = 0.f;
  if (deg > 0) {
    int cnt = deg < 64 ? deg : 64;
    int jj = (lane < cnt) ? srcj[b0 + lane] : 0;
    // ---- logits for first 64 edges: 4 groups x 16 lanes, 4 edges per iter ----
    float lg = -INFINITY;
    int capbase = lane & ~3;
    int capsrc  = (lane & 3) << 4;
    for (int ss = 0; ss < cnt; ss += 4) {
      int sl = ss + g4;
      int j = __shfl(jj, sl < cnt ? sl : cnt - 1);
      uint2 vv = P2[(size_t)j * 16 + lane16];
      float2 va = __half22float2(*(const __half2*)&vv.x);
      float2 vb = __half22float2(*(const __half2*)&vv.y);
      float d0 = ua.x - va.x, d1 = ua.y - va.y, d2 = ub.x - vb.x, d3 = ub.y - vb.y;
      float p = d0 * d0 + d1 * d1 + d2 * d2 + d3 * d3;
      p += __shfl_xor(p, 1, 16);
      p += __shfl_xor(p, 2, 16);
      p += __shfl_xor(p, 4, 16);
      p += __shfl_xor(p, 8, 16);
      float val = __shfl(p, capsrc);          // lane t grabs group (t&3)'s result
      if (ss == capbase && lane < cnt) lg = -val;
    }
    // ---- max (incl. rare deg>64 tail) ----
    float mx = lg;
    for (int s = b0 + 64; s < b1; ++s) {
      int j = srcj[s];
      float d = psl - __half2float(PS[(size_t)j * 64 + lane]);
      float p = d * d;
      for (int m = 32; m; m >>= 1) p += __shfl_xor(p, m);
      mx = fmaxf(mx, -p);
    }
    for (int m = 32; m; m >>= 1) mx = fmaxf(mx, __shfl_xor(mx, m));
    // ---- exp-sum ----
    float ex = (lane < cnt) ? __expf(lg - mx) : 0.f;
    float sm = ex;
    for (int s = b0 + 64; s < b1; ++s) {
      int j = srcj[s];
      float d = psl - __half2float(PS[(size_t)j * 64 + lane]);
      float p = d * d;
      for (int m = 32; m; m >>= 1) p += __shfl_xor(p, m);
      if (lane == 0) sm += __expf(-p - mx);
    }
    for (int m = 32; m; m >>= 1) sm += __shfl_xor(sm, m);
    float inv = 1.0f / (sm + 1e-16f);
    float w = ex * inv;
    // ---- weighted UN aggregation ----
    int ss = 0;
    for (; ss + 4 <= cnt; ss += 4) {
      int   j0 = __shfl(jj, ss),     j1 = __shfl(jj, ss + 1);
      int   j2 = __shfl(jj, ss + 2), j3 = __shfl(jj, ss + 3);
      float w0 = __shfl(w, ss),      w1 = __shfl(w, ss + 1);
      float w2 = __shfl(w, ss + 2),  w3 = __shfl(w, ss + 3);
      float v0 = bf2f(UN[(size_t)j0 * 64 + lane]);
      float v1 = bf2f(UN[(size_t)j1 * 64 + lane]);
      float v2 = bf2f(UN[(size_t)j2 * 64 + lane]);
      float v3 = bf2f(UN[(size_t)j3 * 64 + lane]);
      acc += w0 * v0 + w1 * v1 + w2 * v2 + w3 * v3;
    }
    for (; ss < cnt; ++ss) {
      int j0 = __shfl(jj, ss);
      float w0 = __shfl(w, ss);
      acc += w0 * bf2f(UN[(size_t)j0 * 64 + lane]);
    }
    for (int s = b0 + 64; s < b1; ++s) {       // rare tail
      int j = srcj[s];
      float d = psl - __half2float(PS[(size_t)j * 64 + lane]);
      float p = d * d;
      for (int m = 32; m; m >>= 1) p += __shfl_xor(p, m);
      acc += __expf(-p - mx) * inv * bf2f(UN[(size_t)j * 64 + lane]);
    }
  }
  agg[(size_t)node * 64 + lane] = acc;
}

// ---------- h = (z + agg@C) @ Minv, z = UN (bf16), out bf16 ----------
__global__ __launch_bounds__(256) void k_solve(const u16* __restrict__ UN, const float* __restrict__ agg,
                                               const float* __restrict__ minv, const float* __restrict__ cmw,
                                               u16* __restrict__ HB, int ntiles) {
  __shared__ float mS[4096];
  __shared__ float cS[4096];
  int t = threadIdx.x;
  int c16 = t & 15, rg = t >> 4;
  for (int idx = t; idx < 1024; idx += 256) {
    ((float4*)mS)[idx] = ((const float4*)minv)[idx];
    ((float4*)cS)[idx] = ((const float4*)cmw)[idx];
  }
  __syncthreads();
  for (int tile = blockIdx.x; tile < ntiles; tile += gridDim.x) {
    int row = tile * 16 + rg;
    const u16*  ur = UN + (size_t)row * 64;
    const float* gr = agg + (size_t)row * 64;
    float4 acc = make_float4(0.f, 0.f, 0.f, 0.f);
#pragma unroll 4
    for (int k = 0; k < 64; ++k) {
      float z = bf2f(ur[k]);
      float g = gr[k];
      float4 m4 = ((const float4*)mS)[k * 16 + c16];
      float4 c4 = ((const float4*)cS)[k * 16 + c16];
      acc.x += z * m4.x + g * c4.x;
      acc.y += z * m4.y + g * c4.y;
      acc.z += z * m4.z + g * c4.z;
      acc.w += z * m4.w + g * c4.w;
    }
    ((ushort4*)HB)[(size_t)row * 16 + c16] =
        make_ushort4(f2bf(acc.x), f2bf(acc.y), f2bf(acc.z), f2bf(acc.w));
  }
}

// ---------- final BN + leaky: bf16 raw -> f32 out ----------
__global__ __launch_bounds__(256) void k_bnact16(const u16* __restrict__ raw, const float* __restrict__ af,
                                                 const float* __restrict__ bfp, float* __restrict__ out, int n8) {
  int i = blockIdx.x * 256 + threadIdx.x;
  int stride = gridDim.x * 256;
  for (; i < n8; i += stride) {
    int c0 = (i & 31) * 8;
    float av[8], bv[8];
    *(float4*)(av) = *(const float4*)(af + c0);  *(float4*)(av + 4) = *(const float4*)(af + c0 + 4);
    *(float4*)(bv) = *(const float4*)(bfp + c0); *(float4*)(bv + 4) = *(const float4*)(bfp + c0 + 4);
    u16x8 r = ((const u16x8*)raw)[i];
    float o[8];
#pragma unroll
    for (int j = 0; j < 8; ++j) {
      float v = bf2f((u16)r[j]) * av[j] + bv[j];
      o[j] = (v > 0.f) ? v : 0.01f * v;
    }
    ((float4*)out)[i * 2]     = *(float4*)(o);
    ((float4*)out)[i * 2 + 1] = *(float4*)(o + 4);
  }
}

extern "C" void kernel_launch(void* const* d_in, const int* in_sizes, int n_in,
                              void* d_out, int out_size, void* d_ws, size_t ws_size,
                              hipStream_t stream) {
  const float* x    = (const float*)d_in[0];
  const float* y    = (const float*)d_in[1];
  const int*   eidx = (const int*)d_in[3];
  const float* Wu   = (const float*)d_in[4];
  const float* gu   = (const float*)d_in[5];
  const float* bu   = (const float*)d_in[6];
  const float* Wp   = (const float*)d_in[7];
  const float* gp   = (const float*)d_in[8];
  const float* bp   = (const float*)d_in[9];
  const float* cIn  = (const float*)d_in[10];
  const float* Wm   = (const float*)d_in[11];
  const float* gm   = (const float*)d_in[12];
  const float* bm   = (const float*)d_in[13];
  const float* Wf   = (const float*)d_in[14];
  const float* gf   = (const float*)d_in[15];
  const float* bfv  = (const float*)d_in[16];

  const int N = in_sizes[0] / 256;
  const int E = in_sizes[3] / 2;
  const int* ei = eidx;
  const int* ej = eidx + E;

  char* ws = (char*)d_ws;
  float* MINV  = (float*)(ws + OFF_MINV);
  float* CMW   = (float*)(ws + OFF_CM);
  float* AU    = (float*)(ws + OFF_AU);
  float* BUE   = (float*)(ws + OFF_BUE);
  float* AP    = (float*)(ws + OFF_AP);
  float* APBE  = (float*)(ws + OFF_APBE);
  float* AM    = (float*)(ws + OFF_AM);
  float* BM    = (float*)(ws + OFF_BM);
  float* AF    = (float*)(ws + OFF_AF);
  float* BF    = (float*)(ws + OFF_BF);
  int*   BSC   = (int*)(ws + OFF_BS);
  u16*   WUT   = (u16*)(ws + OFF_WUT);
  u16*   WMT   = (u16*)(ws + OFF_WMT);
  u16*   WFT   = (u16*)(ws + OFF_WFT);
  u16*   WPH   = (u16*)(ws + OFF_WPH);
  u16*   WPL   = (u16*)(ws + OFF_WPL);
  float* PART1 = (float*)(ws + OFF_PART1);
  float* PART2 = (float*)(ws + OFF_PART2);
  int*   ROWPTR= (int*)(ws + OFF_ROWPTR);
  int*   COUNT = (int*)(ws + OFF_COUNT);
  int*   RANK  = (int*)(ws + OFF_RANK);
  u16*   HB    = (u16*)(ws + OFF_RANK);      // reuse (RANK dead after k_fill)
  int*   SRCJ  = (int*)(ws + OFF_SRCJ);
  u16*   RAWO  = (u16*)(ws + OFF_SRCJ);      // reuse (SRCJ dead after k_nodeall)
  u16*   UBRAW = (u16*)(ws + OFF_U);
  u16*   UN    = (u16*)(ws + OFF_UN);
  float* P     = (float*)(ws + OFF_P);
  float* AGG   = (float*)(ws + OFF_P);       // reuse P region (P dead after k_scaleP) — fixes PS/AGG overlap
  __half* PS   = (__half*)(ws + OFF_PS);
  u16*   H2    = (u16*)(ws + OFF_H2);

  const float invN = 1.0f / (float)N;
  const int ntiles16 = N / 16;
  const int nbScan   = (N + 255) / 256;
  const int mtiles   = (N + 127) / 128;
  const int n8_64    = N * 64 / 8;
  const int n8_256   = N * 256 / 8;

  hipMemsetAsync(COUNT, 0, (size_t)N * 4, stream);

  k_prep<<<1, 256, 0, stream>>>(cIn, MINV, CMW);
  k_tcvt<<<64,  256, 0, stream>>>(Wu, WUT, 256, 64);
  k_tcvt<<<64,  256, 0, stream>>>(Wm, WMT, 64, 256);
  k_tcvt<<<512, 256, 0, stream>>>(Wf, WFT, 512, 256);
  k_tcvt_split<<<64, 256, 0, stream>>>(Wp, WPH, WPL);

  // CSR build: single atomic pass (count+rank), scans, atomic-free fill
  k_count<<<2048, 256, 0, stream>>>(ei, E, COUNT, RANK);
  k_scanA<<<nbScan, 256, 0, stream>>>(COUNT, N, ROWPTR, BSC);
  k_scanB<<<1, 512, 0, stream>>>(BSC, nbScan);
  k_scanC<<<nbScan, 256, 0, stream>>>(N, ROWPTR, BSC);
  k_fill<<<2048, 256, 0, stream>>>(ei, ej, RANK, E, ROWPTR, SRCJ);

  // unary embedding (stats fused) -> UBRAW bf16; BN params; UN table
  k_mfma<64, 2, 1, 1><<<dim3(mtiles, 1), 256, 0, stream>>>(
      nullptr, x, 256, 256, N, nullptr, nullptr, nullptr, nullptr, WUT,
      nullptr, UBRAW, 64, 64, PART1, PART2);
  k_reduce_fin<<<64, 256, 0, stream>>>(PART1, PART2, mtiles, 64, invN, gu, bu, AU, BUE);
  k_scaleUN<<<1024, 256, 0, stream>>>(UBRAW, AU, BUE, UN, n8_64);

  // pairwise embedding: split-bf16 MFMA (stats fused) -> P f32; PS f16 table
  k_mfma_split<<<mtiles, 256, 0, stream>>>(y, 256, N, WPH, WPL, P, PART1, PART2);
  k_reduce_fin<<<64, 256, 0, stream>>>(PART1, PART2, mtiles, 64, invN, gp, bp, AP, APBE);
  k_scaleP<<<1024, 256, 0, stream>>>(P, AP, PS, n8_64);

  // fused logits + softmax + aggregation (AGG overwrites P region; PS untouched)
  k_nodeall<<<(N + 3) / 4, 256, 0, stream>>>(PS, SRCJ, ROWPTR, UN, N, AGG);

  // CRF solve -> h bf16 (HB overwrites RANK region)
  k_solve<<<2048, 256, 0, stream>>>(UN, AGG, MINV, CMW, HB, ntiles16);

  // h @ Wm -> h2 bf16 (stats fused)
  k_mfma<128, 0, 1, 1><<<dim3(mtiles, 2), 256, 0, stream>>>(
      HB, nullptr, 64, 64, N, nullptr, nullptr, nullptr, nullptr, WMT,
      nullptr, H2, 256, 256, PART1, PART2);
  k_reduce_fin<<<256, 256, 0, stream>>>(PART1, PART2, mtiles, 256, invN, gm, bm, AM, BM);

  // [leaky(bn(h2)), y] @ Wf -> raw bf16 (stats fused, overwrites SRCJ region), BN + leaky -> d_out
  k_mfma<128, 1, 1, 1><<<dim3(mtiles, 2), 256, 0, stream>>>(
      nullptr, nullptr, 0, 512, N, H2, y, AM, BM, WFT,
      nullptr, RAWO, 256, 256, PART1, PART2);
  k_reduce_fin<<<256, 256, 0, stream>>>(PART1, PART2, mtiles, 256, invN, gf, bfv, AF, BF);
  k_bnact16<<<2048, 256, 0, stream>>>(RAWO, AF, BF, (float*)d_out, n8_256);
}

// Round 7
// 752.769 us; speedup vs baseline: 3.7720x; 1.1716x over previous
//
#include <hip/hip_runtime.h>
#include <hip/hip_fp16.h>
#include <math.h>

typedef unsigned short u16;
typedef short s16x8 __attribute__((ext_vector_type(8)));
typedef unsigned short u16x8 __attribute__((ext_vector_type(8)));
typedef float f32x4 __attribute__((ext_vector_type(4)));

// ---------- helpers ----------
__device__ __forceinline__ float bf2f(u16 u) {
  unsigned x = ((unsigned)u) << 16;
  return __uint_as_float(x);
}
__device__ __forceinline__ u16 f2bf(float f) {
  unsigned x = __float_as_uint(f);
  unsigned r = x + 0x7FFFu + ((x >> 16) & 1u);
  return (u16)(r >> 16);
}

// ---------- ws layout (bytes) ----------
static const size_t OFF_MINV   = 0;
static const size_t OFF_AU     = 32ull * 1024;
static const size_t OFF_BUE    = 32ull * 1024 + 256;
static const size_t OFF_AP     = 32ull * 1024 + 512;
static const size_t OFF_APBE   = 32ull * 1024 + 768;
static const size_t OFF_AM     = 36ull * 1024;
static const size_t OFF_BM     = 37ull * 1024;
static const size_t OFF_AF     = 38ull * 1024;
static const size_t OFF_BF     = 39ull * 1024;
static const size_t OFF_BS     = 40ull * 1024;
static const size_t OFF_WUT    = 64ull * 1024;
static const size_t OFF_WMT    = 128ull * 1024;
static const size_t OFF_WFT    = 192ull * 1024;
static const size_t OFF_WPH    = 512ull * 1024;
static const size_t OFF_WPL    = 576ull * 1024;
static const size_t OFF_PART1  = 1ull  * 1024 * 1024;
static const size_t OFF_PART2  = 2ull  * 1024 * 1024;
static const size_t OFF_ROWPTR = 3ull  * 1024 * 1024;
static const size_t OFF_COUNT  = 3ull  * 1024 * 1024 + 512 * 1024;
static const size_t OFF_RANK   = 5ull  * 1024 * 1024;     // E int; dead after k_fill -> HB bf16 N*64
static const size_t OFF_SRCJ   = 18ull * 1024 * 1024;     // E int; dead after k_nodeall -> RAWO bf16 N*256
static const size_t OFF_U      = 44ull * 1024 * 1024;     // UBRAW bf16 N*64
static const size_t OFF_UN     = 57ull * 1024 * 1024;     // UN bf16 N*64
static const size_t OFF_P      = 70ull * 1024 * 1024;     // P f32 early; AGG f32 after k_scaleP
static const size_t OFF_PS     = 109ull * 1024 * 1024;
static const size_t OFF_H2     = 122ull * 1024 * 1024;

// ---------- K0: Minv = (I + c^T c)^-1 (conflict-free GJ; CM not needed: C@Minv = I - Minv) ----------
__global__ __launch_bounds__(256) void k_prep(const float* __restrict__ c,
                                              float* __restrict__ minv_out) {
  __shared__ float CC[4096];
  __shared__ float aug[64 * 129];   // stride 129: column accesses conflict-free
  __shared__ float fs[64];
  float* cl = aug;                  // overlap: cl dead before aug written
  int t = threadIdx.x;
  for (int idx = t; idx < 4096; idx += 256) cl[idx] = c[idx];
  __syncthreads();
  for (int idx = t; idx < 4096; idx += 256) {
    int a = idx >> 6, b = idx & 63;
    float s = (a == b) ? 1.f : 0.f;           // fold the +I here
    for (int k = 0; k < 64; ++k) s += cl[k * 64 + a] * cl[k * 64 + b];
    CC[idx] = s;
  }
  __syncthreads();
  for (int idx = t; idx < 8192; idx += 256) {
    int r = idx >> 7, cc = idx & 127;
    aug[r * 129 + cc] = (cc < 64) ? CC[r * 64 + cc] : (((cc - 64) == r) ? 1.f : 0.f);
  }
  __syncthreads();
  int cloc = t & 127;
  int rbase = t >> 7;               // 0 or 1
  for (int p = 0; p < 64; ++p) {
    float inv = 1.0f / aug[p * 129 + p];          // broadcast read
    if (t < 64) fs[t] = (t == p) ? 0.f : aug[t * 129 + p];   // stride-129 col read: conflict-free
    __syncthreads();
    if (t < 128) aug[p * 129 + t] *= inv;         // normalize pivot row
    __syncthreads();
    float pc = aug[p * 129 + cloc];               // pivot row value for this column (register)
#pragma unroll
    for (int rr = 0; rr < 64; rr += 2) {
      int r = rr + rbase;
      aug[r * 129 + cloc] -= fs[r] * pc;          // stride-1 across lanes: conflict-free
    }
    __syncthreads();
  }
  for (int idx = t; idx < 4096; idx += 256) {
    int r = idx >> 6, cc = idx & 63;
    minv_out[idx] = aug[r * 129 + 64 + cc];
  }
}

// ---------- transpose + convert weights ----------
__global__ __launch_bounds__(256) void k_tcvt(const float* __restrict__ in, u16* __restrict__ outb,
                                              int Kd, int Nc) {
  int i = blockIdx.x * 256 + threadIdx.x;
  if (i < Kd * Nc) {
    int k = i / Nc, n = i - k * Nc;
    outb[(size_t)n * Kd + k] = f2bf(in[i]);
  }
}

__global__ __launch_bounds__(256) void k_tcvt_split(const float* __restrict__ in,
                                                    u16* __restrict__ outh, u16* __restrict__ outl) {
  int i = blockIdx.x * 256 + threadIdx.x;
  if (i < 256 * 64) {
    int k = i >> 6, n = i & 63;
    float v = in[i];
    u16 h = f2bf(v);
    float lo = v - bf2f(h);
    outh[(size_t)n * 256 + k] = h;
    outl[(size_t)n * 256 + k] = f2bf(lo);
  }
}

// ---------- MFMA GEMM with optional fused column-stats ----------
template<int BN, int AMODE, int OBF, int STATS>
__global__ __launch_bounds__(256) void k_mfma(const u16* __restrict__ Abf, const float* __restrict__ Af32,
                                              int ldA, int K, int M,
                                              const u16* __restrict__ h2, const float* __restrict__ yy,
                                              const float* __restrict__ am, const float* __restrict__ bm,
                                              const u16* __restrict__ Bt,
                                              float* __restrict__ Cf, u16* __restrict__ Cb, int ldC,
                                              int ncTot, float* __restrict__ p1, float* __restrict__ p2) {
  constexpr int WN  = BN / 2;
  constexpr int FN  = WN / 16;
  constexpr int NPB = BN / 32;
  __shared__ u16 lds[2][(128 + BN) * 64];

  int t = threadIdx.x;
  int wid = t >> 6, lane = t & 63;
  int wr = wid >> 1, wc = wid & 1;
  int lr = lane & 15, lk = lane >> 4;
  int m0 = blockIdx.x * 128;
  int n0 = blockIdx.y * BN;
  int nK = K >> 6;

  int sidx = t;
  u16x8 ra[4];
  u16x8 rb[NPB];

  f32x4 acc[4][FN];
#pragma unroll
  for (int m = 0; m < 4; ++m)
#pragma unroll
    for (int n = 0; n < FN; ++n) acc[m][n] = (f32x4){0.f, 0.f, 0.f, 0.f};

  auto loadTile = [&](int kk) {
    int kk0 = kk * 64;
#pragma unroll
    for (int p = 0; p < 4; ++p) {
      int idx = p * 256 + sidx;
      int r = idx >> 3, c8 = idx & 7;
      int row = m0 + r; if (row >= M) row = M - 1;
      int k = kk0 + c8 * 8;
      if constexpr (AMODE == 0) {
        ra[p] = *(const u16x8*)(Abf + (size_t)row * ldA + k);
      } else if constexpr (AMODE == 2) {
        const float* src = Af32 + (size_t)row * ldA + k;
        float4 a = *(const float4*)src;
        float4 b = *(const float4*)(src + 4);
        u16x8 o;
        o[0] = f2bf(a.x); o[1] = f2bf(a.y); o[2] = f2bf(a.z); o[3] = f2bf(a.w);
        o[4] = f2bf(b.x); o[5] = f2bf(b.y); o[6] = f2bf(b.z); o[7] = f2bf(b.w);
        ra[p] = o;
      } else {
        if (kk0 < 256) {
          u16x8 h8 = *(const u16x8*)(h2 + (size_t)row * 256 + k);
          float av[8], bv[8];
          *(float4*)(av)     = *(const float4*)(am + k);
          *(float4*)(av + 4) = *(const float4*)(am + k + 4);
          *(float4*)(bv)     = *(const float4*)(bm + k);
          *(float4*)(bv + 4) = *(const float4*)(bm + k + 4);
          u16x8 o;
#pragma unroll
          for (int j = 0; j < 8; ++j) {
            float v = bf2f((u16)h8[j]) * av[j] + bv[j];
            v = v > 0.f ? v : 0.01f * v;
            o[j] = f2bf(v);
          }
          ra[p] = o;
        } else {
          float yv[8];
          *(float4*)(yv)     = *(const float4*)(yy + (size_t)row * 256 + (k - 256));
          *(float4*)(yv + 4) = *(const float4*)(yy + (size_t)row * 256 + (k - 256) + 4);
          u16x8 o;
#pragma unroll
          for (int j = 0; j < 8; ++j) o[j] = f2bf(yv[j]);
          ra[p] = o;
        }
      }
    }
#pragma unroll
    for (int p = 0; p < NPB; ++p) {
      int idx = p * 256 + sidx;
      int r = idx >> 3, c8 = idx & 7;
      rb[p] = *(const u16x8*)(Bt + (size_t)(n0 + r) * K + kk0 + c8 * 8);
    }
  };

  auto dswrite = [&](int b) {
    char* As  = (char*)&lds[b][0];
    char* Bsc = As + 128 * 64 * 2;
#pragma unroll
    for (int p = 0; p < 4; ++p) {
      int idx = p * 256 + sidx;
      int r = idx >> 3, c8 = idx & 7;
      *(u16x8*)(As + r * 128 + ((c8 * 16) ^ ((r & 7) << 4))) = ra[p];
    }
#pragma unroll
    for (int p = 0; p < NPB; ++p) {
      int idx = p * 256 + sidx;
      int r = idx >> 3, c8 = idx & 7;
      *(u16x8*)(Bsc + r * 128 + ((c8 * 16) ^ ((r & 7) << 4))) = rb[p];
    }
  };

  auto compute = [&](int b) {
    const char* As  = (const char*)&lds[b][0];
    const char* Bsc = As + 128 * 64 * 2;
#pragma unroll
    for (int ks = 0; ks < 2; ++ks) {
      int kb = ks * 64 + lk * 16;
      s16x8 af[4], bfr[FN];
#pragma unroll
      for (int m = 0; m < 4; ++m) {
        int row = wr * 64 + m * 16 + lr;
        af[m] = *(const s16x8*)(As + row * 128 + (kb ^ ((row & 7) << 4)));
      }
#pragma unroll
      for (int n = 0; n < FN; ++n) {
        int row = wc * WN + n * 16 + lr;
        bfr[n] = *(const s16x8*)(Bsc + row * 128 + (kb ^ ((row & 7) << 4)));
      }
#pragma unroll
      for (int m = 0; m < 4; ++m)
#pragma unroll
        for (int n = 0; n < FN; ++n)
          acc[m][n] = __builtin_amdgcn_mfma_f32_16x16x32_bf16(af[m], bfr[n], acc[m][n], 0, 0, 0);
    }
  };

  loadTile(0);
  dswrite(0);
  __syncthreads();
  for (int kk = 0; kk < nK; ++kk) {
    int b = kk & 1;
    if (kk + 1 < nK) loadTile(kk + 1);
    compute(b);
    if (kk + 1 < nK) { dswrite(b ^ 1); __syncthreads(); }
  }

#pragma unroll
  for (int m = 0; m < 4; ++m) {
#pragma unroll
    for (int n = 0; n < FN; ++n) {
      int col = n0 + wc * WN + n * 16 + lr;
#pragma unroll
      for (int q = 0; q < 4; ++q) {
        int row = m0 + wr * 64 + m * 16 + lk * 4 + q;
        if (row < M) {
          if constexpr (OBF) Cb[(size_t)row * ldC + col] = f2bf(acc[m][n][q]);
          else               Cf[(size_t)row * ldC + col] = acc[m][n][q];
        }
      }
    }
  }

  if constexpr (STATS) {
    __syncthreads();
    float* sb = (float*)&lds[0][0];
#pragma unroll
    for (int n = 0; n < FN; ++n) {
      float s1 = 0.f, s2 = 0.f;
#pragma unroll
      for (int m = 0; m < 4; ++m)
#pragma unroll
        for (int q = 0; q < 4; ++q) {
          int row = m0 + wr * 64 + m * 16 + lk * 4 + q;
          float v = (row < M) ? acc[m][n][q] : 0.f;
          s1 += v; s2 += v * v;
        }
      s1 += __shfl_xor(s1, 16); s2 += __shfl_xor(s2, 16);
      s1 += __shfl_xor(s1, 32); s2 += __shfl_xor(s2, 32);
      if (lk == 0) {
        int c = wc * WN + n * 16 + lr;
        sb[(wr * BN + c) * 2 + 0] = s1;
        sb[(wr * BN + c) * 2 + 1] = s2;
      }
    }
    __syncthreads();
    if (t < BN) {
      float s1 = sb[t * 2]     + sb[(BN + t) * 2];
      float s2 = sb[t * 2 + 1] + sb[(BN + t) * 2 + 1];
      p1[(size_t)blockIdx.x * ncTot + n0 + t] = s1;
      p2[(size_t)blockIdx.x * ncTot + n0 + t] = s2;
    }
  }
}

// ---------- split-bf16 MFMA (f32 accuracy) with fused stats ----------
__global__ __launch_bounds__(256) void k_mfma_split(const float* __restrict__ Af, int K, int M,
                                                    const u16* __restrict__ Bh, const u16* __restrict__ Bl,
                                                    float* __restrict__ Cf,
                                                    float* __restrict__ p1, float* __restrict__ p2) {
  __shared__ u16 sAh[128 * 64], sAl[128 * 64], sBh[64 * 64], sBl[64 * 64];
  int t = threadIdx.x;
  int wid = t >> 6, lane = t & 63;
  int wr = wid >> 1, wc = wid & 1;
  int lr = lane & 15, lk = lane >> 4;
  int m0 = blockIdx.x * 128;
  int nK = K >> 6;

  u16x8 rah[4], ral[4], rbh[2], rbl[2];
  f32x4 acc[4][2];
#pragma unroll
  for (int m = 0; m < 4; ++m)
#pragma unroll
    for (int n = 0; n < 2; ++n) acc[m][n] = (f32x4){0.f, 0.f, 0.f, 0.f};

  auto loadTile = [&](int kk) {
    int kk0 = kk * 64;
#pragma unroll
    for (int p = 0; p < 4; ++p) {
      int idx = p * 256 + t;
      int r = idx >> 3, c8 = idx & 7;
      int row = m0 + r; if (row >= M) row = M - 1;
      const float* src = Af + (size_t)row * K + kk0 + c8 * 8;
      float4 a = *(const float4*)src;
      float4 b = *(const float4*)(src + 4);
      float v[8];
      *(float4*)(v) = a; *(float4*)(v + 4) = b;
      u16x8 oh, ol;
#pragma unroll
      for (int j = 0; j < 8; ++j) {
        u16 h = f2bf(v[j]);
        oh[j] = h;
        ol[j] = f2bf(v[j] - bf2f(h));
      }
      rah[p] = oh; ral[p] = ol;
    }
#pragma unroll
    for (int p = 0; p < 2; ++p) {
      int idx = p * 256 + t;
      int r = idx >> 3, c8 = idx & 7;
      rbh[p] = *(const u16x8*)(Bh + (size_t)r * K + kk0 + c8 * 8);
      rbl[p] = *(const u16x8*)(Bl + (size_t)r * K + kk0 + c8 * 8);
    }
  };

  auto dswrite = [&]() {
    char* Ah = (char*)sAh; char* Al = (char*)sAl;
    char* Bhc = (char*)sBh; char* Blc = (char*)sBl;
#pragma unroll
    for (int p = 0; p < 4; ++p) {
      int idx = p * 256 + t;
      int r = idx >> 3, c8 = idx & 7;
      int off = r * 128 + ((c8 * 16) ^ ((r & 7) << 4));
      *(u16x8*)(Ah + off) = rah[p];
      *(u16x8*)(Al + off) = ral[p];
    }
#pragma unroll
    for (int p = 0; p < 2; ++p) {
      int idx = p * 256 + t;
      int r = idx >> 3, c8 = idx & 7;
      int off = r * 128 + ((c8 * 16) ^ ((r & 7) << 4));
      *(u16x8*)(Bhc + off) = rbh[p];
      *(u16x8*)(Blc + off) = rbl[p];
    }
  };

  auto compute = [&]() {
    const char* Ah = (const char*)sAh; const char* Al = (const char*)sAl;
    const char* Bhc = (const char*)sBh; const char* Blc = (const char*)sBl;
#pragma unroll
    for (int ks = 0; ks < 2; ++ks) {
      int kb = ks * 64 + lk * 16;
      s16x8 fah[4], fal[4], fbh[2], fbl[2];
#pragma unroll
      for (int m = 0; m < 4; ++m) {
        int row = wr * 64 + m * 16 + lr;
        int off = row * 128 + (kb ^ ((row & 7) << 4));
        fah[m] = *(const s16x8*)(Ah + off);
        fal[m] = *(const s16x8*)(Al + off);
      }
#pragma unroll
      for (int n = 0; n < 2; ++n) {
        int row = wc * 32 + n * 16 + lr;
        int off = row * 128 + (kb ^ ((row & 7) << 4));
        fbh[n] = *(const s16x8*)(Bhc + off);
        fbl[n] = *(const s16x8*)(Blc + off);
      }
#pragma unroll
      for (int m = 0; m < 4; ++m)
#pragma unroll
        for (int n = 0; n < 2; ++n) {
          acc[m][n] = __builtin_amdgcn_mfma_f32_16x16x32_bf16(fah[m], fbh[n], acc[m][n], 0, 0, 0);
          acc[m][n] = __builtin_amdgcn_mfma_f32_16x16x32_bf16(fah[m], fbl[n], acc[m][n], 0, 0, 0);
          acc[m][n] = __builtin_amdgcn_mfma_f32_16x16x32_bf16(fal[m], fbh[n], acc[m][n], 0, 0, 0);
        }
    }
  };

  loadTile(0);
  for (int kk = 0; kk < nK; ++kk) {
    __syncthreads();
    dswrite();
    __syncthreads();
    if (kk + 1 < nK) loadTile(kk + 1);
    compute();
  }

#pragma unroll
  for (int m = 0; m < 4; ++m) {
#pragma unroll
    for (int n = 0; n < 2; ++n) {
      int col = wc * 32 + n * 16 + lr;
#pragma unroll
      for (int q = 0; q < 4; ++q) {
        int row = m0 + wr * 64 + m * 16 + lk * 4 + q;
        if (row < M) Cf[(size_t)row * 64 + col] = acc[m][n][q];
      }
    }
  }

  __syncthreads();
  float* sb = (float*)sAh;
#pragma unroll
  for (int n = 0; n < 2; ++n) {
    float s1 = 0.f, s2 = 0.f;
#pragma unroll
    for (int m = 0; m < 4; ++m)
#pragma unroll
      for (int q = 0; q < 4; ++q) {
        int row = m0 + wr * 64 + m * 16 + lk * 4 + q;
        float v = (row < M) ? acc[m][n][q] : 0.f;
        s1 += v; s2 += v * v;
      }
    s1 += __shfl_xor(s1, 16); s2 += __shfl_xor(s2, 16);
    s1 += __shfl_xor(s1, 32); s2 += __shfl_xor(s2, 32);
    if (lk == 0) {
      int c = wc * 32 + n * 16 + lr;
      sb[(wr * 64 + c) * 2 + 0] = s1;
      sb[(wr * 64 + c) * 2 + 1] = s2;
    }
  }
  __syncthreads();
  if (t < 64) {
    float s1 = sb[t * 2]     + sb[(64 + t) * 2];
    float s2 = sb[t * 2 + 1] + sb[(64 + t) * 2 + 1];
    p1[(size_t)blockIdx.x * 64 + t] = s1;
    p2[(size_t)blockIdx.x * 64 + t] = s2;
  }
}

// ---------- reduce partials -> BN scale/shift ----------
__global__ __launch_bounds__(256) void k_reduce_fin(const float* __restrict__ part1,
                                                    const float* __restrict__ part2,
                                                    int nb, int C, float invN,
                                                    const float* __restrict__ gamma,
                                                    const float* __restrict__ beta,
                                                    float* __restrict__ a_out,
                                                    float* __restrict__ b_out) {
  int c = blockIdx.x;
  int t = threadIdx.x;
  float s1 = 0.f, s2 = 0.f;
  for (int b = t; b < nb; b += 256) {
    s1 += part1[(size_t)b * C + c];
    s2 += part2[(size_t)b * C + c];
  }
  for (int m = 32; m; m >>= 1) { s1 += __shfl_xor(s1, m); s2 += __shfl_xor(s2, m); }
  __shared__ float l1[4], l2[4];
  if ((t & 63) == 0) { l1[t >> 6] = s1; l2[t >> 6] = s2; }
  __syncthreads();
  if (t == 0) {
    s1 = l1[0] + l1[1] + l1[2] + l1[3];
    s2 = l2[0] + l2[1] + l2[2] + l2[3];
    float mu  = s1 * invN;
    float var = s2 * invN - mu * mu;
    float a = gamma[c] * rsqrtf(var + 1e-5f);
    a_out[c] = a;
    b_out[c] = beta[c] - mu * a;
  }
}

// ---------- UN = bf16(au*xu + bue) ----------
__global__ __launch_bounds__(256) void k_scaleUN(const u16* __restrict__ ub, const float* __restrict__ au,
                                                 const float* __restrict__ bue, u16* __restrict__ un, int n8) {
  for (int i = blockIdx.x * 256 + threadIdx.x; i < n8; i += gridDim.x * 256) {
    int c0 = (i & 7) * 8;
    float av[8], bv[8];
    *(float4*)(av) = *(const float4*)(au + c0);  *(float4*)(av + 4) = *(const float4*)(au + c0 + 4);
    *(float4*)(bv) = *(const float4*)(bue + c0); *(float4*)(bv + 4) = *(const float4*)(bue + c0 + 4);
    u16x8 in = ((const u16x8*)ub)[i];
    u16x8 o;
#pragma unroll
    for (int j = 0; j < 8; ++j) o[j] = f2bf(bf2f((u16)in[j]) * av[j] + bv[j]);
    ((u16x8*)un)[i] = o;
  }
}

// ---------- PS = f16(ap * su) ----------
__global__ __launch_bounds__(256) void k_scaleP(const float* __restrict__ P, const float* __restrict__ ap,
                                                __half* __restrict__ PS, int n8) {
  for (int i = blockIdx.x * 256 + threadIdx.x; i < n8; i += gridDim.x * 256) {
    int c0 = (i & 7) * 8;
    float4 s0 = *(const float4*)(ap + c0), s1 = *(const float4*)(ap + c0 + 4);
    float4 a = ((const float4*)P)[i * 2];
    float4 b = ((const float4*)P)[i * 2 + 1];
    __half2 o0 = __floats2half2_rn(a.x * s0.x, a.y * s0.y);
    __half2 o1 = __floats2half2_rn(a.z * s0.z, a.w * s0.w);
    __half2 o2 = __floats2half2_rn(b.x * s1.x, b.y * s1.y);
    __half2 o3 = __floats2half2_rn(b.z * s1.z, b.w * s1.w);
    uint4 out;
    out.x = *(unsigned*)&o0; out.y = *(unsigned*)&o1;
    out.z = *(unsigned*)&o2; out.w = *(unsigned*)&o3;
    ((uint4*)PS)[i] = out;
  }
}

// ---------- degree count + per-edge rank (one atomic pass) ----------
__global__ void k_count(const int* __restrict__ ei, int E, int* __restrict__ cnt,
                        int* __restrict__ rank) {
  for (int e = blockIdx.x * blockDim.x + threadIdx.x; e < E; e += gridDim.x * blockDim.x)
    rank[e] = atomicAdd(&cnt[ei[e]], 1);
}

// ---------- CSR scans ----------
__global__ __launch_bounds__(256) void k_scanA(const int* __restrict__ cnt, int N,
                                               int* __restrict__ rowptr, int* __restrict__ bs) {
  __shared__ int s[256];
  int t = threadIdx.x, gi = blockIdx.x * 256 + t;
  int v = (gi < N) ? cnt[gi] : 0;
  s[t] = v;
  __syncthreads();
  for (int off = 1; off < 256; off <<= 1) {
    int add = (t >= off) ? s[t - off] : 0;
    __syncthreads();
    s[t] += add;
    __syncthreads();
  }
  if (gi < N) rowptr[gi + 1] = s[t];
  if (t == 255) bs[blockIdx.x] = s[255];
}

__global__ __launch_bounds__(512) void k_scanB(int* __restrict__ bs, int nb) {
  __shared__ int s[512];
  int t = threadIdx.x;
  s[t] = (t < nb) ? bs[t] : 0;
  __syncthreads();
  for (int off = 1; off < 512; off <<= 1) {
    int add = (t >= off) ? s[t - off] : 0;
    __syncthreads();
    s[t] += add;
    __syncthreads();
  }
  if (t < nb) bs[t] = s[t];
}

__global__ __launch_bounds__(256) void k_scanC(int N, int* __restrict__ rowptr, const int* __restrict__ bs) {
  int gi = blockIdx.x * 256 + threadIdx.x;
  if (gi == 0) rowptr[0] = 0;
  if (gi < N && blockIdx.x > 0) rowptr[gi + 1] += bs[blockIdx.x - 1];
}

// ---------- bucket fill: atomic-free 4B scatter ----------
__global__ void k_fill(const int* __restrict__ ei, const int* __restrict__ ej,
                       const int* __restrict__ rank, int E,
                       const int* __restrict__ rowptr, int* __restrict__ srcj) {
  for (int e = blockIdx.x * blockDim.x + threadIdx.x; e < E; e += gridDim.x * blockDim.x)
    srcj[rowptr[ei[e]] + rank[e]] = ej[e];
}

// ---------- fused per-node: logits from PS + softmax + UN aggregation ----------
__global__ __launch_bounds__(256) void k_nodeall(const __half* __restrict__ PS,
                                                 const int* __restrict__ srcj,
                                                 const int* __restrict__ rowptr,
                                                 const u16* __restrict__ UN,
                                                 int N, float* __restrict__ agg) {
  int lane = threadIdx.x & 63;
  int node = blockIdx.x * 4 + (threadIdx.x >> 6);
  if (node >= N) return;
  int lane16 = lane & 15;
  int g4 = lane >> 4;
  const uint2* P2 = (const uint2*)PS;
  uint2 uu = P2[(size_t)node * 16 + lane16];
  float2 ua = __half22float2(*(const __half2*)&uu.x);
  float2 ub = __half22float2(*(const __half2*)&uu.y);
  float psl = __half2float(PS[(size_t)node * 64 + lane]);
  int b0 = rowptr[node], b1 = rowptr[node + 1];
  int deg = b1 - b0;
  float acc = 0.f;
  if (deg > 0) {
    int cnt = deg < 64 ? deg : 64;
    int jj = (lane < cnt) ? srcj[b0 + lane] : 0;
    float lg = -INFINITY;
    int capbase = lane & ~3;
    int capsrc  = (lane & 3) << 4;
    for (int ss = 0; ss < cnt; ss += 4) {
      int sl = ss + g4;
      int j = __shfl(jj, sl < cnt ? sl : cnt - 1);
      uint2 vv = P2[(size_t)j * 16 + lane16];
      float2 va = __half22float2(*(const __half2*)&vv.x);
      float2 vb = __half22float2(*(const __half2*)&vv.y);
      float d0 = ua.x - va.x, d1 = ua.y - va.y, d2 = ub.x - vb.x, d3 = ub.y - vb.y;
      float p = d0 * d0 + d1 * d1 + d2 * d2 + d3 * d3;
      p += __shfl_xor(p, 1, 16);
      p += __shfl_xor(p, 2, 16);
      p += __shfl_xor(p, 4, 16);
      p += __shfl_xor(p, 8, 16);
      float val = __shfl(p, capsrc);
      if (ss == capbase && lane < cnt) lg = -val;
    }
    float mx = lg;
    for (int s = b0 + 64; s < b1; ++s) {
      int j = srcj[s];
      float d = psl - __half2float(PS[(size_t)j * 64 + lane]);
      float p = d * d;
      for (int m = 32; m; m >>= 1) p += __shfl_xor(p, m);
      mx = fmaxf(mx, -p);
    }
    for (int m = 32; m; m >>= 1) mx = fmaxf(mx, __shfl_xor(mx, m));
    float ex = (lane < cnt) ? __expf(lg - mx) : 0.f;
    float sm = ex;
    for (int s = b0 + 64; s < b1; ++s) {
      int j = srcj[s];
      float d = psl - __half2float(PS[(size_t)j * 64 + lane]);
      float p = d * d;
      for (int m = 32; m; m >>= 1) p += __shfl_xor(p, m);
      if (lane == 0) sm += __expf(-p - mx);
    }
    for (int m = 32; m; m >>= 1) sm += __shfl_xor(sm, m);
    float inv = 1.0f / (sm + 1e-16f);
    float w = ex * inv;
    int ss = 0;
    for (; ss + 4 <= cnt; ss += 4) {
      int   j0 = __shfl(jj, ss),     j1 = __shfl(jj, ss + 1);
      int   j2 = __shfl(jj, ss + 2), j3 = __shfl(jj, ss + 3);
      float w0 = __shfl(w, ss),      w1 = __shfl(w, ss + 1);
      float w2 = __shfl(w, ss + 2),  w3 = __shfl(w, ss + 3);
      float v0 = bf2f(UN[(size_t)j0 * 64 + lane]);
      float v1 = bf2f(UN[(size_t)j1 * 64 + lane]);
      float v2 = bf2f(UN[(size_t)j2 * 64 + lane]);
      float v3 = bf2f(UN[(size_t)j3 * 64 + lane]);
      acc += w0 * v0 + w1 * v1 + w2 * v2 + w3 * v3;
    }
    for (; ss < cnt; ++ss) {
      int j0 = __shfl(jj, ss);
      float w0 = __shfl(w, ss);
      acc += w0 * bf2f(UN[(size_t)j0 * 64 + lane]);
    }
    for (int s = b0 + 64; s < b1; ++s) {
      int j = srcj[s];
      float d = psl - __half2float(PS[(size_t)j * 64 + lane]);
      float p = d * d;
      for (int m = 32; m; m >>= 1) p += __shfl_xor(p, m);
      acc += __expf(-p - mx) * inv * bf2f(UN[(size_t)j * 64 + lane]);
    }
  }
  agg[(size_t)node * 64 + lane] = acc;
}

// ---------- h = (z - agg) @ Minv + agg   (uses C@Minv = I - Minv), out bf16 ----------
__global__ __launch_bounds__(256) void k_solve(const u16* __restrict__ UN, const float* __restrict__ agg,
                                               const float* __restrict__ minv,
                                               u16* __restrict__ HB, int ntiles) {
  __shared__ float mS[4096];
  int t = threadIdx.x;
  int c16 = t & 15, rg = t >> 4;
  for (int idx = t; idx < 1024; idx += 256)
    ((float4*)mS)[idx] = ((const float4*)minv)[idx];
  __syncthreads();
  for (int tile = blockIdx.x; tile < ntiles; tile += gridDim.x) {
    int row = tile * 16 + rg;
    const u16*  ur = UN + (size_t)row * 64;
    const float* gr = agg + (size_t)row * 64;
    float4 acc = *(const float4*)(gr + c16 * 4);   // + agg term
#pragma unroll 4
    for (int k = 0; k < 64; ++k) {
      float z = bf2f(ur[k]) - gr[k];
      float4 m4 = ((const float4*)mS)[k * 16 + c16];
      acc.x += z * m4.x;
      acc.y += z * m4.y;
      acc.z += z * m4.z;
      acc.w += z * m4.w;
    }
    ((ushort4*)HB)[(size_t)row * 16 + c16] =
        make_ushort4(f2bf(acc.x), f2bf(acc.y), f2bf(acc.z), f2bf(acc.w));
  }
}

// ---------- final BN + leaky: bf16 raw -> f32 out ----------
__global__ __launch_bounds__(256) void k_bnact16(const u16* __restrict__ raw, const float* __restrict__ af,
                                                 const float* __restrict__ bfp, float* __restrict__ out, int n8) {
  int i = blockIdx.x * 256 + threadIdx.x;
  int stride = gridDim.x * 256;
  for (; i < n8; i += stride) {
    int c0 = (i & 31) * 8;
    float av[8], bv[8];
    *(float4*)(av) = *(const float4*)(af + c0);  *(float4*)(av + 4) = *(const float4*)(af + c0 + 4);
    *(float4*)(bv) = *(const float4*)(bfp + c0); *(float4*)(bv + 4) = *(const float4*)(bfp + c0 + 4);
    u16x8 r = ((const u16x8*)raw)[i];
    float o[8];
#pragma unroll
    for (int j = 0; j < 8; ++j) {
      float v = bf2f((u16)r[j]) * av[j] + bv[j];
      o[j] = (v > 0.f) ? v : 0.01f * v;
    }
    ((float4*)out)[i * 2]     = *(float4*)(o);
    ((float4*)out)[i * 2 + 1] = *(float4*)(o + 4);
  }
}

extern "C" void kernel_launch(void* const* d_in, const int* in_sizes, int n_in,
                              void* d_out, int out_size, void* d_ws, size_t ws_size,
                              hipStream_t stream) {
  const float* x    = (const float*)d_in[0];
  const float* y    = (const float*)d_in[1];
  const int*   eidx = (const int*)d_in[3];
  const float* Wu   = (const float*)d_in[4];
  const float* gu   = (const float*)d_in[5];
  const float* bu   = (const float*)d_in[6];
  const float* Wp   = (const float*)d_in[7];
  const float* gp   = (const float*)d_in[8];
  const float* bp   = (const float*)d_in[9];
  const float* cIn  = (const float*)d_in[10];
  const float* Wm   = (const float*)d_in[11];
  const float* gm   = (const float*)d_in[12];
  const float* bm   = (const float*)d_in[13];
  const float* Wf   = (const float*)d_in[14];
  const float* gf   = (const float*)d_in[15];
  const float* bfv  = (const float*)d_in[16];

  const int N = in_sizes[0] / 256;
  const int E = in_sizes[3] / 2;
  const int* ei = eidx;
  const int* ej = eidx + E;

  char* ws = (char*)d_ws;
  float* MINV  = (float*)(ws + OFF_MINV);
  float* AU    = (float*)(ws + OFF_AU);
  float* BUE   = (float*)(ws + OFF_BUE);
  float* AP    = (float*)(ws + OFF_AP);
  float* APBE  = (float*)(ws + OFF_APBE);
  float* AM    = (float*)(ws + OFF_AM);
  float* BM    = (float*)(ws + OFF_BM);
  float* AF    = (float*)(ws + OFF_AF);
  float* BF    = (float*)(ws + OFF_BF);
  int*   BSC   = (int*)(ws + OFF_BS);
  u16*   WUT   = (u16*)(ws + OFF_WUT);
  u16*   WMT   = (u16*)(ws + OFF_WMT);
  u16*   WFT   = (u16*)(ws + OFF_WFT);
  u16*   WPH   = (u16*)(ws + OFF_WPH);
  u16*   WPL   = (u16*)(ws + OFF_WPL);
  float* PART1 = (float*)(ws + OFF_PART1);
  float* PART2 = (float*)(ws + OFF_PART2);
  int*   ROWPTR= (int*)(ws + OFF_ROWPTR);
  int*   COUNT = (int*)(ws + OFF_COUNT);
  int*   RANK  = (int*)(ws + OFF_RANK);
  u16*   HB    = (u16*)(ws + OFF_RANK);      // reuse (RANK dead after k_fill)
  int*   SRCJ  = (int*)(ws + OFF_SRCJ);
  u16*   RAWO  = (u16*)(ws + OFF_SRCJ);      // reuse (SRCJ dead after k_nodeall)
  u16*   UBRAW = (u16*)(ws + OFF_U);
  u16*   UN    = (u16*)(ws + OFF_UN);
  float* P     = (float*)(ws + OFF_P);
  float* AGG   = (float*)(ws + OFF_P);       // reuse P region (P dead after k_scaleP)
  __half* PS   = (__half*)(ws + OFF_PS);
  u16*   H2    = (u16*)(ws + OFF_H2);

  const float invN = 1.0f / (float)N;
  const int ntiles16 = N / 16;
  const int nbScan   = (N + 255) / 256;
  const int mtiles   = (N + 127) / 128;
  const int n8_64    = N * 64 / 8;
  const int n8_256   = N * 256 / 8;

  hipMemsetAsync(COUNT, 0, (size_t)N * 4, stream);

  k_prep<<<1, 256, 0, stream>>>(cIn, MINV);
  k_tcvt<<<64,  256, 0, stream>>>(Wu, WUT, 256, 64);
  k_tcvt<<<64,  256, 0, stream>>>(Wm, WMT, 64, 256);
  k_tcvt<<<512, 256, 0, stream>>>(Wf, WFT, 512, 256);
  k_tcvt_split<<<64, 256, 0, stream>>>(Wp, WPH, WPL);

  // CSR build: single atomic pass (count+rank), scans, atomic-free fill
  k_count<<<2048, 256, 0, stream>>>(ei, E, COUNT, RANK);
  k_scanA<<<nbScan, 256, 0, stream>>>(COUNT, N, ROWPTR, BSC);
  k_scanB<<<1, 512, 0, stream>>>(BSC, nbScan);
  k_scanC<<<nbScan, 256, 0, stream>>>(N, ROWPTR, BSC);
  k_fill<<<2048, 256, 0, stream>>>(ei, ej, RANK, E, ROWPTR, SRCJ);

  // unary embedding (stats fused) -> UBRAW bf16; BN params; UN table
  k_mfma<64, 2, 1, 1><<<dim3(mtiles, 1), 256, 0, stream>>>(
      nullptr, x, 256, 256, N, nullptr, nullptr, nullptr, nullptr, WUT,
      nullptr, UBRAW, 64, 64, PART1, PART2);
  k_reduce_fin<<<64, 256, 0, stream>>>(PART1, PART2, mtiles, 64, invN, gu, bu, AU, BUE);
  k_scaleUN<<<1024, 256, 0, stream>>>(UBRAW, AU, BUE, UN, n8_64);

  // pairwise embedding: split-bf16 MFMA (stats fused) -> P f32; PS f16 table
  k_mfma_split<<<mtiles, 256, 0, stream>>>(y, 256, N, WPH, WPL, P, PART1, PART2);
  k_reduce_fin<<<64, 256, 0, stream>>>(PART1, PART2, mtiles, 64, invN, gp, bp, AP, APBE);
  k_scaleP<<<1024, 256, 0, stream>>>(P, AP, PS, n8_64);

  // fused logits + softmax + aggregation (AGG overwrites P region)
  k_nodeall<<<(N + 3) / 4, 256, 0, stream>>>(PS, SRCJ, ROWPTR, UN, N, AGG);

  // CRF solve -> h bf16 (HB overwrites RANK region)
  k_solve<<<2048, 256, 0, stream>>>(UN, AGG, MINV, HB, ntiles16);

  // h @ Wm -> h2 bf16 (stats fused)
  k_mfma<128, 0, 1, 1><<<dim3(mtiles, 2), 256, 0, stream>>>(
      HB, nullptr, 64, 64, N, nullptr, nullptr, nullptr, nullptr, WMT,
      nullptr, H2, 256, 256, PART1, PART2);
  k_reduce_fin<<<256, 256, 0, stream>>>(PART1, PART2, mtiles, 256, invN, gm, bm, AM, BM);

  // [leaky(bn(h2)), y] @ Wf -> raw bf16 (stats fused, overwrites SRCJ region), BN + leaky -> d_out
  k_mfma<128, 1, 1, 1><<<dim3(mtiles, 2), 256, 0, stream>>>(
      nullptr, nullptr, 0, 512, N, H2, y, AM, BM, WFT,
      nullptr, RAWO, 256, 256, PART1, PART2);
  k_reduce_fin<<<256, 256, 0, stream>>>(PART1, PART2, mtiles, 256, invN, gf, bfv, AF, BF);
  k_bnact16<<<2048, 256, 0, stream>>>(RAWO, AF, BF, (float*)d_out, n8_256);
}

// Round 8
// 595.695 us; speedup vs baseline: 4.7667x; 1.2637x over previous
//
#include <hip/hip_runtime.h>
#include <hip/hip_fp16.h>
#include <math.h>

typedef unsigned short u16;
typedef short s16x8 __attribute__((ext_vector_type(8)));
typedef unsigned short u16x8 __attribute__((ext_vector_type(8)));
typedef float f32x4 __attribute__((ext_vector_type(4)));

// ---------- helpers ----------
__device__ __forceinline__ float bf2f(u16 u) {
  unsigned x = ((unsigned)u) << 16;
  return __uint_as_float(x);
}
__device__ __forceinline__ u16 f2bf(float f) {
  unsigned x = __float_as_uint(f);
  unsigned r = x + 0x7FFFu + ((x >> 16) & 1u);
  return (u16)(r >> 16);
}

// ---------- ws layout (bytes) ----------
static const size_t OFF_MINV   = 0;
static const size_t OFF_AU     = 32ull * 1024;
static const size_t OFF_BUE    = 32ull * 1024 + 256;
static const size_t OFF_AP     = 32ull * 1024 + 512;
static const size_t OFF_APBE   = 32ull * 1024 + 768;
static const size_t OFF_AM     = 36ull * 1024;
static const size_t OFF_BM     = 37ull * 1024;
static const size_t OFF_AF     = 38ull * 1024;
static const size_t OFF_BF     = 39ull * 1024;
static const size_t OFF_BTOT   = 40ull * 1024;            // bucket totals (512 int)
static const size_t OFF_BOFF   = 44ull * 1024;            // bucket offsets (513 int)
static const size_t OFF_WUT    = 64ull * 1024;
static const size_t OFF_WMT    = 128ull * 1024;
static const size_t OFF_WFT    = 192ull * 1024;
static const size_t OFF_WPH    = 512ull * 1024;
static const size_t OFF_WPL    = 576ull * 1024;
static const size_t OFF_PART1  = 1ull  * 1024 * 1024;
static const size_t OFF_PART2  = 2ull  * 1024 * 1024;
static const size_t OFF_ROWPTR = 3ull  * 1024 * 1024;
static const size_t OFF_BLKCNT = 5ull  * 1024 * 1024;     // 1024*512 int = 2MB; dead after kA3 -> HB bf16 N*64
static const size_t OFF_SRCJ   = 18ull * 1024 * 1024;     // E int; dead after k_nodeall -> RAWO bf16 N*256
static const size_t OFF_U      = 44ull * 1024 * 1024;     // UBRAW bf16 N*64
static const size_t OFF_UN     = 57ull * 1024 * 1024;     // UN bf16 N*64
static const size_t OFF_P      = 70ull * 1024 * 1024;     // TMP uint2 E early; then P f32; then AGG f32
static const size_t OFF_PS     = 109ull * 1024 * 1024;
static const size_t OFF_H2     = 122ull * 1024 * 1024;

#define NBLK_BIN 1024

// ---------- K0: Minv = (I + c^T c)^-1 (conflict-free GJ; C@Minv = I - Minv) ----------
__global__ __launch_bounds__(256) void k_prep(const float* __restrict__ c,
                                              float* __restrict__ minv_out) {
  __shared__ float CC[4096];
  __shared__ float aug[64 * 129];
  __shared__ float fs[64];
  float* cl = aug;
  int t = threadIdx.x;
  for (int idx = t; idx < 4096; idx += 256) cl[idx] = c[idx];
  __syncthreads();
  for (int idx = t; idx < 4096; idx += 256) {
    int a = idx >> 6, b = idx & 63;
    float s = (a == b) ? 1.f : 0.f;
    for (int k = 0; k < 64; ++k) s += cl[k * 64 + a] * cl[k * 64 + b];
    CC[idx] = s;
  }
  __syncthreads();
  for (int idx = t; idx < 8192; idx += 256) {
    int r = idx >> 7, cc = idx & 127;
    aug[r * 129 + cc] = (cc < 64) ? CC[r * 64 + cc] : (((cc - 64) == r) ? 1.f : 0.f);
  }
  __syncthreads();
  int cloc = t & 127;
  int rbase = t >> 7;
  for (int p = 0; p < 64; ++p) {
    float inv = 1.0f / aug[p * 129 + p];
    if (t < 64) fs[t] = (t == p) ? 0.f : aug[t * 129 + p];
    __syncthreads();
    if (t < 128) aug[p * 129 + t] *= inv;
    __syncthreads();
    float pc = aug[p * 129 + cloc];
#pragma unroll
    for (int rr = 0; rr < 64; rr += 2) {
      int r = rr + rbase;
      aug[r * 129 + cloc] -= fs[r] * pc;
    }
    __syncthreads();
  }
  for (int idx = t; idx < 4096; idx += 256) {
    int r = idx >> 6, cc = idx & 63;
    minv_out[idx] = aug[r * 129 + 64 + cc];
  }
}

// ---------- transpose + convert weights ----------
__global__ __launch_bounds__(256) void k_tcvt(const float* __restrict__ in, u16* __restrict__ outb,
                                              int Kd, int Nc) {
  int i = blockIdx.x * 256 + threadIdx.x;
  if (i < Kd * Nc) {
    int k = i / Nc, n = i - k * Nc;
    outb[(size_t)n * Kd + k] = f2bf(in[i]);
  }
}

__global__ __launch_bounds__(256) void k_tcvt_split(const float* __restrict__ in,
                                                    u16* __restrict__ outh, u16* __restrict__ outl) {
  int i = blockIdx.x * 256 + threadIdx.x;
  if (i < 256 * 64) {
    int k = i >> 6, n = i & 63;
    float v = in[i];
    u16 h = f2bf(v);
    float lo = v - bf2f(h);
    outh[(size_t)n * 256 + k] = h;
    outl[(size_t)n * 256 + k] = f2bf(lo);
  }
}

// ---------- binned CSR build ----------
// A1: per-block bucket histogram (bucket = i>>8)
__global__ __launch_bounds__(256) void kA1(const int* __restrict__ ei, int E, int chunk,
                                           int* __restrict__ blockCnt, int nbk) {
  __shared__ int c[512];
  int t = threadIdx.x, bid = blockIdx.x;
  c[t] = 0; c[t + 256] = 0;
  __syncthreads();
  int e0 = bid * chunk, e1 = min(E, e0 + chunk);
  for (int e = e0 + t; e < e1; e += 256) atomicAdd(&c[ei[e] >> 8], 1);
  __syncthreads();
  for (int b = t; b < nbk; b += 256) blockCnt[(size_t)bid * nbk + b] = c[b];
}

// A2: per-bucket exclusive scan over blocks (in place), bucket totals out
__global__ __launch_bounds__(256) void kA2(int* __restrict__ blockCnt, int nbk,
                                           int* __restrict__ bucketTot) {
  int b = blockIdx.x, t = threadIdx.x;
  int base = t * 4;
  int v0 = blockCnt[(size_t)(base + 0) * nbk + b];
  int v1 = blockCnt[(size_t)(base + 1) * nbk + b];
  int v2 = blockCnt[(size_t)(base + 2) * nbk + b];
  int v3 = blockCnt[(size_t)(base + 3) * nbk + b];
  int s1 = v0 + v1, s2 = s1 + v2, tot = s2 + v3;
  __shared__ int ps[256];
  ps[t] = tot;
  __syncthreads();
  for (int off = 1; off < 256; off <<= 1) {
    int a = (t >= off) ? ps[t - off] : 0;
    __syncthreads();
    ps[t] += a;
    __syncthreads();
  }
  int ex = (t > 0) ? ps[t - 1] : 0;
  blockCnt[(size_t)(base + 0) * nbk + b] = ex;
  blockCnt[(size_t)(base + 1) * nbk + b] = ex + v0;
  blockCnt[(size_t)(base + 2) * nbk + b] = ex + s1;
  blockCnt[(size_t)(base + 3) * nbk + b] = ex + s2;
  if (t == 255) bucketTot[b] = ps[255];
}

// A2b: scan bucket totals -> bucket offsets
__global__ __launch_bounds__(512) void kA2b(const int* __restrict__ bucketTot,
                                            int* __restrict__ bucketOff, int nbk) {
  __shared__ int s[512];
  int t = threadIdx.x;
  s[t] = (t < nbk) ? bucketTot[t] : 0;
  __syncthreads();
  for (int off = 1; off < 512; off <<= 1) {
    int a = (t >= off) ? s[t - off] : 0;
    __syncthreads();
    s[t] += a;
    __syncthreads();
  }
  if (t == 0) bucketOff[0] = 0;
  if (t < nbk) bucketOff[t + 1] = s[t];
}

// A3: LDS counting-sort of each block's chunk by bucket; write contiguous runs to TMP
__global__ __launch_bounds__(256) void kA3(const int* __restrict__ ei, const int* __restrict__ ej,
                                           int E, int chunk,
                                           const int* __restrict__ blockExc,
                                           const int* __restrict__ bucketOff,
                                           int nbk, uint2* __restrict__ tmp) {
  __shared__ int c[512], off[512], gb[512], cur[512];
  __shared__ uint2 stage[4096];
  int t = threadIdx.x, bid = blockIdx.x;
  c[t] = 0; c[t + 256] = 0;
  __syncthreads();
  int e0 = bid * chunk, e1 = min(E, e0 + chunk);
  int m = e1 - e0;
  for (int e = e0 + t; e < e1; e += 256) atomicAdd(&c[ei[e] >> 8], 1);
  __syncthreads();
  int v0 = c[t], v1 = c[t + 256];
  off[t] = v0; off[t + 256] = v1;
  __syncthreads();
  for (int o = 1; o < 512; o <<= 1) {
    int a0 = (t >= o) ? off[t - o] : 0;
    int a1 = ((t + 256) >= o) ? off[t + 256 - o] : 0;
    __syncthreads();
    off[t] += a0; off[t + 256] += a1;
    __syncthreads();
  }
  int ex0 = off[t] - v0, ex1 = off[t + 256] - v1;
  if (t < nbk)
    gb[t] = bucketOff[t] + blockExc[(size_t)bid * nbk + t] - ex0;
  if (t + 256 < nbk)
    gb[t + 256] = bucketOff[t + 256] + blockExc[(size_t)bid * nbk + t + 256] - ex1;
  cur[t] = ex0; cur[t + 256] = ex1;
  __syncthreads();
  for (int e = e0 + t; e < e1; e += 256) {
    int i = ei[e];
    int p = atomicAdd(&cur[i >> 8], 1);
    stage[p] = make_uint2((unsigned)i, (unsigned)ej[e]);
  }
  __syncthreads();
  for (int s = t; s < m; s += 256) {
    uint2 v = stage[s];
    tmp[gb[v.x >> 8] + s] = v;
  }
}

// B: per-bucket (256 nodes) LDS sort by node -> ROWPTR + coalesced SRCJ
#define BCAP 12288
__global__ __launch_bounds__(256) void kB(const uint2* __restrict__ tmp,
                                          const int* __restrict__ bucketOff,
                                          int nbk, int N, int E,
                                          int* __restrict__ rowptr, int* __restrict__ srcj) {
  __shared__ int cnt[256], sc[256], cur[256];
  __shared__ int jbuf[BCAP];
  int b = blockIdx.x, t = threadIdx.x;
  int nb0 = b << 8;
  int e0 = bucketOff[b], e1 = bucketOff[b + 1];
  int m = e1 - e0;
  cnt[t] = 0;
  __syncthreads();
  for (int s = t; s < m; s += 256) atomicAdd(&cnt[tmp[e0 + s].x - nb0], 1);
  __syncthreads();
  int v = cnt[t];
  sc[t] = v;
  __syncthreads();
  for (int off = 1; off < 256; off <<= 1) {
    int a = (t >= off) ? sc[t - off] : 0;
    __syncthreads();
    sc[t] += a;
    __syncthreads();
  }
  int exc = sc[t] - v;
  cur[t] = exc;
  if (nb0 + t < N) rowptr[nb0 + t] = e0 + exc;
  if (b == nbk - 1 && t == 0) rowptr[N] = E;
  __syncthreads();
  for (int s = t; s < m; s += 256) {
    uint2 e = tmp[e0 + s];
    int p = atomicAdd(&cur[e.x - nb0], 1);
    if (p < BCAP) jbuf[p] = (int)e.y;
  }
  __syncthreads();
  for (int s = t; s < m; s += 256) srcj[e0 + s] = jbuf[s];
}

// ---------- MFMA GEMM with optional fused column-stats ----------
template<int BN, int AMODE, int OBF, int STATS>
__global__ __launch_bounds__(256) void k_mfma(const u16* __restrict__ Abf, const float* __restrict__ Af32,
                                              int ldA, int K, int M,
                                              const u16* __restrict__ h2, const float* __restrict__ yy,
                                              const float* __restrict__ am, const float* __restrict__ bm,
                                              const u16* __restrict__ Bt,
                                              float* __restrict__ Cf, u16* __restrict__ Cb, int ldC,
                                              int ncTot, float* __restrict__ p1, float* __restrict__ p2) {
  constexpr int WN  = BN / 2;
  constexpr int FN  = WN / 16;
  constexpr int NPB = BN / 32;
  __shared__ u16 lds[2][(128 + BN) * 64];

  int t = threadIdx.x;
  int wid = t >> 6, lane = t & 63;
  int wr = wid >> 1, wc = wid & 1;
  int lr = lane & 15, lk = lane >> 4;
  int m0 = blockIdx.x * 128;
  int n0 = blockIdx.y * BN;
  int nK = K >> 6;

  int sidx = t;
  u16x8 ra[4];
  u16x8 rb[NPB];

  f32x4 acc[4][FN];
#pragma unroll
  for (int m = 0; m < 4; ++m)
#pragma unroll
    for (int n = 0; n < FN; ++n) acc[m][n] = (f32x4){0.f, 0.f, 0.f, 0.f};

  auto loadTile = [&](int kk) {
    int kk0 = kk * 64;
#pragma unroll
    for (int p = 0; p < 4; ++p) {
      int idx = p * 256 + sidx;
      int r = idx >> 3, c8 = idx & 7;
      int row = m0 + r; if (row >= M) row = M - 1;
      int k = kk0 + c8 * 8;
      if constexpr (AMODE == 0) {
        ra[p] = *(const u16x8*)(Abf + (size_t)row * ldA + k);
      } else if constexpr (AMODE == 2) {
        const float* src = Af32 + (size_t)row * ldA + k;
        float4 a = *(const float4*)src;
        float4 b = *(const float4*)(src + 4);
        u16x8 o;
        o[0] = f2bf(a.x); o[1] = f2bf(a.y); o[2] = f2bf(a.z); o[3] = f2bf(a.w);
        o[4] = f2bf(b.x); o[5] = f2bf(b.y); o[6] = f2bf(b.z); o[7] = f2bf(b.w);
        ra[p] = o;
      } else {
        if (kk0 < 256) {
          u16x8 h8 = *(const u16x8*)(h2 + (size_t)row * 256 + k);
          float av[8], bv[8];
          *(float4*)(av)     = *(const float4*)(am + k);
          *(float4*)(av + 4) = *(const float4*)(am + k + 4);
          *(float4*)(bv)     = *(const float4*)(bm + k);
          *(float4*)(bv + 4) = *(const float4*)(bm + k + 4);
          u16x8 o;
#pragma unroll
          for (int j = 0; j < 8; ++j) {
            float v = bf2f((u16)h8[j]) * av[j] + bv[j];
            v = v > 0.f ? v : 0.01f * v;
            o[j] = f2bf(v);
          }
          ra[p] = o;
        } else {
          float yv[8];
          *(float4*)(yv)     = *(const float4*)(yy + (size_t)row * 256 + (k - 256));
          *(float4*)(yv + 4) = *(const float4*)(yy + (size_t)row * 256 + (k - 256) + 4);
          u16x8 o;
#pragma unroll
          for (int j = 0; j < 8; ++j) o[j] = f2bf(yv[j]);
          ra[p] = o;
        }
      }
    }
#pragma unroll
    for (int p = 0; p < NPB; ++p) {
      int idx = p * 256 + sidx;
      int r = idx >> 3, c8 = idx & 7;
      rb[p] = *(const u16x8*)(Bt + (size_t)(n0 + r) * K + kk0 + c8 * 8);
    }
  };

  auto dswrite = [&](int b) {
    char* As  = (char*)&lds[b][0];
    char* Bsc = As + 128 * 64 * 2;
#pragma unroll
    for (int p = 0; p < 4; ++p) {
      int idx = p * 256 + sidx;
      int r = idx >> 3, c8 = idx & 7;
      *(u16x8*)(As + r * 128 + ((c8 * 16) ^ ((r & 7) << 4))) = ra[p];
    }
#pragma unroll
    for (int p = 0; p < NPB; ++p) {
      int idx = p * 256 + sidx;
      int r = idx >> 3, c8 = idx & 7;
      *(u16x8*)(Bsc + r * 128 + ((c8 * 16) ^ ((r & 7) << 4))) = rb[p];
    }
  };

  auto compute = [&](int b) {
    const char* As  = (const char*)&lds[b][0];
    const char* Bsc = As + 128 * 64 * 2;
#pragma unroll
    for (int ks = 0; ks < 2; ++ks) {
      int kb = ks * 64 + lk * 16;
      s16x8 af[4], bfr[FN];
#pragma unroll
      for (int m = 0; m < 4; ++m) {
        int row = wr * 64 + m * 16 + lr;
        af[m] = *(const s16x8*)(As + row * 128 + (kb ^ ((row & 7) << 4)));
      }
#pragma unroll
      for (int n = 0; n < FN; ++n) {
        int row = wc * WN + n * 16 + lr;
        bfr[n] = *(const s16x8*)(Bsc + row * 128 + (kb ^ ((row & 7) << 4)));
      }
#pragma unroll
      for (int m = 0; m < 4; ++m)
#pragma unroll
        for (int n = 0; n < FN; ++n)
          acc[m][n] = __builtin_amdgcn_mfma_f32_16x16x32_bf16(af[m], bfr[n], acc[m][n], 0, 0, 0);
    }
  };

  loadTile(0);
  dswrite(0);
  __syncthreads();
  for (int kk = 0; kk < nK; ++kk) {
    int b = kk & 1;
    if (kk + 1 < nK) loadTile(kk + 1);
    compute(b);
    if (kk + 1 < nK) { dswrite(b ^ 1); __syncthreads(); }
  }

#pragma unroll
  for (int m = 0; m < 4; ++m) {
#pragma unroll
    for (int n = 0; n < FN; ++n) {
      int col = n0 + wc * WN + n * 16 + lr;
#pragma unroll
      for (int q = 0; q < 4; ++q) {
        int row = m0 + wr * 64 + m * 16 + lk * 4 + q;
        if (row < M) {
          if constexpr (OBF) Cb[(size_t)row * ldC + col] = f2bf(acc[m][n][q]);
          else               Cf[(size_t)row * ldC + col] = acc[m][n][q];
        }
      }
    }
  }

  if constexpr (STATS) {
    __syncthreads();
    float* sb = (float*)&lds[0][0];
#pragma unroll
    for (int n = 0; n < FN; ++n) {
      float s1 = 0.f, s2 = 0.f;
#pragma unroll
      for (int m = 0; m < 4; ++m)
#pragma unroll
        for (int q = 0; q < 4; ++q) {
          int row = m0 + wr * 64 + m * 16 + lk * 4 + q;
          float v = (row < M) ? acc[m][n][q] : 0.f;
          s1 += v; s2 += v * v;
        }
      s1 += __shfl_xor(s1, 16); s2 += __shfl_xor(s2, 16);
      s1 += __shfl_xor(s1, 32); s2 += __shfl_xor(s2, 32);
      if (lk == 0) {
        int c = wc * WN + n * 16 + lr;
        sb[(wr * BN + c) * 2 + 0] = s1;
        sb[(wr * BN + c) * 2 + 1] = s2;
      }
    }
    __syncthreads();
    if (t < BN) {
      float s1 = sb[t * 2]     + sb[(BN + t) * 2];
      float s2 = sb[t * 2 + 1] + sb[(BN + t) * 2 + 1];
      p1[(size_t)blockIdx.x * ncTot + n0 + t] = s1;
      p2[(size_t)blockIdx.x * ncTot + n0 + t] = s2;
    }
  }
}

// ---------- split-bf16 MFMA (f32 accuracy) with fused stats ----------
__global__ __launch_bounds__(256) void k_mfma_split(const float* __restrict__ Af, int K, int M,
                                                    const u16* __restrict__ Bh, const u16* __restrict__ Bl,
                                                    float* __restrict__ Cf,
                                                    float* __restrict__ p1, float* __restrict__ p2) {
  __shared__ u16 sAh[128 * 64], sAl[128 * 64], sBh[64 * 64], sBl[64 * 64];
  int t = threadIdx.x;
  int wid = t >> 6, lane = t & 63;
  int wr = wid >> 1, wc = wid & 1;
  int lr = lane & 15, lk = lane >> 4;
  int m0 = blockIdx.x * 128;
  int nK = K >> 6;

  u16x8 rah[4], ral[4], rbh[2], rbl[2];
  f32x4 acc[4][2];
#pragma unroll
  for (int m = 0; m < 4; ++m)
#pragma unroll
    for (int n = 0; n < 2; ++n) acc[m][n] = (f32x4){0.f, 0.f, 0.f, 0.f};

  auto loadTile = [&](int kk) {
    int kk0 = kk * 64;
#pragma unroll
    for (int p = 0; p < 4; ++p) {
      int idx = p * 256 + t;
      int r = idx >> 3, c8 = idx & 7;
      int row = m0 + r; if (row >= M) row = M - 1;
      const float* src = Af + (size_t)row * K + kk0 + c8 * 8;
      float4 a = *(const float4*)src;
      float4 b = *(const float4*)(src + 4);
      float v[8];
      *(float4*)(v) = a; *(float4*)(v + 4) = b;
      u16x8 oh, ol;
#pragma unroll
      for (int j = 0; j < 8; ++j) {
        u16 h = f2bf(v[j]);
        oh[j] = h;
        ol[j] = f2bf(v[j] - bf2f(h));
      }
      rah[p] = oh; ral[p] = ol;
    }
#pragma unroll
    for (int p = 0; p < 2; ++p) {
      int idx = p * 256 + t;
      int r = idx >> 3, c8 = idx & 7;
      rbh[p] = *(const u16x8*)(Bh + (size_t)r * K + kk0 + c8 * 8);
      rbl[p] = *(const u16x8*)(Bl + (size_t)r * K + kk0 + c8 * 8);
    }
  };

  auto dswrite = [&]() {
    char* Ah = (char*)sAh; char* Al = (char*)sAl;
    char* Bhc = (char*)sBh; char* Blc = (char*)sBl;
#pragma unroll
    for (int p = 0; p < 4; ++p) {
      int idx = p * 256 + t;
      int r = idx >> 3, c8 = idx & 7;
      int off = r * 128 + ((c8 * 16) ^ ((r & 7) << 4));
      *(u16x8*)(Ah + off) = rah[p];
      *(u16x8*)(Al + off) = ral[p];
    }
#pragma unroll
    for (int p = 0; p < 2; ++p) {
      int idx = p * 256 + t;
      int r = idx >> 3, c8 = idx & 7;
      int off = r * 128 + ((c8 * 16) ^ ((r & 7) << 4));
      *(u16x8*)(Bhc + off) = rbh[p];
      *(u16x8*)(Blc + off) = rbl[p];
    }
  };

  auto compute = [&]() {
    const char* Ah = (const char*)sAh; const char* Al = (const char*)sAl;
    const char* Bhc = (const char*)sBh; const char* Blc = (const char*)sBl;
#pragma unroll
    for (int ks = 0; ks < 2; ++ks) {
      int kb = ks * 64 + lk * 16;
      s16x8 fah[4], fal[4], fbh[2], fbl[2];
#pragma unroll
      for (int m = 0; m < 4; ++m) {
        int row = wr * 64 + m * 16 + lr;
        int off = row * 128 + (kb ^ ((row & 7) << 4));
        fah[m] = *(const s16x8*)(Ah + off);
        fal[m] = *(const s16x8*)(Al + off);
      }
#pragma unroll
      for (int n = 0; n < 2; ++n) {
        int row = wc * 32 + n * 16 + lr;
        int off = row * 128 + (kb ^ ((row & 7) << 4));
        fbh[n] = *(const s16x8*)(Bhc + off);
        fbl[n] = *(const s16x8*)(Blc + off);
      }
#pragma unroll
      for (int m = 0; m < 4; ++m)
#pragma unroll
        for (int n = 0; n < 2; ++n) {
          acc[m][n] = __builtin_amdgcn_mfma_f32_16x16x32_bf16(fah[m], fbh[n], acc[m][n], 0, 0, 0);
          acc[m][n] = __builtin_amdgcn_mfma_f32_16x16x32_bf16(fah[m], fbl[n], acc[m][n], 0, 0, 0);
          acc[m][n] = __builtin_amdgcn_mfma_f32_16x16x32_bf16(fal[m], fbh[n], acc[m][n], 0, 0, 0);
        }
    }
  };

  loadTile(0);
  for (int kk = 0; kk < nK; ++kk) {
    __syncthreads();
    dswrite();
    __syncthreads();
    if (kk + 1 < nK) loadTile(kk + 1);
    compute();
  }

#pragma unroll
  for (int m = 0; m < 4; ++m) {
#pragma unroll
    for (int n = 0; n < 2; ++n) {
      int col = wc * 32 + n * 16 + lr;
#pragma unroll
      for (int q = 0; q < 4; ++q) {
        int row = m0 + wr * 64 + m * 16 + lk * 4 + q;
        if (row < M) Cf[(size_t)row * 64 + col] = acc[m][n][q];
      }
    }
  }

  __syncthreads();
  float* sb = (float*)sAh;
#pragma unroll
  for (int n = 0; n < 2; ++n) {
    float s1 = 0.f, s2 = 0.f;
#pragma unroll
    for (int m = 0; m < 4; ++m)
#pragma unroll
      for (int q = 0; q < 4; ++q) {
        int row = m0 + wr * 64 + m * 16 + lk * 4 + q;
        float v = (row < M) ? acc[m][n][q] : 0.f;
        s1 += v; s2 += v * v;
      }
    s1 += __shfl_xor(s1, 16); s2 += __shfl_xor(s2, 16);
    s1 += __shfl_xor(s1, 32); s2 += __shfl_xor(s2, 32);
    if (lk == 0) {
      int c = wc * 32 + n * 16 + lr;
      sb[(wr * 64 + c) * 2 + 0] = s1;
      sb[(wr * 64 + c) * 2 + 1] = s2;
    }
  }
  __syncthreads();
  if (t < 64) {
    float s1 = sb[t * 2]     + sb[(64 + t) * 2];
    float s2 = sb[t * 2 + 1] + sb[(64 + t) * 2 + 1];
    p1[(size_t)blockIdx.x * 64 + t] = s1;
    p2[(size_t)blockIdx.x * 64 + t] = s2;
  }
}

// ---------- reduce partials -> BN scale/shift ----------
__global__ __launch_bounds__(256) void k_reduce_fin(const float* __restrict__ part1,
                                                    const float* __restrict__ part2,
                                                    int nb, int C, float invN,
                                                    const float* __restrict__ gamma,
                                                    const float* __restrict__ beta,
                                                    float* __restrict__ a_out,
                                                    float* __restrict__ b_out) {
  int c = blockIdx.x;
  int t = threadIdx.x;
  float s1 = 0.f, s2 = 0.f;
  for (int b = t; b < nb; b += 256) {
    s1 += part1[(size_t)b * C + c];
    s2 += part2[(size_t)b * C + c];
  }
  for (int m = 32; m; m >>= 1) { s1 += __shfl_xor(s1, m); s2 += __shfl_xor(s2, m); }
  __shared__ float l1[4], l2[4];
  if ((t & 63) == 0) { l1[t >> 6] = s1; l2[t >> 6] = s2; }
  __syncthreads();
  if (t == 0) {
    s1 = l1[0] + l1[1] + l1[2] + l1[3];
    s2 = l2[0] + l2[1] + l2[2] + l2[3];
    float mu  = s1 * invN;
    float var = s2 * invN - mu * mu;
    float a = gamma[c] * rsqrtf(var + 1e-5f);
    a_out[c] = a;
    b_out[c] = beta[c] - mu * a;
  }
}

// ---------- UN = bf16(au*xu + bue) ----------
__global__ __launch_bounds__(256) void k_scaleUN(const u16* __restrict__ ub, const float* __restrict__ au,
                                                 const float* __restrict__ bue, u16* __restrict__ un, int n8) {
  for (int i = blockIdx.x * 256 + threadIdx.x; i < n8; i += gridDim.x * 256) {
    int c0 = (i & 7) * 8;
    float av[8], bv[8];
    *(float4*)(av) = *(const float4*)(au + c0);  *(float4*)(av + 4) = *(const float4*)(au + c0 + 4);
    *(float4*)(bv) = *(const float4*)(bue + c0); *(float4*)(bv + 4) = *(const float4*)(bue + c0 + 4);
    u16x8 in = ((const u16x8*)ub)[i];
    u16x8 o;
#pragma unroll
    for (int j = 0; j < 8; ++j) o[j] = f2bf(bf2f((u16)in[j]) * av[j] + bv[j]);
    ((u16x8*)un)[i] = o;
  }
}

// ---------- PS = f16(ap * su) ----------
__global__ __launch_bounds__(256) void k_scaleP(const float* __restrict__ P, const float* __restrict__ ap,
                                                __half* __restrict__ PS, int n8) {
  for (int i = blockIdx.x * 256 + threadIdx.x; i < n8; i += gridDim.x * 256) {
    int c0 = (i & 7) * 8;
    float4 s0 = *(const float4*)(ap + c0), s1 = *(const float4*)(ap + c0 + 4);
    float4 a = ((const float4*)P)[i * 2];
    float4 b = ((const float4*)P)[i * 2 + 1];
    __half2 o0 = __floats2half2_rn(a.x * s0.x, a.y * s0.y);
    __half2 o1 = __floats2half2_rn(a.z * s0.z, a.w * s0.w);
    __half2 o2 = __floats2half2_rn(b.x * s1.x, b.y * s1.y);
    __half2 o3 = __floats2half2_rn(b.z * s1.z, b.w * s1.w);
    uint4 out;
    out.x = *(unsigned*)&o0; out.y = *(unsigned*)&o1;
    out.z = *(unsigned*)&o2; out.w = *(unsigned*)&o3;
    ((uint4*)PS)[i] = out;
  }
}

// ---------- fused per-node: logits from PS + softmax + UN aggregation ----------
__global__ __launch_bounds__(256) void k_nodeall(const __half* __restrict__ PS,
                                                 const int* __restrict__ srcj,
                                                 const int* __restrict__ rowptr,
                                                 const u16* __restrict__ UN,
                                                 int N, float* __restrict__ agg) {
  int lane = threadIdx.x & 63;
  int node = blockIdx.x * 4 + (threadIdx.x >> 6);
  if (node >= N) return;
  int lane16 = lane & 15;
  int g4 = lane >> 4;
  const uint2* P2 = (const uint2*)PS;
  uint2 uu = P2[(size_t)node * 16 + lane16];
  float2 ua = __half22float2(*(const __half2*)&uu.x);
  float2 ub = __half22float2(*(const __half2*)&uu.y);
  float psl = __half2float(PS[(size_t)node * 64 + lane]);
  int b0 = rowptr[node], b1 = rowptr[node + 1];
  int deg = b1 - b0;
  float acc = 0.f;
  if (deg > 0) {
    int cnt = deg < 64 ? deg : 64;
    int jj = (lane < cnt) ? srcj[b0 + lane] : 0;
    float lg = -INFINITY;
    int capbase = lane & ~3;
    int capsrc  = (lane & 3) << 4;
    for (int ss = 0; ss < cnt; ss += 4) {
      int sl = ss + g4;
      int j = __shfl(jj, sl < cnt ? sl : cnt - 1);
      uint2 vv = P2[(size_t)j * 16 + lane16];
      float2 va = __half22float2(*(const __half2*)&vv.x);
      float2 vb = __half22float2(*(const __half2*)&vv.y);
      float d0 = ua.x - va.x, d1 = ua.y - va.y, d2 = ub.x - vb.x, d3 = ub.y - vb.y;
      float p = d0 * d0 + d1 * d1 + d2 * d2 + d3 * d3;
      p += __shfl_xor(p, 1, 16);
      p += __shfl_xor(p, 2, 16);
      p += __shfl_xor(p, 4, 16);
      p += __shfl_xor(p, 8, 16);
      float val = __shfl(p, capsrc);
      if (ss == capbase && lane < cnt) lg = -val;
    }
    float mx = lg;
    for (int s = b0 + 64; s < b1; ++s) {
      int j = srcj[s];
      float d = psl - __half2float(PS[(size_t)j * 64 + lane]);
      float p = d * d;
      for (int m = 32; m; m >>= 1) p += __shfl_xor(p, m);
      mx = fmaxf(mx, -p);
    }
    for (int m = 32; m; m >>= 1) mx = fmaxf(mx, __shfl_xor(mx, m));
    float ex = (lane < cnt) ? __expf(lg - mx) : 0.f;
    float sm = ex;
    for (int s = b0 + 64; s < b1; ++s) {
      int j = srcj[s];
      float d = psl - __half2float(PS[(size_t)j * 64 + lane]);
      float p = d * d;
      for (int m = 32; m; m >>= 1) p += __shfl_xor(p, m);
      if (lane == 0) sm += __expf(-p - mx);
    }
    for (int m = 32; m; m >>= 1) sm += __shfl_xor(sm, m);
    float inv = 1.0f / (sm + 1e-16f);
    float w = ex * inv;
    int ss = 0;
    for (; ss + 4 <= cnt; ss += 4) {
      int   j0 = __shfl(jj, ss),     j1 = __shfl(jj, ss + 1);
      int   j2 = __shfl(jj, ss + 2), j3 = __shfl(jj, ss + 3);
      float w0 = __shfl(w, ss),      w1 = __shfl(w, ss + 1);
      float w2 = __shfl(w, ss + 2),  w3 = __shfl(w, ss + 3);
      float v0 = bf2f(UN[(size_t)j0 * 64 + lane]);
      float v1 = bf2f(UN[(size_t)j1 * 64 + lane]);
      float v2 = bf2f(UN[(size_t)j2 * 64 + lane]);
      float v3 = bf2f(UN[(size_t)j3 * 64 + lane]);
      acc += w0 * v0 + w1 * v1 + w2 * v2 + w3 * v3;
    }
    for (; ss < cnt; ++ss) {
      int j0 = __shfl(jj, ss);
      float w0 = __shfl(w, ss);
      acc += w0 * bf2f(UN[(size_t)j0 * 64 + lane]);
    }
    for (int s = b0 + 64; s < b1; ++s) {
      int j = srcj[s];
      float d = psl - __half2float(PS[(size_t)j * 64 + lane]);
      float p = d * d;
      for (int m = 32; m; m >>= 1) p += __shfl_xor(p, m);
      acc += __expf(-p - mx) * inv * bf2f(UN[(size_t)j * 64 + lane]);
    }
  }
  agg[(size_t)node * 64 + lane] = acc;
}

// ---------- h = (z - agg) @ Minv + agg, out bf16 ----------
__global__ __launch_bounds__(256) void k_solve(const u16* __restrict__ UN, const float* __restrict__ agg,
                                               const float* __restrict__ minv,
                                               u16* __restrict__ HB, int ntiles) {
  __shared__ float mS[4096];
  int t = threadIdx.x;
  int c16 = t & 15, rg = t >> 4;
  for (int idx = t; idx < 1024; idx += 256)
    ((float4*)mS)[idx] = ((const float4*)minv)[idx];
  __syncthreads();
  for (int tile = blockIdx.x; tile < ntiles; tile += gridDim.x) {
    int row = tile * 16 + rg;
    const u16*  ur = UN + (size_t)row * 64;
    const float* gr = agg + (size_t)row * 64;
    float4 acc = *(const float4*)(gr + c16 * 4);
#pragma unroll 4
    for (int k = 0; k < 64; ++k) {
      float z = bf2f(ur[k]) - gr[k];
      float4 m4 = ((const float4*)mS)[k * 16 + c16];
      acc.x += z * m4.x;
      acc.y += z * m4.y;
      acc.z += z * m4.z;
      acc.w += z * m4.w;
    }
    ((ushort4*)HB)[(size_t)row * 16 + c16] =
        make_ushort4(f2bf(acc.x), f2bf(acc.y), f2bf(acc.z), f2bf(acc.w));
  }
}

// ---------- final BN + leaky: bf16 raw -> f32 out ----------
__global__ __launch_bounds__(256) void k_bnact16(const u16* __restrict__ raw, const float* __restrict__ af,
                                                 const float* __restrict__ bfp, float* __restrict__ out, int n8) {
  int i = blockIdx.x * 256 + threadIdx.x;
  int stride = gridDim.x * 256;
  for (; i < n8; i += stride) {
    int c0 = (i & 31) * 8;
    float av[8], bv[8];
    *(float4*)(av) = *(const float4*)(af + c0);  *(float4*)(av + 4) = *(const float4*)(af + c0 + 4);
    *(float4*)(bv) = *(const float4*)(bfp + c0); *(float4*)(bv + 4) = *(const float4*)(bfp + c0 + 4);
    u16x8 r = ((const u16x8*)raw)[i];
    float o[8];
#pragma unroll
    for (int j = 0; j < 8; ++j) {
      float v = bf2f((u16)r[j]) * av[j] + bv[j];
      o[j] = (v > 0.f) ? v : 0.01f * v;
    }
    ((float4*)out)[i * 2]     = *(float4*)(o);
    ((float4*)out)[i * 2 + 1] = *(float4*)(o + 4);
  }
}

extern "C" void kernel_launch(void* const* d_in, const int* in_sizes, int n_in,
                              void* d_out, int out_size, void* d_ws, size_t ws_size,
                              hipStream_t stream) {
  const float* x    = (const float*)d_in[0];
  const float* y    = (const float*)d_in[1];
  const int*   eidx = (const int*)d_in[3];
  const float* Wu   = (const float*)d_in[4];
  const float* gu   = (const float*)d_in[5];
  const float* bu   = (const float*)d_in[6];
  const float* Wp   = (const float*)d_in[7];
  const float* gp   = (const float*)d_in[8];
  const float* bp   = (const float*)d_in[9];
  const float* cIn  = (const float*)d_in[10];
  const float* Wm   = (const float*)d_in[11];
  const float* gm   = (const float*)d_in[12];
  const float* bm   = (const float*)d_in[13];
  const float* Wf   = (const float*)d_in[14];
  const float* gf   = (const float*)d_in[15];
  const float* bfv  = (const float*)d_in[16];

  const int N = in_sizes[0] / 256;
  const int E = in_sizes[3] / 2;
  const int* ei = eidx;
  const int* ej = eidx + E;

  char* ws = (char*)d_ws;
  float* MINV  = (float*)(ws + OFF_MINV);
  float* AU    = (float*)(ws + OFF_AU);
  float* BUE   = (float*)(ws + OFF_BUE);
  float* AP    = (float*)(ws + OFF_AP);
  float* APBE  = (float*)(ws + OFF_APBE);
  float* AM    = (float*)(ws + OFF_AM);
  float* BM    = (float*)(ws + OFF_BM);
  float* AF    = (float*)(ws + OFF_AF);
  float* BF    = (float*)(ws + OFF_BF);
  int*   BTOT  = (int*)(ws + OFF_BTOT);
  int*   BOFF  = (int*)(ws + OFF_BOFF);
  u16*   WUT   = (u16*)(ws + OFF_WUT);
  u16*   WMT   = (u16*)(ws + OFF_WMT);
  u16*   WFT   = (u16*)(ws + OFF_WFT);
  u16*   WPH   = (u16*)(ws + OFF_WPH);
  u16*   WPL   = (u16*)(ws + OFF_WPL);
  float* PART1 = (float*)(ws + OFF_PART1);
  float* PART2 = (float*)(ws + OFF_PART2);
  int*   ROWPTR= (int*)(ws + OFF_ROWPTR);
  int*   BLKCNT= (int*)(ws + OFF_BLKCNT);
  u16*   HB    = (u16*)(ws + OFF_BLKCNT);    // reuse (BLKCNT dead after kA3)
  int*   SRCJ  = (int*)(ws + OFF_SRCJ);
  u16*   RAWO  = (u16*)(ws + OFF_SRCJ);      // reuse (SRCJ dead after k_nodeall)
  u16*   UBRAW = (u16*)(ws + OFF_U);
  u16*   UN    = (u16*)(ws + OFF_UN);
  uint2* TMP   = (uint2*)(ws + OFF_P);       // binned edges; dead after kB
  float* P     = (float*)(ws + OFF_P);
  float* AGG   = (float*)(ws + OFF_P);       // P dead after k_scaleP
  __half* PS   = (__half*)(ws + OFF_PS);
  u16*   H2    = (u16*)(ws + OFF_H2);

  const float invN = 1.0f / (float)N;
  const int ntiles16 = N / 16;
  const int mtiles   = (N + 127) / 128;
  const int n8_64    = N * 64 / 8;
  const int n8_256   = N * 256 / 8;
  const int nbk      = (N + 255) >> 8;
  const int chunk    = (E + NBLK_BIN - 1) / NBLK_BIN;

  k_prep<<<1, 256, 0, stream>>>(cIn, MINV);
  k_tcvt<<<64,  256, 0, stream>>>(Wu, WUT, 256, 64);
  k_tcvt<<<64,  256, 0, stream>>>(Wm, WMT, 64, 256);
  k_tcvt<<<512, 256, 0, stream>>>(Wf, WFT, 512, 256);
  k_tcvt_split<<<64, 256, 0, stream>>>(Wp, WPH, WPL);

  // CSR build: deterministic two-level binned counting sort (no global atomics)
  kA1<<<NBLK_BIN, 256, 0, stream>>>(ei, E, chunk, BLKCNT, nbk);
  kA2<<<nbk, 256, 0, stream>>>(BLKCNT, nbk, BTOT);
  kA2b<<<1, 512, 0, stream>>>(BTOT, BOFF, nbk);
  kA3<<<NBLK_BIN, 256, 0, stream>>>(ei, ej, E, chunk, BLKCNT, BOFF, nbk, TMP);
  kB<<<nbk, 256, 0, stream>>>(TMP, BOFF, nbk, N, E, ROWPTR, SRCJ);

  // unary embedding (stats fused) -> UBRAW bf16; BN params; UN table
  k_mfma<64, 2, 1, 1><<<dim3(mtiles, 1), 256, 0, stream>>>(
      nullptr, x, 256, 256, N, nullptr, nullptr, nullptr, nullptr, WUT,
      nullptr, UBRAW, 64, 64, PART1, PART2);
  k_reduce_fin<<<64, 256, 0, stream>>>(PART1, PART2, mtiles, 64, invN, gu, bu, AU, BUE);
  k_scaleUN<<<1024, 256, 0, stream>>>(UBRAW, AU, BUE, UN, n8_64);

  // pairwise embedding: split-bf16 MFMA (stats fused) -> P f32 (TMP dead); PS f16 table
  k_mfma_split<<<mtiles, 256, 0, stream>>>(y, 256, N, WPH, WPL, P, PART1, PART2);
  k_reduce_fin<<<64, 256, 0, stream>>>(PART1, PART2, mtiles, 64, invN, gp, bp, AP, APBE);
  k_scaleP<<<1024, 256, 0, stream>>>(P, AP, PS, n8_64);

  // fused logits + softmax + aggregation (AGG overwrites P region)
  k_nodeall<<<(N + 3) / 4, 256, 0, stream>>>(PS, SRCJ, ROWPTR, UN, N, AGG);

  // CRF solve -> h bf16 (HB overwrites BLKCNT region)
  k_solve<<<2048, 256, 0, stream>>>(UN, AGG, MINV, HB, ntiles16);

  // h @ Wm -> h2 bf16 (stats fused)
  k_mfma<128, 0, 1, 1><<<dim3(mtiles, 2), 256, 0, stream>>>(
      HB, nullptr, 64, 64, N, nullptr, nullptr, nullptr, nullptr, WMT,
      nullptr, H2, 256, 256, PART1, PART2);
  k_reduce_fin<<<256, 256, 0, stream>>>(PART1, PART2, mtiles, 256, invN, gm, bm, AM, BM);

  // [leaky(bn(h2)), y] @ Wf -> raw bf16 (stats fused, overwrites SRCJ region), BN + leaky -> d_out
  k_mfma<128, 1, 1, 1><<<dim3(mtiles, 2), 256, 0, stream>>>(
      nullptr, nullptr, 0, 512, N, H2, y, AM, BM, WFT,
      nullptr, RAWO, 256, 256, PART1, PART2);
  k_reduce_fin<<<256, 256, 0, stream>>>(PART1, PART2, mtiles, 256, invN, gf, bfv, AF, BF);
  k_bnact16<<<2048, 256, 0, stream>>>(RAWO, AF, BF, (float*)d_out, n8_256);
}

// Round 9
// 550.463 us; speedup vs baseline: 5.1583x; 1.0822x over previous
//
#include <hip/hip_runtime.h>
#include <hip/hip_fp16.h>
#include <math.h>

typedef unsigned short u16;
typedef short s16x8 __attribute__((ext_vector_type(8)));
typedef unsigned short u16x8 __attribute__((ext_vector_type(8)));
typedef float f32x4 __attribute__((ext_vector_type(4)));

// ---------- helpers ----------
__device__ __forceinline__ float bf2f(u16 u) {
  unsigned x = ((unsigned)u) << 16;
  return __uint_as_float(x);
}
__device__ __forceinline__ u16 f2bf(float f) {
  unsigned x = __float_as_uint(f);
  unsigned r = x + 0x7FFFu + ((x >> 16) & 1u);
  return (u16)(r >> 16);
}

// ---------- ws layout (bytes) ----------
static const size_t OFF_MINV   = 0;
static const size_t OFF_AU     = 32ull * 1024;
static const size_t OFF_BUE    = 32ull * 1024 + 256;
static const size_t OFF_AP     = 32ull * 1024 + 512;
static const size_t OFF_APBE   = 32ull * 1024 + 768;
static const size_t OFF_AM     = 36ull * 1024;
static const size_t OFF_BM     = 37ull * 1024;
static const size_t OFF_AF     = 38ull * 1024;
static const size_t OFF_BF     = 39ull * 1024;
static const size_t OFF_BTOT   = 40ull * 1024;
static const size_t OFF_BOFF   = 44ull * 1024;
static const size_t OFF_WUT    = 64ull * 1024;
static const size_t OFF_WMT    = 128ull * 1024;
static const size_t OFF_WFT    = 192ull * 1024;
static const size_t OFF_WPH    = 512ull * 1024;
static const size_t OFF_WPL    = 576ull * 1024;
static const size_t OFF_PART1  = 1ull  * 1024 * 1024;
static const size_t OFF_PART2  = 2ull  * 1024 * 1024;
static const size_t OFF_ROWPTR = 3ull  * 1024 * 1024;
static const size_t OFF_BLKCNT = 5ull  * 1024 * 1024;     // 2MB; dead after kA3 -> HB bf16 N*64 (5..17.8MB)
static const size_t OFF_SRCJ   = 18ull * 1024 * 1024;     // E int; dead after k_nodeall -> RAWO bf16 N*256
static const size_t OFF_U      = 44ull * 1024 * 1024;     // UBRAW bf16 N*64
static const size_t OFF_P      = 70ull * 1024 * 1024;     // TMP uint E early; then P f32
static const size_t OFF_PS     = 109ull * 1024 * 1024;
static const size_t OFF_H2     = 122ull * 1024 * 1024;

#define NBLK_BIN 1024

// ---------- K0: Minv = (I + c^T c)^-1 (conflict-free GJ) ----------
__global__ __launch_bounds__(256) void k_prep(const float* __restrict__ c,
                                              float* __restrict__ minv_out) {
  __shared__ float CC[4096];
  __shared__ float aug[64 * 129];
  __shared__ float fs[64];
  float* cl = aug;
  int t = threadIdx.x;
  for (int idx = t; idx < 4096; idx += 256) cl[idx] = c[idx];
  __syncthreads();
  for (int idx = t; idx < 4096; idx += 256) {
    int a = idx >> 6, b = idx & 63;
    float s = (a == b) ? 1.f : 0.f;
    for (int k = 0; k < 64; ++k) s += cl[k * 64 + a] * cl[k * 64 + b];
    CC[idx] = s;
  }
  __syncthreads();
  for (int idx = t; idx < 8192; idx += 256) {
    int r = idx >> 7, cc = idx & 127;
    aug[r * 129 + cc] = (cc < 64) ? CC[r * 64 + cc] : (((cc - 64) == r) ? 1.f : 0.f);
  }
  __syncthreads();
  int cloc = t & 127;
  int rbase = t >> 7;
  for (int p = 0; p < 64; ++p) {
    float inv = 1.0f / aug[p * 129 + p];
    if (t < 64) fs[t] = (t == p) ? 0.f : aug[t * 129 + p];
    __syncthreads();
    if (t < 128) aug[p * 129 + t] *= inv;
    __syncthreads();
    float pc = aug[p * 129 + cloc];
#pragma unroll
    for (int rr = 0; rr < 64; rr += 2) {
      int r = rr + rbase;
      aug[r * 129 + cloc] -= fs[r] * pc;
    }
    __syncthreads();
  }
  for (int idx = t; idx < 4096; idx += 256) {
    int r = idx >> 6, cc = idx & 63;
    minv_out[idx] = aug[r * 129 + 64 + cc];
  }
}

// ---------- merged weight transpose/convert (all four weight jobs in one kernel) ----------
__global__ __launch_bounds__(256) void k_tcvt_all(const float* __restrict__ Wu, const float* __restrict__ Wm,
                                                  const float* __restrict__ Wf, const float* __restrict__ Wp,
                                                  u16* __restrict__ WUT, u16* __restrict__ WMT,
                                                  u16* __restrict__ WFT, u16* __restrict__ WPH,
                                                  u16* __restrict__ WPL) {
  int b = blockIdx.x, t = threadIdx.x;
  if (b < 64) {                       // Wu [256][64] -> WUT [64][256]
    int i = b * 256 + t;
    int k = i >> 6, n = i & 63;
    WUT[(size_t)n * 256 + k] = f2bf(Wu[i]);
  } else if (b < 128) {               // Wm [64][256] -> WMT [256][64]
    int i = (b - 64) * 256 + t;
    int k = i >> 8, n = i & 255;
    WMT[(size_t)n * 64 + k] = f2bf(Wm[i]);
  } else if (b < 640) {               // Wf [512][256] -> WFT [256][512]
    int i = (b - 128) * 256 + t;
    int k = i >> 8, n = i & 255;
    WFT[(size_t)n * 512 + k] = f2bf(Wf[i]);
  } else {                            // Wp [256][64] -> WPH/WPL [64][256]
    int i = (b - 640) * 256 + t;
    int k = i >> 6, n = i & 63;
    float v = Wp[i];
    u16 h = f2bf(v);
    WPH[(size_t)n * 256 + k] = h;
    WPL[(size_t)n * 256 + k] = f2bf(v - bf2f(h));
  }
}

// ---------- binned CSR build ----------
__global__ __launch_bounds__(256) void kA1(const int* __restrict__ ei, int E, int chunk,
                                           int* __restrict__ blockCnt, int nbk) {
  __shared__ int c[512];
  int t = threadIdx.x, bid = blockIdx.x;
  c[t] = 0; c[t + 256] = 0;
  __syncthreads();
  int e0 = bid * chunk, e1 = min(E, e0 + chunk);
  for (int e = e0 + t; e < e1; e += 256) atomicAdd(&c[ei[e] >> 8], 1);
  __syncthreads();
  for (int b = t; b < nbk; b += 256) blockCnt[(size_t)bid * nbk + b] = c[b];
}

__global__ __launch_bounds__(256) void kA2(int* __restrict__ blockCnt, int nbk,
                                           int* __restrict__ bucketTot) {
  int b = blockIdx.x, t = threadIdx.x;
  int base = t * 4;
  int v0 = blockCnt[(size_t)(base + 0) * nbk + b];
  int v1 = blockCnt[(size_t)(base + 1) * nbk + b];
  int v2 = blockCnt[(size_t)(base + 2) * nbk + b];
  int v3 = blockCnt[(size_t)(base + 3) * nbk + b];
  int s1 = v0 + v1, s2 = s1 + v2, tot = s2 + v3;
  __shared__ int ps[256];
  ps[t] = tot;
  __syncthreads();
  for (int off = 1; off < 256; off <<= 1) {
    int a = (t >= off) ? ps[t - off] : 0;
    __syncthreads();
    ps[t] += a;
    __syncthreads();
  }
  int ex = (t > 0) ? ps[t - 1] : 0;
  blockCnt[(size_t)(base + 0) * nbk + b] = ex;
  blockCnt[(size_t)(base + 1) * nbk + b] = ex + v0;
  blockCnt[(size_t)(base + 2) * nbk + b] = ex + s1;
  blockCnt[(size_t)(base + 3) * nbk + b] = ex + s2;
  if (t == 255) bucketTot[b] = ps[255];
}

__global__ __launch_bounds__(512) void kA2b(const int* __restrict__ bucketTot,
                                            int* __restrict__ bucketOff, int nbk) {
  __shared__ int s[512];
  int t = threadIdx.x;
  s[t] = (t < nbk) ? bucketTot[t] : 0;
  __syncthreads();
  for (int off = 1; off < 512; off <<= 1) {
    int a = (t >= off) ? s[t - off] : 0;
    __syncthreads();
    s[t] += a;
    __syncthreads();
  }
  if (t == 0) bucketOff[0] = 0;
  if (t < nbk) bucketOff[t + 1] = s[t];
}

// A3: LDS counting-sort by bucket; write PACKED 4B {iloc,j} runs to TMP
__global__ __launch_bounds__(256) void kA3(const int* __restrict__ ei, const int* __restrict__ ej,
                                           int E, int chunk,
                                           const int* __restrict__ blockExc,
                                           const int* __restrict__ bucketOff,
                                           int nbk, unsigned* __restrict__ tmp) {
  __shared__ int c[512], off[512], gb[512], cur[512];
  __shared__ uint2 stage[4096];
  int t = threadIdx.x, bid = blockIdx.x;
  c[t] = 0; c[t + 256] = 0;
  __syncthreads();
  int e0 = bid * chunk, e1 = min(E, e0 + chunk);
  int m = e1 - e0;
  for (int e = e0 + t; e < e1; e += 256) atomicAdd(&c[ei[e] >> 8], 1);
  __syncthreads();
  int v0 = c[t], v1 = c[t + 256];
  off[t] = v0; off[t + 256] = v1;
  __syncthreads();
  for (int o = 1; o < 512; o <<= 1) {
    int a0 = (t >= o) ? off[t - o] : 0;
    int a1 = ((t + 256) >= o) ? off[t + 256 - o] : 0;
    __syncthreads();
    off[t] += a0; off[t + 256] += a1;
    __syncthreads();
  }
  int ex0 = off[t] - v0, ex1 = off[t + 256] - v1;
  if (t < nbk)
    gb[t] = bucketOff[t] + blockExc[(size_t)bid * nbk + t] - ex0;
  if (t + 256 < nbk)
    gb[t + 256] = bucketOff[t + 256] + blockExc[(size_t)bid * nbk + t + 256] - ex1;
  cur[t] = ex0; cur[t + 256] = ex1;
  __syncthreads();
  for (int e = e0 + t; e < e1; e += 256) {
    int i = ei[e];
    int p = atomicAdd(&cur[i >> 8], 1);
    stage[p] = make_uint2((unsigned)i, (unsigned)ej[e]);
  }
  __syncthreads();
  for (int s = t; s < m; s += 256) {
    uint2 v = stage[s];
    tmp[gb[v.x >> 8] + s] = ((v.x & 255u) << 24) | v.y;   // j < 2^24
  }
}

// B: per-bucket LDS sort by node -> ROWPTR + coalesced SRCJ
#define BCAP 12288
__global__ __launch_bounds__(256) void kB(const unsigned* __restrict__ tmp,
                                          const int* __restrict__ bucketOff,
                                          int nbk, int N, int E,
                                          int* __restrict__ rowptr, int* __restrict__ srcj) {
  __shared__ int cnt[256], sc[256], cur[256];
  __shared__ int jbuf[BCAP];
  int b = blockIdx.x, t = threadIdx.x;
  int nb0 = b << 8;
  int e0 = bucketOff[b], e1 = bucketOff[b + 1];
  int m = e1 - e0;
  cnt[t] = 0;
  __syncthreads();
  for (int s = t; s < m; s += 256) atomicAdd(&cnt[tmp[e0 + s] >> 24], 1);
  __syncthreads();
  int v = cnt[t];
  sc[t] = v;
  __syncthreads();
  for (int off = 1; off < 256; off <<= 1) {
    int a = (t >= off) ? sc[t - off] : 0;
    __syncthreads();
    sc[t] += a;
    __syncthreads();
  }
  int exc = sc[t] - v;
  cur[t] = exc;
  if (nb0 + t < N) rowptr[nb0 + t] = e0 + exc;
  if (b == nbk - 1 && t == 0) rowptr[N] = E;
  __syncthreads();
  for (int s = t; s < m; s += 256) {
    unsigned e = tmp[e0 + s];
    int p = atomicAdd(&cur[e >> 24], 1);
    if (p < BCAP) jbuf[p] = (int)(e & 0xFFFFFFu);
  }
  __syncthreads();
  for (int s = t; s < m; s += 256) srcj[e0 + s] = jbuf[s];
}

// ---------- MFMA GEMM with optional fused column-stats ----------
template<int BN, int AMODE, int OBF, int STATS>
__global__ __launch_bounds__(256) void k_mfma(const u16* __restrict__ Abf, const float* __restrict__ Af32,
                                              int ldA, int K, int M,
                                              const u16* __restrict__ h2, const float* __restrict__ yy,
                                              const float* __restrict__ am, const float* __restrict__ bm,
                                              const u16* __restrict__ Bt,
                                              float* __restrict__ Cf, u16* __restrict__ Cb, int ldC,
                                              int ncTot, float* __restrict__ p1, float* __restrict__ p2) {
  constexpr int WN  = BN / 2;
  constexpr int FN  = WN / 16;
  constexpr int NPB = BN / 32;
  __shared__ u16 lds[2][(128 + BN) * 64];

  int t = threadIdx.x;
  int wid = t >> 6, lane = t & 63;
  int wr = wid >> 1, wc = wid & 1;
  int lr = lane & 15, lk = lane >> 4;
  int m0 = blockIdx.x * 128;
  int n0 = blockIdx.y * BN;
  int nK = K >> 6;

  int sidx = t;
  u16x8 ra[4];
  u16x8 rb[NPB];

  f32x4 acc[4][FN];
#pragma unroll
  for (int m = 0; m < 4; ++m)
#pragma unroll
    for (int n = 0; n < FN; ++n) acc[m][n] = (f32x4){0.f, 0.f, 0.f, 0.f};

  auto loadTile = [&](int kk) {
    int kk0 = kk * 64;
#pragma unroll
    for (int p = 0; p < 4; ++p) {
      int idx = p * 256 + sidx;
      int r = idx >> 3, c8 = idx & 7;
      int row = m0 + r; if (row >= M) row = M - 1;
      int k = kk0 + c8 * 8;
      if constexpr (AMODE == 0) {
        ra[p] = *(const u16x8*)(Abf + (size_t)row * ldA + k);
      } else if constexpr (AMODE == 2) {
        const float* src = Af32 + (size_t)row * ldA + k;
        float4 a = *(const float4*)src;
        float4 b = *(const float4*)(src + 4);
        u16x8 o;
        o[0] = f2bf(a.x); o[1] = f2bf(a.y); o[2] = f2bf(a.z); o[3] = f2bf(a.w);
        o[4] = f2bf(b.x); o[5] = f2bf(b.y); o[6] = f2bf(b.z); o[7] = f2bf(b.w);
        ra[p] = o;
      } else {
        if (kk0 < 256) {
          u16x8 h8 = *(const u16x8*)(h2 + (size_t)row * 256 + k);
          float av[8], bv[8];
          *(float4*)(av)     = *(const float4*)(am + k);
          *(float4*)(av + 4) = *(const float4*)(am + k + 4);
          *(float4*)(bv)     = *(const float4*)(bm + k);
          *(float4*)(bv + 4) = *(const float4*)(bm + k + 4);
          u16x8 o;
#pragma unroll
          for (int j = 0; j < 8; ++j) {
            float v = bf2f((u16)h8[j]) * av[j] + bv[j];
            v = v > 0.f ? v : 0.01f * v;
            o[j] = f2bf(v);
          }
          ra[p] = o;
        } else {
          float yv[8];
          *(float4*)(yv)     = *(const float4*)(yy + (size_t)row * 256 + (k - 256));
          *(float4*)(yv + 4) = *(const float4*)(yy + (size_t)row * 256 + (k - 256) + 4);
          u16x8 o;
#pragma unroll
          for (int j = 0; j < 8; ++j) o[j] = f2bf(yv[j]);
          ra[p] = o;
        }
      }
    }
#pragma unroll
    for (int p = 0; p < NPB; ++p) {
      int idx = p * 256 + sidx;
      int r = idx >> 3, c8 = idx & 7;
      rb[p] = *(const u16x8*)(Bt + (size_t)(n0 + r) * K + kk0 + c8 * 8);
    }
  };

  auto dswrite = [&](int b) {
    char* As  = (char*)&lds[b][0];
    char* Bsc = As + 128 * 64 * 2;
#pragma unroll
    for (int p = 0; p < 4; ++p) {
      int idx = p * 256 + sidx;
      int r = idx >> 3, c8 = idx & 7;
      *(u16x8*)(As + r * 128 + ((c8 * 16) ^ ((r & 7) << 4))) = ra[p];
    }
#pragma unroll
    for (int p = 0; p < NPB; ++p) {
      int idx = p * 256 + sidx;
      int r = idx >> 3, c8 = idx & 7;
      *(u16x8*)(Bsc + r * 128 + ((c8 * 16) ^ ((r & 7) << 4))) = rb[p];
    }
  };

  auto compute = [&](int b) {
    const char* As  = (const char*)&lds[b][0];
    const char* Bsc = As + 128 * 64 * 2;
#pragma unroll
    for (int ks = 0; ks < 2; ++ks) {
      int kb = ks * 64 + lk * 16;
      s16x8 af[4], bfr[FN];
#pragma unroll
      for (int m = 0; m < 4; ++m) {
        int row = wr * 64 + m * 16 + lr;
        af[m] = *(const s16x8*)(As + row * 128 + (kb ^ ((row & 7) << 4)));
      }
#pragma unroll
      for (int n = 0; n < FN; ++n) {
        int row = wc * WN + n * 16 + lr;
        bfr[n] = *(const s16x8*)(Bsc + row * 128 + (kb ^ ((row & 7) << 4)));
      }
#pragma unroll
      for (int m = 0; m < 4; ++m)
#pragma unroll
        for (int n = 0; n < FN; ++n)
          acc[m][n] = __builtin_amdgcn_mfma_f32_16x16x32_bf16(af[m], bfr[n], acc[m][n], 0, 0, 0);
    }
  };

  loadTile(0);
  dswrite(0);
  __syncthreads();
  for (int kk = 0; kk < nK; ++kk) {
    int b = kk & 1;
    if (kk + 1 < nK) loadTile(kk + 1);
    compute(b);
    if (kk + 1 < nK) { dswrite(b ^ 1); __syncthreads(); }
  }

#pragma unroll
  for (int m = 0; m < 4; ++m) {
#pragma unroll
    for (int n = 0; n < FN; ++n) {
      int col = n0 + wc * WN + n * 16 + lr;
#pragma unroll
      for (int q = 0; q < 4; ++q) {
        int row = m0 + wr * 64 + m * 16 + lk * 4 + q;
        if (row < M) {
          if constexpr (OBF) Cb[(size_t)row * ldC + col] = f2bf(acc[m][n][q]);
          else               Cf[(size_t)row * ldC + col] = acc[m][n][q];
        }
      }
    }
  }

  if constexpr (STATS) {
    __syncthreads();
    float* sb = (float*)&lds[0][0];
#pragma unroll
    for (int n = 0; n < FN; ++n) {
      float s1 = 0.f, s2 = 0.f;
#pragma unroll
      for (int m = 0; m < 4; ++m)
#pragma unroll
        for (int q = 0; q < 4; ++q) {
          int row = m0 + wr * 64 + m * 16 + lk * 4 + q;
          float v = (row < M) ? acc[m][n][q] : 0.f;
          s1 += v; s2 += v * v;
        }
      s1 += __shfl_xor(s1, 16); s2 += __shfl_xor(s2, 16);
      s1 += __shfl_xor(s1, 32); s2 += __shfl_xor(s2, 32);
      if (lk == 0) {
        int c = wc * WN + n * 16 + lr;
        sb[(wr * BN + c) * 2 + 0] = s1;
        sb[(wr * BN + c) * 2 + 1] = s2;
      }
    }
    __syncthreads();
    if (t < BN) {
      float s1 = sb[t * 2]     + sb[(BN + t) * 2];
      float s2 = sb[t * 2 + 1] + sb[(BN + t) * 2 + 1];
      p1[(size_t)blockIdx.x * ncTot + n0 + t] = s1;
      p2[(size_t)blockIdx.x * ncTot + n0 + t] = s2;
    }
  }
}

// ---------- split-bf16 MFMA (f32 accuracy) with fused stats ----------
__global__ __launch_bounds__(256) void k_mfma_split(const float* __restrict__ Af, int K, int M,
                                                    const u16* __restrict__ Bh, const u16* __restrict__ Bl,
                                                    float* __restrict__ Cf,
                                                    float* __restrict__ p1, float* __restrict__ p2) {
  __shared__ u16 sAh[128 * 64], sAl[128 * 64], sBh[64 * 64], sBl[64 * 64];
  int t = threadIdx.x;
  int wid = t >> 6, lane = t & 63;
  int wr = wid >> 1, wc = wid & 1;
  int lr = lane & 15, lk = lane >> 4;
  int m0 = blockIdx.x * 128;
  int nK = K >> 6;

  u16x8 rah[4], ral[4], rbh[2], rbl[2];
  f32x4 acc[4][2];
#pragma unroll
  for (int m = 0; m < 4; ++m)
#pragma unroll
    for (int n = 0; n < 2; ++n) acc[m][n] = (f32x4){0.f, 0.f, 0.f, 0.f};

  auto loadTile = [&](int kk) {
    int kk0 = kk * 64;
#pragma unroll
    for (int p = 0; p < 4; ++p) {
      int idx = p * 256 + t;
      int r = idx >> 3, c8 = idx & 7;
      int row = m0 + r; if (row >= M) row = M - 1;
      const float* src = Af + (size_t)row * K + kk0 + c8 * 8;
      float4 a = *(const float4*)src;
      float4 b = *(const float4*)(src + 4);
      float v[8];
      *(float4*)(v) = a; *(float4*)(v + 4) = b;
      u16x8 oh, ol;
#pragma unroll
      for (int j = 0; j < 8; ++j) {
        u16 h = f2bf(v[j]);
        oh[j] = h;
        ol[j] = f2bf(v[j] - bf2f(h));
      }
      rah[p] = oh; ral[p] = ol;
    }
#pragma unroll
    for (int p = 0; p < 2; ++p) {
      int idx = p * 256 + t;
      int r = idx >> 3, c8 = idx & 7;
      rbh[p] = *(const u16x8*)(Bh + (size_t)r * K + kk0 + c8 * 8);
      rbl[p] = *(const u16x8*)(Bl + (size_t)r * K + kk0 + c8 * 8);
    }
  };

  auto dswrite = [&]() {
    char* Ah = (char*)sAh; char* Al = (char*)sAl;
    char* Bhc = (char*)sBh; char* Blc = (char*)sBl;
#pragma unroll
    for (int p = 0; p < 4; ++p) {
      int idx = p * 256 + t;
      int r = idx >> 3, c8 = idx & 7;
      int off = r * 128 + ((c8 * 16) ^ ((r & 7) << 4));
      *(u16x8*)(Ah + off) = rah[p];
      *(u16x8*)(Al + off) = ral[p];
    }
#pragma unroll
    for (int p = 0; p < 2; ++p) {
      int idx = p * 256 + t;
      int r = idx >> 3, c8 = idx & 7;
      int off = r * 128 + ((c8 * 16) ^ ((r & 7) << 4));
      *(u16x8*)(Bhc + off) = rbh[p];
      *(u16x8*)(Blc + off) = rbl[p];
    }
  };

  auto compute = [&]() {
    const char* Ah = (const char*)sAh; const char* Al = (const char*)sAl;
    const char* Bhc = (const char*)sBh; const char* Blc = (const char*)sBl;
#pragma unroll
    for (int ks = 0; ks < 2; ++ks) {
      int kb = ks * 64 + lk * 16;
      s16x8 fah[4], fal[4], fbh[2], fbl[2];
#pragma unroll
      for (int m = 0; m < 4; ++m) {
        int row = wr * 64 + m * 16 + lr;
        int off = row * 128 + (kb ^ ((row & 7) << 4));
        fah[m] = *(const s16x8*)(Ah + off);
        fal[m] = *(const s16x8*)(Al + off);
      }
#pragma unroll
      for (int n = 0; n < 2; ++n) {
        int row = wc * 32 + n * 16 + lr;
        int off = row * 128 + (kb ^ ((row & 7) << 4));
        fbh[n] = *(const s16x8*)(Bhc + off);
        fbl[n] = *(const s16x8*)(Blc + off);
      }
#pragma unroll
      for (int m = 0; m < 4; ++m)
#pragma unroll
        for (int n = 0; n < 2; ++n) {
          acc[m][n] = __builtin_amdgcn_mfma_f32_16x16x32_bf16(fah[m], fbh[n], acc[m][n], 0, 0, 0);
          acc[m][n] = __builtin_amdgcn_mfma_f32_16x16x32_bf16(fah[m], fbl[n], acc[m][n], 0, 0, 0);
          acc[m][n] = __builtin_amdgcn_mfma_f32_16x16x32_bf16(fal[m], fbh[n], acc[m][n], 0, 0, 0);
        }
    }
  };

  loadTile(0);
  for (int kk = 0; kk < nK; ++kk) {
    __syncthreads();
    dswrite();
    __syncthreads();
    if (kk + 1 < nK) loadTile(kk + 1);
    compute();
  }

#pragma unroll
  for (int m = 0; m < 4; ++m) {
#pragma unroll
    for (int n = 0; n < 2; ++n) {
      int col = wc * 32 + n * 16 + lr;
#pragma unroll
      for (int q = 0; q < 4; ++q) {
        int row = m0 + wr * 64 + m * 16 + lk * 4 + q;
        if (row < M) Cf[(size_t)row * 64 + col] = acc[m][n][q];
      }
    }
  }

  __syncthreads();
  float* sb = (float*)sAh;
#pragma unroll
  for (int n = 0; n < 2; ++n) {
    float s1 = 0.f, s2 = 0.f;
#pragma unroll
    for (int m = 0; m < 4; ++m)
#pragma unroll
      for (int q = 0; q < 4; ++q) {
        int row = m0 + wr * 64 + m * 16 + lk * 4 + q;
        float v = (row < M) ? acc[m][n][q] : 0.f;
        s1 += v; s2 += v * v;
      }
    s1 += __shfl_xor(s1, 16); s2 += __shfl_xor(s2, 16);
    s1 += __shfl_xor(s1, 32); s2 += __shfl_xor(s2, 32);
    if (lk == 0) {
      int c = wc * 32 + n * 16 + lr;
      sb[(wr * 64 + c) * 2 + 0] = s1;
      sb[(wr * 64 + c) * 2 + 1] = s2;
    }
  }
  __syncthreads();
  if (t < 64) {
    float s1 = sb[t * 2]     + sb[(64 + t) * 2];
    float s2 = sb[t * 2 + 1] + sb[(64 + t) * 2 + 1];
    p1[(size_t)blockIdx.x * 64 + t] = s1;
    p2[(size_t)blockIdx.x * 64 + t] = s2;
  }
}

// ---------- reduce partials -> BN scale/shift ----------
__global__ __launch_bounds__(256) void k_reduce_fin(const float* __restrict__ part1,
                                                    const float* __restrict__ part2,
                                                    int nb, int C, float invN,
                                                    const float* __restrict__ gamma,
                                                    const float* __restrict__ beta,
                                                    float* __restrict__ a_out,
                                                    float* __restrict__ b_out) {
  int c = blockIdx.x;
  int t = threadIdx.x;
  float s1 = 0.f, s2 = 0.f;
  for (int b = t; b < nb; b += 256) {
    s1 += part1[(size_t)b * C + c];
    s2 += part2[(size_t)b * C + c];
  }
  for (int m = 32; m; m >>= 1) { s1 += __shfl_xor(s1, m); s2 += __shfl_xor(s2, m); }
  __shared__ float l1[4], l2[4];
  if ((t & 63) == 0) { l1[t >> 6] = s1; l2[t >> 6] = s2; }
  __syncthreads();
  if (t == 0) {
    s1 = l1[0] + l1[1] + l1[2] + l1[3];
    s2 = l2[0] + l2[1] + l2[2] + l2[3];
    float mu  = s1 * invN;
    float var = s2 * invN - mu * mu;
    float a = gamma[c] * rsqrtf(var + 1e-5f);
    a_out[c] = a;
    b_out[c] = beta[c] - mu * a;
  }
}

// ---------- PS = f16(ap * su) ----------
__global__ __launch_bounds__(256) void k_scaleP(const float* __restrict__ P, const float* __restrict__ ap,
                                                __half* __restrict__ PS, int n8) {
  for (int i = blockIdx.x * 256 + threadIdx.x; i < n8; i += gridDim.x * 256) {
    int c0 = (i & 7) * 8;
    float4 s0 = *(const float4*)(ap + c0), s1 = *(const float4*)(ap + c0 + 4);
    float4 a = ((const float4*)P)[i * 2];
    float4 b = ((const float4*)P)[i * 2 + 1];
    __half2 o0 = __floats2half2_rn(a.x * s0.x, a.y * s0.y);
    __half2 o1 = __floats2half2_rn(a.z * s0.z, a.w * s0.w);
    __half2 o2 = __floats2half2_rn(b.x * s1.x, b.y * s1.y);
    __half2 o3 = __floats2half2_rn(b.z * s1.z, b.w * s1.w);
    uint4 out;
    out.x = *(unsigned*)&o0; out.y = *(unsigned*)&o1;
    out.z = *(unsigned*)&o2; out.w = *(unsigned*)&o3;
    ((uint4*)PS)[i] = out;
  }
}

// ---------- fused per-node: logits + softmax + RAW aggregation + BN + CRF solve ----------
// agg = au*(sum w_j * UBRAW[j]) + bue  (since sum w = 1);  h = (z - agg)@Minv + agg.
__global__ __launch_bounds__(256) void k_nodeall(const __half* __restrict__ PS,
                                                 const int* __restrict__ srcj,
                                                 const int* __restrict__ rowptr,
                                                 const u16* __restrict__ UB,
                                                 const float* __restrict__ au,
                                                 const float* __restrict__ bue,
                                                 const float* __restrict__ minv,
                                                 int N, u16* __restrict__ HB) {
  __shared__ float mS[4096];
  __shared__ float zma[4][64];
  int t = threadIdx.x;
  for (int idx = t; idx < 1024; idx += 256)
    ((float4*)mS)[idx] = ((const float4*)minv)[idx];
  __syncthreads();

  int lane = t & 63, wid = t >> 6;
  int node = blockIdx.x * 4 + wid;
  if (node >= N) return;    // no further block-wide syncs below

  int lane8 = lane & 7, g8 = lane >> 3;
  const uint4* P4 = (const uint4*)PS;
  uint4 uv = P4[(size_t)node * 8 + lane8];
  float2 u0 = __half22float2(*(const __half2*)&uv.x);
  float2 u1 = __half22float2(((const __half2*)&uv.x)[1]);
  float2 u2 = __half22float2(*(const __half2*)&uv.z);
  float2 u3 = __half22float2(((const __half2*)&uv.z)[1]);
  float psl = __half2float(PS[(size_t)node * 64 + lane]);
  int b0 = rowptr[node], b1 = rowptr[node + 1];
  int deg = b1 - b0;
  float aggv = 0.f;
  if (deg > 0) {
    int cnt = deg < 64 ? deg : 64;
    int jj = (lane < cnt) ? srcj[b0 + lane] : 0;
    // ---- logits: 8 groups x 8 lanes, 8 edges/iter, uint4 loads ----
    float lg = -INFINITY;
    int capbase = lane & ~7;
    int capsrc  = (lane & 7) << 3;
    for (int ss = 0; ss < cnt; ss += 8) {
      int sl = ss + g8; if (sl >= cnt) sl = cnt - 1;
      int j = __shfl(jj, sl);
      uint4 vv = P4[(size_t)j * 8 + lane8];
      float2 v0 = __half22float2(*(const __half2*)&vv.x);
      float2 v1 = __half22float2(((const __half2*)&vv.x)[1]);
      float2 v2 = __half22float2(*(const __half2*)&vv.z);
      float2 v3 = __half22float2(((const __half2*)&vv.z)[1]);
      float d0 = u0.x - v0.x, d1 = u0.y - v0.y;
      float d2 = u1.x - v1.x, d3 = u1.y - v1.y;
      float d4 = u2.x - v2.x, d5 = u2.y - v2.y;
      float d6 = u3.x - v3.x, d7 = u3.y - v3.y;
      float p = d0*d0 + d1*d1 + d2*d2 + d3*d3 + d4*d4 + d5*d5 + d6*d6 + d7*d7;
      p += __shfl_xor(p, 1, 8);
      p += __shfl_xor(p, 2, 8);
      p += __shfl_xor(p, 4, 8);
      float val = __shfl(p, capsrc);
      if (ss == capbase && lane < cnt) lg = -val;
    }
    // ---- max (incl. rare deg>64 tail) ----
    float mx = lg;
    for (int s = b0 + 64; s < b1; ++s) {
      int j = srcj[s];
      float d = psl - __half2float(PS[(size_t)j * 64 + lane]);
      float p = d * d;
      for (int m = 32; m; m >>= 1) p += __shfl_xor(p, m);
      mx = fmaxf(mx, -p);
    }
    for (int m = 32; m; m >>= 1) mx = fmaxf(mx, __shfl_xor(mx, m));
    // ---- exp-sum ----
    float ex = (lane < cnt) ? __expf(lg - mx) : 0.f;
    float sm = ex;
    for (int s = b0 + 64; s < b1; ++s) {
      int j = srcj[s];
      float d = psl - __half2float(PS[(size_t)j * 64 + lane]);
      float p = d * d;
      for (int m = 32; m; m >>= 1) p += __shfl_xor(p, m);
      if (lane == 0) sm += __expf(-p - mx);
    }
    for (int m = 32; m; m >>= 1) sm += __shfl_xor(sm, m);
    float inv = 1.0f / (sm + 1e-16f);
    float w = ex * inv;
    // ---- weighted RAW aggregation (8-wide) ----
    float acc = 0.f;
    int ss = 0;
    for (; ss + 8 <= cnt; ss += 8) {
      int   j0 = __shfl(jj, ss),     j1 = __shfl(jj, ss + 1);
      int   j2 = __shfl(jj, ss + 2), j3 = __shfl(jj, ss + 3);
      int   j4 = __shfl(jj, ss + 4), j5 = __shfl(jj, ss + 5);
      int   j6 = __shfl(jj, ss + 6), j7 = __shfl(jj, ss + 7);
      float w0 = __shfl(w, ss),      w1 = __shfl(w, ss + 1);
      float w2 = __shfl(w, ss + 2),  w3 = __shfl(w, ss + 3);
      float w4 = __shfl(w, ss + 4),  w5 = __shfl(w, ss + 5);
      float w6 = __shfl(w, ss + 6),  w7 = __shfl(w, ss + 7);
      float v0 = bf2f(UB[(size_t)j0 * 64 + lane]);
      float v1 = bf2f(UB[(size_t)j1 * 64 + lane]);
      float v2 = bf2f(UB[(size_t)j2 * 64 + lane]);
      float v3 = bf2f(UB[(size_t)j3 * 64 + lane]);
      float v4 = bf2f(UB[(size_t)j4 * 64 + lane]);
      float v5 = bf2f(UB[(size_t)j5 * 64 + lane]);
      float v6 = bf2f(UB[(size_t)j6 * 64 + lane]);
      float v7 = bf2f(UB[(size_t)j7 * 64 + lane]);
      acc += w0 * v0 + w1 * v1 + w2 * v2 + w3 * v3;
      acc += w4 * v4 + w5 * v5 + w6 * v6 + w7 * v7;
    }
    for (; ss < cnt; ++ss) {
      int j0 = __shfl(jj, ss);
      float w0 = __shfl(w, ss);
      acc += w0 * bf2f(UB[(size_t)j0 * 64 + lane]);
    }
    for (int s = b0 + 64; s < b1; ++s) {   // rare tail
      int j = srcj[s];
      float d = psl - __half2float(PS[(size_t)j * 64 + lane]);
      float p = d * d;
      for (int m = 32; m; m >>= 1) p += __shfl_xor(p, m);
      acc += __expf(-p - mx) * inv * bf2f(UB[(size_t)j * 64 + lane]);
    }
    aggv = au[lane] * acc + bue[lane];   // BN applied once (sum w = 1)
  }
  // ---- CRF solve in-wave: h = aggv + sum_k (z_k - agg_k) * Minv[k][lane] ----
  float z = au[lane] * bf2f(UB[(size_t)node * 64 + lane]) + bue[lane];
  zma[wid][lane] = z - aggv;
  float h = aggv;
#pragma unroll 8
  for (int k = 0; k < 64; ++k) h += zma[wid][k] * mS[k * 64 + lane];
  HB[(size_t)node * 64 + lane] = f2bf(h);
}

// ---------- final BN + leaky: bf16 raw -> f32 out ----------
__global__ __launch_bounds__(256) void k_bnact16(const u16* __restrict__ raw, const float* __restrict__ af,
                                                 const float* __restrict__ bfp, float* __restrict__ out, int n8) {
  int i = blockIdx.x * 256 + threadIdx.x;
  int stride = gridDim.x * 256;
  for (; i < n8; i += stride) {
    int c0 = (i & 31) * 8;
    float av[8], bv[8];
    *(float4*)(av) = *(const float4*)(af + c0);  *(float4*)(av + 4) = *(const float4*)(af + c0 + 4);
    *(float4*)(bv) = *(const float4*)(bfp + c0); *(float4*)(bv + 4) = *(const float4*)(bfp + c0 + 4);
    u16x8 r = ((const u16x8*)raw)[i];
    float o[8];
#pragma unroll
    for (int j = 0; j < 8; ++j) {
      float v = bf2f((u16)r[j]) * av[j] + bv[j];
      o[j] = (v > 0.f) ? v : 0.01f * v;
    }
    ((float4*)out)[i * 2]     = *(float4*)(o);
    ((float4*)out)[i * 2 + 1] = *(float4*)(o + 4);
  }
}

extern "C" void kernel_launch(void* const* d_in, const int* in_sizes, int n_in,
                              void* d_out, int out_size, void* d_ws, size_t ws_size,
                              hipStream_t stream) {
  const float* x    = (const float*)d_in[0];
  const float* y    = (const float*)d_in[1];
  const int*   eidx = (const int*)d_in[3];
  const float* Wu   = (const float*)d_in[4];
  const float* gu   = (const float*)d_in[5];
  const float* bu   = (const float*)d_in[6];
  const float* Wp   = (const float*)d_in[7];
  const float* gp   = (const float*)d_in[8];
  const float* bp   = (const float*)d_in[9];
  const float* cIn  = (const float*)d_in[10];
  const float* Wm   = (const float*)d_in[11];
  const float* gm   = (const float*)d_in[12];
  const float* bm   = (const float*)d_in[13];
  const float* Wf   = (const float*)d_in[14];
  const float* gf   = (const float*)d_in[15];
  const float* bfv  = (const float*)d_in[16];

  const int N = in_sizes[0] / 256;
  const int E = in_sizes[3] / 2;
  const int* ei = eidx;
  const int* ej = eidx + E;

  char* ws = (char*)d_ws;
  float* MINV  = (float*)(ws + OFF_MINV);
  float* AU    = (float*)(ws + OFF_AU);
  float* BUE   = (float*)(ws + OFF_BUE);
  float* AP    = (float*)(ws + OFF_AP);
  float* APBE  = (float*)(ws + OFF_APBE);
  float* AM    = (float*)(ws + OFF_AM);
  float* BM    = (float*)(ws + OFF_BM);
  float* AF    = (float*)(ws + OFF_AF);
  float* BF    = (float*)(ws + OFF_BF);
  int*   BTOT  = (int*)(ws + OFF_BTOT);
  int*   BOFF  = (int*)(ws + OFF_BOFF);
  u16*   WUT   = (u16*)(ws + OFF_WUT);
  u16*   WMT   = (u16*)(ws + OFF_WMT);
  u16*   WFT   = (u16*)(ws + OFF_WFT);
  u16*   WPH   = (u16*)(ws + OFF_WPH);
  u16*   WPL   = (u16*)(ws + OFF_WPL);
  float* PART1 = (float*)(ws + OFF_PART1);
  float* PART2 = (float*)(ws + OFF_PART2);
  int*   ROWPTR= (int*)(ws + OFF_ROWPTR);
  int*   BLKCNT= (int*)(ws + OFF_BLKCNT);
  u16*   HB    = (u16*)(ws + OFF_BLKCNT);    // reuse (BLKCNT dead after kA3)
  int*   SRCJ  = (int*)(ws + OFF_SRCJ);
  u16*   RAWO  = (u16*)(ws + OFF_SRCJ);      // reuse (SRCJ dead after k_nodeall)
  u16*   UBRAW = (u16*)(ws + OFF_U);
  unsigned* TMP= (unsigned*)(ws + OFF_P);    // packed bins; dead after kB
  float* P     = (float*)(ws + OFF_P);
  __half* PS   = (__half*)(ws + OFF_PS);
  u16*   H2    = (u16*)(ws + OFF_H2);

  const float invN = 1.0f / (float)N;
  const int mtiles   = (N + 127) / 128;
  const int n8_64    = N * 64 / 8;
  const int n8_256   = N * 256 / 8;
  const int nbk      = (N + 255) >> 8;
  const int chunk    = (E + NBLK_BIN - 1) / NBLK_BIN;

  k_prep<<<1, 256, 0, stream>>>(cIn, MINV);
  k_tcvt_all<<<704, 256, 0, stream>>>(Wu, Wm, Wf, Wp, WUT, WMT, WFT, WPH, WPL);

  // CSR build: deterministic two-level binned counting sort (no global atomics)
  kA1<<<NBLK_BIN, 256, 0, stream>>>(ei, E, chunk, BLKCNT, nbk);
  kA2<<<nbk, 256, 0, stream>>>(BLKCNT, nbk, BTOT);
  kA2b<<<1, 512, 0, stream>>>(BTOT, BOFF, nbk);
  kA3<<<NBLK_BIN, 256, 0, stream>>>(ei, ej, E, chunk, BLKCNT, BOFF, nbk, TMP);
  kB<<<nbk, 256, 0, stream>>>(TMP, BOFF, nbk, N, E, ROWPTR, SRCJ);

  // unary embedding (stats fused) -> UBRAW bf16; BN params (UN table no longer needed)
  k_mfma<64, 2, 1, 1><<<dim3(mtiles, 1), 256, 0, stream>>>(
      nullptr, x, 256, 256, N, nullptr, nullptr, nullptr, nullptr, WUT,
      nullptr, UBRAW, 64, 64, PART1, PART2);
  k_reduce_fin<<<64, 256, 0, stream>>>(PART1, PART2, mtiles, 64, invN, gu, bu, AU, BUE);

  // pairwise embedding: split-bf16 MFMA (stats fused) -> P f32 (TMP dead); PS f16 table
  k_mfma_split<<<mtiles, 256, 0, stream>>>(y, 256, N, WPH, WPL, P, PART1, PART2);
  k_reduce_fin<<<64, 256, 0, stream>>>(PART1, PART2, mtiles, 64, invN, gp, bp, AP, APBE);
  k_scaleP<<<1024, 256, 0, stream>>>(P, AP, PS, n8_64);

  // fused logits + softmax + aggregation + BN + CRF solve -> HB (no AGG buffer)
  k_nodeall<<<(N + 3) / 4, 256, 0, stream>>>(PS, SRCJ, ROWPTR, UBRAW, AU, BUE, MINV, N, HB);

  // h @ Wm -> h2 bf16 (stats fused)
  k_mfma<128, 0, 1, 1><<<dim3(mtiles, 2), 256, 0, stream>>>(
      HB, nullptr, 64, 64, N, nullptr, nullptr, nullptr, nullptr, WMT,
      nullptr, H2, 256, 256, PART1, PART2);
  k_reduce_fin<<<256, 256, 0, stream>>>(PART1, PART2, mtiles, 256, invN, gm, bm, AM, BM);

  // [leaky(bn(h2)), y] @ Wf -> raw bf16 (stats fused, overwrites SRCJ region), BN + leaky -> d_out
  k_mfma<128, 1, 1, 1><<<dim3(mtiles, 2), 256, 0, stream>>>(
      nullptr, nullptr, 0, 512, N, H2, y, AM, BM, WFT,
      nullptr, RAWO, 256, 256, PART1, PART2);
  k_reduce_fin<<<256, 256, 0, stream>>>(PART1, PART2, mtiles, 256, invN, gf, bfv, AF, BF);
  k_bnact16<<<2048, 256, 0, stream>>>(RAWO, AF, BF, (float*)d_out, n8_256);
}

// Round 10
// 536.701 us; speedup vs baseline: 5.2906x; 1.0256x over previous
//
#include <hip/hip_runtime.h>
#include <hip/hip_fp16.h>
#include <math.h>

typedef unsigned short u16;
typedef short s16x8 __attribute__((ext_vector_type(8)));
typedef unsigned short u16x8 __attribute__((ext_vector_type(8)));
typedef float f32x4 __attribute__((ext_vector_type(4)));

// ---------- helpers ----------
__device__ __forceinline__ float bf2f(u16 u) {
  unsigned x = ((unsigned)u) << 16;
  return __uint_as_float(x);
}
__device__ __forceinline__ u16 f2bf(float f) {
  unsigned x = __float_as_uint(f);
  unsigned r = x + 0x7FFFu + ((x >> 16) & 1u);
  return (u16)(r >> 16);
}

// ---------- ws layout (bytes) ----------
static const size_t OFF_MINV   = 0;
static const size_t OFF_AU     = 32ull * 1024;
static const size_t OFF_BUE    = 32ull * 1024 + 256;
static const size_t OFF_AP     = 32ull * 1024 + 512;
static const size_t OFF_APBE   = 32ull * 1024 + 768;
static const size_t OFF_AM     = 36ull * 1024;
static const size_t OFF_BM     = 37ull * 1024;
static const size_t OFF_AF     = 38ull * 1024;
static const size_t OFF_BF     = 39ull * 1024;
static const size_t OFF_BTOT   = 40ull * 1024;
static const size_t OFF_BOFF   = 44ull * 1024;
static const size_t OFF_WUT    = 64ull * 1024;
static const size_t OFF_WMT    = 128ull * 1024;
static const size_t OFF_WFT    = 192ull * 1024;
static const size_t OFF_WPH    = 512ull * 1024;
static const size_t OFF_WPL    = 576ull * 1024;
static const size_t OFF_PART1  = 1ull  * 1024 * 1024;
static const size_t OFF_PART2  = 2ull  * 1024 * 1024;
static const size_t OFF_ROWPTR = 3ull  * 1024 * 1024;
static const size_t OFF_BLKCNT = 5ull  * 1024 * 1024;     // 2MB; dead after kA3 -> HB bf16 N*64
static const size_t OFF_SRCJ   = 18ull * 1024 * 1024;     // E int; dead after k_nodeall -> RAWO bf16 N*256
static const size_t OFF_U      = 44ull * 1024 * 1024;     // UBRAW bf16 N*64
static const size_t OFF_P      = 70ull * 1024 * 1024;     // TMP uint E early; then P f32
static const size_t OFF_PS     = 109ull * 1024 * 1024;
static const size_t OFF_H2     = 122ull * 1024 * 1024;

#define NBLK_BIN 1024

// ---------- K0: Minv = (I + c^T c)^-1 (conflict-free GJ, deferred normalization: 2 syncs/pivot) ----------
__global__ __launch_bounds__(256) void k_prep(const float* __restrict__ c,
                                              float* __restrict__ minv_out) {
  __shared__ float CC[4096];
  __shared__ float aug[64 * 129];
  __shared__ float fs[64];
  float* cl = aug;
  int t = threadIdx.x;
  for (int idx = t; idx < 4096; idx += 256) cl[idx] = c[idx];
  __syncthreads();
  for (int idx = t; idx < 4096; idx += 256) {
    int a = idx >> 6, b = idx & 63;
    float s = (a == b) ? 1.f : 0.f;
    for (int k = 0; k < 64; ++k) s += cl[k * 64 + a] * cl[k * 64 + b];
    CC[idx] = s;
  }
  __syncthreads();
  for (int idx = t; idx < 8192; idx += 256) {
    int r = idx >> 7, cc = idx & 127;
    aug[r * 129 + cc] = (cc < 64) ? CC[r * 64 + cc] : (((cc - 64) == r) ? 1.f : 0.f);
  }
  __syncthreads();
  int cloc = t & 127;
  int rbase = t >> 7;
  for (int p = 0; p < 64; ++p) {
    if (t < 64) fs[t] = (t == p) ? 0.f : aug[t * 129 + p] / aug[p * 129 + p];
    __syncthreads();
    float pc = aug[p * 129 + cloc];
#pragma unroll
    for (int rr = 0; rr < 64; rr += 2) {
      int r = rr + rbase;
      aug[r * 129 + cloc] -= fs[r] * pc;   // fs[p]=0: benign rewrite of row p
    }
    __syncthreads();
  }
  for (int idx = t; idx < 4096; idx += 256) {
    int r = idx >> 6, cc = idx & 63;
    minv_out[idx] = aug[r * 129 + 64 + cc] / aug[r * 129 + r];
  }
}

// ---------- merged weight transpose/convert ----------
__global__ __launch_bounds__(256) void k_tcvt_all(const float* __restrict__ Wu, const float* __restrict__ Wm,
                                                  const float* __restrict__ Wf, const float* __restrict__ Wp,
                                                  u16* __restrict__ WUT, u16* __restrict__ WMT,
                                                  u16* __restrict__ WFT, u16* __restrict__ WPH,
                                                  u16* __restrict__ WPL) {
  int b = blockIdx.x, t = threadIdx.x;
  if (b < 64) {
    int i = b * 256 + t;
    int k = i >> 6, n = i & 63;
    WUT[(size_t)n * 256 + k] = f2bf(Wu[i]);
  } else if (b < 128) {
    int i = (b - 64) * 256 + t;
    int k = i >> 8, n = i & 255;
    WMT[(size_t)n * 64 + k] = f2bf(Wm[i]);
  } else if (b < 640) {
    int i = (b - 128) * 256 + t;
    int k = i >> 8, n = i & 255;
    WFT[(size_t)n * 512 + k] = f2bf(Wf[i]);
  } else {
    int i = (b - 640) * 256 + t;
    int k = i >> 6, n = i & 63;
    float v = Wp[i];
    u16 h = f2bf(v);
    WPH[(size_t)n * 256 + k] = h;
    WPL[(size_t)n * 256 + k] = f2bf(v - bf2f(h));
  }
}

// ---------- binned CSR build ----------
__global__ __launch_bounds__(256) void kA1(const int* __restrict__ ei, int E, int chunk,
                                           int* __restrict__ blockCnt, int nbk) {
  __shared__ int c[512];
  int t = threadIdx.x, bid = blockIdx.x;
  c[t] = 0; c[t + 256] = 0;
  __syncthreads();
  int e0 = bid * chunk, e1 = min(E, e0 + chunk);
  for (int e = e0 + t; e < e1; e += 256) atomicAdd(&c[ei[e] >> 8], 1);
  __syncthreads();
  for (int b = t; b < nbk; b += 256) blockCnt[(size_t)bid * nbk + b] = c[b];
}

__global__ __launch_bounds__(256) void kA2(int* __restrict__ blockCnt, int nbk,
                                           int* __restrict__ bucketTot) {
  int b = blockIdx.x, t = threadIdx.x;
  int base = t * 4;
  int v0 = blockCnt[(size_t)(base + 0) * nbk + b];
  int v1 = blockCnt[(size_t)(base + 1) * nbk + b];
  int v2 = blockCnt[(size_t)(base + 2) * nbk + b];
  int v3 = blockCnt[(size_t)(base + 3) * nbk + b];
  int s1 = v0 + v1, s2 = s1 + v2, tot = s2 + v3;
  __shared__ int ps[256];
  ps[t] = tot;
  __syncthreads();
  for (int off = 1; off < 256; off <<= 1) {
    int a = (t >= off) ? ps[t - off] : 0;
    __syncthreads();
    ps[t] += a;
    __syncthreads();
  }
  int ex = (t > 0) ? ps[t - 1] : 0;
  blockCnt[(size_t)(base + 0) * nbk + b] = ex;
  blockCnt[(size_t)(base + 1) * nbk + b] = ex + v0;
  blockCnt[(size_t)(base + 2) * nbk + b] = ex + s1;
  blockCnt[(size_t)(base + 3) * nbk + b] = ex + s2;
  if (t == 255) bucketTot[b] = ps[255];
}

__global__ __launch_bounds__(512) void kA2b(const int* __restrict__ bucketTot,
                                            int* __restrict__ bucketOff, int nbk) {
  __shared__ int s[512];
  int t = threadIdx.x;
  s[t] = (t < nbk) ? bucketTot[t] : 0;
  __syncthreads();
  for (int off = 1; off < 512; off <<= 1) {
    int a = (t >= off) ? s[t - off] : 0;
    __syncthreads();
    s[t] += a;
    __syncthreads();
  }
  if (t == 0) bucketOff[0] = 0;
  if (t < nbk) bucketOff[t + 1] = s[t];
}

__global__ __launch_bounds__(256) void kA3(const int* __restrict__ ei, const int* __restrict__ ej,
                                           int E, int chunk,
                                           const int* __restrict__ blockExc,
                                           const int* __restrict__ bucketOff,
                                           int nbk, unsigned* __restrict__ tmp) {
  __shared__ int c[512], off[512], gb[512], cur[512];
  __shared__ uint2 stage[4096];
  int t = threadIdx.x, bid = blockIdx.x;
  c[t] = 0; c[t + 256] = 0;
  __syncthreads();
  int e0 = bid * chunk, e1 = min(E, e0 + chunk);
  int m = e1 - e0;
  for (int e = e0 + t; e < e1; e += 256) atomicAdd(&c[ei[e] >> 8], 1);
  __syncthreads();
  int v0 = c[t], v1 = c[t + 256];
  off[t] = v0; off[t + 256] = v1;
  __syncthreads();
  for (int o = 1; o < 512; o <<= 1) {
    int a0 = (t >= o) ? off[t - o] : 0;
    int a1 = ((t + 256) >= o) ? off[t + 256 - o] : 0;
    __syncthreads();
    off[t] += a0; off[t + 256] += a1;
    __syncthreads();
  }
  int ex0 = off[t] - v0, ex1 = off[t + 256] - v1;
  if (t < nbk)
    gb[t] = bucketOff[t] + blockExc[(size_t)bid * nbk + t] - ex0;
  if (t + 256 < nbk)
    gb[t + 256] = bucketOff[t + 256] + blockExc[(size_t)bid * nbk + t + 256] - ex1;
  cur[t] = ex0; cur[t + 256] = ex1;
  __syncthreads();
  for (int e = e0 + t; e < e1; e += 256) {
    int i = ei[e];
    int p = atomicAdd(&cur[i >> 8], 1);
    stage[p] = make_uint2((unsigned)i, (unsigned)ej[e]);
  }
  __syncthreads();
  for (int s = t; s < m; s += 256) {
    uint2 v = stage[s];
    tmp[gb[v.x >> 8] + s] = ((v.x & 255u) << 24) | v.y;
  }
}

#define BCAP 12288
__global__ __launch_bounds__(256) void kB(const unsigned* __restrict__ tmp,
                                          const int* __restrict__ bucketOff,
                                          int nbk, int N, int E,
                                          int* __restrict__ rowptr, int* __restrict__ srcj) {
  __shared__ int cnt[256], sc[256], cur[256];
  __shared__ int jbuf[BCAP];
  int b = blockIdx.x, t = threadIdx.x;
  int nb0 = b << 8;
  int e0 = bucketOff[b], e1 = bucketOff[b + 1];
  int m = e1 - e0;
  cnt[t] = 0;
  __syncthreads();
  for (int s = t; s < m; s += 256) atomicAdd(&cnt[tmp[e0 + s] >> 24], 1);
  __syncthreads();
  int v = cnt[t];
  sc[t] = v;
  __syncthreads();
  for (int off = 1; off < 256; off <<= 1) {
    int a = (t >= off) ? sc[t - off] : 0;
    __syncthreads();
    sc[t] += a;
    __syncthreads();
  }
  int exc = sc[t] - v;
  cur[t] = exc;
  if (nb0 + t < N) rowptr[nb0 + t] = e0 + exc;
  if (b == nbk - 1 && t == 0) rowptr[N] = E;
  __syncthreads();
  for (int s = t; s < m; s += 256) {
    unsigned e = tmp[e0 + s];
    int p = atomicAdd(&cur[e >> 24], 1);
    if (p < BCAP) jbuf[p] = (int)(e & 0xFFFFFFu);
  }
  __syncthreads();
  for (int s = t; s < m; s += 256) srcj[e0 + s] = jbuf[s];
}

// ---------- MFMA GEMM BM=128 x BN=64 (xu path, AMODE 2) ----------
template<int BN, int AMODE, int OBF, int STATS>
__global__ __launch_bounds__(256) void k_mfma(const u16* __restrict__ Abf, const float* __restrict__ Af32,
                                              int ldA, int K, int M,
                                              const u16* __restrict__ Bt,
                                              float* __restrict__ Cf, u16* __restrict__ Cb, int ldC,
                                              int ncTot, float* __restrict__ p1, float* __restrict__ p2) {
  constexpr int WN  = BN / 2;
  constexpr int FN  = WN / 16;
  constexpr int NPB = BN / 32;
  __shared__ u16 lds[2][(128 + BN) * 64];

  int t = threadIdx.x;
  int wid = t >> 6, lane = t & 63;
  int wr = wid >> 1, wc = wid & 1;
  int lr = lane & 15, lk = lane >> 4;
  int m0 = blockIdx.x * 128;
  int n0 = blockIdx.y * BN;
  int nK = K >> 6;

  int sidx = t;
  u16x8 ra[4];
  u16x8 rb[NPB];

  f32x4 acc[4][FN];
#pragma unroll
  for (int m = 0; m < 4; ++m)
#pragma unroll
    for (int n = 0; n < FN; ++n) acc[m][n] = (f32x4){0.f, 0.f, 0.f, 0.f};

  auto loadTile = [&](int kk) {
    int kk0 = kk * 64;
#pragma unroll
    for (int p = 0; p < 4; ++p) {
      int idx = p * 256 + sidx;
      int r = idx >> 3, c8 = idx & 7;
      int row = m0 + r; if (row >= M) row = M - 1;
      int k = kk0 + c8 * 8;
      if constexpr (AMODE == 0) {
        ra[p] = *(const u16x8*)(Abf + (size_t)row * ldA + k);
      } else {
        const float* src = Af32 + (size_t)row * ldA + k;
        float4 a = *(const float4*)src;
        float4 b = *(const float4*)(src + 4);
        u16x8 o;
        o[0] = f2bf(a.x); o[1] = f2bf(a.y); o[2] = f2bf(a.z); o[3] = f2bf(a.w);
        o[4] = f2bf(b.x); o[5] = f2bf(b.y); o[6] = f2bf(b.z); o[7] = f2bf(b.w);
        ra[p] = o;
      }
    }
#pragma unroll
    for (int p = 0; p < NPB; ++p) {
      int idx = p * 256 + sidx;
      int r = idx >> 3, c8 = idx & 7;
      rb[p] = *(const u16x8*)(Bt + (size_t)(n0 + r) * K + kk0 + c8 * 8);
    }
  };

  auto dswrite = [&](int b) {
    char* As  = (char*)&lds[b][0];
    char* Bsc = As + 128 * 64 * 2;
#pragma unroll
    for (int p = 0; p < 4; ++p) {
      int idx = p * 256 + sidx;
      int r = idx >> 3, c8 = idx & 7;
      *(u16x8*)(As + r * 128 + ((c8 * 16) ^ ((r & 7) << 4))) = ra[p];
    }
#pragma unroll
    for (int p = 0; p < NPB; ++p) {
      int idx = p * 256 + sidx;
      int r = idx >> 3, c8 = idx & 7;
      *(u16x8*)(Bsc + r * 128 + ((c8 * 16) ^ ((r & 7) << 4))) = rb[p];
    }
  };

  auto compute = [&](int b) {
    const char* As  = (const char*)&lds[b][0];
    const char* Bsc = As + 128 * 64 * 2;
#pragma unroll
    for (int ks = 0; ks < 2; ++ks) {
      int kb = ks * 64 + lk * 16;
      s16x8 af[4], bfr[FN];
#pragma unroll
      for (int m = 0; m < 4; ++m) {
        int row = wr * 64 + m * 16 + lr;
        af[m] = *(const s16x8*)(As + row * 128 + (kb ^ ((row & 7) << 4)));
      }
#pragma unroll
      for (int n = 0; n < FN; ++n) {
        int row = wc * WN + n * 16 + lr;
        bfr[n] = *(const s16x8*)(Bsc + row * 128 + (kb ^ ((row & 7) << 4)));
      }
#pragma unroll
      for (int m = 0; m < 4; ++m)
#pragma unroll
        for (int n = 0; n < FN; ++n)
          acc[m][n] = __builtin_amdgcn_mfma_f32_16x16x32_bf16(af[m], bfr[n], acc[m][n], 0, 0, 0);
    }
  };

  loadTile(0);
  dswrite(0);
  __syncthreads();
  for (int kk = 0; kk < nK; ++kk) {
    int b = kk & 1;
    if (kk + 1 < nK) loadTile(kk + 1);
    compute(b);
    if (kk + 1 < nK) { dswrite(b ^ 1); __syncthreads(); }
  }

#pragma unroll
  for (int m = 0; m < 4; ++m) {
#pragma unroll
    for (int n = 0; n < FN; ++n) {
      int col = n0 + wc * WN + n * 16 + lr;
#pragma unroll
      for (int q = 0; q < 4; ++q) {
        int row = m0 + wr * 64 + m * 16 + lk * 4 + q;
        if (row < M) {
          if constexpr (OBF) Cb[(size_t)row * ldC + col] = f2bf(acc[m][n][q]);
          else               Cf[(size_t)row * ldC + col] = acc[m][n][q];
        }
      }
    }
  }

  if constexpr (STATS) {
    __syncthreads();
    float* sb = (float*)&lds[0][0];
#pragma unroll
    for (int n = 0; n < FN; ++n) {
      float s1 = 0.f, s2 = 0.f;
#pragma unroll
      for (int m = 0; m < 4; ++m)
#pragma unroll
        for (int q = 0; q < 4; ++q) {
          int row = m0 + wr * 64 + m * 16 + lk * 4 + q;
          float v = (row < M) ? acc[m][n][q] : 0.f;
          s1 += v; s2 += v * v;
        }
      s1 += __shfl_xor(s1, 16); s2 += __shfl_xor(s2, 16);
      s1 += __shfl_xor(s1, 32); s2 += __shfl_xor(s2, 32);
      if (lk == 0) {
        int c = wc * WN + n * 16 + lr;
        sb[(wr * BN + c) * 2 + 0] = s1;
        sb[(wr * BN + c) * 2 + 1] = s2;
      }
    }
    __syncthreads();
    if (t < BN) {
      float s1 = sb[t * 2]     + sb[(BN + t) * 2];
      float s2 = sb[t * 2 + 1] + sb[(BN + t) * 2 + 1];
      p1[(size_t)blockIdx.x * ncTot + n0 + t] = s1;
      p2[(size_t)blockIdx.x * ncTot + n0 + t] = s2;
    }
  }
}

// ---------- MFMA GEMM2: BM=128 x BN=256 in ONE block (512 threads, 8 waves 2x4) ----------
// A read once per row-tile (no y-grid reread). AMODE 0: A bf16; AMODE 1: [leaky(am*h2+bm)|y].
template<int AMODE>
__global__ __launch_bounds__(512) void k_mfma2(const u16* __restrict__ Abf, int ldA, int K, int M,
                                               const u16* __restrict__ h2, const float* __restrict__ yy,
                                               const float* __restrict__ am, const float* __restrict__ bm,
                                               const u16* __restrict__ Bt,
                                               u16* __restrict__ Cb,
                                               float* __restrict__ p1, float* __restrict__ p2) {
  __shared__ u16 lds[2][(128 + 256) * 64];   // 96KB
  int t = threadIdx.x;
  int wid = t >> 6, lane = t & 63;
  int wr = wid >> 2, wc = wid & 3;
  int lr = lane & 15, lk = lane >> 4;
  int m0 = blockIdx.x * 128;
  int nK = K >> 6;

  u16x8 ra[2];
  u16x8 rb[4];
  f32x4 acc[4][4];
#pragma unroll
  for (int m = 0; m < 4; ++m)
#pragma unroll
    for (int n = 0; n < 4; ++n) acc[m][n] = (f32x4){0.f, 0.f, 0.f, 0.f};

  auto loadTile = [&](int kk) {
    int kk0 = kk * 64;
#pragma unroll
    for (int p = 0; p < 2; ++p) {
      int idx = p * 512 + t;
      int r = idx >> 3, c8 = idx & 7;
      int row = m0 + r; if (row >= M) row = M - 1;
      int k = kk0 + c8 * 8;
      if constexpr (AMODE == 0) {
        ra[p] = *(const u16x8*)(Abf + (size_t)row * ldA + k);
      } else {
        if (kk0 < 256) {
          u16x8 h8 = *(const u16x8*)(h2 + (size_t)row * 256 + k);
          float av[8], bv[8];
          *(float4*)(av)     = *(const float4*)(am + k);
          *(float4*)(av + 4) = *(const float4*)(am + k + 4);
          *(float4*)(bv)     = *(const float4*)(bm + k);
          *(float4*)(bv + 4) = *(const float4*)(bm + k + 4);
          u16x8 o;
#pragma unroll
          for (int j = 0; j < 8; ++j) {
            float v = bf2f((u16)h8[j]) * av[j] + bv[j];
            v = v > 0.f ? v : 0.01f * v;
            o[j] = f2bf(v);
          }
          ra[p] = o;
        } else {
          float yv[8];
          *(float4*)(yv)     = *(const float4*)(yy + (size_t)row * 256 + (k - 256));
          *(float4*)(yv + 4) = *(const float4*)(yy + (size_t)row * 256 + (k - 256) + 4);
          u16x8 o;
#pragma unroll
          for (int j = 0; j < 8; ++j) o[j] = f2bf(yv[j]);
          ra[p] = o;
        }
      }
    }
#pragma unroll
    for (int p = 0; p < 4; ++p) {
      int idx = p * 512 + t;
      int r = idx >> 3, c8 = idx & 7;
      rb[p] = *(const u16x8*)(Bt + (size_t)r * K + kk0 + c8 * 8);
    }
  };

  auto dswrite = [&](int b) {
    char* As  = (char*)&lds[b][0];
    char* Bsc = As + 128 * 64 * 2;
#pragma unroll
    for (int p = 0; p < 2; ++p) {
      int idx = p * 512 + t;
      int r = idx >> 3, c8 = idx & 7;
      *(u16x8*)(As + r * 128 + ((c8 * 16) ^ ((r & 7) << 4))) = ra[p];
    }
#pragma unroll
    for (int p = 0; p < 4; ++p) {
      int idx = p * 512 + t;
      int r = idx >> 3, c8 = idx & 7;
      *(u16x8*)(Bsc + r * 128 + ((c8 * 16) ^ ((r & 7) << 4))) = rb[p];
    }
  };

  auto compute = [&](int b) {
    const char* As  = (const char*)&lds[b][0];
    const char* Bsc = As + 128 * 64 * 2;
#pragma unroll
    for (int ks = 0; ks < 2; ++ks) {
      int kb = ks * 64 + lk * 16;
      s16x8 af[4], bfr[4];
#pragma unroll
      for (int m = 0; m < 4; ++m) {
        int row = wr * 64 + m * 16 + lr;
        af[m] = *(const s16x8*)(As + row * 128 + (kb ^ ((row & 7) << 4)));
      }
#pragma unroll
      for (int n = 0; n < 4; ++n) {
        int row = wc * 64 + n * 16 + lr;
        bfr[n] = *(const s16x8*)(Bsc + row * 128 + (kb ^ ((row & 7) << 4)));
      }
#pragma unroll
      for (int m = 0; m < 4; ++m)
#pragma unroll
        for (int n = 0; n < 4; ++n)
          acc[m][n] = __builtin_amdgcn_mfma_f32_16x16x32_bf16(af[m], bfr[n], acc[m][n], 0, 0, 0);
    }
  };

  loadTile(0);
  dswrite(0);
  __syncthreads();
  for (int kk = 0; kk < nK; ++kk) {
    int b = kk & 1;
    if (kk + 1 < nK) loadTile(kk + 1);
    compute(b);
    if (kk + 1 < nK) { dswrite(b ^ 1); __syncthreads(); }
  }

#pragma unroll
  for (int m = 0; m < 4; ++m) {
#pragma unroll
    for (int n = 0; n < 4; ++n) {
      int col = wc * 64 + n * 16 + lr;
#pragma unroll
      for (int q = 0; q < 4; ++q) {
        int row = m0 + wr * 64 + m * 16 + lk * 4 + q;
        if (row < M) Cb[(size_t)row * 256 + col] = f2bf(acc[m][n][q]);
      }
    }
  }

  // fused column stats
  __syncthreads();
  float* sb = (float*)&lds[0][0];   // [2 wr][256 col][2]
#pragma unroll
  for (int n = 0; n < 4; ++n) {
    float s1 = 0.f, s2 = 0.f;
#pragma unroll
    for (int m = 0; m < 4; ++m)
#pragma unroll
      for (int q = 0; q < 4; ++q) {
        int row = m0 + wr * 64 + m * 16 + lk * 4 + q;
        float v = (row < M) ? acc[m][n][q] : 0.f;
        s1 += v; s2 += v * v;
      }
    s1 += __shfl_xor(s1, 16); s2 += __shfl_xor(s2, 16);
    s1 += __shfl_xor(s1, 32); s2 += __shfl_xor(s2, 32);
    if (lk == 0) {
      int c = wc * 64 + n * 16 + lr;
      sb[(wr * 256 + c) * 2 + 0] = s1;
      sb[(wr * 256 + c) * 2 + 1] = s2;
    }
  }
  __syncthreads();
  if (t < 256) {
    float s1 = sb[t * 2]     + sb[(256 + t) * 2];
    float s2 = sb[t * 2 + 1] + sb[(256 + t) * 2 + 1];
    p1[(size_t)blockIdx.x * 256 + t] = s1;
    p2[(size_t)blockIdx.x * 256 + t] = s2;
  }
}

// ---------- split-bf16 MFMA (f32 accuracy) with fused stats ----------
__global__ __launch_bounds__(256) void k_mfma_split(const float* __restrict__ Af, int K, int M,
                                                    const u16* __restrict__ Bh, const u16* __restrict__ Bl,
                                                    float* __restrict__ Cf,
                                                    float* __restrict__ p1, float* __restrict__ p2) {
  __shared__ u16 sAh[128 * 64], sAl[128 * 64], sBh[64 * 64], sBl[64 * 64];
  int t = threadIdx.x;
  int wid = t >> 6, lane = t & 63;
  int wr = wid >> 1, wc = wid & 1;
  int lr = lane & 15, lk = lane >> 4;
  int m0 = blockIdx.x * 128;
  int nK = K >> 6;

  u16x8 rah[4], ral[4], rbh[2], rbl[2];
  f32x4 acc[4][2];
#pragma unroll
  for (int m = 0; m < 4; ++m)
#pragma unroll
    for (int n = 0; n < 2; ++n) acc[m][n] = (f32x4){0.f, 0.f, 0.f, 0.f};

  auto loadTile = [&](int kk) {
    int kk0 = kk * 64;
#pragma unroll
    for (int p = 0; p < 4; ++p) {
      int idx = p * 256 + t;
      int r = idx >> 3, c8 = idx & 7;
      int row = m0 + r; if (row >= M) row = M - 1;
      const float* src = Af + (size_t)row * K + kk0 + c8 * 8;
      float4 a = *(const float4*)src;
      float4 b = *(const float4*)(src + 4);
      float v[8];
      *(float4*)(v) = a; *(float4*)(v + 4) = b;
      u16x8 oh, ol;
#pragma unroll
      for (int j = 0; j < 8; ++j) {
        u16 h = f2bf(v[j]);
        oh[j] = h;
        ol[j] = f2bf(v[j] - bf2f(h));
      }
      rah[p] = oh; ral[p] = ol;
    }
#pragma unroll
    for (int p = 0; p < 2; ++p) {
      int idx = p * 256 + t;
      int r = idx >> 3, c8 = idx & 7;
      rbh[p] = *(const u16x8*)(Bh + (size_t)r * K + kk0 + c8 * 8);
      rbl[p] = *(const u16x8*)(Bl + (size_t)r * K + kk0 + c8 * 8);
    }
  };

  auto dswrite = [&]() {
    char* Ah = (char*)sAh; char* Al = (char*)sAl;
    char* Bhc = (char*)sBh; char* Blc = (char*)sBl;
#pragma unroll
    for (int p = 0; p < 4; ++p) {
      int idx = p * 256 + t;
      int r = idx >> 3, c8 = idx & 7;
      int off = r * 128 + ((c8 * 16) ^ ((r & 7) << 4));
      *(u16x8*)(Ah + off) = rah[p];
      *(u16x8*)(Al + off) = ral[p];
    }
#pragma unroll
    for (int p = 0; p < 2; ++p) {
      int idx = p * 256 + t;
      int r = idx >> 3, c8 = idx & 7;
      int off = r * 128 + ((c8 * 16) ^ ((r & 7) << 4));
      *(u16x8*)(Bhc + off) = rbh[p];
      *(u16x8*)(Blc + off) = rbl[p];
    }
  };

  auto compute = [&]() {
    const char* Ah = (const char*)sAh; const char* Al = (const char*)sAl;
    const char* Bhc = (const char*)sBh; const char* Blc = (const char*)sBl;
#pragma unroll
    for (int ks = 0; ks < 2; ++ks) {
      int kb = ks * 64 + lk * 16;
      s16x8 fah[4], fal[4], fbh[2], fbl[2];
#pragma unroll
      for (int m = 0; m < 4; ++m) {
        int row = wr * 64 + m * 16 + lr;
        int off = row * 128 + (kb ^ ((row & 7) << 4));
        fah[m] = *(const s16x8*)(Ah + off);
        fal[m] = *(const s16x8*)(Al + off);
      }
#pragma unroll
      for (int n = 0; n < 2; ++n) {
        int row = wc * 32 + n * 16 + lr;
        int off = row * 128 + (kb ^ ((row & 7) << 4));
        fbh[n] = *(const s16x8*)(Bhc + off);
        fbl[n] = *(const s16x8*)(Blc + off);
      }
#pragma unroll
      for (int m = 0; m < 4; ++m)
#pragma unroll
        for (int n = 0; n < 2; ++n) {
          acc[m][n] = __builtin_amdgcn_mfma_f32_16x16x32_bf16(fah[m], fbh[n], acc[m][n], 0, 0, 0);
          acc[m][n] = __builtin_amdgcn_mfma_f32_16x16x32_bf16(fah[m], fbl[n], acc[m][n], 0, 0, 0);
          acc[m][n] = __builtin_amdgcn_mfma_f32_16x16x32_bf16(fal[m], fbh[n], acc[m][n], 0, 0, 0);
        }
    }
  };

  loadTile(0);
  for (int kk = 0; kk < nK; ++kk) {
    __syncthreads();
    dswrite();
    __syncthreads();
    if (kk + 1 < nK) loadTile(kk + 1);
    compute();
  }

#pragma unroll
  for (int m = 0; m < 4; ++m) {
#pragma unroll
    for (int n = 0; n < 2; ++n) {
      int col = wc * 32 + n * 16 + lr;
#pragma unroll
      for (int q = 0; q < 4; ++q) {
        int row = m0 + wr * 64 + m * 16 + lk * 4 + q;
        if (row < M) Cf[(size_t)row * 64 + col] = acc[m][n][q];
      }
    }
  }

  __syncthreads();
  float* sb = (float*)sAh;
#pragma unroll
  for (int n = 0; n < 2; ++n) {
    float s1 = 0.f, s2 = 0.f;
#pragma unroll
    for (int m = 0; m < 4; ++m)
#pragma unroll
      for (int q = 0; q < 4; ++q) {
        int row = m0 + wr * 64 + m * 16 + lk * 4 + q;
        float v = (row < M) ? acc[m][n][q] : 0.f;
        s1 += v; s2 += v * v;
      }
    s1 += __shfl_xor(s1, 16); s2 += __shfl_xor(s2, 16);
    s1 += __shfl_xor(s1, 32); s2 += __shfl_xor(s2, 32);
    if (lk == 0) {
      int c = wc * 32 + n * 16 + lr;
      sb[(wr * 64 + c) * 2 + 0] = s1;
      sb[(wr * 64 + c) * 2 + 1] = s2;
    }
  }
  __syncthreads();
  if (t < 64) {
    float s1 = sb[t * 2]     + sb[(64 + t) * 2];
    float s2 = sb[t * 2 + 1] + sb[(64 + t) * 2 + 1];
    p1[(size_t)blockIdx.x * 64 + t] = s1;
    p2[(size_t)blockIdx.x * 64 + t] = s2;
  }
}

// ---------- reduce partials -> BN scale/shift ----------
__global__ __launch_bounds__(256) void k_reduce_fin(const float* __restrict__ part1,
                                                    const float* __restrict__ part2,
                                                    int nb, int C, float invN,
                                                    const float* __restrict__ gamma,
                                                    const float* __restrict__ beta,
                                                    float* __restrict__ a_out,
                                                    float* __restrict__ b_out) {
  int c = blockIdx.x;
  int t = threadIdx.x;
  float s1 = 0.f, s2 = 0.f;
  for (int b = t; b < nb; b += 256) {
    s1 += part1[(size_t)b * C + c];
    s2 += part2[(size_t)b * C + c];
  }
  for (int m = 32; m; m >>= 1) { s1 += __shfl_xor(s1, m); s2 += __shfl_xor(s2, m); }
  __shared__ float l1[4], l2[4];
  if ((t & 63) == 0) { l1[t >> 6] = s1; l2[t >> 6] = s2; }
  __syncthreads();
  if (t == 0) {
    s1 = l1[0] + l1[1] + l1[2] + l1[3];
    s2 = l2[0] + l2[1] + l2[2] + l2[3];
    float mu  = s1 * invN;
    float var = s2 * invN - mu * mu;
    float a = gamma[c] * rsqrtf(var + 1e-5f);
    a_out[c] = a;
    b_out[c] = beta[c] - mu * a;
  }
}

// ---------- PS = f16(ap * su) ----------
__global__ __launch_bounds__(256) void k_scaleP(const float* __restrict__ P, const float* __restrict__ ap,
                                                __half* __restrict__ PS, int n8) {
  for (int i = blockIdx.x * 256 + threadIdx.x; i < n8; i += gridDim.x * 256) {
    int c0 = (i & 7) * 8;
    float4 s0 = *(const float4*)(ap + c0), s1 = *(const float4*)(ap + c0 + 4);
    float4 a = ((const float4*)P)[i * 2];
    float4 b = ((const float4*)P)[i * 2 + 1];
    __half2 o0 = __floats2half2_rn(a.x * s0.x, a.y * s0.y);
    __half2 o1 = __floats2half2_rn(a.z * s0.z, a.w * s0.w);
    __half2 o2 = __floats2half2_rn(b.x * s1.x, b.y * s1.y);
    __half2 o3 = __floats2half2_rn(b.z * s1.z, b.w * s1.w);
    uint4 out;
    out.x = *(unsigned*)&o0; out.y = *(unsigned*)&o1;
    out.z = *(unsigned*)&o2; out.w = *(unsigned*)&o3;
    ((uint4*)PS)[i] = out;
  }
}

// ---------- fused per-node: logits + softmax + RAW aggregation + BN + CRF solve ----------
__global__ __launch_bounds__(256) void k_nodeall(const __half* __restrict__ PS,
                                                 const int* __restrict__ srcj,
                                                 const int* __restrict__ rowptr,
                                                 const u16* __restrict__ UB,
                                                 const float* __restrict__ au,
                                                 const float* __restrict__ bue,
                                                 const float* __restrict__ minv,
                                                 int N, u16* __restrict__ HB) {
  __shared__ float mS[4096];
  __shared__ float zma[4][64];
  int t = threadIdx.x;
  for (int idx = t; idx < 1024; idx += 256)
    ((float4*)mS)[idx] = ((const float4*)minv)[idx];
  __syncthreads();

  int lane = t & 63, wid = t >> 6;
  int node = blockIdx.x * 4 + wid;
  if (node >= N) return;

  int lane8 = lane & 7, g8 = lane >> 3;
  const uint4* P4 = (const uint4*)PS;
  uint4 uv = P4[(size_t)node * 8 + lane8];
  float2 u0 = __half22float2(*(const __half2*)&uv.x);
  float2 u1 = __half22float2(((const __half2*)&uv.x)[1]);
  float2 u2 = __half22float2(*(const __half2*)&uv.z);
  float2 u3 = __half22float2(((const __half2*)&uv.z)[1]);
  float psl = __half2float(PS[(size_t)node * 64 + lane]);
  int b0 = rowptr[node], b1 = rowptr[node + 1];
  int deg = b1 - b0;
  float aggv = 0.f;
  if (deg > 0) {
    int cnt = deg < 64 ? deg : 64;
    int jj = (lane < cnt) ? srcj[b0 + lane] : 0;
    float lg = -INFINITY;
    int capbase = lane & ~7;
    int capsrc  = (lane & 7) << 3;
    for (int ss = 0; ss < cnt; ss += 8) {
      int sl = ss + g8; if (sl >= cnt) sl = cnt - 1;
      int j = __shfl(jj, sl);
      uint4 vv = P4[(size_t)j * 8 + lane8];
      float2 v0 = __half22float2(*(const __half2*)&vv.x);
      float2 v1 = __half22float2(((const __half2*)&vv.x)[1]);
      float2 v2 = __half22float2(*(const __half2*)&vv.z);
      float2 v3 = __half22float2(((const __half2*)&vv.z)[1]);
      float d0 = u0.x - v0.x, d1 = u0.y - v0.y;
      float d2 = u1.x - v1.x, d3 = u1.y - v1.y;
      float d4 = u2.x - v2.x, d5 = u2.y - v2.y;
      float d6 = u3.x - v3.x, d7 = u3.y - v3.y;
      float p = d0*d0 + d1*d1 + d2*d2 + d3*d3 + d4*d4 + d5*d5 + d6*d6 + d7*d7;
      p += __shfl_xor(p, 1, 8);
      p += __shfl_xor(p, 2, 8);
      p += __shfl_xor(p, 4, 8);
      float val = __shfl(p, capsrc);
      if (ss == capbase && lane < cnt) lg = -val;
    }
    float mx = lg;
    for (int s = b0 + 64; s < b1; ++s) {
      int j = srcj[s];
      float d = psl - __half2float(PS[(size_t)j * 64 + lane]);
      float p = d * d;
      for (int m = 32; m; m >>= 1) p += __shfl_xor(p, m);
      mx = fmaxf(mx, -p);
    }
    for (int m = 32; m; m >>= 1) mx = fmaxf(mx, __shfl_xor(mx, m));
    float ex = (lane < cnt) ? __expf(lg - mx) : 0.f;
    float sm = ex;
    for (int s = b0 + 64; s < b1; ++s) {
      int j = srcj[s];
      float d = psl - __half2float(PS[(size_t)j * 64 + lane]);
      float p = d * d;
      for (int m = 32; m; m >>= 1) p += __shfl_xor(p, m);
      if (lane == 0) sm += __expf(-p - mx);
    }
    for (int m = 32; m; m >>= 1) sm += __shfl_xor(sm, m);
    float inv = 1.0f / (sm + 1e-16f);
    float w = ex * inv;
    float acc = 0.f;
    int ss = 0;
    for (; ss + 8 <= cnt; ss += 8) {
      int   j0 = __shfl(jj, ss),     j1 = __shfl(jj, ss + 1);
      int   j2 = __shfl(jj, ss + 2), j3 = __shfl(jj, ss + 3);
      int   j4 = __shfl(jj, ss + 4), j5 = __shfl(jj, ss + 5);
      int   j6 = __shfl(jj, ss + 6), j7 = __shfl(jj, ss + 7);
      float w0 = __shfl(w, ss),      w1 = __shfl(w, ss + 1);
      float w2 = __shfl(w, ss + 2),  w3 = __shfl(w, ss + 3);
      float w4 = __shfl(w, ss + 4),  w5 = __shfl(w, ss + 5);
      float w6 = __shfl(w, ss + 6),  w7 = __shfl(w, ss + 7);
      float v0 = bf2f(UB[(size_t)j0 * 64 + lane]);
      float v1 = bf2f(UB[(size_t)j1 * 64 + lane]);
      float v2 = bf2f(UB[(size_t)j2 * 64 + lane]);
      float v3 = bf2f(UB[(size_t)j3 * 64 + lane]);
      float v4 = bf2f(UB[(size_t)j4 * 64 + lane]);
      float v5 = bf2f(UB[(size_t)j5 * 64 + lane]);
      float v6 = bf2f(UB[(size_t)j6 * 64 + lane]);
      float v7 = bf2f(UB[(size_t)j7 * 64 + lane]);
      acc += w0 * v0 + w1 * v1 + w2 * v2 + w3 * v3;
      acc += w4 * v4 + w5 * v5 + w6 * v6 + w7 * v7;
    }
    for (; ss < cnt; ++ss) {
      int j0 = __shfl(jj, ss);
      float w0 = __shfl(w, ss);
      acc += w0 * bf2f(UB[(size_t)j0 * 64 + lane]);
    }
    for (int s = b0 + 64; s < b1; ++s) {
      int j = srcj[s];
      float d = psl - __half2float(PS[(size_t)j * 64 + lane]);
      float p = d * d;
      for (int m = 32; m; m >>= 1) p += __shfl_xor(p, m);
      acc += __expf(-p - mx) * inv * bf2f(UB[(size_t)j * 64 + lane]);
    }
    aggv = au[lane] * acc + bue[lane];
  }
  float z = au[lane] * bf2f(UB[(size_t)node * 64 + lane]) + bue[lane];
  zma[wid][lane] = z - aggv;
  float h = aggv;
#pragma unroll 8
  for (int k = 0; k < 64; ++k) h += zma[wid][k] * mS[k * 64 + lane];
  HB[(size_t)node * 64 + lane] = f2bf(h);
}

// ---------- final BN + leaky: bf16 raw -> f32 out ----------
__global__ __launch_bounds__(256) void k_bnact16(const u16* __restrict__ raw, const float* __restrict__ af,
                                                 const float* __restrict__ bfp, float* __restrict__ out, int n8) {
  int i = blockIdx.x * 256 + threadIdx.x;
  int stride = gridDim.x * 256;
  for (; i < n8; i += stride) {
    int c0 = (i & 31) * 8;
    float av[8], bv[8];
    *(float4*)(av) = *(const float4*)(af + c0);  *(float4*)(av + 4) = *(const float4*)(af + c0 + 4);
    *(float4*)(bv) = *(const float4*)(bfp + c0); *(float4*)(bv + 4) = *(const float4*)(bfp + c0 + 4);
    u16x8 r = ((const u16x8*)raw)[i];
    float o[8];
#pragma unroll
    for (int j = 0; j < 8; ++j) {
      float v = bf2f((u16)r[j]) * av[j] + bv[j];
      o[j] = (v > 0.f) ? v : 0.01f * v;
    }
    ((float4*)out)[i * 2]     = *(float4*)(o);
    ((float4*)out)[i * 2 + 1] = *(float4*)(o + 4);
  }
}

extern "C" void kernel_launch(void* const* d_in, const int* in_sizes, int n_in,
                              void* d_out, int out_size, void* d_ws, size_t ws_size,
                              hipStream_t stream) {
  const float* x    = (const float*)d_in[0];
  const float* y    = (const float*)d_in[1];
  const int*   eidx = (const int*)d_in[3];
  const float* Wu   = (const float*)d_in[4];
  const float* gu   = (const float*)d_in[5];
  const float* bu   = (const float*)d_in[6];
  const float* Wp   = (const float*)d_in[7];
  const float* gp   = (const float*)d_in[8];
  const float* bp   = (const float*)d_in[9];
  const float* cIn  = (const float*)d_in[10];
  const float* Wm   = (const float*)d_in[11];
  const float* gm   = (const float*)d_in[12];
  const float* bm   = (const float*)d_in[13];
  const float* Wf   = (const float*)d_in[14];
  const float* gf   = (const float*)d_in[15];
  const float* bfv  = (const float*)d_in[16];

  const int N = in_sizes[0] / 256;
  const int E = in_sizes[3] / 2;
  const int* ei = eidx;
  const int* ej = eidx + E;

  char* ws = (char*)d_ws;
  float* MINV  = (float*)(ws + OFF_MINV);
  float* AU    = (float*)(ws + OFF_AU);
  float* BUE   = (float*)(ws + OFF_BUE);
  float* AP    = (float*)(ws + OFF_AP);
  float* APBE  = (float*)(ws + OFF_APBE);
  float* AM    = (float*)(ws + OFF_AM);
  float* BM    = (float*)(ws + OFF_BM);
  float* AF    = (float*)(ws + OFF_AF);
  float* BF    = (float*)(ws + OFF_BF);
  int*   BTOT  = (int*)(ws + OFF_BTOT);
  int*   BOFF  = (int*)(ws + OFF_BOFF);
  u16*   WUT   = (u16*)(ws + OFF_WUT);
  u16*   WMT   = (u16*)(ws + OFF_WMT);
  u16*   WFT   = (u16*)(ws + OFF_WFT);
  u16*   WPH   = (u16*)(ws + OFF_WPH);
  u16*   WPL   = (u16*)(ws + OFF_WPL);
  float* PART1 = (float*)(ws + OFF_PART1);
  float* PART2 = (float*)(ws + OFF_PART2);
  int*   ROWPTR= (int*)(ws + OFF_ROWPTR);
  int*   BLKCNT= (int*)(ws + OFF_BLKCNT);
  u16*   HB    = (u16*)(ws + OFF_BLKCNT);    // reuse (BLKCNT dead after kA3)
  int*   SRCJ  = (int*)(ws + OFF_SRCJ);
  u16*   RAWO  = (u16*)(ws + OFF_SRCJ);      // reuse (SRCJ dead after k_nodeall)
  u16*   UBRAW = (u16*)(ws + OFF_U);
  unsigned* TMP= (unsigned*)(ws + OFF_P);    // packed bins; dead after kB
  float* P     = (float*)(ws + OFF_P);
  __half* PS   = (__half*)(ws + OFF_PS);
  u16*   H2    = (u16*)(ws + OFF_H2);

  const float invN = 1.0f / (float)N;
  const int mtiles   = (N + 127) / 128;
  const int n8_64    = N * 64 / 8;
  const int n8_256   = N * 256 / 8;
  const int nbk      = (N + 255) >> 8;
  const int chunk    = (E + NBLK_BIN - 1) / NBLK_BIN;

  k_prep<<<1, 256, 0, stream>>>(cIn, MINV);
  k_tcvt_all<<<704, 256, 0, stream>>>(Wu, Wm, Wf, Wp, WUT, WMT, WFT, WPH, WPL);

  // CSR build: deterministic two-level binned counting sort (no global atomics)
  kA1<<<NBLK_BIN, 256, 0, stream>>>(ei, E, chunk, BLKCNT, nbk);
  kA2<<<nbk, 256, 0, stream>>>(BLKCNT, nbk, BTOT);
  kA2b<<<1, 512, 0, stream>>>(BTOT, BOFF, nbk);
  kA3<<<NBLK_BIN, 256, 0, stream>>>(ei, ej, E, chunk, BLKCNT, BOFF, nbk, TMP);
  kB<<<nbk, 256, 0, stream>>>(TMP, BOFF, nbk, N, E, ROWPTR, SRCJ);

  // unary embedding (stats fused) -> UBRAW bf16; BN params
  k_mfma<64, 2, 1, 1><<<dim3(mtiles, 1), 256, 0, stream>>>(
      nullptr, x, 256, 256, N, WUT, nullptr, UBRAW, 64, 64, PART1, PART2);
  k_reduce_fin<<<64, 256, 0, stream>>>(PART1, PART2, mtiles, 64, invN, gu, bu, AU, BUE);

  // pairwise embedding: split-bf16 MFMA (stats fused) -> P f32 (TMP dead); PS f16 table
  k_mfma_split<<<mtiles, 256, 0, stream>>>(y, 256, N, WPH, WPL, P, PART1, PART2);
  k_reduce_fin<<<64, 256, 0, stream>>>(PART1, PART2, mtiles, 64, invN, gp, bp, AP, APBE);
  k_scaleP<<<1024, 256, 0, stream>>>(P, AP, PS, n8_64);

  // fused logits + softmax + aggregation + BN + CRF solve -> HB
  k_nodeall<<<(N + 3) / 4, 256, 0, stream>>>(PS, SRCJ, ROWPTR, UBRAW, AU, BUE, MINV, N, HB);

  // h @ Wm -> h2 bf16 (BN=256 single block per row-tile; A read once)
  k_mfma2<0><<<mtiles, 512, 0, stream>>>(
      HB, 64, 64, N, nullptr, nullptr, nullptr, nullptr, WMT, H2, PART1, PART2);
  k_reduce_fin<<<256, 256, 0, stream>>>(PART1, PART2, mtiles, 256, invN, gm, bm, AM, BM);

  // [leaky(bn(h2)), y] @ Wf -> raw bf16 (A read once), BN + leaky -> d_out
  k_mfma2<1><<<mtiles, 512, 0, stream>>>(
      nullptr, 0, 512, N, H2, y, AM, BM, WFT, RAWO, PART1, PART2);
  k_reduce_fin<<<256, 256, 0, stream>>>(PART1, PART2, mtiles, 256, invN, gf, bfv, AF, BF);
  k_bnact16<<<2048, 256, 0, stream>>>(RAWO, AF, BF, (float*)d_out, n8_256);
}

// Round 11
// 527.311 us; speedup vs baseline: 5.3848x; 1.0178x over previous
//
#include <hip/hip_runtime.h>
#include <hip/hip_fp16.h>
#include <math.h>

typedef unsigned short u16;
typedef short s16x8 __attribute__((ext_vector_type(8)));
typedef unsigned short u16x8 __attribute__((ext_vector_type(8)));
typedef _Float16 f16x8 __attribute__((ext_vector_type(8)));
typedef float f32x4 __attribute__((ext_vector_type(4)));

// ---------- helpers ----------
__device__ __forceinline__ float bf2f(u16 u) {
  unsigned x = ((unsigned)u) << 16;
  return __uint_as_float(x);
}
__device__ __forceinline__ u16 f2bf(float f) {
  unsigned x = __float_as_uint(f);
  unsigned r = x + 0x7FFFu + ((x >> 16) & 1u);
  return (u16)(r >> 16);
}
__device__ __forceinline__ u16 f2h(float f) {
  __half h = __float2half_rn(f);
  return *reinterpret_cast<u16*>(&h);
}

// ---------- ws layout (bytes) ----------
static const size_t OFF_MINV   = 0;
static const size_t OFF_AU     = 32ull * 1024;
static const size_t OFF_BUE    = 32ull * 1024 + 256;
static const size_t OFF_AP     = 32ull * 1024 + 512;
static const size_t OFF_APBE   = 32ull * 1024 + 768;
static const size_t OFF_AM     = 36ull * 1024;
static const size_t OFF_BM     = 37ull * 1024;
static const size_t OFF_AF     = 38ull * 1024;
static const size_t OFF_BF     = 39ull * 1024;
static const size_t OFF_BTOT   = 40ull * 1024;
static const size_t OFF_BOFF   = 44ull * 1024;
static const size_t OFF_WUT    = 64ull * 1024;
static const size_t OFF_WMT    = 128ull * 1024;
static const size_t OFF_WFT    = 192ull * 1024;
static const size_t OFF_WPH    = 512ull * 1024;            // Wp^T f16 [64][256]
static const size_t OFF_PART1A = 1ull  * 1024 * 1024;      // xu partials
static const size_t OFF_PART1B = 1ull  * 1024 * 1024 + 512 * 1024;   // su partials
static const size_t OFF_PART2A = 2ull  * 1024 * 1024;
static const size_t OFF_PART2B = 2ull  * 1024 * 1024 + 512 * 1024;
static const size_t OFF_ROWPTR = 3ull  * 1024 * 1024;
static const size_t OFF_BLKCNT = 5ull  * 1024 * 1024;     // 2MB; dead after kA3 -> HB bf16 N*64
static const size_t OFF_SRCJ   = 18ull * 1024 * 1024;     // E int; dead after k_nodeall -> RAWO bf16 N*256
static const size_t OFF_U      = 44ull * 1024 * 1024;     // UBRAW bf16 N*64
static const size_t OFF_P      = 70ull * 1024 * 1024;     // TMP uint E early; then P f32
static const size_t OFF_PS     = 109ull * 1024 * 1024;
static const size_t OFF_H2     = 122ull * 1024 * 1024;

#define NBLK_BIN 1024

// ---------- K0: Minv = (I + c^T c)^-1 ----------
__global__ __launch_bounds__(256) void k_prep(const float* __restrict__ c,
                                              float* __restrict__ minv_out) {
  __shared__ float CC[4096];
  __shared__ float aug[64 * 129];
  __shared__ float fs[64];
  float* cl = aug;
  int t = threadIdx.x;
  for (int idx = t; idx < 4096; idx += 256) cl[idx] = c[idx];
  __syncthreads();
  for (int idx = t; idx < 4096; idx += 256) {
    int a = idx >> 6, b = idx & 63;
    float s = (a == b) ? 1.f : 0.f;
    for (int k = 0; k < 64; ++k) s += cl[k * 64 + a] * cl[k * 64 + b];
    CC[idx] = s;
  }
  __syncthreads();
  for (int idx = t; idx < 8192; idx += 256) {
    int r = idx >> 7, cc = idx & 127;
    aug[r * 129 + cc] = (cc < 64) ? CC[r * 64 + cc] : (((cc - 64) == r) ? 1.f : 0.f);
  }
  __syncthreads();
  int cloc = t & 127;
  int rbase = t >> 7;
  for (int p = 0; p < 64; ++p) {
    if (t < 64) fs[t] = (t == p) ? 0.f : aug[t * 129 + p] / aug[p * 129 + p];
    __syncthreads();
    float pc = aug[p * 129 + cloc];
#pragma unroll
    for (int rr = 0; rr < 64; rr += 2) {
      int r = rr + rbase;
      aug[r * 129 + cloc] -= fs[r] * pc;
    }
    __syncthreads();
  }
  for (int idx = t; idx < 4096; idx += 256) {
    int r = idx >> 6, cc = idx & 63;
    minv_out[idx] = aug[r * 129 + 64 + cc] / aug[r * 129 + r];
  }
}

// ---------- merged weight transpose/convert ----------
__global__ __launch_bounds__(256) void k_tcvt_all(const float* __restrict__ Wu, const float* __restrict__ Wm,
                                                  const float* __restrict__ Wf, const float* __restrict__ Wp,
                                                  u16* __restrict__ WUT, u16* __restrict__ WMT,
                                                  u16* __restrict__ WFT, u16* __restrict__ WPH) {
  int b = blockIdx.x, t = threadIdx.x;
  if (b < 64) {
    int i = b * 256 + t;
    int k = i >> 6, n = i & 63;
    WUT[(size_t)n * 256 + k] = f2bf(Wu[i]);
  } else if (b < 128) {
    int i = (b - 64) * 256 + t;
    int k = i >> 8, n = i & 255;
    WMT[(size_t)n * 64 + k] = f2bf(Wm[i]);
  } else if (b < 640) {
    int i = (b - 128) * 256 + t;
    int k = i >> 8, n = i & 255;
    WFT[(size_t)n * 512 + k] = f2bf(Wf[i]);
  } else {
    int i = (b - 640) * 256 + t;
    int k = i >> 6, n = i & 63;
    WPH[(size_t)n * 256 + k] = f2h(Wp[i]);
  }
}

// ---------- binned CSR build ----------
__global__ __launch_bounds__(256) void kA1(const int* __restrict__ ei, int E, int chunk,
                                           int* __restrict__ blockCnt, int nbk) {
  __shared__ int c[512];
  int t = threadIdx.x, bid = blockIdx.x;
  c[t] = 0; c[t + 256] = 0;
  __syncthreads();
  int e0 = bid * chunk, e1 = min(E, e0 + chunk);
  for (int e = e0 + t; e < e1; e += 256) atomicAdd(&c[ei[e] >> 8], 1);
  __syncthreads();
  for (int b = t; b < nbk; b += 256) blockCnt[(size_t)bid * nbk + b] = c[b];
}

__global__ __launch_bounds__(256) void kA2(int* __restrict__ blockCnt, int nbk,
                                           int* __restrict__ bucketTot) {
  int b = blockIdx.x, t = threadIdx.x;
  int base = t * 4;
  int v0 = blockCnt[(size_t)(base + 0) * nbk + b];
  int v1 = blockCnt[(size_t)(base + 1) * nbk + b];
  int v2 = blockCnt[(size_t)(base + 2) * nbk + b];
  int v3 = blockCnt[(size_t)(base + 3) * nbk + b];
  int s1 = v0 + v1, s2 = s1 + v2, tot = s2 + v3;
  __shared__ int ps[256];
  ps[t] = tot;
  __syncthreads();
  for (int off = 1; off < 256; off <<= 1) {
    int a = (t >= off) ? ps[t - off] : 0;
    __syncthreads();
    ps[t] += a;
    __syncthreads();
  }
  int ex = (t > 0) ? ps[t - 1] : 0;
  blockCnt[(size_t)(base + 0) * nbk + b] = ex;
  blockCnt[(size_t)(base + 1) * nbk + b] = ex + v0;
  blockCnt[(size_t)(base + 2) * nbk + b] = ex + s1;
  blockCnt[(size_t)(base + 3) * nbk + b] = ex + s2;
  if (t == 255) bucketTot[b] = ps[255];
}

__global__ __launch_bounds__(512) void kA2b(const int* __restrict__ bucketTot,
                                            int* __restrict__ bucketOff, int nbk) {
  __shared__ int s[512];
  int t = threadIdx.x;
  s[t] = (t < nbk) ? bucketTot[t] : 0;
  __syncthreads();
  for (int off = 1; off < 512; off <<= 1) {
    int a = (t >= off) ? s[t - off] : 0;
    __syncthreads();
    s[t] += a;
    __syncthreads();
  }
  if (t == 0) bucketOff[0] = 0;
  if (t < nbk) bucketOff[t + 1] = s[t];
}

__global__ __launch_bounds__(256) void kA3(const int* __restrict__ ei, const int* __restrict__ ej,
                                           int E, int chunk,
                                           const int* __restrict__ blockExc,
                                           const int* __restrict__ bucketOff,
                                           int nbk, unsigned* __restrict__ tmp) {
  __shared__ int c[512], off[512], gb[512], cur[512];
  __shared__ uint2 stage[4096];
  int t = threadIdx.x, bid = blockIdx.x;
  c[t] = 0; c[t + 256] = 0;
  __syncthreads();
  int e0 = bid * chunk, e1 = min(E, e0 + chunk);
  int m = e1 - e0;
  for (int e = e0 + t; e < e1; e += 256) atomicAdd(&c[ei[e] >> 8], 1);
  __syncthreads();
  int v0 = c[t], v1 = c[t + 256];
  off[t] = v0; off[t + 256] = v1;
  __syncthreads();
  for (int o = 1; o < 512; o <<= 1) {
    int a0 = (t >= o) ? off[t - o] : 0;
    int a1 = ((t + 256) >= o) ? off[t + 256 - o] : 0;
    __syncthreads();
    off[t] += a0; off[t + 256] += a1;
    __syncthreads();
  }
  int ex0 = off[t] - v0, ex1 = off[t + 256] - v1;
  if (t < nbk)
    gb[t] = bucketOff[t] + blockExc[(size_t)bid * nbk + t] - ex0;
  if (t + 256 < nbk)
    gb[t + 256] = bucketOff[t + 256] + blockExc[(size_t)bid * nbk + t + 256] - ex1;
  cur[t] = ex0; cur[t + 256] = ex1;
  __syncthreads();
  for (int e = e0 + t; e < e1; e += 256) {
    int i = ei[e];
    int p = atomicAdd(&cur[i >> 8], 1);
    stage[p] = make_uint2((unsigned)i, (unsigned)ej[e]);
  }
  __syncthreads();
  for (int s = t; s < m; s += 256) {
    uint2 v = stage[s];
    tmp[gb[v.x >> 8] + s] = ((v.x & 255u) << 24) | v.y;
  }
}

#define BCAP 12288
__global__ __launch_bounds__(256) void kB(const unsigned* __restrict__ tmp,
                                          const int* __restrict__ bucketOff,
                                          int nbk, int N, int E,
                                          int* __restrict__ rowptr, int* __restrict__ srcj) {
  __shared__ int cnt[256], sc[256], cur[256];
  __shared__ int jbuf[BCAP];
  int b = blockIdx.x, t = threadIdx.x;
  int nb0 = b << 8;
  int e0 = bucketOff[b], e1 = bucketOff[b + 1];
  int m = e1 - e0;
  cnt[t] = 0;
  __syncthreads();
  for (int s = t; s < m; s += 256) atomicAdd(&cnt[tmp[e0 + s] >> 24], 1);
  __syncthreads();
  int v = cnt[t];
  sc[t] = v;
  __syncthreads();
  for (int off = 1; off < 256; off <<= 1) {
    int a = (t >= off) ? sc[t - off] : 0;
    __syncthreads();
    sc[t] += a;
    __syncthreads();
  }
  int exc = sc[t] - v;
  cur[t] = exc;
  if (nb0 + t < N) rowptr[nb0 + t] = e0 + exc;
  if (b == nbk - 1 && t == 0) rowptr[N] = E;
  __syncthreads();
  for (int s = t; s < m; s += 256) {
    unsigned e = tmp[e0 + s];
    int p = atomicAdd(&cur[e >> 24], 1);
    if (p < BCAP) jbuf[p] = (int)(e & 0xFFFFFFu);
  }
  __syncthreads();
  for (int s = t; s < m; s += 256) srcj[e0 + s] = jbuf[s];
}

// ---------- MFMA GEMM BM=128 x BN=64 (skinny paths) ----------
// AMODE 0: A bf16. AMODE 2: A f32 converted in staging (to bf16 or f16 per FP16).
// OBF: 0 f32 out, 1 bf16 out. FP16: use f16 MFMA (B buffer holds f16 bits).
template<int BN, int AMODE, int OBF, int STATS, int FP16>
__global__ __launch_bounds__(256) void k_mfma(const u16* __restrict__ Abf, const float* __restrict__ Af32,
                                              int ldA, int K, int M,
                                              const u16* __restrict__ Bt,
                                              float* __restrict__ Cf, u16* __restrict__ Cb, int ldC,
                                              int ncTot, float* __restrict__ p1, float* __restrict__ p2) {
  constexpr int WN  = BN / 2;
  constexpr int FN  = WN / 16;
  constexpr int NPB = BN / 32;
  __shared__ u16 lds[2][(128 + BN) * 64];

  int t = threadIdx.x;
  int wid = t >> 6, lane = t & 63;
  int wr = wid >> 1, wc = wid & 1;
  int lr = lane & 15, lk = lane >> 4;
  int m0 = blockIdx.x * 128;
  int n0 = blockIdx.y * BN;
  int nK = K >> 6;

  int sidx = t;
  u16x8 ra[4];
  u16x8 rb[NPB];

  f32x4 acc[4][FN];
#pragma unroll
  for (int m = 0; m < 4; ++m)
#pragma unroll
    for (int n = 0; n < FN; ++n) acc[m][n] = (f32x4){0.f, 0.f, 0.f, 0.f};

  auto loadTile = [&](int kk) {
    int kk0 = kk * 64;
#pragma unroll
    for (int p = 0; p < 4; ++p) {
      int idx = p * 256 + sidx;
      int r = idx >> 3, c8 = idx & 7;
      int row = m0 + r; if (row >= M) row = M - 1;
      int k = kk0 + c8 * 8;
      if constexpr (AMODE == 0) {
        ra[p] = *(const u16x8*)(Abf + (size_t)row * ldA + k);
      } else {
        const float* src = Af32 + (size_t)row * ldA + k;
        float4 a = *(const float4*)src;
        float4 b = *(const float4*)(src + 4);
        u16x8 o;
        if constexpr (FP16) {
          o[0] = f2h(a.x); o[1] = f2h(a.y); o[2] = f2h(a.z); o[3] = f2h(a.w);
          o[4] = f2h(b.x); o[5] = f2h(b.y); o[6] = f2h(b.z); o[7] = f2h(b.w);
        } else {
          o[0] = f2bf(a.x); o[1] = f2bf(a.y); o[2] = f2bf(a.z); o[3] = f2bf(a.w);
          o[4] = f2bf(b.x); o[5] = f2bf(b.y); o[6] = f2bf(b.z); o[7] = f2bf(b.w);
        }
        ra[p] = o;
      }
    }
#pragma unroll
    for (int p = 0; p < NPB; ++p) {
      int idx = p * 256 + sidx;
      int r = idx >> 3, c8 = idx & 7;
      rb[p] = *(const u16x8*)(Bt + (size_t)(n0 + r) * K + kk0 + c8 * 8);
    }
  };

  auto dswrite = [&](int b) {
    char* As  = (char*)&lds[b][0];
    char* Bsc = As + 128 * 64 * 2;
#pragma unroll
    for (int p = 0; p < 4; ++p) {
      int idx = p * 256 + sidx;
      int r = idx >> 3, c8 = idx & 7;
      *(u16x8*)(As + r * 128 + ((c8 * 16) ^ ((r & 7) << 4))) = ra[p];
    }
#pragma unroll
    for (int p = 0; p < NPB; ++p) {
      int idx = p * 256 + sidx;
      int r = idx >> 3, c8 = idx & 7;
      *(u16x8*)(Bsc + r * 128 + ((c8 * 16) ^ ((r & 7) << 4))) = rb[p];
    }
  };

  auto compute = [&](int b) {
    const char* As  = (const char*)&lds[b][0];
    const char* Bsc = As + 128 * 64 * 2;
#pragma unroll
    for (int ks = 0; ks < 2; ++ks) {
      int kb = ks * 64 + lk * 16;
#pragma unroll
      for (int m = 0; m < 4; ++m) {
        int rowA = wr * 64 + m * 16 + lr;
        const char* pa = As + rowA * 128 + (kb ^ ((rowA & 7) << 4));
#pragma unroll
        for (int n = 0; n < FN; ++n) {
          int rowB = wc * WN + n * 16 + lr;
          const char* pb = Bsc + rowB * 128 + (kb ^ ((rowB & 7) << 4));
          if constexpr (FP16) {
            f16x8 af = *(const f16x8*)pa;
            f16x8 bf = *(const f16x8*)pb;
            acc[m][n] = __builtin_amdgcn_mfma_f32_16x16x32_f16(af, bf, acc[m][n], 0, 0, 0);
          } else {
            s16x8 af = *(const s16x8*)pa;
            s16x8 bf = *(const s16x8*)pb;
            acc[m][n] = __builtin_amdgcn_mfma_f32_16x16x32_bf16(af, bf, acc[m][n], 0, 0, 0);
          }
        }
      }
    }
  };

  loadTile(0);
  dswrite(0);
  __syncthreads();
  for (int kk = 0; kk < nK; ++kk) {
    int b = kk & 1;
    if (kk + 1 < nK) loadTile(kk + 1);
    compute(b);
    if (kk + 1 < nK) { dswrite(b ^ 1); __syncthreads(); }
  }

#pragma unroll
  for (int m = 0; m < 4; ++m) {
#pragma unroll
    for (int n = 0; n < FN; ++n) {
      int col = n0 + wc * WN + n * 16 + lr;
#pragma unroll
      for (int q = 0; q < 4; ++q) {
        int row = m0 + wr * 64 + m * 16 + lk * 4 + q;
        if (row < M) {
          if constexpr (OBF) Cb[(size_t)row * ldC + col] = f2bf(acc[m][n][q]);
          else               Cf[(size_t)row * ldC + col] = acc[m][n][q];
        }
      }
    }
  }

  if constexpr (STATS) {
    __syncthreads();
    float* sb = (float*)&lds[0][0];
#pragma unroll
    for (int n = 0; n < FN; ++n) {
      float s1 = 0.f, s2 = 0.f;
#pragma unroll
      for (int m = 0; m < 4; ++m)
#pragma unroll
        for (int q = 0; q < 4; ++q) {
          int row = m0 + wr * 64 + m * 16 + lk * 4 + q;
          float v = (row < M) ? acc[m][n][q] : 0.f;
          s1 += v; s2 += v * v;
        }
      s1 += __shfl_xor(s1, 16); s2 += __shfl_xor(s2, 16);
      s1 += __shfl_xor(s1, 32); s2 += __shfl_xor(s2, 32);
      if (lk == 0) {
        int c = wc * WN + n * 16 + lr;
        sb[(wr * BN + c) * 2 + 0] = s1;
        sb[(wr * BN + c) * 2 + 1] = s2;
      }
    }
    __syncthreads();
    if (t < BN) {
      float s1 = sb[t * 2]     + sb[(BN + t) * 2];
      float s2 = sb[t * 2 + 1] + sb[(BN + t) * 2 + 1];
      p1[(size_t)blockIdx.x * ncTot + n0 + t] = s1;
      p2[(size_t)blockIdx.x * ncTot + n0 + t] = s2;
    }
  }
}

// ---------- MFMA GEMM2: BM=128 x BN=256, SINGLE-buffered LDS (48KB -> 3 blocks/CU) ----------
template<int AMODE>
__global__ __launch_bounds__(512) void k_mfma2(const u16* __restrict__ Abf, int ldA, int K, int M,
                                               const u16* __restrict__ h2, const float* __restrict__ yy,
                                               const float* __restrict__ am, const float* __restrict__ bm,
                                               const u16* __restrict__ Bt,
                                               u16* __restrict__ Cb,
                                               float* __restrict__ p1, float* __restrict__ p2) {
  __shared__ u16 lds[(128 + 256) * 64];   // 48KB single buffer
  int t = threadIdx.x;
  int wid = t >> 6, lane = t & 63;
  int wr = wid >> 2, wc = wid & 3;
  int lr = lane & 15, lk = lane >> 4;
  int m0 = blockIdx.x * 128;
  int nK = K >> 6;

  u16x8 ra[2];
  u16x8 rb[4];
  f32x4 acc[4][4];
#pragma unroll
  for (int m = 0; m < 4; ++m)
#pragma unroll
    for (int n = 0; n < 4; ++n) acc[m][n] = (f32x4){0.f, 0.f, 0.f, 0.f};

  auto loadTile = [&](int kk) {
    int kk0 = kk * 64;
#pragma unroll
    for (int p = 0; p < 2; ++p) {
      int idx = p * 512 + t;
      int r = idx >> 3, c8 = idx & 7;
      int row = m0 + r; if (row >= M) row = M - 1;
      int k = kk0 + c8 * 8;
      if constexpr (AMODE == 0) {
        ra[p] = *(const u16x8*)(Abf + (size_t)row * ldA + k);
      } else {
        if (kk0 < 256) {
          u16x8 h8 = *(const u16x8*)(h2 + (size_t)row * 256 + k);
          float av[8], bv[8];
          *(float4*)(av)     = *(const float4*)(am + k);
          *(float4*)(av + 4) = *(const float4*)(am + k + 4);
          *(float4*)(bv)     = *(const float4*)(bm + k);
          *(float4*)(bv + 4) = *(const float4*)(bm + k + 4);
          u16x8 o;
#pragma unroll
          for (int j = 0; j < 8; ++j) {
            float v = bf2f((u16)h8[j]) * av[j] + bv[j];
            v = v > 0.f ? v : 0.01f * v;
            o[j] = f2bf(v);
          }
          ra[p] = o;
        } else {
          float yv[8];
          *(float4*)(yv)     = *(const float4*)(yy + (size_t)row * 256 + (k - 256));
          *(float4*)(yv + 4) = *(const float4*)(yy + (size_t)row * 256 + (k - 256) + 4);
          u16x8 o;
#pragma unroll
          for (int j = 0; j < 8; ++j) o[j] = f2bf(yv[j]);
          ra[p] = o;
        }
      }
    }
#pragma unroll
    for (int p = 0; p < 4; ++p) {
      int idx = p * 512 + t;
      int r = idx >> 3, c8 = idx & 7;
      rb[p] = *(const u16x8*)(Bt + (size_t)r * K + kk0 + c8 * 8);
    }
  };

  auto dswrite = [&]() {
    char* As  = (char*)&lds[0];
    char* Bsc = As + 128 * 64 * 2;
#pragma unroll
    for (int p = 0; p < 2; ++p) {
      int idx = p * 512 + t;
      int r = idx >> 3, c8 = idx & 7;
      *(u16x8*)(As + r * 128 + ((c8 * 16) ^ ((r & 7) << 4))) = ra[p];
    }
#pragma unroll
    for (int p = 0; p < 4; ++p) {
      int idx = p * 512 + t;
      int r = idx >> 3, c8 = idx & 7;
      *(u16x8*)(Bsc + r * 128 + ((c8 * 16) ^ ((r & 7) << 4))) = rb[p];
    }
  };

  auto compute = [&]() {
    const char* As  = (const char*)&lds[0];
    const char* Bsc = As + 128 * 64 * 2;
#pragma unroll
    for (int ks = 0; ks < 2; ++ks) {
      int kb = ks * 64 + lk * 16;
      s16x8 af[4], bfr[4];
#pragma unroll
      for (int m = 0; m < 4; ++m) {
        int row = wr * 64 + m * 16 + lr;
        af[m] = *(const s16x8*)(As + row * 128 + (kb ^ ((row & 7) << 4)));
      }
#pragma unroll
      for (int n = 0; n < 4; ++n) {
        int row = wc * 64 + n * 16 + lr;
        bfr[n] = *(const s16x8*)(Bsc + row * 128 + (kb ^ ((row & 7) << 4)));
      }
#pragma unroll
      for (int m = 0; m < 4; ++m)
#pragma unroll
        for (int n = 0; n < 4; ++n)
          acc[m][n] = __builtin_amdgcn_mfma_f32_16x16x32_bf16(af[m], bfr[n], acc[m][n], 0, 0, 0);
    }
  };

  loadTile(0);
  for (int kk = 0; kk < nK; ++kk) {
    __syncthreads();                       // prior compute done (safe to overwrite)
    dswrite();
    __syncthreads();
    if (kk + 1 < nK) loadTile(kk + 1);     // issue next global loads before MFMA block
    compute();
  }

#pragma unroll
  for (int m = 0; m < 4; ++m) {
#pragma unroll
    for (int n = 0; n < 4; ++n) {
      int col = wc * 64 + n * 16 + lr;
#pragma unroll
      for (int q = 0; q < 4; ++q) {
        int row = m0 + wr * 64 + m * 16 + lk * 4 + q;
        if (row < M) Cb[(size_t)row * 256 + col] = f2bf(acc[m][n][q]);
      }
    }
  }

  __syncthreads();
  float* sb = (float*)&lds[0];
#pragma unroll
  for (int n = 0; n < 4; ++n) {
    float s1 = 0.f, s2 = 0.f;
#pragma unroll
    for (int m = 0; m < 4; ++m)
#pragma unroll
      for (int q = 0; q < 4; ++q) {
        int row = m0 + wr * 64 + m * 16 + lk * 4 + q;
        float v = (row < M) ? acc[m][n][q] : 0.f;
        s1 += v; s2 += v * v;
      }
    s1 += __shfl_xor(s1, 16); s2 += __shfl_xor(s2, 16);
    s1 += __shfl_xor(s1, 32); s2 += __shfl_xor(s2, 32);
    if (lk == 0) {
      int c = wc * 64 + n * 16 + lr;
      sb[(wr * 256 + c) * 2 + 0] = s1;
      sb[(wr * 256 + c) * 2 + 1] = s2;
    }
  }
  __syncthreads();
  if (t < 256) {
    float s1 = sb[t * 2]     + sb[(256 + t) * 2];
    float s2 = sb[t * 2 + 1] + sb[(256 + t) * 2 + 1];
    p1[(size_t)blockIdx.x * 256 + t] = s1;
    p2[(size_t)blockIdx.x * 256 + t] = s2;
  }
}

// ---------- merged reduce: blocks 0-63 xu (AU/BUE), 64-127 su (AP/APBE) ----------
__global__ __launch_bounds__(256) void k_reduce2(const float* __restrict__ p1a, const float* __restrict__ p2a,
                                                 const float* __restrict__ p1b, const float* __restrict__ p2b,
                                                 int nb, float invN,
                                                 const float* __restrict__ gu, const float* __restrict__ bu,
                                                 const float* __restrict__ gp, const float* __restrict__ bp,
                                                 float* __restrict__ AU, float* __restrict__ BUE,
                                                 float* __restrict__ AP, float* __restrict__ APBE) {
  int isB = blockIdx.x >> 6;
  int c = blockIdx.x & 63;
  int t = threadIdx.x;
  const float* part1 = isB ? p1b : p1a;
  const float* part2 = isB ? p2b : p2a;
  float s1 = 0.f, s2 = 0.f;
  for (int b = t; b < nb; b += 256) {
    s1 += part1[(size_t)b * 64 + c];
    s2 += part2[(size_t)b * 64 + c];
  }
  for (int m = 32; m; m >>= 1) { s1 += __shfl_xor(s1, m); s2 += __shfl_xor(s2, m); }
  __shared__ float l1[4], l2[4];
  if ((t & 63) == 0) { l1[t >> 6] = s1; l2[t >> 6] = s2; }
  __syncthreads();
  if (t == 0) {
    s1 = l1[0] + l1[1] + l1[2] + l1[3];
    s2 = l2[0] + l2[1] + l2[2] + l2[3];
    float mu  = s1 * invN;
    float var = s2 * invN - mu * mu;
    if (isB) {
      float a = gp[c] * rsqrtf(var + 1e-5f);
      AP[c] = a;
      APBE[c] = bp[c] - mu * a;
    } else {
      float a = gu[c] * rsqrtf(var + 1e-5f);
      AU[c] = a;
      BUE[c] = bu[c] - mu * a;
    }
  }
}

// ---------- reduce partials -> BN scale/shift (256 col) ----------
__global__ __launch_bounds__(256) void k_reduce_fin(const float* __restrict__ part1,
                                                    const float* __restrict__ part2,
                                                    int nb, int C, float invN,
                                                    const float* __restrict__ gamma,
                                                    const float* __restrict__ beta,
                                                    float* __restrict__ a_out,
                                                    float* __restrict__ b_out) {
  int c = blockIdx.x;
  int t = threadIdx.x;
  float s1 = 0.f, s2 = 0.f;
  for (int b = t; b < nb; b += 256) {
    s1 += part1[(size_t)b * C + c];
    s2 += part2[(size_t)b * C + c];
  }
  for (int m = 32; m; m >>= 1) { s1 += __shfl_xor(s1, m); s2 += __shfl_xor(s2, m); }
  __shared__ float l1[4], l2[4];
  if ((t & 63) == 0) { l1[t >> 6] = s1; l2[t >> 6] = s2; }
  __syncthreads();
  if (t == 0) {
    s1 = l1[0] + l1[1] + l1[2] + l1[3];
    s2 = l2[0] + l2[1] + l2[2] + l2[3];
    float mu  = s1 * invN;
    float var = s2 * invN - mu * mu;
    float a = gamma[c] * rsqrtf(var + 1e-5f);
    a_out[c] = a;
    b_out[c] = beta[c] - mu * a;
  }
}

// ---------- PS = f16(ap * su) ----------
__global__ __launch_bounds__(256) void k_scaleP(const float* __restrict__ P, const float* __restrict__ ap,
                                                __half* __restrict__ PS, int n8) {
  for (int i = blockIdx.x * 256 + threadIdx.x; i < n8; i += gridDim.x * 256) {
    int c0 = (i & 7) * 8;
    float4 s0 = *(const float4*)(ap + c0), s1 = *(const float4*)(ap + c0 + 4);
    float4 a = ((const float4*)P)[i * 2];
    float4 b = ((const float4*)P)[i * 2 + 1];
    __half2 o0 = __floats2half2_rn(a.x * s0.x, a.y * s0.y);
    __half2 o1 = __floats2half2_rn(a.z * s0.z, a.w * s0.w);
    __half2 o2 = __floats2half2_rn(b.x * s1.x, b.y * s1.y);
    __half2 o3 = __floats2half2_rn(b.z * s1.z, b.w * s1.w);
    uint4 out;
    out.x = *(unsigned*)&o0; out.y = *(unsigned*)&o1;
    out.z = *(unsigned*)&o2; out.w = *(unsigned*)&o3;
    ((uint4*)PS)[i] = out;
  }
}

// ---------- fused per-node: logits + softmax + RAW aggregation + BN + CRF solve ----------
__global__ __launch_bounds__(256) void k_nodeall(const __half* __restrict__ PS,
                                                 const int* __restrict__ srcj,
                                                 const int* __restrict__ rowptr,
                                                 const u16* __restrict__ UB,
                                                 const float* __restrict__ au,
                                                 const float* __restrict__ bue,
                                                 const float* __restrict__ minv,
                                                 int N, u16* __restrict__ HB) {
  __shared__ float mS[4096];
  __shared__ float zma[4][64];
  int t = threadIdx.x;
  for (int idx = t; idx < 1024; idx += 256)
    ((float4*)mS)[idx] = ((const float4*)minv)[idx];
  __syncthreads();

  int lane = t & 63, wid = t >> 6;
  int node = blockIdx.x * 4 + wid;
  if (node >= N) return;

  int lane8 = lane & 7, g8 = lane >> 3;
  const uint4* P4 = (const uint4*)PS;
  uint4 uv = P4[(size_t)node * 8 + lane8];
  float2 u0 = __half22float2(*(const __half2*)&uv.x);
  float2 u1 = __half22float2(((const __half2*)&uv.x)[1]);
  float2 u2 = __half22float2(*(const __half2*)&uv.z);
  float2 u3 = __half22float2(((const __half2*)&uv.z)[1]);
  float psl = __half2float(PS[(size_t)node * 64 + lane]);
  int b0 = rowptr[node], b1 = rowptr[node + 1];
  int deg = b1 - b0;
  float aggv = 0.f;
  if (deg > 0) {
    int cnt = deg < 64 ? deg : 64;
    int jj = (lane < cnt) ? srcj[b0 + lane] : 0;
    float lg = -INFINITY;
    int capbase = lane & ~7;
    int capsrc  = (lane & 7) << 3;
    for (int ss = 0; ss < cnt; ss += 8) {
      int sl = ss + g8; if (sl >= cnt) sl = cnt - 1;
      int j = __shfl(jj, sl);
      uint4 vv = P4[(size_t)j * 8 + lane8];
      float2 v0 = __half22float2(*(const __half2*)&vv.x);
      float2 v1 = __half22float2(((const __half2*)&vv.x)[1]);
      float2 v2 = __half22float2(*(const __half2*)&vv.z);
      float2 v3 = __half22float2(((const __half2*)&vv.z)[1]);
      float d0 = u0.x - v0.x, d1 = u0.y - v0.y;
      float d2 = u1.x - v1.x, d3 = u1.y - v1.y;
      float d4 = u2.x - v2.x, d5 = u2.y - v2.y;
      float d6 = u3.x - v3.x, d7 = u3.y - v3.y;
      float p = d0*d0 + d1*d1 + d2*d2 + d3*d3 + d4*d4 + d5*d5 + d6*d6 + d7*d7;
      p += __shfl_xor(p, 1, 8);
      p += __shfl_xor(p, 2, 8);
      p += __shfl_xor(p, 4, 8);
      float val = __shfl(p, capsrc);
      if (ss == capbase && lane < cnt) lg = -val;
    }
    float mx = lg;
    for (int s = b0 + 64; s < b1; ++s) {
      int j = srcj[s];
      float d = psl - __half2float(PS[(size_t)j * 64 + lane]);
      float p = d * d;
      for (int m = 32; m; m >>= 1) p += __shfl_xor(p, m);
      mx = fmaxf(mx, -p);
    }
    for (int m = 32; m; m >>= 1) mx = fmaxf(mx, __shfl_xor(mx, m));
    float ex = (lane < cnt) ? __expf(lg - mx) : 0.f;
    float sm = ex;
    for (int s = b0 + 64; s < b1; ++s) {
      int j = srcj[s];
      float d = psl - __half2float(PS[(size_t)j * 64 + lane]);
      float p = d * d;
      for (int m = 32; m; m >>= 1) p += __shfl_xor(p, m);
      if (lane == 0) sm += __expf(-p - mx);
    }
    for (int m = 32; m; m >>= 1) sm += __shfl_xor(sm, m);
    float inv = 1.0f / (sm + 1e-16f);
    float w = ex * inv;
    float acc = 0.f;
    int ss = 0;
    for (; ss + 8 <= cnt; ss += 8) {
      int   j0 = __shfl(jj, ss),     j1 = __shfl(jj, ss + 1);
      int   j2 = __shfl(jj, ss + 2), j3 = __shfl(jj, ss + 3);
      int   j4 = __shfl(jj, ss + 4), j5 = __shfl(jj, ss + 5);
      int   j6 = __shfl(jj, ss + 6), j7 = __shfl(jj, ss + 7);
      float w0 = __shfl(w, ss),      w1 = __shfl(w, ss + 1);
      float w2 = __shfl(w, ss + 2),  w3 = __shfl(w, ss + 3);
      float w4 = __shfl(w, ss + 4),  w5 = __shfl(w, ss + 5);
      float w6 = __shfl(w, ss + 6),  w7 = __shfl(w, ss + 7);
      float v0 = bf2f(UB[(size_t)j0 * 64 + lane]);
      float v1 = bf2f(UB[(size_t)j1 * 64 + lane]);
      float v2 = bf2f(UB[(size_t)j2 * 64 + lane]);
      float v3 = bf2f(UB[(size_t)j3 * 64 + lane]);
      float v4 = bf2f(UB[(size_t)j4 * 64 + lane]);
      float v5 = bf2f(UB[(size_t)j5 * 64 + lane]);
      float v6 = bf2f(UB[(size_t)j6 * 64 + lane]);
      float v7 = bf2f(UB[(size_t)j7 * 64 + lane]);
      acc += w0 * v0 + w1 * v1 + w2 * v2 + w3 * v3;
      acc += w4 * v4 + w5 * v5 + w6 * v6 + w7 * v7;
    }
    for (; ss < cnt; ++ss) {
      int j0 = __shfl(jj, ss);
      float w0 = __shfl(w, ss);
      acc += w0 * bf2f(UB[(size_t)j0 * 64 + lane]);
    }
    for (int s = b0 + 64; s < b1; ++s) {
      int j = srcj[s];
      float d = psl - __half2float(PS[(size_t)j * 64 + lane]);
      float p = d * d;
      for (int m = 32; m; m >>= 1) p += __shfl_xor(p, m);
      acc += __expf(-p - mx) * inv * bf2f(UB[(size_t)j * 64 + lane]);
    }
    aggv = au[lane] * acc + bue[lane];
  }
  float z = au[lane] * bf2f(UB[(size_t)node * 64 + lane]) + bue[lane];
  zma[wid][lane] = z - aggv;
  float h = aggv;
#pragma unroll 8
  for (int k = 0; k < 64; ++k) h += zma[wid][k] * mS[k * 64 + lane];
  HB[(size_t)node * 64 + lane] = f2bf(h);
}

// ---------- final BN + leaky: bf16 raw -> f32 out ----------
__global__ __launch_bounds__(256) void k_bnact16(const u16* __restrict__ raw, const float* __restrict__ af,
                                                 const float* __restrict__ bfp, float* __restrict__ out, int n8) {
  int i = blockIdx.x * 256 + threadIdx.x;
  int stride = gridDim.x * 256;
  for (; i < n8; i += stride) {
    int c0 = (i & 31) * 8;
    float av[8], bv[8];
    *(float4*)(av) = *(const float4*)(af + c0);  *(float4*)(av + 4) = *(const float4*)(af + c0 + 4);
    *(float4*)(bv) = *(const float4*)(bfp + c0); *(float4*)(bv + 4) = *(const float4*)(bfp + c0 + 4);
    u16x8 r = ((const u16x8*)raw)[i];
    float o[8];
#pragma unroll
    for (int j = 0; j < 8; ++j) {
      float v = bf2f((u16)r[j]) * av[j] + bv[j];
      o[j] = (v > 0.f) ? v : 0.01f * v;
    }
    ((float4*)out)[i * 2]     = *(float4*)(o);
    ((float4*)out)[i * 2 + 1] = *(float4*)(o + 4);
  }
}

extern "C" void kernel_launch(void* const* d_in, const int* in_sizes, int n_in,
                              void* d_out, int out_size, void* d_ws, size_t ws_size,
                              hipStream_t stream) {
  const float* x    = (const float*)d_in[0];
  const float* y    = (const float*)d_in[1];
  const int*   eidx = (const int*)d_in[3];
  const float* Wu   = (const float*)d_in[4];
  const float* gu   = (const float*)d_in[5];
  const float* bu   = (const float*)d_in[6];
  const float* Wp   = (const float*)d_in[7];
  const float* gp   = (const float*)d_in[8];
  const float* bp   = (const float*)d_in[9];
  const float* cIn  = (const float*)d_in[10];
  const float* Wm   = (const float*)d_in[11];
  const float* gm   = (const float*)d_in[12];
  const float* bm   = (const float*)d_in[13];
  const float* Wf   = (const float*)d_in[14];
  const float* gf   = (const float*)d_in[15];
  const float* bfv  = (const float*)d_in[16];

  const int N = in_sizes[0] / 256;
  const int E = in_sizes[3] / 2;
  const int* ei = eidx;
  const int* ej = eidx + E;

  char* ws = (char*)d_ws;
  float* MINV  = (float*)(ws + OFF_MINV);
  float* AU    = (float*)(ws + OFF_AU);
  float* BUE   = (float*)(ws + OFF_BUE);
  float* AP    = (float*)(ws + OFF_AP);
  float* APBE  = (float*)(ws + OFF_APBE);
  float* AM    = (float*)(ws + OFF_AM);
  float* BM    = (float*)(ws + OFF_BM);
  float* AF    = (float*)(ws + OFF_AF);
  float* BF    = (float*)(ws + OFF_BF);
  int*   BTOT  = (int*)(ws + OFF_BTOT);
  int*   BOFF  = (int*)(ws + OFF_BOFF);
  u16*   WUT   = (u16*)(ws + OFF_WUT);
  u16*   WMT   = (u16*)(ws + OFF_WMT);
  u16*   WFT   = (u16*)(ws + OFF_WFT);
  u16*   WPH   = (u16*)(ws + OFF_WPH);
  float* PART1A= (float*)(ws + OFF_PART1A);
  float* PART1B= (float*)(ws + OFF_PART1B);
  float* PART2A= (float*)(ws + OFF_PART2A);
  float* PART2B= (float*)(ws + OFF_PART2B);
  int*   ROWPTR= (int*)(ws + OFF_ROWPTR);
  int*   BLKCNT= (int*)(ws + OFF_BLKCNT);
  u16*   HB    = (u16*)(ws + OFF_BLKCNT);    // reuse (BLKCNT dead after kA3)
  int*   SRCJ  = (int*)(ws + OFF_SRCJ);
  u16*   RAWO  = (u16*)(ws + OFF_SRCJ);      // reuse (SRCJ dead after k_nodeall)
  u16*   UBRAW = (u16*)(ws + OFF_U);
  unsigned* TMP= (unsigned*)(ws + OFF_P);    // packed bins; dead after kB
  float* P     = (float*)(ws + OFF_P);
  __half* PS   = (__half*)(ws + OFF_PS);
  u16*   H2    = (u16*)(ws + OFF_H2);

  const float invN = 1.0f / (float)N;
  const int mtiles   = (N + 127) / 128;
  const int n8_64    = N * 64 / 8;
  const int n8_256   = N * 256 / 8;
  const int nbk      = (N + 255) >> 8;
  const int chunk    = (E + NBLK_BIN - 1) / NBLK_BIN;

  k_prep<<<1, 256, 0, stream>>>(cIn, MINV);
  k_tcvt_all<<<704, 256, 0, stream>>>(Wu, Wm, Wf, Wp, WUT, WMT, WFT, WPH);

  // CSR build: deterministic two-level binned counting sort (no global atomics)
  kA1<<<NBLK_BIN, 256, 0, stream>>>(ei, E, chunk, BLKCNT, nbk);
  kA2<<<nbk, 256, 0, stream>>>(BLKCNT, nbk, BTOT);
  kA2b<<<1, 512, 0, stream>>>(BTOT, BOFF, nbk);
  kA3<<<NBLK_BIN, 256, 0, stream>>>(ei, ej, E, chunk, BLKCNT, BOFF, nbk, TMP);
  kB<<<nbk, 256, 0, stream>>>(TMP, BOFF, nbk, N, E, ROWPTR, SRCJ);

  // unary embedding (bf16 MFMA, stats fused) -> UBRAW
  k_mfma<64, 2, 1, 1, 0><<<dim3(mtiles, 1), 256, 0, stream>>>(
      nullptr, x, 256, 256, N, WUT, nullptr, UBRAW, 64, 64, PART1A, PART2A);

  // pairwise embedding (f16 MFMA, stats fused) -> P f32 (TMP dead)
  k_mfma<64, 2, 0, 1, 1><<<dim3(mtiles, 1), 256, 0, stream>>>(
      nullptr, y, 256, 256, N, WPH, P, nullptr, 64, 64, PART1B, PART2B);

  // merged BN reduce for xu + su
  k_reduce2<<<128, 256, 0, stream>>>(PART1A, PART2A, PART1B, PART2B, mtiles, invN,
                                     gu, bu, gp, bp, AU, BUE, AP, APBE);
  k_scaleP<<<1024, 256, 0, stream>>>(P, AP, PS, n8_64);

  // fused logits + softmax + aggregation + BN + CRF solve -> HB
  k_nodeall<<<(N + 3) / 4, 256, 0, stream>>>(PS, SRCJ, ROWPTR, UBRAW, AU, BUE, MINV, N, HB);

  // h @ Wm -> h2 bf16 (single-buffer LDS, 3 blocks/CU)
  k_mfma2<0><<<mtiles, 512, 0, stream>>>(
      HB, 64, 64, N, nullptr, nullptr, nullptr, nullptr, WMT, H2, PART1A, PART2A);
  k_reduce_fin<<<256, 256, 0, stream>>>(PART1A, PART2A, mtiles, 256, invN, gm, bm, AM, BM);

  // [leaky(bn(h2)), y] @ Wf -> raw bf16, BN + leaky -> d_out
  k_mfma2<1><<<mtiles, 512, 0, stream>>>(
      nullptr, 0, 512, N, H2, y, AM, BM, WFT, RAWO, PART1A, PART2A);
  k_reduce_fin<<<256, 256, 0, stream>>>(PART1A, PART2A, mtiles, 256, invN, gf, bfv, AF, BF);
  k_bnact16<<<2048, 256, 0, stream>>>(RAWO, AF, BF, (float*)d_out, n8_256);
}